// Round 2
// baseline (359.309 us; speedup 1.0000x reference)
//
#include <hip/hip_runtime.h>

// ---------------- types / helpers ----------------
typedef __attribute__((ext_vector_type(8))) short short8;   // 8 x bf16 (16B)
typedef __attribute__((ext_vector_type(4))) short short4v;  // 4 x bf16 (8B)
typedef __attribute__((ext_vector_type(4))) float f32x4;

#define B_ 2
#define N_ 4096
#define D_ 1024
#define G_ 2
#define H_ 16
#define DH_ 64
#define NSLOT 1088              // 1024 tokens + 1 null + pad to 17*64
#define LOGK 7.0492548412558374f  // log(1152)
#define LDP 72                  // padded LDS row (shorts): 144B = 9*16B

__device__ __forceinline__ float bf2f(short s) {
  return __uint_as_float(((unsigned)(unsigned short)s) << 16);
}
__device__ __forceinline__ short f2bf(float f) {   // RNE
  unsigned u = __float_as_uint(f);
  u = (u + 0x7FFFu + ((u >> 16) & 1u)) >> 16;
  return (short)u;
}

// ---------------- 1) sim = einsum('bnd,gd->bgn') for both routings ----------------
__global__ __launch_bounds__(256) void sim_kernel(
    const float* __restrict__ x, const float* __restrict__ rtq,
    const float* __restrict__ rtkv, float* __restrict__ sim)
{
  int wid = threadIdx.x >> 6, lane = threadIdx.x & 63;
  int row = blockIdx.x * 4 + wid;              // b*N + n
  int b = row >> 12, n = row & (N_ - 1);
  const float* xr = x + (size_t)row * D_;
  float a0 = 0.f, a1 = 0.f, a2 = 0.f, a3 = 0.f;
#pragma unroll
  for (int c = 0; c < 4; ++c) {
    int d = c * 256 + lane * 4;
    f32x4 xv = *(const f32x4*)(xr + d);
    f32x4 r0 = *(const f32x4*)(rtq + d);
    f32x4 r1 = *(const f32x4*)(rtq + D_ + d);
    f32x4 r2 = *(const f32x4*)(rtkv + d);
    f32x4 r3 = *(const f32x4*)(rtkv + D_ + d);
#pragma unroll
    for (int e = 0; e < 4; ++e) {
      a0 += xv[e] * r0[e];
      a1 += xv[e] * r1[e];
      a2 += xv[e] * r2[e];
      a3 += xv[e] * r3[e];
    }
  }
#pragma unroll
  for (int o = 32; o; o >>= 1) {
    a0 += __shfl_xor(a0, o); a1 += __shfl_xor(a1, o);
    a2 += __shfl_xor(a2, o); a3 += __shfl_xor(a3, o);
  }
  if (lane == 0) {
    sim[((size_t)(b)*G_ + 0) * N_ + n] = a0;
    sim[((size_t)(b)*G_ + 1) * N_ + n] = a1;
    sim[((size_t)(B_ + b)*G_ + 0) * N_ + n] = a2;
    sim[((size_t)(B_ + b)*G_ + 1) * N_ + n] = a3;
  }
}

// ---------------- 2) coor_descent + top-k (exact tie semantics) ----------------
__global__ __launch_bounds__(1024) void coor_topk(
    const float* __restrict__ sim, int* __restrict__ idxout, int* __restrict__ inv)
{
  __shared__ float rbuf[16];
  __shared__ float res;
  __shared__ unsigned keys[N_];
  __shared__ int scanbuf[16];

  int r = blockIdx.x >> 2, b = (blockIdx.x >> 1) & 1, g = blockIdx.x & 1;
  const float* srow = sim + ((size_t)blockIdx.x << 12);
  int tid = threadIdx.x, lane = tid & 63, wid = tid >> 6;

  float sv[4];
#pragma unroll
  for (int j = 0; j < 4; ++j) sv[j] = srow[tid * 4 + j];

  float a = 0.f;
  double epsd = 4.0;
  for (int it = 0; it < 20; ++it) {
    float eps = (float)fmax(epsd, 0.03);
    epsd *= 0.7;
    float sb[4]; float lmax = -INFINITY;
#pragma unroll
    for (int j = 0; j < 4; ++j) {
      float bb = (it == 0) ? (-sv[j]) : (-fmaxf(sv[j] + a, 0.f));
      sb[j] = (sv[j] + bb) / eps;
      lmax = fmaxf(lmax, sb[j]);
    }
#pragma unroll
    for (int o = 32; o; o >>= 1) lmax = fmaxf(lmax, __shfl_xor(lmax, o));
    if (lane == 0) rbuf[wid] = lmax;
    __syncthreads();
    if (tid == 0) {
      float m = rbuf[0];
      for (int i = 1; i < 16; ++i) m = fmaxf(m, rbuf[i]);
      res = m;
    }
    __syncthreads();
    float mx = res;
    __syncthreads();
    float lsum = 0.f;
#pragma unroll
    for (int j = 0; j < 4; ++j) lsum += expf(sb[j] - mx);
#pragma unroll
    for (int o = 32; o; o >>= 1) lsum += __shfl_xor(lsum, o);
    if (lane == 0) rbuf[wid] = lsum;
    __syncthreads();
    if (tid == 0) {
      float s = 0.f;
      for (int i = 0; i < 16; ++i) s += rbuf[i];
      res = logf(s) + mx;
    }
    __syncthreads();
    float lse = res;
    __syncthreads();
    a = eps * (LOGK - lse);
  }

  // final scores: exp(min(s+a,0)/0.03); saturated entries are EXACTLY 1.0f
  unsigned kb[4]; int c1 = 0;
#pragma unroll
  for (int j = 0; j < 4; ++j) {
    float sc = expf(fminf(sv[j] + a, 0.f) / 0.03f);
    kb[j] = __float_as_uint(sc);
    keys[tid * 4 + j] = kb[j];
    c1 += (kb[j] == 0x3F800000u);
  }
#pragma unroll
  for (int o = 32; o; o >>= 1) c1 += __shfl_xor(c1, o);
  if (lane == 0) scanbuf[wid] = c1;
  __syncthreads();
  int c1tot = 0;
  for (int i = 0; i < 16; ++i) c1tot += scanbuf[i];
  __syncthreads();

  int flag[4];
  if (c1tot >= 1024) {
#pragma unroll
    for (int j = 0; j < 4; ++j) flag[j] = (kb[j] == 0x3F800000u);
  } else {
#pragma unroll
    for (int j = 0; j < 4; ++j) {
      unsigned kn = kb[j]; int n = tid * 4 + j; int rank = 0;
      for (int m = 0; m < N_; ++m) {
        unsigned km = keys[m];
        rank += (km > kn) || (km == kn && m < n);
      }
      flag[j] = (rank < 1024);
    }
  }

  int cnt = flag[0] + flag[1] + flag[2] + flag[3];
  int inc = cnt;
#pragma unroll
  for (int o = 1; o < 64; o <<= 1) {
    int tt = __shfl_up(inc, o);
    if (lane >= o) inc += tt;
  }
  if (lane == 63) scanbuf[wid] = inc;
  __syncthreads();
  int off = 0;
  for (int w = 0; w < wid; ++w) off += scanbuf[w];
  int pos = off + inc - cnt;
  int* op = idxout + ((size_t)blockIdx.x << 10);
  int* ip = inv + ((size_t)(b * G_ + g) << 12);
#pragma unroll
  for (int j = 0; j < 4; ++j) {
    if (flag[j]) {
      if (pos < 1024) {
        int n = tid * 4 + j;
        op[pos] = n;
        if (r == 0) ip[n] = pos;
      }
      pos++;
    }
  }
}

// ---------------- 3) gather + RMSNorm -> bf16 rows ----------------
__global__ __launch_bounds__(256) void gather_rms(
    const float* __restrict__ x, const int* __restrict__ idx,
    const float* __restrict__ gamma_q, const float* __restrict__ gamma_c,
    short* __restrict__ qn, short* __restrict__ cn)
{
  __shared__ float rb[4];
  __shared__ float tot;
  int id = blockIdx.x;                  // ((r*B+b)*G+g)*1024 + slot
  int r = id >> 12, rem = id & 4095;
  int g = (rem >> 10) & 1;
  int b = rem >> 11;
  int tok = idx[id];
  int t = threadIdx.x;
  const float* xr = x + ((size_t)b * N_ + tok) * D_;
  f32x4 v = *(const f32x4*)(xr + t * 4);
  float ss = v[0]*v[0] + v[1]*v[1] + v[2]*v[2] + v[3]*v[3];
#pragma unroll
  for (int o = 32; o; o >>= 1) ss += __shfl_xor(ss, o);
  if ((t & 63) == 0) rb[t >> 6] = ss;
  __syncthreads();
  if (t == 0) tot = rb[0] + rb[1] + rb[2] + rb[3];
  __syncthreads();
  float scale = 32.0f / fmaxf(sqrtf(tot), 1e-12f);
  const float* gm = (r ? gamma_c : gamma_q) + g * D_;
  f32x4 gv = *(const f32x4*)(gm + t * 4);
  short* dst = (r ? cn : qn) + ((size_t)rem << 10) + t * 4;
  short4v ov;
#pragma unroll
  for (int e = 0; e < 4; ++e) ov[e] = f2bf(v[e] * scale * gv[e]);
  *(short4v*)dst = ov;
}

// ---------------- 4) NT GEMM: C[m,n] = sum_k A[m,k]*W[n,k] ----------------
// A bf16 [BG][1024][1024], W f32 [G][NB][1024]. 128x128 tile, BK=64, 4 waves.
// MODE 0: C -> bf16 row-major [bg][1024][NB(=1024)]
// MODE 1: NB=2048; n<1024 -> k[bgh][slot][dh]; n>=1024 -> vT[bgh][dh][slot]
// MODE 2: C -> f32 row-major [bg][1024][NB(=1024)]
template<int MODE>
__global__ __launch_bounds__(256) void gemm_nt(
    const short* __restrict__ A, const float* __restrict__ Bw,
    short* __restrict__ out, float* __restrict__ outf,
    short* __restrict__ kout, short* __restrict__ vout, int NB)
{
  __shared__ short As[128 * LDP];
  __shared__ short Bs[128 * LDP];
  int t = threadIdx.x, lane = t & 63, wid = t >> 6;
  int grp = lane >> 4, l15 = lane & 15;
  int wm = wid >> 1, wn = wid & 1;
  int mbase = blockIdx.x * 128, nbase = blockIdx.y * 128;
  int bg = blockIdx.z, g = bg & 1;
  const short* Ab = A + ((size_t)bg << 20);
  const float* Bp = Bw + ((size_t)g * NB + nbase) * 1024;

  f32x4 zero = {0.f, 0.f, 0.f, 0.f};
  f32x4 acc[4][4];
#pragma unroll
  for (int i = 0; i < 4; ++i)
#pragma unroll
    for (int j = 0; j < 4; ++j) acc[i][j] = zero;

  int srow = t >> 1, shalf = t & 1;
  const short* ap = Ab + ((size_t)(mbase + srow) << 10) + shalf * 32;
  const float* bp = Bp + ((size_t)srow << 10) + shalf * 32;
  short* aw = As + srow * LDP + shalf * 32;
  short* bw = Bs + srow * LDP + shalf * 32;

  for (int kb = 0; kb < 16; ++kb) {
    short8 av[4];
#pragma unroll
    for (int i = 0; i < 4; ++i) av[i] = *(const short8*)(ap + i * 8);
    f32x4 bv[8];
#pragma unroll
    for (int i = 0; i < 8; ++i) bv[i] = *(const f32x4*)(bp + i * 4);
    ap += 64; bp += 64;
    __syncthreads();
#pragma unroll
    for (int i = 0; i < 4; ++i) *(short8*)(aw + i * 8) = av[i];
#pragma unroll
    for (int c = 0; c < 4; ++c) {
      short8 pk;
#pragma unroll
      for (int e = 0; e < 4; ++e) { pk[e] = f2bf(bv[2*c][e]); pk[4+e] = f2bf(bv[2*c+1][e]); }
      *(short8*)(bw + c * 8) = pk;
    }
    __syncthreads();
#pragma unroll
    for (int kf = 0; kf < 2; ++kf) {
      short8 af[4], bf_[4];
#pragma unroll
      for (int mt = 0; mt < 4; ++mt)
        af[mt] = *(const short8*)(As + (wm*64 + mt*16 + l15) * LDP + grp*8 + kf*32);
#pragma unroll
      for (int nt = 0; nt < 4; ++nt)
        bf_[nt] = *(const short8*)(Bs + (wn*64 + nt*16 + l15) * LDP + grp*8 + kf*32);
#pragma unroll
      for (int mt = 0; mt < 4; ++mt)
#pragma unroll
        for (int nt = 0; nt < 4; ++nt)
          acc[mt][nt] = __builtin_amdgcn_mfma_f32_16x16x32_bf16(af[mt], bf_[nt], acc[mt][nt], 0, 0, 0);
    }
  }

  // direct epilogue from C-layout: row=(lane>>4)*4+rr, col=lane&15
#pragma unroll
  for (int mt = 0; mt < 4; ++mt)
#pragma unroll
    for (int nt = 0; nt < 4; ++nt) {
      int n = nbase + wn*64 + nt*16 + l15;
#pragma unroll
      for (int rr = 0; rr < 4; ++rr) {
        int m = mbase + wm*64 + mt*16 + grp*4 + rr;
        float v = acc[mt][nt][rr];
        if (MODE == 0) {
          out[((size_t)bg * 1024 + m) * 1024 + n] = f2bf(v);
        } else if (MODE == 2) {
          outf[((size_t)bg * 1024 + m) * 1024 + n] = v;
        } else {
          if (n < 1024) {
            kout[(((size_t)bg * H_ + (n >> 6)) * NSLOT + m) * DH_ + (n & 63)] = f2bf(v);
          } else {
            int e = n - 1024;
            vout[(((size_t)bg * H_ + (e >> 6)) * DH_ + (e & 63)) * NSLOT + m] = f2bf(v);
          }
        }
      }
    }
}

// ---------------- 5) null kv fill (slot 1024) ----------------
__global__ void null_fill(const float* __restrict__ null_kv,
                          short* __restrict__ kb_, short* __restrict__ vb_)
{
  int bgh = blockIdx.x;                 // (b*G+g)*H + h
  int g = (bgh >> 4) & 1, h = bgh & 15;
  int t = threadIdx.x;                  // 0..63
  float kvk = null_kv[((size_t)(0 * G_ + g) * H_ + h) * DH_ + t];
  float kvv = null_kv[((size_t)(1 * G_ + g) * H_ + h) * DH_ + t];
  kb_[((size_t)bgh * NSLOT + 1024) * DH_ + t] = f2bf(kvk);
  vb_[((size_t)bgh * DH_ + t) * NSLOT + 1024] = f2bf(kvv);
}

// ---------------- 6) flash attention per (b,g,h), 64 queries per block ----------------
// S = mfma(A=K, B=Q); PV = mfma(A=P, B=vT). P via padded per-wave LDS rows.
__global__ __launch_bounds__(256) void attn_kernel(
    const short* __restrict__ q, const short* __restrict__ k,
    const short* __restrict__ vT, short* __restrict__ o)
{
  __shared__ short plds_all[4 * 16 * LDP];
  int qb = blockIdx.x, bgh = blockIdx.y;
  int bg = bgh >> 4, h = bgh & 15;
  int wid = threadIdx.x >> 6, lane = threadIdx.x & 63;
  int l15 = lane & 15, grp = lane >> 4;
  short* pwave = plds_all + wid * 16 * LDP;   // per-wave [16 q][LDP]
  short* prow = pwave + l15 * LDP;
  int qbase = qb * 64 + wid * 16;

  const short* qp = q + ((size_t)bg * 1024 + qbase + l15) * 1024 + h * 64 + (grp << 3);
  short8 bq0 = *(const short8*)qp;
  short8 bq1 = *(const short8*)(qp + 32);
  const short* kp = k + (size_t)bgh * NSLOT * DH_;
  const short* vp = vT + (size_t)bgh * DH_ * NSLOT;

  f32x4 zero = {0.f, 0.f, 0.f, 0.f};
  f32x4 oacc[4];
#pragma unroll
  for (int dt = 0; dt < 4; ++dt) oacc[dt] = zero;
  float m_run = -INFINITY, l_run = 0.f;

  for (int tile = 0; tile < 17; ++tile) {
    int sbase = tile * 64;
    f32x4 sacc[4];
#pragma unroll
    for (int kt = 0; kt < 4; ++kt) sacc[kt] = zero;
#pragma unroll
    for (int kf = 0; kf < 2; ++kf) {
      short8 bqf = kf ? bq1 : bq0;
#pragma unroll
      for (int kt = 0; kt < 4; ++kt) {
        short8 ka = *(const short8*)(kp + ((size_t)(sbase + kt * 16 + l15)) * DH_ + (grp << 3) + kf * 32);
        sacc[kt] = __builtin_amdgcn_mfma_f32_16x16x32_bf16(ka, bqf, sacc[kt], 0, 0, 0);
      }
    }
#pragma unroll
    for (int kt = 0; kt < 4; ++kt)
#pragma unroll
      for (int rr = 0; rr < 4; ++rr) sacc[kt][rr] *= 0.125f;
    if (tile == 16) {
#pragma unroll
      for (int kt = 0; kt < 4; ++kt)
#pragma unroll
        for (int rr = 0; rr < 4; ++rr)
          if ((kt * 16 + (grp << 2) + rr) != 0) sacc[kt][rr] = -INFINITY;
    }
    float pm = -INFINITY;
#pragma unroll
    for (int kt = 0; kt < 4; ++kt)
#pragma unroll
      for (int rr = 0; rr < 4; ++rr) pm = fmaxf(pm, sacc[kt][rr]);
    pm = fmaxf(pm, __shfl_xor(pm, 16));
    pm = fmaxf(pm, __shfl_xor(pm, 32));
    float m_new = fmaxf(m_run, pm);
    float psum = 0.f;
#pragma unroll
    for (int kt = 0; kt < 4; ++kt)
#pragma unroll
      for (int rr = 0; rr < 4; ++rr) {
        float p = expf(sacc[kt][rr] - m_new);
        sacc[kt][rr] = p;
        psum += p;
      }
    psum += __shfl_xor(psum, 16);
    psum += __shfl_xor(psum, 32);
    float alpha = expf(m_run - m_new);
    l_run = l_run * alpha + psum;
    m_run = m_new;
    // P -> LDS: P[q=l15][koff]
#pragma unroll
    for (int kt = 0; kt < 4; ++kt)
#pragma unroll
      for (int rr = 0; rr < 4; ++rr) {
        int koff = kt * 16 + (grp << 2) + rr;
        prow[koff] = f2bf(sacc[kt][rr]);
      }
    // rescale O: row q = (grp<<2)+rr
    f32x4 avec;
#pragma unroll
    for (int rr = 0; rr < 4; ++rr) avec[rr] = __shfl(alpha, (grp << 2) + rr);
#pragma unroll
    for (int dt = 0; dt < 4; ++dt) oacc[dt] *= avec;
    // PV: pa = P[q=l15][grp*8 + j + ks*32], vb = vT[dh=dt*16+l15][slot]
#pragma unroll
    for (int ks = 0; ks < 2; ++ks) {
      short8 pa = *(const short8*)(prow + (grp << 3) + ks * 32);
#pragma unroll
      for (int dt = 0; dt < 4; ++dt) {
        short8 vb = *(const short8*)(vp + ((size_t)(dt * 16 + l15)) * NSLOT + sbase + ks * 32 + (grp << 3));
        oacc[dt] = __builtin_amdgcn_mfma_f32_16x16x32_bf16(pa, vb, oacc[dt], 0, 0, 0);
      }
    }
  }
  f32x4 lvec;
#pragma unroll
  for (int rr = 0; rr < 4; ++rr) lvec[rr] = __shfl(l_run, (grp << 2) + rr);
  // direct store: oacc[dt][rr] = O[q=(grp<<2)+rr][dh=dt*16+l15]
#pragma unroll
  for (int dt = 0; dt < 4; ++dt)
#pragma unroll
    for (int rr = 0; rr < 4; ++rr) {
      int qq = (grp << 2) + rr;
      int dh = dt * 16 + l15;
      o[((size_t)bg * 1024 + qbase + qq) * 1024 + h * 64 + dh] = f2bf(oacc[dt][rr] / lvec[rr]);
    }
}

// ---------------- 7) finalize: scatter-average + null_token ----------------
__global__ __launch_bounds__(256) void finalize_kernel(
    const float* __restrict__ wo_out, const int* __restrict__ inv,
    const float* __restrict__ null_token, float* __restrict__ outp)
{
  int id = blockIdx.x;                  // b*N + n
  int b = id >> 12, n = id & (N_ - 1);
  int s0 = inv[((size_t)(b * G_ + 0) << 12) + n];
  int s1 = inv[((size_t)(b * G_ + 1) << 12) + n];
  int t = threadIdx.x;
  float* dst = outp + (size_t)id * D_ + t * 4;
  if (s0 < 0 && s1 < 0) {
    *(f32x4*)dst = *(const f32x4*)(null_token + t * 4);
  } else {
    f32x4 sum = {0.f, 0.f, 0.f, 0.f};
    float cnt = 0.f;
    if (s0 >= 0) {
      f32x4 v = *(const f32x4*)(wo_out + (((size_t)(b * G_ + 0) * 1024 + s0) << 10) + t * 4);
#pragma unroll
      for (int e = 0; e < 4; ++e) sum[e] += v[e];
      cnt += 1.f;
    }
    if (s1 >= 0) {
      f32x4 v = *(const f32x4*)(wo_out + (((size_t)(b * G_ + 1) * 1024 + s1) << 10) + t * 4);
#pragma unroll
      for (int e = 0; e < 4; ++e) sum[e] += v[e];
      cnt += 1.f;
    }
    f32x4 rv;
#pragma unroll
    for (int e = 0; e < 4; ++e) rv[e] = sum[e] / cnt;
    *(f32x4*)dst = rv;
  }
}

// ---------------- launch ----------------
extern "C" void kernel_launch(void* const* d_in, const int* in_sizes, int n_in,
                              void* d_out, int out_size, void* d_ws, size_t ws_size,
                              hipStream_t stream) {
  (void)in_sizes; (void)n_in; (void)out_size; (void)ws_size;
  const float* x        = (const float*)d_in[0];
  const float* rt_q     = (const float*)d_in[1];
  const float* rt_kv    = (const float*)d_in[2];
  const float* gamma_q  = (const float*)d_in[3];
  const float* gamma_c  = (const float*)d_in[4];
  const float* wq       = (const float*)d_in[5];
  const float* wkv      = (const float*)d_in[6];
  const float* wo       = (const float*)d_in[7];
  const float* null_kv  = (const float*)d_in[8];
  const float* null_tok = (const float*)d_in[9];
  float* outp = (float*)d_out;

  char* ws = (char*)d_ws;
  size_t off = 0;
  auto alloc = [&](size_t bytes) { char* p = ws + off; off += (bytes + 255) & ~(size_t)255; return p; };
  float* sim   = (float*)alloc((size_t)2 * B_ * G_ * N_ * 4);
  int*   idx   = (int*)  alloc((size_t)2 * B_ * G_ * 1024 * 4);
  int*   inv   = (int*)  alloc((size_t)B_ * G_ * N_ * 4);
  short* qn    = (short*)alloc((size_t)B_ * G_ * 1024 * 1024 * 2);
  short* cn    = (short*)alloc((size_t)B_ * G_ * 1024 * 1024 * 2);
  short* qproj = (short*)alloc((size_t)B_ * G_ * 1024 * 1024 * 2);
  size_t kvbytes = (size_t)B_ * G_ * H_ * NSLOT * DH_ * 2;
  short* kbuf  = (short*)alloc(kvbytes);
  short* vbuf  = (short*)alloc(kvbytes);
  short* obuf  = (short*)alloc((size_t)B_ * G_ * 1024 * 1024 * 2);
  float* wobuf = (float*)alloc((size_t)B_ * G_ * 1024 * 1024 * 4);

  hipMemsetAsync(kbuf, 0, kvbytes, stream);
  hipMemsetAsync(vbuf, 0, kvbytes, stream);
  hipMemsetAsync(inv, 0xFF, (size_t)B_ * G_ * N_ * 4, stream);

  sim_kernel<<<B_ * N_ / 4, 256, 0, stream>>>(x, rt_q, rt_kv, sim);
  coor_topk<<<8, 1024, 0, stream>>>(sim, idx, inv);
  gather_rms<<<2 * B_ * G_ * 1024, 256, 0, stream>>>(x, idx, gamma_q, gamma_c, qn, cn);
  gemm_nt<0><<<dim3(8, 8, B_ * G_), 256, 0, stream>>>(qn, wq, qproj, nullptr, nullptr, nullptr, 1024);
  gemm_nt<1><<<dim3(8, 16, B_ * G_), 256, 0, stream>>>(cn, wkv, nullptr, nullptr, kbuf, vbuf, 2048);
  null_fill<<<B_ * G_ * H_, 64, 0, stream>>>(null_kv, kbuf, vbuf);
  attn_kernel<<<dim3(16, B_ * G_ * H_), 256, 0, stream>>>(qproj, kbuf, vbuf, obuf);
  gemm_nt<2><<<dim3(8, 8, B_ * G_), 256, 0, stream>>>(obuf, wo, nullptr, wobuf, nullptr, nullptr, 1024);
  finalize_kernel<<<B_ * N_, 256, 0, stream>>>(wobuf, inv, null_tok, outp);
}

// Round 3
// 303.760 us; speedup vs baseline: 1.1829x; 1.1829x over previous
//
#include <hip/hip_runtime.h>

// ---------------- types / helpers ----------------
typedef __attribute__((ext_vector_type(8))) short short8;   // 8 x bf16 (16B)
typedef __attribute__((ext_vector_type(4))) short short4v;  // 4 x bf16 (8B)
typedef __attribute__((ext_vector_type(4))) float f32x4;

#define B_ 2
#define N_ 4096
#define D_ 1024
#define G_ 2
#define H_ 16
#define DH_ 64
#define NSLOT 1088              // 1024 tokens + 1 null + pad to 17*64
#define LOGK 7.0492548412558374f  // log(1152)
#define LDP 72                  // padded LDS row (shorts): 144B = 9*16B
#define ATTN_SCALE 0.18033688011112043f  // dh^-0.5 * log2(e): S in log2 domain

__device__ __forceinline__ float bf2f(short s) {
  return __uint_as_float(((unsigned)(unsigned short)s) << 16);
}
__device__ __forceinline__ short f2bf(float f) {   // RNE
  unsigned u = __float_as_uint(f);
  u = (u + 0x7FFFu + ((u >> 16) & 1u)) >> 16;
  return (short)u;
}

// ---------------- 0) W f32 -> bf16 pre-convert ----------------
__global__ __launch_bounds__(256) void wconv(
    const float* __restrict__ src, short* __restrict__ dst, int n4)
{
  int i = blockIdx.x * 256 + threadIdx.x;
  if (i >= n4) return;
  f32x4 v = ((const f32x4*)src)[i];
  short4v o;
#pragma unroll
  for (int e = 0; e < 4; ++e) o[e] = f2bf(v[e]);
  ((short4v*)dst)[i] = o;
}

// ---------------- 1) sim = einsum('bnd,gd->bgn') for both routings ----------------
__global__ __launch_bounds__(256) void sim_kernel(
    const float* __restrict__ x, const float* __restrict__ rtq,
    const float* __restrict__ rtkv, float* __restrict__ sim)
{
  int wid = threadIdx.x >> 6, lane = threadIdx.x & 63;
  int row = blockIdx.x * 4 + wid;              // b*N + n
  int b = row >> 12, n = row & (N_ - 1);
  const float* xr = x + (size_t)row * D_;
  float a0 = 0.f, a1 = 0.f, a2 = 0.f, a3 = 0.f;
#pragma unroll
  for (int c = 0; c < 4; ++c) {
    int d = c * 256 + lane * 4;
    f32x4 xv = *(const f32x4*)(xr + d);
    f32x4 r0 = *(const f32x4*)(rtq + d);
    f32x4 r1 = *(const f32x4*)(rtq + D_ + d);
    f32x4 r2 = *(const f32x4*)(rtkv + d);
    f32x4 r3 = *(const f32x4*)(rtkv + D_ + d);
#pragma unroll
    for (int e = 0; e < 4; ++e) {
      a0 += xv[e] * r0[e];
      a1 += xv[e] * r1[e];
      a2 += xv[e] * r2[e];
      a3 += xv[e] * r3[e];
    }
  }
#pragma unroll
  for (int o = 32; o; o >>= 1) {
    a0 += __shfl_xor(a0, o); a1 += __shfl_xor(a1, o);
    a2 += __shfl_xor(a2, o); a3 += __shfl_xor(a3, o);
  }
  if (lane == 0) {
    sim[((size_t)(b)*G_ + 0) * N_ + n] = a0;
    sim[((size_t)(b)*G_ + 1) * N_ + n] = a1;
    sim[((size_t)(B_ + b)*G_ + 0) * N_ + n] = a2;
    sim[((size_t)(B_ + b)*G_ + 1) * N_ + n] = a3;
  }
}

// ---------------- 2) coor_descent + top-k (exact tie semantics) ----------------
__global__ __launch_bounds__(1024) void coor_topk(
    const float* __restrict__ sim, int* __restrict__ idxout, int* __restrict__ inv)
{
  __shared__ float rbuf[16];
  __shared__ float res;
  __shared__ unsigned keys[N_];
  __shared__ int scanbuf[16];

  int r = blockIdx.x >> 2, b = (blockIdx.x >> 1) & 1, g = blockIdx.x & 1;
  const float* srow = sim + ((size_t)blockIdx.x << 12);
  int tid = threadIdx.x, lane = tid & 63, wid = tid >> 6;

  float sv[4];
#pragma unroll
  for (int j = 0; j < 4; ++j) sv[j] = srow[tid * 4 + j];

  float a = 0.f;
  double epsd = 4.0;
  for (int it = 0; it < 20; ++it) {
    float eps = (float)fmax(epsd, 0.03);
    epsd *= 0.7;
    float sb[4]; float lmax = -INFINITY;
#pragma unroll
    for (int j = 0; j < 4; ++j) {
      float bb = (it == 0) ? (-sv[j]) : (-fmaxf(sv[j] + a, 0.f));
      sb[j] = (sv[j] + bb) / eps;
      lmax = fmaxf(lmax, sb[j]);
    }
#pragma unroll
    for (int o = 32; o; o >>= 1) lmax = fmaxf(lmax, __shfl_xor(lmax, o));
    if (lane == 0) rbuf[wid] = lmax;
    __syncthreads();
    if (tid == 0) {
      float m = rbuf[0];
      for (int i = 1; i < 16; ++i) m = fmaxf(m, rbuf[i]);
      res = m;
    }
    __syncthreads();
    float mx = res;
    __syncthreads();
    float lsum = 0.f;
#pragma unroll
    for (int j = 0; j < 4; ++j) lsum += expf(sb[j] - mx);
#pragma unroll
    for (int o = 32; o; o >>= 1) lsum += __shfl_xor(lsum, o);
    if (lane == 0) rbuf[wid] = lsum;
    __syncthreads();
    if (tid == 0) {
      float s = 0.f;
      for (int i = 0; i < 16; ++i) s += rbuf[i];
      res = logf(s) + mx;
    }
    __syncthreads();
    float lse = res;
    __syncthreads();
    a = eps * (LOGK - lse);
  }

  // final scores: exp(min(s+a,0)/0.03); saturated entries are EXACTLY 1.0f
  unsigned kb[4]; int c1 = 0;
#pragma unroll
  for (int j = 0; j < 4; ++j) {
    float sc = expf(fminf(sv[j] + a, 0.f) / 0.03f);
    kb[j] = __float_as_uint(sc);
    keys[tid * 4 + j] = kb[j];
    c1 += (kb[j] == 0x3F800000u);
  }
#pragma unroll
  for (int o = 32; o; o >>= 1) c1 += __shfl_xor(c1, o);
  if (lane == 0) scanbuf[wid] = c1;
  __syncthreads();
  int c1tot = 0;
  for (int i = 0; i < 16; ++i) c1tot += scanbuf[i];
  __syncthreads();

  int flag[4];
  if (c1tot >= 1024) {
#pragma unroll
    for (int j = 0; j < 4; ++j) flag[j] = (kb[j] == 0x3F800000u);
  } else {
#pragma unroll
    for (int j = 0; j < 4; ++j) {
      unsigned kn = kb[j]; int n = tid * 4 + j; int rank = 0;
      for (int m = 0; m < N_; ++m) {
        unsigned km = keys[m];
        rank += (km > kn) || (km == kn && m < n);
      }
      flag[j] = (rank < 1024);
    }
  }

  int cnt = flag[0] + flag[1] + flag[2] + flag[3];
  int inc = cnt;
#pragma unroll
  for (int o = 1; o < 64; o <<= 1) {
    int tt = __shfl_up(inc, o);
    if (lane >= o) inc += tt;
  }
  if (lane == 63) scanbuf[wid] = inc;
  __syncthreads();
  int off = 0;
  for (int w = 0; w < wid; ++w) off += scanbuf[w];
  int pos = off + inc - cnt;
  int* op = idxout + ((size_t)blockIdx.x << 10);
  int* ip = inv + ((size_t)(b * G_ + g) << 12);
#pragma unroll
  for (int j = 0; j < 4; ++j) {
    if (flag[j]) {
      if (pos < 1024) {
        int n = tid * 4 + j;
        op[pos] = n;
        if (r == 0) ip[n] = pos;
      }
      pos++;
    }
  }
}

// ---------------- 3) gather + RMSNorm -> bf16 rows ----------------
__global__ __launch_bounds__(256) void gather_rms(
    const float* __restrict__ x, const int* __restrict__ idx,
    const float* __restrict__ gamma_q, const float* __restrict__ gamma_c,
    short* __restrict__ qn, short* __restrict__ cn)
{
  __shared__ float rb[4];
  __shared__ float tot;
  int id = blockIdx.x;                  // ((r*B+b)*G+g)*1024 + slot
  int r = id >> 12, rem = id & 4095;
  int g = (rem >> 10) & 1;
  int b = rem >> 11;
  int tok = idx[id];
  int t = threadIdx.x;
  const float* xr = x + ((size_t)b * N_ + tok) * D_;
  f32x4 v = *(const f32x4*)(xr + t * 4);
  float ss = v[0]*v[0] + v[1]*v[1] + v[2]*v[2] + v[3]*v[3];
#pragma unroll
  for (int o = 32; o; o >>= 1) ss += __shfl_xor(ss, o);
  if ((t & 63) == 0) rb[t >> 6] = ss;
  __syncthreads();
  if (t == 0) tot = rb[0] + rb[1] + rb[2] + rb[3];
  __syncthreads();
  float scale = 32.0f / fmaxf(sqrtf(tot), 1e-12f);
  const float* gm = (r ? gamma_c : gamma_q) + g * D_;
  f32x4 gv = *(const f32x4*)(gm + t * 4);
  short* dst = (r ? cn : qn) + ((size_t)rem << 10) + t * 4;
  short4v ov;
#pragma unroll
  for (int e = 0; e < 4; ++e) ov[e] = f2bf(v[e] * scale * gv[e]);
  *(short4v*)dst = ov;
}

// ---------------- 4) NT GEMM: C[m,n] = sum_k A[m,k]*W[n,k], both bf16 ----------------
// A bf16 [BG][1024][1024], W bf16 [G][NB][1024]. 128x128 tile, BK=64, 4 waves.
// MODE 0: C -> bf16 row-major [bg][1024][NB(=1024)], scaled by oscale
// MODE 1: NB=2048; n<1024 -> k[bgh][slot][dh]; n>=1024 -> vT[bgh][dh][slot]
template<int MODE>
__global__ __launch_bounds__(256) void gemm_nt(
    const short* __restrict__ A, const short* __restrict__ Bw,
    short* __restrict__ out, short* __restrict__ kout, short* __restrict__ vout,
    int NB, float oscale)
{
  __shared__ short As[128 * LDP];
  __shared__ short Bs[128 * LDP];
  int t = threadIdx.x, lane = t & 63, wid = t >> 6;
  int grp = lane >> 4, l15 = lane & 15;
  int wm = wid >> 1, wn = wid & 1;
  int mbase = blockIdx.x * 128, nbase = blockIdx.y * 128;
  int bg = blockIdx.z, g = bg & 1;
  const short* Ab = A + ((size_t)bg << 20);
  const short* Bp = Bw + ((size_t)g * NB + nbase) * 1024;

  f32x4 zero = {0.f, 0.f, 0.f, 0.f};
  f32x4 acc[4][4];
#pragma unroll
  for (int i = 0; i < 4; ++i)
#pragma unroll
    for (int j = 0; j < 4; ++j) acc[i][j] = zero;

  int srow = t >> 1, shalf = t & 1;
  const short* ap = Ab + ((size_t)(mbase + srow) << 10) + shalf * 32;
  const short* bp = Bp + ((size_t)srow << 10) + shalf * 32;
  short* aw = As + srow * LDP + shalf * 32;
  short* bw = Bs + srow * LDP + shalf * 32;

  for (int kb = 0; kb < 16; ++kb) {
    short8 av[4], bv[4];
#pragma unroll
    for (int i = 0; i < 4; ++i) {
      av[i] = *(const short8*)(ap + i * 8);
      bv[i] = *(const short8*)(bp + i * 8);
    }
    ap += 64; bp += 64;
    __syncthreads();
#pragma unroll
    for (int i = 0; i < 4; ++i) {
      *(short8*)(aw + i * 8) = av[i];
      *(short8*)(bw + i * 8) = bv[i];
    }
    __syncthreads();
#pragma unroll
    for (int kf = 0; kf < 2; ++kf) {
      short8 af[4], bf_[4];
#pragma unroll
      for (int mt = 0; mt < 4; ++mt)
        af[mt] = *(const short8*)(As + (wm*64 + mt*16 + l15) * LDP + grp*8 + kf*32);
#pragma unroll
      for (int nt = 0; nt < 4; ++nt)
        bf_[nt] = *(const short8*)(Bs + (wn*64 + nt*16 + l15) * LDP + grp*8 + kf*32);
      __builtin_amdgcn_s_setprio(1);
#pragma unroll
      for (int mt = 0; mt < 4; ++mt)
#pragma unroll
        for (int nt = 0; nt < 4; ++nt)
          acc[mt][nt] = __builtin_amdgcn_mfma_f32_16x16x32_bf16(af[mt], bf_[nt], acc[mt][nt], 0, 0, 0);
      __builtin_amdgcn_s_setprio(0);
    }
  }

  // direct epilogue from C-layout: row=(lane>>4)*4+rr, col=lane&15
#pragma unroll
  for (int mt = 0; mt < 4; ++mt)
#pragma unroll
    for (int nt = 0; nt < 4; ++nt) {
      int n = nbase + wn*64 + nt*16 + l15;
#pragma unroll
      for (int rr = 0; rr < 4; ++rr) {
        int m = mbase + wm*64 + mt*16 + grp*4 + rr;
        float v = acc[mt][nt][rr] * oscale;
        if (MODE == 0) {
          out[((size_t)bg * 1024 + m) * 1024 + n] = f2bf(v);
        } else {
          if (n < 1024) {
            kout[(((size_t)bg * H_ + (n >> 6)) * NSLOT + m) * DH_ + (n & 63)] = f2bf(v);
          } else {
            int e = n - 1024;
            vout[(((size_t)bg * H_ + (e >> 6)) * DH_ + (e & 63)) * NSLOT + m] = f2bf(v);
          }
        }
      }
    }
}

// ---------------- 5) null kv fill (slot 1024) ----------------
__global__ void null_fill(const float* __restrict__ null_kv,
                          short* __restrict__ kb_, short* __restrict__ vb_)
{
  int bgh = blockIdx.x;                 // (b*G+g)*H + h
  int g = (bgh >> 4) & 1, h = bgh & 15;
  int t = threadIdx.x;                  // 0..63
  float kvk = null_kv[((size_t)(0 * G_ + g) * H_ + h) * DH_ + t];
  float kvv = null_kv[((size_t)(1 * G_ + g) * H_ + h) * DH_ + t];
  kb_[((size_t)bgh * NSLOT + 1024) * DH_ + t] = f2bf(kvk);
  vb_[((size_t)bgh * DH_ + t) * NSLOT + 1024] = f2bf(kvv);
}

// ---------------- 6) flash attention per (b,g,h), 64 queries per block ----------------
// S = mfma(A=K, B=Q) arrives pre-scaled to log2 domain (scale folded into qproj).
// Softmax via exp2f (native v_exp_f32). PV = mfma(A=P, B=vT).
__global__ __launch_bounds__(256) void attn_kernel(
    const short* __restrict__ q, const short* __restrict__ k,
    const short* __restrict__ vT, short* __restrict__ o)
{
  __shared__ short plds_all[4 * 16 * LDP];
  int qb = blockIdx.x, bgh = blockIdx.y;
  int bg = bgh >> 4, h = bgh & 15;
  int wid = threadIdx.x >> 6, lane = threadIdx.x & 63;
  int l15 = lane & 15, grp = lane >> 4;
  short* prow = plds_all + (wid * 16 + l15) * LDP;   // per-wave [16 q][LDP]
  int qbase = qb * 64 + wid * 16;

  const short* qp = q + ((size_t)bg * 1024 + qbase + l15) * 1024 + h * 64 + (grp << 3);
  short8 bq0 = *(const short8*)qp;
  short8 bq1 = *(const short8*)(qp + 32);
  const short* kp = k + (size_t)bgh * NSLOT * DH_ + (grp << 3);
  const short* vp = vT + (size_t)bgh * DH_ * NSLOT + (grp << 3);

  f32x4 zero = {0.f, 0.f, 0.f, 0.f};
  f32x4 oacc[4];
#pragma unroll
  for (int dt = 0; dt < 4; ++dt) oacc[dt] = zero;
  float m_run = -INFINITY, l_run = 0.f;

  for (int tile = 0; tile < 17; ++tile) {
    int sbase = tile * 64;
    // K fragments for this tile
    short8 ka[2][4];
#pragma unroll
    for (int kf = 0; kf < 2; ++kf)
#pragma unroll
      for (int kt = 0; kt < 4; ++kt)
        ka[kf][kt] = *(const short8*)(kp + ((size_t)(sbase + kt * 16 + l15)) * DH_ + kf * 32);
    f32x4 sacc[4];
#pragma unroll
    for (int kt = 0; kt < 4; ++kt) sacc[kt] = zero;
    __builtin_amdgcn_s_setprio(1);
#pragma unroll
    for (int kf = 0; kf < 2; ++kf) {
      short8 bqf = kf ? bq1 : bq0;
#pragma unroll
      for (int kt = 0; kt < 4; ++kt)
        sacc[kt] = __builtin_amdgcn_mfma_f32_16x16x32_bf16(ka[kf][kt], bqf, sacc[kt], 0, 0, 0);
    }
    __builtin_amdgcn_s_setprio(0);
    // prefetch V fragments (latency hides under softmax)
    short8 vb[2][4];
#pragma unroll
    for (int ks = 0; ks < 2; ++ks)
#pragma unroll
      for (int dt = 0; dt < 4; ++dt)
        vb[ks][dt] = *(const short8*)(vp + ((size_t)(dt * 16 + l15)) * NSLOT + sbase + ks * 32);

    if (tile == 16) {
#pragma unroll
      for (int kt = 0; kt < 4; ++kt)
#pragma unroll
        for (int rr = 0; rr < 4; ++rr)
          if ((kt * 16 + (grp << 2) + rr) != 0) sacc[kt][rr] = -INFINITY;
    }
    float pm = -INFINITY;
#pragma unroll
    for (int kt = 0; kt < 4; ++kt)
#pragma unroll
      for (int rr = 0; rr < 4; ++rr) pm = fmaxf(pm, sacc[kt][rr]);
    pm = fmaxf(pm, __shfl_xor(pm, 16));
    pm = fmaxf(pm, __shfl_xor(pm, 32));
    float m_new = fmaxf(m_run, pm);
    float psum = 0.f;
#pragma unroll
    for (int kt = 0; kt < 4; ++kt)
#pragma unroll
      for (int rr = 0; rr < 4; ++rr) {
        float p = exp2f(sacc[kt][rr] - m_new);
        sacc[kt][rr] = p;
        psum += p;
      }
    psum += __shfl_xor(psum, 16);
    psum += __shfl_xor(psum, 32);
    float alpha = exp2f(m_run - m_new);
    l_run = l_run * alpha + psum;
    m_run = m_new;
    // P -> LDS, packed b64 per kt (k = kt*16 + grp*4 + rr)
#pragma unroll
    for (int kt = 0; kt < 4; ++kt) {
      short4v pk;
#pragma unroll
      for (int rr = 0; rr < 4; ++rr) pk[rr] = f2bf(sacc[kt][rr]);
      *(short4v*)(prow + kt * 16 + (grp << 2)) = pk;
    }
    // rescale O: row q = (grp<<2)+rr
    f32x4 avec;
#pragma unroll
    for (int rr = 0; rr < 4; ++rr) avec[rr] = __shfl(alpha, (grp << 2) + rr);
#pragma unroll
    for (int dt = 0; dt < 4; ++dt) oacc[dt] *= avec;
    // PV
    __builtin_amdgcn_s_setprio(1);
#pragma unroll
    for (int ks = 0; ks < 2; ++ks) {
      short8 pa = *(const short8*)(prow + (grp << 3) + ks * 32);
#pragma unroll
      for (int dt = 0; dt < 4; ++dt)
        oacc[dt] = __builtin_amdgcn_mfma_f32_16x16x32_bf16(pa, vb[ks][dt], oacc[dt], 0, 0, 0);
    }
    __builtin_amdgcn_s_setprio(0);
  }
  f32x4 lvec;
#pragma unroll
  for (int rr = 0; rr < 4; ++rr) lvec[rr] = __shfl(l_run, (grp << 2) + rr);
  // direct store: oacc[dt][rr] = O[q=(grp<<2)+rr][dh=dt*16+l15]
#pragma unroll
  for (int dt = 0; dt < 4; ++dt)
#pragma unroll
    for (int rr = 0; rr < 4; ++rr) {
      int qq = (grp << 2) + rr;
      int dh = dt * 16 + l15;
      o[((size_t)bg * 1024 + qbase + qq) * 1024 + h * 64 + dh] = f2bf(oacc[dt][rr] / lvec[rr]);
    }
}

// ---------------- 7) finalize: scatter-average + null_token ----------------
__global__ __launch_bounds__(256) void finalize_kernel(
    const short* __restrict__ wo_out, const int* __restrict__ inv,
    const float* __restrict__ null_token, float* __restrict__ outp)
{
  int id = blockIdx.x;                  // b*N + n
  int b = id >> 12, n = id & (N_ - 1);
  int s0 = inv[((size_t)(b * G_ + 0) << 12) + n];
  int s1 = inv[((size_t)(b * G_ + 1) << 12) + n];
  int t = threadIdx.x;
  float* dst = outp + (size_t)id * D_ + t * 4;
  if (s0 < 0 && s1 < 0) {
    *(f32x4*)dst = *(const f32x4*)(null_token + t * 4);
  } else {
    f32x4 sum = {0.f, 0.f, 0.f, 0.f};
    float cnt = 0.f;
    if (s0 >= 0) {
      short4v v = *(const short4v*)(wo_out + (((size_t)(b * G_ + 0) * 1024 + s0) << 10) + t * 4);
#pragma unroll
      for (int e = 0; e < 4; ++e) sum[e] += bf2f(v[e]);
      cnt += 1.f;
    }
    if (s1 >= 0) {
      short4v v = *(const short4v*)(wo_out + (((size_t)(b * G_ + 1) * 1024 + s1) << 10) + t * 4);
#pragma unroll
      for (int e = 0; e < 4; ++e) sum[e] += bf2f(v[e]);
      cnt += 1.f;
    }
    f32x4 rv;
#pragma unroll
    for (int e = 0; e < 4; ++e) rv[e] = sum[e] / cnt;
    *(f32x4*)dst = rv;
  }
}

// ---------------- launch ----------------
extern "C" void kernel_launch(void* const* d_in, const int* in_sizes, int n_in,
                              void* d_out, int out_size, void* d_ws, size_t ws_size,
                              hipStream_t stream) {
  (void)in_sizes; (void)n_in; (void)out_size; (void)ws_size;
  const float* x        = (const float*)d_in[0];
  const float* rt_q     = (const float*)d_in[1];
  const float* rt_kv    = (const float*)d_in[2];
  const float* gamma_q  = (const float*)d_in[3];
  const float* gamma_c  = (const float*)d_in[4];
  const float* wq       = (const float*)d_in[5];
  const float* wkv      = (const float*)d_in[6];
  const float* wo       = (const float*)d_in[7];
  const float* null_kv  = (const float*)d_in[8];
  const float* null_tok = (const float*)d_in[9];
  float* outp = (float*)d_out;

  char* ws = (char*)d_ws;
  size_t off = 0;
  auto alloc = [&](size_t bytes) { char* p = ws + off; off += (bytes + 255) & ~(size_t)255; return p; };
  float* sim   = (float*)alloc((size_t)2 * B_ * G_ * N_ * 4);
  int*   idx   = (int*)  alloc((size_t)2 * B_ * G_ * 1024 * 4);
  int*   inv   = (int*)  alloc((size_t)B_ * G_ * N_ * 4);
  short* qn    = (short*)alloc((size_t)B_ * G_ * 1024 * 1024 * 2);
  short* cn    = (short*)alloc((size_t)B_ * G_ * 1024 * 1024 * 2);
  short* qproj = (short*)alloc((size_t)B_ * G_ * 1024 * 1024 * 2);
  size_t kvbytes = (size_t)B_ * G_ * H_ * NSLOT * DH_ * 2;
  short* kbuf  = (short*)alloc(kvbytes);
  short* vbuf  = (short*)alloc(kvbytes);
  short* obuf  = (short*)alloc((size_t)B_ * G_ * 1024 * 1024 * 2);
  short* wobuf = (short*)alloc((size_t)B_ * G_ * 1024 * 1024 * 2);
  // bf16 weight buffers aliased into dead regions (lifetimes verified):
  short* wq_bf  = wobuf;  // 4.2MB <= 8.4MB; dead before gemm#3 writes wobuf
  short* wkv_bf = obuf;   // 8.4MB == 8.4MB; dead before attn writes obuf
  short* wo_bf  = qn;     // 4.2MB <= 8.4MB; converted after gemm#1 consumed qn

  hipMemsetAsync(kbuf, 0, kvbytes, stream);
  hipMemsetAsync(vbuf, 0, kvbytes, stream);
  hipMemsetAsync(inv, 0xFF, (size_t)B_ * G_ * N_ * 4, stream);

  wconv<<<2048, 256, 0, stream>>>(wq, wq_bf, 524288);
  wconv<<<4096, 256, 0, stream>>>(wkv, wkv_bf, 1048576);
  sim_kernel<<<B_ * N_ / 4, 256, 0, stream>>>(x, rt_q, rt_kv, sim);
  coor_topk<<<8, 1024, 0, stream>>>(sim, idx, inv);
  gather_rms<<<2 * B_ * G_ * 1024, 256, 0, stream>>>(x, idx, gamma_q, gamma_c, qn, cn);
  gemm_nt<0><<<dim3(8, 8, B_ * G_), 256, 0, stream>>>(qn, wq_bf, qproj, nullptr, nullptr, 1024, ATTN_SCALE);
  wconv<<<2048, 256, 0, stream>>>(wo, wo_bf, 524288);   // into qn (now dead)
  gemm_nt<1><<<dim3(8, 16, B_ * G_), 256, 0, stream>>>(cn, wkv_bf, nullptr, kbuf, vbuf, 2048, 1.0f);
  null_fill<<<B_ * G_ * H_, 64, 0, stream>>>(null_kv, kbuf, vbuf);
  attn_kernel<<<dim3(16, B_ * G_ * H_), 256, 0, stream>>>(qproj, kbuf, vbuf, obuf);
  gemm_nt<0><<<dim3(8, 8, B_ * G_), 256, 0, stream>>>(obuf, wo_bf, wobuf, nullptr, nullptr, 1024, 1.0f);
  finalize_kernel<<<B_ * N_, 256, 0, stream>>>(wobuf, inv, null_tok, outp);
}

// Round 4
// 300.398 us; speedup vs baseline: 1.1961x; 1.0112x over previous
//
#include <hip/hip_runtime.h>

// ---------------- types / helpers ----------------
typedef __attribute__((ext_vector_type(8))) short short8;   // 8 x bf16 (16B)
typedef __attribute__((ext_vector_type(4))) short short4v;  // 4 x bf16 (8B)
typedef __attribute__((ext_vector_type(4))) float f32x4;
typedef __attribute__((ext_vector_type(2))) float f32x2;

#define B_ 2
#define N_ 4096
#define D_ 1024
#define G_ 2
#define H_ 16
#define DH_ 64
#define NSLOT 1088              // 1024 tokens + 1 null + pad to 17*64
#define LOGK 7.0492548412558374f  // log(1152)
#define ATTN_SCALE 0.18033688011112043f  // dh^-0.5 * log2(e): S in log2 domain

__device__ __forceinline__ float bf2f(short s) {
  return __uint_as_float(((unsigned)(unsigned short)s) << 16);
}
__device__ __forceinline__ short f2bf(float f) {   // RNE
  unsigned u = __float_as_uint(f);
  u = (u + 0x7FFFu + ((u >> 16) & 1u)) >> 16;
  return (short)u;
}

// ---------------- 0) W f32 -> bf16 pre-convert ----------------
__global__ __launch_bounds__(256) void wconv(
    const float* __restrict__ src, short* __restrict__ dst, int n4)
{
  int i = blockIdx.x * 256 + threadIdx.x;
  if (i >= n4) return;
  f32x4 v = ((const f32x4*)src)[i];
  short4v o;
#pragma unroll
  for (int e = 0; e < 4; ++e) o[e] = f2bf(v[e]);
  ((short4v*)dst)[i] = o;
}

// ---------------- 1) sim = einsum('bnd,gd->bgn') for both routings ----------------
__global__ __launch_bounds__(256) void sim_kernel(
    const float* __restrict__ x, const float* __restrict__ rtq,
    const float* __restrict__ rtkv, float* __restrict__ sim)
{
  int wid = threadIdx.x >> 6, lane = threadIdx.x & 63;
  int row = blockIdx.x * 4 + wid;              // b*N + n
  int b = row >> 12, n = row & (N_ - 1);
  const float* xr = x + (size_t)row * D_;
  float a0 = 0.f, a1 = 0.f, a2 = 0.f, a3 = 0.f;
#pragma unroll
  for (int c = 0; c < 4; ++c) {
    int d = c * 256 + lane * 4;
    f32x4 xv = *(const f32x4*)(xr + d);
    f32x4 r0 = *(const f32x4*)(rtq + d);
    f32x4 r1 = *(const f32x4*)(rtq + D_ + d);
    f32x4 r2 = *(const f32x4*)(rtkv + d);
    f32x4 r3 = *(const f32x4*)(rtkv + D_ + d);
#pragma unroll
    for (int e = 0; e < 4; ++e) {
      a0 += xv[e] * r0[e];
      a1 += xv[e] * r1[e];
      a2 += xv[e] * r2[e];
      a3 += xv[e] * r3[e];
    }
  }
#pragma unroll
  for (int o = 32; o; o >>= 1) {
    a0 += __shfl_xor(a0, o); a1 += __shfl_xor(a1, o);
    a2 += __shfl_xor(a2, o); a3 += __shfl_xor(a3, o);
  }
  if (lane == 0) {
    sim[((size_t)(b)*G_ + 0) * N_ + n] = a0;
    sim[((size_t)(b)*G_ + 1) * N_ + n] = a1;
    sim[((size_t)(B_ + b)*G_ + 0) * N_ + n] = a2;
    sim[((size_t)(B_ + b)*G_ + 1) * N_ + n] = a3;
  }
}

// ---------------- 2) coor_descent + top-k (exact tie semantics) ----------------
__global__ __launch_bounds__(1024) void coor_topk(
    const float* __restrict__ sim, int* __restrict__ idxout, int* __restrict__ inv)
{
  __shared__ float rbuf[16];
  __shared__ float res;
  __shared__ unsigned keys[N_];
  __shared__ int scanbuf[16];

  int r = blockIdx.x >> 2, b = (blockIdx.x >> 1) & 1, g = blockIdx.x & 1;
  const float* srow = sim + ((size_t)blockIdx.x << 12);
  int tid = threadIdx.x, lane = tid & 63, wid = tid >> 6;

  float sv[4];
#pragma unroll
  for (int j = 0; j < 4; ++j) sv[j] = srow[tid * 4 + j];

  float a = 0.f;
  double epsd = 4.0;
  for (int it = 0; it < 20; ++it) {
    float eps = (float)fmax(epsd, 0.03);
    epsd *= 0.7;
    float sb[4]; float lmax = -INFINITY;
#pragma unroll
    for (int j = 0; j < 4; ++j) {
      float bb = (it == 0) ? (-sv[j]) : (-fmaxf(sv[j] + a, 0.f));
      sb[j] = (sv[j] + bb) / eps;
      lmax = fmaxf(lmax, sb[j]);
    }
#pragma unroll
    for (int o = 32; o; o >>= 1) lmax = fmaxf(lmax, __shfl_xor(lmax, o));
    if (lane == 0) rbuf[wid] = lmax;
    __syncthreads();
    if (tid == 0) {
      float m = rbuf[0];
      for (int i = 1; i < 16; ++i) m = fmaxf(m, rbuf[i]);
      res = m;
    }
    __syncthreads();
    float mx = res;
    __syncthreads();
    float lsum = 0.f;
#pragma unroll
    for (int j = 0; j < 4; ++j) lsum += expf(sb[j] - mx);
#pragma unroll
    for (int o = 32; o; o >>= 1) lsum += __shfl_xor(lsum, o);
    if (lane == 0) rbuf[wid] = lsum;
    __syncthreads();
    if (tid == 0) {
      float s = 0.f;
      for (int i = 0; i < 16; ++i) s += rbuf[i];
      res = logf(s) + mx;
    }
    __syncthreads();
    float lse = res;
    __syncthreads();
    a = eps * (LOGK - lse);
  }

  // final scores: exp(min(s+a,0)/0.03); saturated entries are EXACTLY 1.0f
  unsigned kb[4]; int c1 = 0;
#pragma unroll
  for (int j = 0; j < 4; ++j) {
    float sc = expf(fminf(sv[j] + a, 0.f) / 0.03f);
    kb[j] = __float_as_uint(sc);
    keys[tid * 4 + j] = kb[j];
    c1 += (kb[j] == 0x3F800000u);
  }
#pragma unroll
  for (int o = 32; o; o >>= 1) c1 += __shfl_xor(c1, o);
  if (lane == 0) scanbuf[wid] = c1;
  __syncthreads();
  int c1tot = 0;
  for (int i = 0; i < 16; ++i) c1tot += scanbuf[i];
  __syncthreads();

  int flag[4];
  if (c1tot >= 1024) {
#pragma unroll
    for (int j = 0; j < 4; ++j) flag[j] = (kb[j] == 0x3F800000u);
  } else {
#pragma unroll
    for (int j = 0; j < 4; ++j) {
      unsigned kn = kb[j]; int n = tid * 4 + j; int rank = 0;
      for (int m = 0; m < N_; ++m) {
        unsigned km = keys[m];
        rank += (km > kn) || (km == kn && m < n);
      }
      flag[j] = (rank < 1024);
    }
  }

  int cnt = flag[0] + flag[1] + flag[2] + flag[3];
  int inc = cnt;
#pragma unroll
  for (int o = 1; o < 64; o <<= 1) {
    int tt = __shfl_up(inc, o);
    if (lane >= o) inc += tt;
  }
  if (lane == 63) scanbuf[wid] = inc;
  __syncthreads();
  int off = 0;
  for (int w = 0; w < wid; ++w) off += scanbuf[w];
  int pos = off + inc - cnt;
  int* op = idxout + ((size_t)blockIdx.x << 10);
  int* ip = inv + ((size_t)(b * G_ + g) << 12);
#pragma unroll
  for (int j = 0; j < 4; ++j) {
    if (flag[j]) {
      if (pos < 1024) {
        int n = tid * 4 + j;
        op[pos] = n;
        if (r == 0) ip[n] = pos;
      }
      pos++;
    }
  }
}

// ---------------- 3) gather + RMSNorm -> bf16 rows ----------------
__global__ __launch_bounds__(256) void gather_rms(
    const float* __restrict__ x, const int* __restrict__ idx,
    const float* __restrict__ gamma_q, const float* __restrict__ gamma_c,
    short* __restrict__ qn, short* __restrict__ cn)
{
  __shared__ float rb[4];
  __shared__ float tot;
  int id = blockIdx.x;                  // ((r*B+b)*G+g)*1024 + slot
  int r = id >> 12, rem = id & 4095;
  int g = (rem >> 10) & 1;
  int b = rem >> 11;
  int tok = idx[id];
  int t = threadIdx.x;
  const float* xr = x + ((size_t)b * N_ + tok) * D_;
  f32x4 v = *(const f32x4*)(xr + t * 4);
  float ss = v[0]*v[0] + v[1]*v[1] + v[2]*v[2] + v[3]*v[3];
#pragma unroll
  for (int o = 32; o; o >>= 1) ss += __shfl_xor(ss, o);
  if ((t & 63) == 0) rb[t >> 6] = ss;
  __syncthreads();
  if (t == 0) tot = rb[0] + rb[1] + rb[2] + rb[3];
  __syncthreads();
  float scale = 32.0f / fmaxf(sqrtf(tot), 1e-12f);
  const float* gm = (r ? gamma_c : gamma_q) + g * D_;
  f32x4 gv = *(const f32x4*)(gm + t * 4);
  short* dst = (r ? cn : qn) + ((size_t)rem << 10) + t * 4;
  short4v ov;
#pragma unroll
  for (int e = 0; e < 4; ++e) ov[e] = f2bf(v[e] * scale * gv[e]);
  *(short4v*)dst = ov;
}

// ---------------- 4) NT GEMM: C[m,n] = sum_k A[m,k]*W[n,k], both bf16 ----------------
// m97 pattern: global_load_lds(16B) staging, linear LDS dest, inverse-XOR-swizzled
// global SOURCE, XOR-swizzled ds_read_b128 (both-sides involution, rule #21).
// MODE 0: C -> bf16 row-major [bg][1024][NB(=1024)], scaled by oscale
// MODE 1: NB=2048; n<1024 -> k[bgh][slot][dh]; n>=1024 -> vT[bgh][dh][slot]
template<int MODE>
__global__ __launch_bounds__(256) void gemm_nt(
    const short* __restrict__ A, const short* __restrict__ Bw,
    short* __restrict__ out, short* __restrict__ kout, short* __restrict__ vout,
    int NB, float oscale)
{
  __shared__ short As[128 * 64];   // [128 rows][64 k] bf16, content XOR-swizzled
  __shared__ short Bs[128 * 64];
  int t = threadIdx.x, lane = t & 63, wid = t >> 6;
  int grp = lane >> 4, l15 = lane & 15;
  int wm = wid >> 1, wn = wid & 1;
  int mbase = blockIdx.x * 128, nbase = blockIdx.y * 128;
  int bg = blockIdx.z, g = bg & 1;
  const short* Ab = A + ((size_t)bg << 20);
  const short* Bp = Bw + ((size_t)g * NB + nbase) * 1024;

  f32x4 zero = {0.f, 0.f, 0.f, 0.f};
  f32x4 acc[4][4];
#pragma unroll
  for (int i = 0; i < 4; ++i)
#pragma unroll
    for (int j = 0; j < 4; ++j) acc[i][j] = zero;

  // staging: 16B unit u = i*256 + t; row = u>>3, j = u&7; source col-unit = j ^ (row&7)
  const short* aps[4]; const short* bps[4];
  short* adst[4]; short* bdst[4];
#pragma unroll
  for (int i = 0; i < 4; ++i) {
    int u = i * 256 + t;
    int row = u >> 3, j = u & 7;
    int cs = ((j ^ (row & 7)) << 3);     // shorts
    aps[i] = Ab + ((size_t)(mbase + row) << 10) + cs;
    bps[i] = Bp + ((size_t)row << 10) + cs;
    adst[i] = As + (i * 256 + wid * 64) * 8;   // wave-uniform base; +lane*16B by HW
    bdst[i] = Bs + (i * 256 + wid * 64) * 8;
  }

  for (int kb = 0; kb < 16; ++kb) {
    __syncthreads();
#pragma unroll
    for (int i = 0; i < 4; ++i) {
      __builtin_amdgcn_global_load_lds(
          (const __attribute__((address_space(1))) void*)aps[i],
          (__attribute__((address_space(3))) void*)adst[i], 16, 0, 0);
      __builtin_amdgcn_global_load_lds(
          (const __attribute__((address_space(1))) void*)bps[i],
          (__attribute__((address_space(3))) void*)bdst[i], 16, 0, 0);
      aps[i] += 64; bps[i] += 64;
    }
    asm volatile("s_waitcnt vmcnt(0)" ::: "memory");
    __syncthreads();
    const char* Ac = (const char*)As;
    const char* Bc = (const char*)Bs;
#pragma unroll
    for (int kf = 0; kf < 2; ++kf) {
      short8 af[4], bf_[4];
#pragma unroll
      for (int mt = 0; mt < 4; ++mt) {
        int ra = wm * 64 + mt * 16 + l15;
        af[mt] = *(const short8*)(Ac + ra * 128 + (((grp << 4) + (kf << 6)) ^ ((ra & 7) << 4)));
      }
#pragma unroll
      for (int nt = 0; nt < 4; ++nt) {
        int rb = wn * 64 + nt * 16 + l15;
        bf_[nt] = *(const short8*)(Bc + rb * 128 + (((grp << 4) + (kf << 6)) ^ ((rb & 7) << 4)));
      }
      __builtin_amdgcn_s_setprio(1);
#pragma unroll
      for (int mt = 0; mt < 4; ++mt)
#pragma unroll
        for (int nt = 0; nt < 4; ++nt)
          acc[mt][nt] = __builtin_amdgcn_mfma_f32_16x16x32_bf16(af[mt], bf_[nt], acc[mt][nt], 0, 0, 0);
      __builtin_amdgcn_s_setprio(0);
    }
  }

  // direct epilogue from C-layout: row=(lane>>4)*4+rr, col=lane&15
#pragma unroll
  for (int mt = 0; mt < 4; ++mt)
#pragma unroll
    for (int nt = 0; nt < 4; ++nt) {
      int n = nbase + wn*64 + nt*16 + l15;
#pragma unroll
      for (int rr = 0; rr < 4; ++rr) {
        int m = mbase + wm*64 + mt*16 + grp*4 + rr;
        float v = acc[mt][nt][rr] * oscale;
        if (MODE == 0) {
          out[((size_t)bg * 1024 + m) * 1024 + n] = f2bf(v);
        } else {
          if (n < 1024) {
            kout[(((size_t)bg * H_ + (n >> 6)) * NSLOT + m) * DH_ + (n & 63)] = f2bf(v);
          } else {
            int e = n - 1024;
            vout[(((size_t)bg * H_ + (e >> 6)) * DH_ + (e & 63)) * NSLOT + m] = f2bf(v);
          }
        }
      }
    }
}

// ---------------- 5) null kv fill (slot 1024) ----------------
__global__ void null_fill(const float* __restrict__ null_kv,
                          short* __restrict__ kb_, short* __restrict__ vb_)
{
  int bgh = blockIdx.x;                 // (b*G+g)*H + h
  int g = (bgh >> 4) & 1, h = bgh & 15;
  int t = threadIdx.x;                  // 0..63
  float kvk = null_kv[((size_t)(0 * G_ + g) * H_ + h) * DH_ + t];
  float kvv = null_kv[((size_t)(1 * G_ + g) * H_ + h) * DH_ + t];
  kb_[((size_t)bgh * NSLOT + 1024) * DH_ + t] = f2bf(kvk);
  vb_[((size_t)bgh * DH_ + t) * NSLOT + 1024] = f2bf(kvv);
}

// ---------------- 6) flash attention, KV-split 2, partial outputs ----------------
// grid (bgh=64, qb=16, sp=2): linear%8 = bgh%8 -> all blocks of a head share one XCD.
// S = mfma(A=K, B=Q) in log2 domain; softmax exp2; PV = mfma(A=P, B=vT).
// Writes UN-normalized partial O (bf16) + per-q-row (m,l) f32; merged by attn_merge.
__global__ __launch_bounds__(256) void attn_kernel(
    const short* __restrict__ q, const short* __restrict__ k,
    const short* __restrict__ vT, short* __restrict__ o0,
    short* __restrict__ o1, float* __restrict__ ml)
{
  __shared__ short plds_all[4 * 16 * 72];
  int bgh = blockIdx.x, qb = blockIdx.y, sp = blockIdx.z;
  int bg = bgh >> 4, h = bgh & 15;
  int wid = threadIdx.x >> 6, lane = threadIdx.x & 63;
  int l15 = lane & 15, grp = lane >> 4;
  short* prow = plds_all + (wid * 16 + l15) * 72;   // per-wave [16 q][72]
  int qbase = qb * 64 + wid * 16;

  const short* qp = q + ((size_t)bg * 1024 + qbase + l15) * 1024 + h * 64 + (grp << 3);
  short8 bq0 = *(const short8*)qp;
  short8 bq1 = *(const short8*)(qp + 32);
  const short* kp = k + (size_t)bgh * NSLOT * DH_ + (grp << 3);
  const short* vp = vT + (size_t)bgh * DH_ * NSLOT + (grp << 3);

  f32x4 zero = {0.f, 0.f, 0.f, 0.f};
  f32x4 oacc[4];
#pragma unroll
  for (int dt = 0; dt < 4; ++dt) oacc[dt] = zero;
  float m_run = -INFINITY, l_run = 0.f;

  int t0 = sp ? 9 : 0, t1 = sp ? 17 : 9;
  for (int tile = t0; tile < t1; ++tile) {
    int sbase = tile * 64;
    short8 ka[2][4];
#pragma unroll
    for (int kf = 0; kf < 2; ++kf)
#pragma unroll
      for (int kt = 0; kt < 4; ++kt)
        ka[kf][kt] = *(const short8*)(kp + ((size_t)(sbase + kt * 16 + l15)) * DH_ + kf * 32);
    f32x4 sacc[4];
#pragma unroll
    for (int kt = 0; kt < 4; ++kt) sacc[kt] = zero;
    __builtin_amdgcn_s_setprio(1);
#pragma unroll
    for (int kf = 0; kf < 2; ++kf) {
      short8 bqf = kf ? bq1 : bq0;
#pragma unroll
      for (int kt = 0; kt < 4; ++kt)
        sacc[kt] = __builtin_amdgcn_mfma_f32_16x16x32_bf16(ka[kf][kt], bqf, sacc[kt], 0, 0, 0);
    }
    __builtin_amdgcn_s_setprio(0);
    // prefetch V fragments (latency hides under softmax)
    short8 vb[2][4];
#pragma unroll
    for (int ks = 0; ks < 2; ++ks)
#pragma unroll
      for (int dt = 0; dt < 4; ++dt)
        vb[ks][dt] = *(const short8*)(vp + ((size_t)(dt * 16 + l15)) * NSLOT + sbase + ks * 32);

    if (tile == 16) {
#pragma unroll
      for (int kt = 0; kt < 4; ++kt)
#pragma unroll
        for (int rr = 0; rr < 4; ++rr)
          if ((kt * 16 + (grp << 2) + rr) != 0) sacc[kt][rr] = -INFINITY;
    }
    float pm = -INFINITY;
#pragma unroll
    for (int kt = 0; kt < 4; ++kt)
#pragma unroll
      for (int rr = 0; rr < 4; ++rr) pm = fmaxf(pm, sacc[kt][rr]);
    pm = fmaxf(pm, __shfl_xor(pm, 16));
    pm = fmaxf(pm, __shfl_xor(pm, 32));
    float m_new = fmaxf(m_run, pm);
    float psum = 0.f;
#pragma unroll
    for (int kt = 0; kt < 4; ++kt)
#pragma unroll
      for (int rr = 0; rr < 4; ++rr) {
        float p = exp2f(sacc[kt][rr] - m_new);
        sacc[kt][rr] = p;
        psum += p;
      }
    psum += __shfl_xor(psum, 16);
    psum += __shfl_xor(psum, 32);
    float alpha = exp2f(m_run - m_new);
    l_run = l_run * alpha + psum;
    m_run = m_new;
    // P -> LDS, packed b64 per kt (k = kt*16 + grp*4 + rr)
#pragma unroll
    for (int kt = 0; kt < 4; ++kt) {
      short4v pk;
#pragma unroll
      for (int rr = 0; rr < 4; ++rr) pk[rr] = f2bf(sacc[kt][rr]);
      *(short4v*)(prow + kt * 16 + (grp << 2)) = pk;
    }
    // rescale O: row q = (grp<<2)+rr
    f32x4 avec;
#pragma unroll
    for (int rr = 0; rr < 4; ++rr) avec[rr] = __shfl(alpha, (grp << 2) + rr);
#pragma unroll
    for (int dt = 0; dt < 4; ++dt) oacc[dt] *= avec;
    // PV
    __builtin_amdgcn_s_setprio(1);
#pragma unroll
    for (int ks = 0; ks < 2; ++ks) {
      short8 pa = *(const short8*)(prow + (grp << 3) + ks * 32);
#pragma unroll
      for (int dt = 0; dt < 4; ++dt)
        oacc[dt] = __builtin_amdgcn_mfma_f32_16x16x32_bf16(pa, vb[ks][dt], oacc[dt], 0, 0, 0);
    }
    __builtin_amdgcn_s_setprio(0);
  }
  // per-q-row (m,l): lane holds them for q row l15 (replicated over grp)
  if (grp == 0) {
    int idx = ((sp * 64 + bgh) * 16 + qb) * 64 + wid * 16 + l15;
    f32x2 v; v[0] = m_run; v[1] = l_run;
    *(f32x2*)(ml + (size_t)idx * 2) = v;
  }
  // un-normalized partial O store: oacc[dt][rr] = O[q=(grp<<2)+rr][dh=dt*16+l15]
#pragma unroll
  for (int dt = 0; dt < 4; ++dt)
#pragma unroll
    for (int rr = 0; rr < 4; ++rr) {
      int qq = (grp << 2) + rr;
      int dh = dt * 16 + l15;
      if (sp == 0)
        o0[((size_t)bg * 1024 + qbase + qq) * 1024 + h * 64 + dh] = f2bf(oacc[dt][rr]);
      else
        o1[(((size_t)(bgh * 16 + qb)) * 64 + wid * 16 + qq) * 64 + dh] = f2bf(oacc[dt][rr]);
    }
}

// ---------------- 6b) merge the two KV-splits (log2 domain) ----------------
__global__ __launch_bounds__(256) void attn_merge(
    short* __restrict__ obuf, const short* __restrict__ op1,
    const float* __restrict__ ml)
{
  int id = blockIdx.x;                  // bgh*16 + qb
  int bgh = id >> 4, qb = id & 15;
  int bg = bgh >> 4, h = bgh & 15;
  int t = threadIdx.x;
  int qq = t >> 2, c = t & 3;
  int base0 = (id * 64 + qq) * 2;
  int base1 = ((64 * 16 * 64) + id * 64 + qq) * 2;
  float m0 = ml[base0], l0 = ml[base0 + 1];
  float m1 = ml[base1], l1 = ml[base1 + 1];
  float M = fmaxf(m0, m1);
  float w0 = exp2f(m0 - M), w1 = exp2f(m1 - M);
  float linv = 1.0f / (l0 * w0 + l1 * w1);
  w0 *= linv; w1 *= linv;
  size_t loc0 = ((size_t)bg * 1024 + qb * 64 + qq) * 1024 + h * 64 + c * 16;
  size_t loc1 = ((size_t)(id * 64 + qq)) * 64 + c * 16;
  short8 a0 = *(const short8*)(obuf + loc0);
  short8 a1 = *(const short8*)(obuf + loc0 + 8);
  short8 b0 = *(const short8*)(op1 + loc1);
  short8 b1 = *(const short8*)(op1 + loc1 + 8);
  short8 r0, r1;
#pragma unroll
  for (int e = 0; e < 8; ++e) {
    r0[e] = f2bf(bf2f(a0[e]) * w0 + bf2f(b0[e]) * w1);
    r1[e] = f2bf(bf2f(a1[e]) * w0 + bf2f(b1[e]) * w1);
  }
  *(short8*)(obuf + loc0) = r0;
  *(short8*)(obuf + loc0 + 8) = r1;
}

// ---------------- 7) finalize: scatter-average + null_token ----------------
__global__ __launch_bounds__(256) void finalize_kernel(
    const short* __restrict__ wo_out, const int* __restrict__ inv,
    const float* __restrict__ null_token, float* __restrict__ outp)
{
  int id = blockIdx.x;                  // b*N + n
  int b = id >> 12, n = id & (N_ - 1);
  int s0 = inv[((size_t)(b * G_ + 0) << 12) + n];
  int s1 = inv[((size_t)(b * G_ + 1) << 12) + n];
  int t = threadIdx.x;
  float* dst = outp + (size_t)id * D_ + t * 4;
  if (s0 < 0 && s1 < 0) {
    *(f32x4*)dst = *(const f32x4*)(null_token + t * 4);
  } else {
    f32x4 sum = {0.f, 0.f, 0.f, 0.f};
    float cnt = 0.f;
    if (s0 >= 0) {
      short4v v = *(const short4v*)(wo_out + (((size_t)(b * G_ + 0) * 1024 + s0) << 10) + t * 4);
#pragma unroll
      for (int e = 0; e < 4; ++e) sum[e] += bf2f(v[e]);
      cnt += 1.f;
    }
    if (s1 >= 0) {
      short4v v = *(const short4v*)(wo_out + (((size_t)(b * G_ + 1) * 1024 + s1) << 10) + t * 4);
#pragma unroll
      for (int e = 0; e < 4; ++e) sum[e] += bf2f(v[e]);
      cnt += 1.f;
    }
    f32x4 rv;
#pragma unroll
    for (int e = 0; e < 4; ++e) rv[e] = sum[e] / cnt;
    *(f32x4*)dst = rv;
  }
}

// ---------------- launch ----------------
extern "C" void kernel_launch(void* const* d_in, const int* in_sizes, int n_in,
                              void* d_out, int out_size, void* d_ws, size_t ws_size,
                              hipStream_t stream) {
  (void)in_sizes; (void)n_in; (void)out_size; (void)ws_size;
  const float* x        = (const float*)d_in[0];
  const float* rt_q     = (const float*)d_in[1];
  const float* rt_kv    = (const float*)d_in[2];
  const float* gamma_q  = (const float*)d_in[3];
  const float* gamma_c  = (const float*)d_in[4];
  const float* wq       = (const float*)d_in[5];
  const float* wkv      = (const float*)d_in[6];
  const float* wo       = (const float*)d_in[7];
  const float* null_kv  = (const float*)d_in[8];
  const float* null_tok = (const float*)d_in[9];
  float* outp = (float*)d_out;

  char* ws = (char*)d_ws;
  size_t off = 0;
  auto alloc = [&](size_t bytes) { char* p = ws + off; off += (bytes + 255) & ~(size_t)255; return p; };
  float* sim   = (float*)alloc((size_t)2 * B_ * G_ * N_ * 4);
  int*   idx   = (int*)  alloc((size_t)2 * B_ * G_ * 1024 * 4);
  int*   inv   = (int*)  alloc((size_t)B_ * G_ * N_ * 4);
  float* ml    = (float*)alloc((size_t)2 * 64 * 16 * 64 * 2 * 4);   // 1MB (m,l) partials
  short* qn    = (short*)alloc((size_t)B_ * G_ * 1024 * 1024 * 2);
  short* cn    = (short*)alloc((size_t)B_ * G_ * 1024 * 1024 * 2);
  short* qproj = (short*)alloc((size_t)B_ * G_ * 1024 * 1024 * 2);
  size_t kvbytes = (size_t)B_ * G_ * H_ * NSLOT * DH_ * 2;
  short* kbuf  = (short*)alloc(kvbytes);
  short* vbuf  = (short*)alloc(kvbytes);
  short* obuf  = (short*)alloc((size_t)B_ * G_ * 1024 * 1024 * 2);
  short* wobuf = (short*)alloc((size_t)B_ * G_ * 1024 * 1024 * 2);
  // aliases into dead regions (lifetimes verified):
  short* wq_bf  = wobuf;  // dead until final gemm writes wobuf
  short* wkv_bf = obuf;   // consumed by gemm<1> before attn writes obuf
  short* wo_bf  = qn;     // converted after gemm#1 consumed qn
  short* op1    = cn;     // split-1 partial O; cn dead after gemm<1>

  hipMemsetAsync(kbuf, 0, kvbytes, stream);
  hipMemsetAsync(vbuf, 0, kvbytes, stream);
  hipMemsetAsync(inv, 0xFF, (size_t)B_ * G_ * N_ * 4, stream);

  wconv<<<2048, 256, 0, stream>>>(wq, wq_bf, 524288);
  wconv<<<4096, 256, 0, stream>>>(wkv, wkv_bf, 1048576);
  sim_kernel<<<B_ * N_ / 4, 256, 0, stream>>>(x, rt_q, rt_kv, sim);
  coor_topk<<<8, 1024, 0, stream>>>(sim, idx, inv);
  gather_rms<<<2 * B_ * G_ * 1024, 256, 0, stream>>>(x, idx, gamma_q, gamma_c, qn, cn);
  gemm_nt<0><<<dim3(8, 8, B_ * G_), 256, 0, stream>>>(qn, wq_bf, qproj, nullptr, nullptr, 1024, ATTN_SCALE);
  wconv<<<2048, 256, 0, stream>>>(wo, wo_bf, 524288);   // into qn (now dead)
  gemm_nt<1><<<dim3(8, 16, B_ * G_), 256, 0, stream>>>(cn, wkv_bf, nullptr, kbuf, vbuf, 2048, 1.0f);
  null_fill<<<B_ * G_ * H_, 64, 0, stream>>>(null_kv, kbuf, vbuf);
  attn_kernel<<<dim3(64, 16, 2), 256, 0, stream>>>(qproj, kbuf, vbuf, obuf, op1, ml);
  attn_merge<<<1024, 256, 0, stream>>>(obuf, op1, ml);
  gemm_nt<0><<<dim3(8, 8, B_ * G_), 256, 0, stream>>>(obuf, wo_bf, wobuf, nullptr, nullptr, 1024, 1.0f);
  finalize_kernel<<<B_ * N_, 256, 0, stream>>>(wobuf, inv, null_tok, outp);
}

// Round 5
// 299.476 us; speedup vs baseline: 1.1998x; 1.0031x over previous
//
#include <hip/hip_runtime.h>

// ---------------- types / helpers ----------------
typedef __attribute__((ext_vector_type(8))) short short8;   // 8 x bf16 (16B)
typedef __attribute__((ext_vector_type(4))) short short4v;  // 4 x bf16 (8B)
typedef __attribute__((ext_vector_type(4))) float f32x4;
typedef __attribute__((ext_vector_type(2))) float f32x2;

#define B_ 2
#define N_ 4096
#define D_ 1024
#define G_ 2
#define H_ 16
#define DH_ 64
#define NSLOT 1088              // 1024 tokens + 1 null + pad to 17*64
#define LOGK 7.0492548412558374f  // log(1152)
#define ATTN_SCALE 0.18033688011112043f  // dh^-0.5 * log2(e): S in log2 domain

__device__ __forceinline__ float bf2f(short s) {
  return __uint_as_float(((unsigned)(unsigned short)s) << 16);
}
__device__ __forceinline__ short f2bf(float f) {   // RNE
  unsigned u = __float_as_uint(f);
  u = (u + 0x7FFFu + ((u >> 16) & 1u)) >> 16;
  return (short)u;
}
__device__ __forceinline__ short f2bf_trunc(float f) {   // truncation (hot path)
  return (short)(__float_as_uint(f) >> 16);
}
__device__ __forceinline__ float vmax4(f32x4 v) {
  return fmaxf(fmaxf(v[0], v[1]), fmaxf(v[2], v[3]));
}
__device__ __forceinline__ float vsum4(f32x4 v) {
  return (v[0] + v[1]) + (v[2] + v[3]);
}

// ---------------- 0) W f32 -> bf16 pre-convert ----------------
__global__ __launch_bounds__(256) void wconv(
    const float* __restrict__ src, short* __restrict__ dst, int n4)
{
  int i = blockIdx.x * 256 + threadIdx.x;
  if (i >= n4) return;
  f32x4 v = ((const f32x4*)src)[i];
  short4v o;
#pragma unroll
  for (int e = 0; e < 4; ++e) o[e] = f2bf(v[e]);
  ((short4v*)dst)[i] = o;
}

// ---------------- 1) sim = einsum('bnd,gd->bgn') for both routings ----------------
__global__ __launch_bounds__(256) void sim_kernel(
    const float* __restrict__ x, const float* __restrict__ rtq,
    const float* __restrict__ rtkv, float* __restrict__ sim)
{
  int wid = threadIdx.x >> 6, lane = threadIdx.x & 63;
  int row = blockIdx.x * 4 + wid;              // b*N + n
  int b = row >> 12, n = row & (N_ - 1);
  const float* xr = x + (size_t)row * D_;
  float a0 = 0.f, a1 = 0.f, a2 = 0.f, a3 = 0.f;
#pragma unroll
  for (int c = 0; c < 4; ++c) {
    int d = c * 256 + lane * 4;
    f32x4 xv = *(const f32x4*)(xr + d);
    f32x4 r0 = *(const f32x4*)(rtq + d);
    f32x4 r1 = *(const f32x4*)(rtq + D_ + d);
    f32x4 r2 = *(const f32x4*)(rtkv + d);
    f32x4 r3 = *(const f32x4*)(rtkv + D_ + d);
#pragma unroll
    for (int e = 0; e < 4; ++e) {
      a0 += xv[e] * r0[e];
      a1 += xv[e] * r1[e];
      a2 += xv[e] * r2[e];
      a3 += xv[e] * r3[e];
    }
  }
#pragma unroll
  for (int o = 32; o; o >>= 1) {
    a0 += __shfl_xor(a0, o); a1 += __shfl_xor(a1, o);
    a2 += __shfl_xor(a2, o); a3 += __shfl_xor(a3, o);
  }
  if (lane == 0) {
    sim[((size_t)(b)*G_ + 0) * N_ + n] = a0;
    sim[((size_t)(b)*G_ + 1) * N_ + n] = a1;
    sim[((size_t)(B_ + b)*G_ + 0) * N_ + n] = a2;
    sim[((size_t)(B_ + b)*G_ + 1) * N_ + n] = a3;
  }
}

// ---------------- 2) coor_descent + top-k (exact tie semantics) ----------------
__global__ __launch_bounds__(1024) void coor_topk(
    const float* __restrict__ sim, int* __restrict__ idxout, int* __restrict__ inv)
{
  __shared__ float rbuf[16];
  __shared__ float res;
  __shared__ unsigned keys[N_];
  __shared__ int scanbuf[16];

  int r = blockIdx.x >> 2, b = (blockIdx.x >> 1) & 1, g = blockIdx.x & 1;
  const float* srow = sim + ((size_t)blockIdx.x << 12);
  int tid = threadIdx.x, lane = tid & 63, wid = tid >> 6;

  float sv[4];
#pragma unroll
  for (int j = 0; j < 4; ++j) sv[j] = srow[tid * 4 + j];

  float a = 0.f;
  double epsd = 4.0;
  for (int it = 0; it < 20; ++it) {
    float eps = (float)fmax(epsd, 0.03);
    epsd *= 0.7;
    float sb[4]; float lmax = -INFINITY;
#pragma unroll
    for (int j = 0; j < 4; ++j) {
      float bb = (it == 0) ? (-sv[j]) : (-fmaxf(sv[j] + a, 0.f));
      sb[j] = (sv[j] + bb) / eps;
      lmax = fmaxf(lmax, sb[j]);
    }
#pragma unroll
    for (int o = 32; o; o >>= 1) lmax = fmaxf(lmax, __shfl_xor(lmax, o));
    if (lane == 0) rbuf[wid] = lmax;
    __syncthreads();
    if (tid == 0) {
      float m = rbuf[0];
      for (int i = 1; i < 16; ++i) m = fmaxf(m, rbuf[i]);
      res = m;
    }
    __syncthreads();
    float mx = res;
    __syncthreads();
    float lsum = 0.f;
#pragma unroll
    for (int j = 0; j < 4; ++j) lsum += expf(sb[j] - mx);
#pragma unroll
    for (int o = 32; o; o >>= 1) lsum += __shfl_xor(lsum, o);
    if (lane == 0) rbuf[wid] = lsum;
    __syncthreads();
    if (tid == 0) {
      float s = 0.f;
      for (int i = 0; i < 16; ++i) s += rbuf[i];
      res = logf(s) + mx;
    }
    __syncthreads();
    float lse = res;
    __syncthreads();
    a = eps * (LOGK - lse);
  }

  // final scores: exp(min(s+a,0)/0.03); saturated entries are EXACTLY 1.0f
  unsigned kb[4]; int c1 = 0;
#pragma unroll
  for (int j = 0; j < 4; ++j) {
    float sc = expf(fminf(sv[j] + a, 0.f) / 0.03f);
    kb[j] = __float_as_uint(sc);
    keys[tid * 4 + j] = kb[j];
    c1 += (kb[j] == 0x3F800000u);
  }
#pragma unroll
  for (int o = 32; o; o >>= 1) c1 += __shfl_xor(c1, o);
  if (lane == 0) scanbuf[wid] = c1;
  __syncthreads();
  int c1tot = 0;
  for (int i = 0; i < 16; ++i) c1tot += scanbuf[i];
  __syncthreads();

  int flag[4];
  if (c1tot >= 1024) {
#pragma unroll
    for (int j = 0; j < 4; ++j) flag[j] = (kb[j] == 0x3F800000u);
  } else {
#pragma unroll
    for (int j = 0; j < 4; ++j) {
      unsigned kn = kb[j]; int n = tid * 4 + j; int rank = 0;
      for (int m = 0; m < N_; ++m) {
        unsigned km = keys[m];
        rank += (km > kn) || (km == kn && m < n);
      }
      flag[j] = (rank < 1024);
    }
  }

  int cnt = flag[0] + flag[1] + flag[2] + flag[3];
  int inc = cnt;
#pragma unroll
  for (int o = 1; o < 64; o <<= 1) {
    int tt = __shfl_up(inc, o);
    if (lane >= o) inc += tt;
  }
  if (lane == 63) scanbuf[wid] = inc;
  __syncthreads();
  int off = 0;
  for (int w = 0; w < wid; ++w) off += scanbuf[w];
  int pos = off + inc - cnt;
  int* op = idxout + ((size_t)blockIdx.x << 10);
  int* ip = inv + ((size_t)(b * G_ + g) << 12);
#pragma unroll
  for (int j = 0; j < 4; ++j) {
    if (flag[j]) {
      if (pos < 1024) {
        int n = tid * 4 + j;
        op[pos] = n;
        if (r == 0) ip[n] = pos;
      }
      pos++;
    }
  }
}

// ---------------- 3) gather + RMSNorm -> bf16 rows ----------------
__global__ __launch_bounds__(256) void gather_rms(
    const float* __restrict__ x, const int* __restrict__ idx,
    const float* __restrict__ gamma_q, const float* __restrict__ gamma_c,
    short* __restrict__ qn, short* __restrict__ cn)
{
  __shared__ float rb[4];
  __shared__ float tot;
  int id = blockIdx.x;                  // ((r*B+b)*G+g)*1024 + slot
  int r = id >> 12, rem = id & 4095;
  int g = (rem >> 10) & 1;
  int b = rem >> 11;
  int tok = idx[id];
  int t = threadIdx.x;
  const float* xr = x + ((size_t)b * N_ + tok) * D_;
  f32x4 v = *(const f32x4*)(xr + t * 4);
  float ss = v[0]*v[0] + v[1]*v[1] + v[2]*v[2] + v[3]*v[3];
#pragma unroll
  for (int o = 32; o; o >>= 1) ss += __shfl_xor(ss, o);
  if ((t & 63) == 0) rb[t >> 6] = ss;
  __syncthreads();
  if (t == 0) tot = rb[0] + rb[1] + rb[2] + rb[3];
  __syncthreads();
  float scale = 32.0f / fmaxf(sqrtf(tot), 1e-12f);
  const float* gm = (r ? gamma_c : gamma_q) + g * D_;
  f32x4 gv = *(const f32x4*)(gm + t * 4);
  short* dst = (r ? cn : qn) + ((size_t)rem << 10) + t * 4;
  short4v ov;
#pragma unroll
  for (int e = 0; e < 4; ++e) ov[e] = f2bf(v[e] * scale * gv[e]);
  *(short4v*)dst = ov;
}

// ---------------- 4) NT GEMM: C[m,n] = sum_k A[m,k]*W[n,k], both bf16 ----------------
// m97 pattern: global_load_lds(16B) staging, linear LDS dest, inverse-XOR-swizzled
// global SOURCE, XOR-swizzled ds_read_b128 (both-sides involution, rule #21).
// MODE 0: C -> bf16 row-major [bg][1024][NB(=1024)], scaled by oscale
// MODE 1: NB=2048; n<1024 -> k[bgh][slot][dh]; n>=1024 -> vT[bgh][dh][slot]
template<int MODE>
__global__ __launch_bounds__(256) void gemm_nt(
    const short* __restrict__ A, const short* __restrict__ Bw,
    short* __restrict__ out, short* __restrict__ kout, short* __restrict__ vout,
    int NB, float oscale)
{
  __shared__ short As[128 * 64];   // [128 rows][64 k] bf16, content XOR-swizzled
  __shared__ short Bs[128 * 64];
  int t = threadIdx.x, lane = t & 63, wid = t >> 6;
  int grp = lane >> 4, l15 = lane & 15;
  int wm = wid >> 1, wn = wid & 1;
  int mbase = blockIdx.x * 128, nbase = blockIdx.y * 128;
  int bg = blockIdx.z, g = bg & 1;
  const short* Ab = A + ((size_t)bg << 20);
  const short* Bp = Bw + ((size_t)g * NB + nbase) * 1024;

  f32x4 zero = {0.f, 0.f, 0.f, 0.f};
  f32x4 acc[4][4];
#pragma unroll
  for (int i = 0; i < 4; ++i)
#pragma unroll
    for (int j = 0; j < 4; ++j) acc[i][j] = zero;

  // staging: 16B unit u = i*256 + t; row = u>>3, j = u&7; source col-unit = j ^ (row&7)
  const short* aps[4]; const short* bps[4];
  short* adst[4]; short* bdst[4];
#pragma unroll
  for (int i = 0; i < 4; ++i) {
    int u = i * 256 + t;
    int row = u >> 3, j = u & 7;
    int cs = ((j ^ (row & 7)) << 3);     // shorts
    aps[i] = Ab + ((size_t)(mbase + row) << 10) + cs;
    bps[i] = Bp + ((size_t)row << 10) + cs;
    adst[i] = As + (i * 256 + wid * 64) * 8;   // wave-uniform base; +lane*16B by HW
    bdst[i] = Bs + (i * 256 + wid * 64) * 8;
  }

  for (int kb = 0; kb < 16; ++kb) {
    __syncthreads();
#pragma unroll
    for (int i = 0; i < 4; ++i) {
      __builtin_amdgcn_global_load_lds(
          (const __attribute__((address_space(1))) void*)aps[i],
          (__attribute__((address_space(3))) void*)adst[i], 16, 0, 0);
      __builtin_amdgcn_global_load_lds(
          (const __attribute__((address_space(1))) void*)bps[i],
          (__attribute__((address_space(3))) void*)bdst[i], 16, 0, 0);
      aps[i] += 64; bps[i] += 64;
    }
    asm volatile("s_waitcnt vmcnt(0)" ::: "memory");
    __syncthreads();
    const char* Ac = (const char*)As;
    const char* Bc = (const char*)Bs;
#pragma unroll
    for (int kf = 0; kf < 2; ++kf) {
      short8 af[4], bf_[4];
#pragma unroll
      for (int mt = 0; mt < 4; ++mt) {
        int ra = wm * 64 + mt * 16 + l15;
        af[mt] = *(const short8*)(Ac + ra * 128 + (((grp << 4) + (kf << 6)) ^ ((ra & 7) << 4)));
      }
#pragma unroll
      for (int nt = 0; nt < 4; ++nt) {
        int rb = wn * 64 + nt * 16 + l15;
        bf_[nt] = *(const short8*)(Bc + rb * 128 + (((grp << 4) + (kf << 6)) ^ ((rb & 7) << 4)));
      }
      __builtin_amdgcn_s_setprio(1);
#pragma unroll
      for (int mt = 0; mt < 4; ++mt)
#pragma unroll
        for (int nt = 0; nt < 4; ++nt)
          acc[mt][nt] = __builtin_amdgcn_mfma_f32_16x16x32_bf16(af[mt], bf_[nt], acc[mt][nt], 0, 0, 0);
      __builtin_amdgcn_s_setprio(0);
    }
  }

  // direct epilogue from C-layout: row=(lane>>4)*4+rr, col=lane&15
#pragma unroll
  for (int mt = 0; mt < 4; ++mt)
#pragma unroll
    for (int nt = 0; nt < 4; ++nt) {
      int n = nbase + wn*64 + nt*16 + l15;
#pragma unroll
      for (int rr = 0; rr < 4; ++rr) {
        int m = mbase + wm*64 + mt*16 + grp*4 + rr;
        float v = acc[mt][nt][rr] * oscale;
        if (MODE == 0) {
          out[((size_t)bg * 1024 + m) * 1024 + n] = f2bf(v);
        } else {
          if (n < 1024) {
            kout[(((size_t)bg * H_ + (n >> 6)) * NSLOT + m) * DH_ + (n & 63)] = f2bf(v);
          } else {
            int e = n - 1024;
            vout[(((size_t)bg * H_ + (e >> 6)) * DH_ + (e & 63)) * NSLOT + m] = f2bf(v);
          }
        }
      }
    }
}

// ---------------- 5) null kv fill (slot 1024) ----------------
__global__ void null_fill(const float* __restrict__ null_kv,
                          short* __restrict__ kb_, short* __restrict__ vb_)
{
  int bgh = blockIdx.x;                 // (b*G+g)*H + h
  int g = (bgh >> 4) & 1, h = bgh & 15;
  int t = threadIdx.x;                  // 0..63
  float kvk = null_kv[((size_t)(0 * G_ + g) * H_ + h) * DH_ + t];
  float kvv = null_kv[((size_t)(1 * G_ + g) * H_ + h) * DH_ + t];
  kb_[((size_t)bgh * NSLOT + 1024) * DH_ + t] = f2bf(kvk);
  vb_[((size_t)bgh * DH_ + t) * NSLOT + 1024] = f2bf(kvv);
}

// ---------------- 6) flash attention, KV-split 2, partial outputs ----------------
// grid (bgh=64, qb=16, sp=2): linear%8 = bgh%8 -> all blocks of a head share one XCD.
// Register-dieted (launch_bounds 256,4 => <=128 unified VGPR+AGPR): ka[4] reused
// across kf halves; defer-max (T13, log2 THR=8); tree reductions; trunc P pack.
__global__ __launch_bounds__(256, 4) void attn_kernel(
    const short* __restrict__ q, const short* __restrict__ k,
    const short* __restrict__ vT, short* __restrict__ o0,
    short* __restrict__ o1, float* __restrict__ ml)
{
  __shared__ short plds_all[4 * 16 * 72];
  int bgh = blockIdx.x, qb = blockIdx.y, sp = blockIdx.z;
  int bg = bgh >> 4, h = bgh & 15;
  int wid = threadIdx.x >> 6, lane = threadIdx.x & 63;
  int l15 = lane & 15, grp = lane >> 4;
  short* prow = plds_all + (wid * 16 + l15) * 72;   // per-wave [16 q][72]
  int qbase = qb * 64 + wid * 16;

  const short* qp = q + ((size_t)bg * 1024 + qbase + l15) * 1024 + h * 64 + (grp << 3);
  short8 bq0 = *(const short8*)qp;
  short8 bq1 = *(const short8*)(qp + 32);
  const short* kp = k + (size_t)bgh * NSLOT * DH_ + (grp << 3);
  const short* vp = vT + (size_t)bgh * DH_ * NSLOT + (grp << 3);

  f32x4 zero = {0.f, 0.f, 0.f, 0.f};
  f32x4 oacc[4];
#pragma unroll
  for (int dt = 0; dt < 4; ++dt) oacc[dt] = zero;
  float m_run = -INFINITY, l_run = 0.f;

  int t0 = sp ? 9 : 0, t1 = sp ? 17 : 9;
  for (int tile = t0; tile < t1; ++tile) {
    int sbase = tile * 64;
    f32x4 sacc[4];
#pragma unroll
    for (int kt = 0; kt < 4; ++kt) sacc[kt] = zero;
    // QK: reuse ka[4] across the two kf halves (register diet)
#pragma unroll
    for (int kf = 0; kf < 2; ++kf) {
      short8 ka[4];
#pragma unroll
      for (int kt = 0; kt < 4; ++kt)
        ka[kt] = *(const short8*)(kp + ((size_t)(sbase + kt * 16 + l15)) * DH_ + kf * 32);
      short8 bqf = kf ? bq1 : bq0;
      __builtin_amdgcn_s_setprio(1);
#pragma unroll
      for (int kt = 0; kt < 4; ++kt)
        sacc[kt] = __builtin_amdgcn_mfma_f32_16x16x32_bf16(ka[kt], bqf, sacc[kt], 0, 0, 0);
      __builtin_amdgcn_s_setprio(0);
    }
    // prefetch V fragments (latency hides under softmax)
    short8 vb[2][4];
#pragma unroll
    for (int ks = 0; ks < 2; ++ks)
#pragma unroll
      for (int dt = 0; dt < 4; ++dt)
        vb[ks][dt] = *(const short8*)(vp + ((size_t)(dt * 16 + l15)) * NSLOT + sbase + ks * 32);

    if (tile == 16) {
#pragma unroll
      for (int kt = 0; kt < 4; ++kt)
#pragma unroll
        for (int rr = 0; rr < 4; ++rr)
          if ((kt * 16 + (grp << 2) + rr) != 0) sacc[kt][rr] = -INFINITY;
    }
    // tree max over 16, then 2 cross-lane steps -> per-q max (lane l15)
    float pm = fmaxf(fmaxf(vmax4(sacc[0]), vmax4(sacc[1])),
                     fmaxf(vmax4(sacc[2]), vmax4(sacc[3])));
    pm = fmaxf(pm, __shfl_xor(pm, 16));
    pm = fmaxf(pm, __shfl_xor(pm, 32));
    bool defer = (__all(pm <= m_run + 8.f) != 0);   // wave-uniform
    float m_new = defer ? m_run : fmaxf(m_run, pm);
#pragma unroll
    for (int kt = 0; kt < 4; ++kt)
#pragma unroll
      for (int rr = 0; rr < 4; ++rr)
        sacc[kt][rr] = exp2f(sacc[kt][rr] - m_new);
    float psum = (vsum4(sacc[0]) + vsum4(sacc[1])) + (vsum4(sacc[2]) + vsum4(sacc[3]));
    psum += __shfl_xor(psum, 16);
    psum += __shfl_xor(psum, 32);
    if (defer) {
      l_run += psum;
    } else {
      float alpha = exp2f(m_run - m_new);
      f32x4 avec;
#pragma unroll
      for (int rr = 0; rr < 4; ++rr) avec[rr] = __shfl(alpha, (grp << 2) + rr);
#pragma unroll
      for (int dt = 0; dt < 4; ++dt) oacc[dt] *= avec;
      l_run = l_run * alpha + psum;
      m_run = m_new;
    }
    // P -> LDS, packed b64 per kt (k = kt*16 + grp*4 + rr), truncating cast
#pragma unroll
    for (int kt = 0; kt < 4; ++kt) {
      short4v pk;
#pragma unroll
      for (int rr = 0; rr < 4; ++rr) pk[rr] = f2bf_trunc(sacc[kt][rr]);
      *(short4v*)(prow + kt * 16 + (grp << 2)) = pk;
    }
    // PV
    __builtin_amdgcn_s_setprio(1);
#pragma unroll
    for (int ks = 0; ks < 2; ++ks) {
      short8 pa = *(const short8*)(prow + (grp << 3) + ks * 32);
#pragma unroll
      for (int dt = 0; dt < 4; ++dt)
        oacc[dt] = __builtin_amdgcn_mfma_f32_16x16x32_bf16(pa, vb[ks][dt], oacc[dt], 0, 0, 0);
    }
    __builtin_amdgcn_s_setprio(0);
  }
  // per-q-row (m,l): lane holds them for q row l15 (replicated over grp)
  if (grp == 0) {
    int idx = ((sp * 64 + bgh) * 16 + qb) * 64 + wid * 16 + l15;
    f32x2 v; v[0] = m_run; v[1] = l_run;
    *(f32x2*)(ml + (size_t)idx * 2) = v;
  }
  // un-normalized partial O store: oacc[dt][rr] = O[q=(grp<<2)+rr][dh=dt*16+l15]
#pragma unroll
  for (int dt = 0; dt < 4; ++dt)
#pragma unroll
    for (int rr = 0; rr < 4; ++rr) {
      int qq = (grp << 2) + rr;
      int dh = dt * 16 + l15;
      if (sp == 0)
        o0[((size_t)bg * 1024 + qbase + qq) * 1024 + h * 64 + dh] = f2bf(oacc[dt][rr]);
      else
        o1[(((size_t)(bgh * 16 + qb)) * 64 + wid * 16 + qq) * 64 + dh] = f2bf(oacc[dt][rr]);
    }
}

// ---------------- 6b) merge the two KV-splits (log2 domain) ----------------
__global__ __launch_bounds__(256) void attn_merge(
    short* __restrict__ obuf, const short* __restrict__ op1,
    const float* __restrict__ ml)
{
  int id = blockIdx.x;                  // bgh*16 + qb
  int bgh = id >> 4, qb = id & 15;
  int bg = bgh >> 4, h = bgh & 15;
  int t = threadIdx.x;
  int qq = t >> 2, c = t & 3;
  int base0 = (id * 64 + qq) * 2;
  int base1 = ((64 * 16 * 64) + id * 64 + qq) * 2;
  float m0 = ml[base0], l0 = ml[base0 + 1];
  float m1 = ml[base1], l1 = ml[base1 + 1];
  float M = fmaxf(m0, m1);
  float w0 = exp2f(m0 - M), w1 = exp2f(m1 - M);
  float linv = 1.0f / (l0 * w0 + l1 * w1);
  w0 *= linv; w1 *= linv;
  size_t loc0 = ((size_t)bg * 1024 + qb * 64 + qq) * 1024 + h * 64 + c * 16;
  size_t loc1 = ((size_t)(id * 64 + qq)) * 64 + c * 16;
  short8 a0 = *(const short8*)(obuf + loc0);
  short8 a1 = *(const short8*)(obuf + loc0 + 8);
  short8 b0 = *(const short8*)(op1 + loc1);
  short8 b1 = *(const short8*)(op1 + loc1 + 8);
  short8 r0, r1;
#pragma unroll
  for (int e = 0; e < 8; ++e) {
    r0[e] = f2bf(bf2f(a0[e]) * w0 + bf2f(b0[e]) * w1);
    r1[e] = f2bf(bf2f(a1[e]) * w0 + bf2f(b1[e]) * w1);
  }
  *(short8*)(obuf + loc0) = r0;
  *(short8*)(obuf + loc0 + 8) = r1;
}

// ---------------- 7) finalize: scatter-average + null_token ----------------
__global__ __launch_bounds__(256) void finalize_kernel(
    const short* __restrict__ wo_out, const int* __restrict__ inv,
    const float* __restrict__ null_token, float* __restrict__ outp)
{
  int id = blockIdx.x;                  // b*N + n
  int b = id >> 12, n = id & (N_ - 1);
  int s0 = inv[((size_t)(b * G_ + 0) << 12) + n];
  int s1 = inv[((size_t)(b * G_ + 1) << 12) + n];
  int t = threadIdx.x;
  float* dst = outp + (size_t)id * D_ + t * 4;
  if (s0 < 0 && s1 < 0) {
    *(f32x4*)dst = *(const f32x4*)(null_token + t * 4);
  } else {
    f32x4 sum = {0.f, 0.f, 0.f, 0.f};
    float cnt = 0.f;
    if (s0 >= 0) {
      short4v v = *(const short4v*)(wo_out + (((size_t)(b * G_ + 0) * 1024 + s0) << 10) + t * 4);
#pragma unroll
      for (int e = 0; e < 4; ++e) sum[e] += bf2f(v[e]);
      cnt += 1.f;
    }
    if (s1 >= 0) {
      short4v v = *(const short4v*)(wo_out + (((size_t)(b * G_ + 1) * 1024 + s1) << 10) + t * 4);
#pragma unroll
      for (int e = 0; e < 4; ++e) sum[e] += bf2f(v[e]);
      cnt += 1.f;
    }
    f32x4 rv;
#pragma unroll
    for (int e = 0; e < 4; ++e) rv[e] = sum[e] / cnt;
    *(f32x4*)dst = rv;
  }
}

// ---------------- launch ----------------
extern "C" void kernel_launch(void* const* d_in, const int* in_sizes, int n_in,
                              void* d_out, int out_size, void* d_ws, size_t ws_size,
                              hipStream_t stream) {
  (void)in_sizes; (void)n_in; (void)out_size; (void)ws_size;
  const float* x        = (const float*)d_in[0];
  const float* rt_q     = (const float*)d_in[1];
  const float* rt_kv    = (const float*)d_in[2];
  const float* gamma_q  = (const float*)d_in[3];
  const float* gamma_c  = (const float*)d_in[4];
  const float* wq       = (const float*)d_in[5];
  const float* wkv      = (const float*)d_in[6];
  const float* wo       = (const float*)d_in[7];
  const float* null_kv  = (const float*)d_in[8];
  const float* null_tok = (const float*)d_in[9];
  float* outp = (float*)d_out;

  char* ws = (char*)d_ws;
  size_t off = 0;
  auto alloc = [&](size_t bytes) { char* p = ws + off; off += (bytes + 255) & ~(size_t)255; return p; };
  float* sim   = (float*)alloc((size_t)2 * B_ * G_ * N_ * 4);
  int*   idx   = (int*)  alloc((size_t)2 * B_ * G_ * 1024 * 4);
  int*   inv   = (int*)  alloc((size_t)B_ * G_ * N_ * 4);
  float* ml    = (float*)alloc((size_t)2 * 64 * 16 * 64 * 2 * 4);   // 1MB (m,l) partials
  short* qn    = (short*)alloc((size_t)B_ * G_ * 1024 * 1024 * 2);
  short* cn    = (short*)alloc((size_t)B_ * G_ * 1024 * 1024 * 2);
  short* qproj = (short*)alloc((size_t)B_ * G_ * 1024 * 1024 * 2);
  size_t kvbytes = (size_t)B_ * G_ * H_ * NSLOT * DH_ * 2;
  short* kbuf  = (short*)alloc(kvbytes);
  short* vbuf  = (short*)alloc(kvbytes);
  short* obuf  = (short*)alloc((size_t)B_ * G_ * 1024 * 1024 * 2);
  short* wobuf = (short*)alloc((size_t)B_ * G_ * 1024 * 1024 * 2);
  // aliases into dead regions (lifetimes verified):
  short* wq_bf  = wobuf;  // dead until final gemm writes wobuf
  short* wkv_bf = obuf;   // consumed by gemm<1> before attn writes obuf
  short* wo_bf  = qn;     // converted after gemm#1 consumed qn
  short* op1    = cn;     // split-1 partial O; cn dead after gemm<1>

  hipMemsetAsync(kbuf, 0, kvbytes, stream);
  hipMemsetAsync(vbuf, 0, kvbytes, stream);
  hipMemsetAsync(inv, 0xFF, (size_t)B_ * G_ * N_ * 4, stream);

  wconv<<<2048, 256, 0, stream>>>(wq, wq_bf, 524288);
  wconv<<<4096, 256, 0, stream>>>(wkv, wkv_bf, 1048576);
  sim_kernel<<<B_ * N_ / 4, 256, 0, stream>>>(x, rt_q, rt_kv, sim);
  coor_topk<<<8, 1024, 0, stream>>>(sim, idx, inv);
  gather_rms<<<2 * B_ * G_ * 1024, 256, 0, stream>>>(x, idx, gamma_q, gamma_c, qn, cn);
  gemm_nt<0><<<dim3(8, 8, B_ * G_), 256, 0, stream>>>(qn, wq_bf, qproj, nullptr, nullptr, 1024, ATTN_SCALE);
  wconv<<<2048, 256, 0, stream>>>(wo, wo_bf, 524288);   // into qn (now dead)
  gemm_nt<1><<<dim3(8, 16, B_ * G_), 256, 0, stream>>>(cn, wkv_bf, nullptr, kbuf, vbuf, 2048, 1.0f);
  null_fill<<<B_ * G_ * H_, 64, 0, stream>>>(null_kv, kbuf, vbuf);
  attn_kernel<<<dim3(64, 16, 2), 256, 0, stream>>>(qproj, kbuf, vbuf, obuf, op1, ml);
  attn_merge<<<1024, 256, 0, stream>>>(obuf, op1, ml);
  gemm_nt<0><<<dim3(8, 8, B_ * G_), 256, 0, stream>>>(obuf, wo_bf, wobuf, nullptr, nullptr, 1024, 1.0f);
  finalize_kernel<<<B_ * N_, 256, 0, stream>>>(wobuf, inv, null_tok, outp);
}

// Round 6
// 217.346 us; speedup vs baseline: 1.6532x; 1.3779x over previous
//
#include <hip/hip_runtime.h>

// ---------------- types / helpers ----------------
typedef __attribute__((ext_vector_type(8))) short short8;   // 8 x bf16 (16B)
typedef __attribute__((ext_vector_type(4))) short short4v;  // 4 x bf16 (8B)
typedef __attribute__((ext_vector_type(4))) float f32x4;
typedef __attribute__((ext_vector_type(2))) float f32x2;

#define B_ 2
#define N_ 4096
#define D_ 1024
#define G_ 2
#define H_ 16
#define DH_ 64
#define NSLOT 1088              // 1024 tokens + 1 null + pad to 17*64
#define LOGK 7.0492548412558374f  // log(1152)
#define ATTN_SCALE 0.18033688011112043f  // dh^-0.5 * log2(e): S in log2 domain

__device__ __forceinline__ float bf2f(short s) {
  return __uint_as_float(((unsigned)(unsigned short)s) << 16);
}
__device__ __forceinline__ short f2bf(float f) {   // RNE
  unsigned u = __float_as_uint(f);
  u = (u + 0x7FFFu + ((u >> 16) & 1u)) >> 16;
  return (short)u;
}
__device__ __forceinline__ short f2bf_trunc(float f) {   // truncation (hot path)
  return (short)(__float_as_uint(f) >> 16);
}
__device__ __forceinline__ float vmax4(f32x4 v) {
  return fmaxf(fmaxf(v[0], v[1]), fmaxf(v[2], v[3]));
}
__device__ __forceinline__ float vsum4(f32x4 v) {
  return (v[0] + v[1]) + (v[2] + v[3]);
}

// ---------------- 0) W f32 -> bf16 pre-convert ----------------
__global__ __launch_bounds__(256) void wconv(
    const float* __restrict__ src, short* __restrict__ dst, int n4)
{
  int i = blockIdx.x * 256 + threadIdx.x;
  if (i >= n4) return;
  f32x4 v = ((const f32x4*)src)[i];
  short4v o;
#pragma unroll
  for (int e = 0; e < 4; ++e) o[e] = f2bf(v[e]);
  ((short4v*)dst)[i] = o;
}

// ---------------- 1) sim = einsum('bnd,gd->bgn') for both routings ----------------
__global__ __launch_bounds__(256) void sim_kernel(
    const float* __restrict__ x, const float* __restrict__ rtq,
    const float* __restrict__ rtkv, float* __restrict__ sim)
{
  int wid = threadIdx.x >> 6, lane = threadIdx.x & 63;
  int row = blockIdx.x * 4 + wid;              // b*N + n
  int b = row >> 12, n = row & (N_ - 1);
  const float* xr = x + (size_t)row * D_;
  float a0 = 0.f, a1 = 0.f, a2 = 0.f, a3 = 0.f;
#pragma unroll
  for (int c = 0; c < 4; ++c) {
    int d = c * 256 + lane * 4;
    f32x4 xv = *(const f32x4*)(xr + d);
    f32x4 r0 = *(const f32x4*)(rtq + d);
    f32x4 r1 = *(const f32x4*)(rtq + D_ + d);
    f32x4 r2 = *(const f32x4*)(rtkv + d);
    f32x4 r3 = *(const f32x4*)(rtkv + D_ + d);
#pragma unroll
    for (int e = 0; e < 4; ++e) {
      a0 += xv[e] * r0[e];
      a1 += xv[e] * r1[e];
      a2 += xv[e] * r2[e];
      a3 += xv[e] * r3[e];
    }
  }
#pragma unroll
  for (int o = 32; o; o >>= 1) {
    a0 += __shfl_xor(a0, o); a1 += __shfl_xor(a1, o);
    a2 += __shfl_xor(a2, o); a3 += __shfl_xor(a3, o);
  }
  if (lane == 0) {
    sim[((size_t)(b)*G_ + 0) * N_ + n] = a0;
    sim[((size_t)(b)*G_ + 1) * N_ + n] = a1;
    sim[((size_t)(B_ + b)*G_ + 0) * N_ + n] = a2;
    sim[((size_t)(B_ + b)*G_ + 1) * N_ + n] = a3;
  }
}

// ---------------- 2) coor_descent + top-k (exact tie semantics) ----------------
__global__ __launch_bounds__(1024) void coor_topk(
    const float* __restrict__ sim, int* __restrict__ idxout, int* __restrict__ inv)
{
  __shared__ float rbuf[16];
  __shared__ float res;
  __shared__ unsigned keys[N_];
  __shared__ int scanbuf[16];

  int r = blockIdx.x >> 2, b = (blockIdx.x >> 1) & 1, g = blockIdx.x & 1;
  const float* srow = sim + ((size_t)blockIdx.x << 12);
  int tid = threadIdx.x, lane = tid & 63, wid = tid >> 6;

  float sv[4];
#pragma unroll
  for (int j = 0; j < 4; ++j) sv[j] = srow[tid * 4 + j];

  float a = 0.f;
  double epsd = 4.0;
  for (int it = 0; it < 20; ++it) {
    float eps = (float)fmax(epsd, 0.03);
    epsd *= 0.7;
    float sb[4]; float lmax = -INFINITY;
#pragma unroll
    for (int j = 0; j < 4; ++j) {
      float bb = (it == 0) ? (-sv[j]) : (-fmaxf(sv[j] + a, 0.f));
      sb[j] = (sv[j] + bb) / eps;
      lmax = fmaxf(lmax, sb[j]);
    }
#pragma unroll
    for (int o = 32; o; o >>= 1) lmax = fmaxf(lmax, __shfl_xor(lmax, o));
    if (lane == 0) rbuf[wid] = lmax;
    __syncthreads();
    if (tid == 0) {
      float m = rbuf[0];
      for (int i = 1; i < 16; ++i) m = fmaxf(m, rbuf[i]);
      res = m;
    }
    __syncthreads();
    float mx = res;
    __syncthreads();
    float lsum = 0.f;
#pragma unroll
    for (int j = 0; j < 4; ++j) lsum += expf(sb[j] - mx);
#pragma unroll
    for (int o = 32; o; o >>= 1) lsum += __shfl_xor(lsum, o);
    if (lane == 0) rbuf[wid] = lsum;
    __syncthreads();
    if (tid == 0) {
      float s = 0.f;
      for (int i = 0; i < 16; ++i) s += rbuf[i];
      res = logf(s) + mx;
    }
    __syncthreads();
    float lse = res;
    __syncthreads();
    a = eps * (LOGK - lse);
  }

  // final scores: exp(min(s+a,0)/0.03); saturated entries are EXACTLY 1.0f
  unsigned kb[4]; int c1 = 0;
#pragma unroll
  for (int j = 0; j < 4; ++j) {
    float sc = expf(fminf(sv[j] + a, 0.f) / 0.03f);
    kb[j] = __float_as_uint(sc);
    keys[tid * 4 + j] = kb[j];
    c1 += (kb[j] == 0x3F800000u);
  }
#pragma unroll
  for (int o = 32; o; o >>= 1) c1 += __shfl_xor(c1, o);
  if (lane == 0) scanbuf[wid] = c1;
  __syncthreads();
  int c1tot = 0;
  for (int i = 0; i < 16; ++i) c1tot += scanbuf[i];
  __syncthreads();

  int flag[4];
  if (c1tot >= 1024) {
#pragma unroll
    for (int j = 0; j < 4; ++j) flag[j] = (kb[j] == 0x3F800000u);
  } else {
#pragma unroll
    for (int j = 0; j < 4; ++j) {
      unsigned kn = kb[j]; int n = tid * 4 + j; int rank = 0;
      for (int m = 0; m < N_; ++m) {
        unsigned km = keys[m];
        rank += (km > kn) || (km == kn && m < n);
      }
      flag[j] = (rank < 1024);
    }
  }

  int cnt = flag[0] + flag[1] + flag[2] + flag[3];
  int inc = cnt;
#pragma unroll
  for (int o = 1; o < 64; o <<= 1) {
    int tt = __shfl_up(inc, o);
    if (lane >= o) inc += tt;
  }
  if (lane == 63) scanbuf[wid] = inc;
  __syncthreads();
  int off = 0;
  for (int w = 0; w < wid; ++w) off += scanbuf[w];
  int pos = off + inc - cnt;
  int* op = idxout + ((size_t)blockIdx.x << 10);
  int* ip = inv + ((size_t)(b * G_ + g) << 12);
#pragma unroll
  for (int j = 0; j < 4; ++j) {
    if (flag[j]) {
      if (pos < 1024) {
        int n = tid * 4 + j;
        op[pos] = n;
        if (r == 0) ip[n] = pos;
      }
      pos++;
    }
  }
}

// ---------------- 3) gather + RMSNorm -> bf16 rows ----------------
__global__ __launch_bounds__(256) void gather_rms(
    const float* __restrict__ x, const int* __restrict__ idx,
    const float* __restrict__ gamma_q, const float* __restrict__ gamma_c,
    short* __restrict__ qn, short* __restrict__ cn)
{
  __shared__ float rb[4];
  __shared__ float tot;
  int id = blockIdx.x;                  // ((r*B+b)*G+g)*1024 + slot
  int r = id >> 12, rem = id & 4095;
  int g = (rem >> 10) & 1;
  int b = rem >> 11;
  int tok = idx[id];
  int t = threadIdx.x;
  const float* xr = x + ((size_t)b * N_ + tok) * D_;
  f32x4 v = *(const f32x4*)(xr + t * 4);
  float ss = v[0]*v[0] + v[1]*v[1] + v[2]*v[2] + v[3]*v[3];
#pragma unroll
  for (int o = 32; o; o >>= 1) ss += __shfl_xor(ss, o);
  if ((t & 63) == 0) rb[t >> 6] = ss;
  __syncthreads();
  if (t == 0) tot = rb[0] + rb[1] + rb[2] + rb[3];
  __syncthreads();
  float scale = 32.0f / fmaxf(sqrtf(tot), 1e-12f);
  const float* gm = (r ? gamma_c : gamma_q) + g * D_;
  f32x4 gv = *(const f32x4*)(gm + t * 4);
  short* dst = (r ? cn : qn) + ((size_t)rem << 10) + t * 4;
  short4v ov;
#pragma unroll
  for (int e = 0; e < 4; ++e) ov[e] = f2bf(v[e] * scale * gv[e]);
  *(short4v*)dst = ov;
}

// ---------------- 4) NT GEMM: C[m,n] = sum_k A[m,k]*W[n,k], both bf16 ----------------
// m97 pattern: global_load_lds(16B) staging, linear LDS dest, inverse-XOR-swizzled
// global SOURCE, XOR-swizzled ds_read_b128 (both-sides involution, rule #21).
// MODE 0: C -> bf16 row-major [bg][1024][NB(=1024)], scaled by oscale
// MODE 1: NB=2048; n<1024 -> k[bgh][slot][dh]; n>=1024 -> vT[bgh][dh][slot]
template<int MODE>
__global__ __launch_bounds__(256) void gemm_nt(
    const short* __restrict__ A, const short* __restrict__ Bw,
    short* __restrict__ out, short* __restrict__ kout, short* __restrict__ vout,
    int NB, float oscale)
{
  __shared__ short As[128 * 64];   // [128 rows][64 k] bf16, content XOR-swizzled
  __shared__ short Bs[128 * 64];
  int t = threadIdx.x, lane = t & 63, wid = t >> 6;
  int grp = lane >> 4, l15 = lane & 15;
  int wm = wid >> 1, wn = wid & 1;
  int mbase = blockIdx.x * 128, nbase = blockIdx.y * 128;
  int bg = blockIdx.z, g = bg & 1;
  const short* Ab = A + ((size_t)bg << 20);
  const short* Bp = Bw + ((size_t)g * NB + nbase) * 1024;

  f32x4 zero = {0.f, 0.f, 0.f, 0.f};
  f32x4 acc[4][4];
#pragma unroll
  for (int i = 0; i < 4; ++i)
#pragma unroll
    for (int j = 0; j < 4; ++j) acc[i][j] = zero;

  // staging: 16B unit u = i*256 + t; row = u>>3, j = u&7; source col-unit = j ^ (row&7)
  const short* aps[4]; const short* bps[4];
  short* adst[4]; short* bdst[4];
#pragma unroll
  for (int i = 0; i < 4; ++i) {
    int u = i * 256 + t;
    int row = u >> 3, j = u & 7;
    int cs = ((j ^ (row & 7)) << 3);     // shorts
    aps[i] = Ab + ((size_t)(mbase + row) << 10) + cs;
    bps[i] = Bp + ((size_t)row << 10) + cs;
    adst[i] = As + (i * 256 + wid * 64) * 8;   // wave-uniform base; +lane*16B by HW
    bdst[i] = Bs + (i * 256 + wid * 64) * 8;
  }

  for (int kb = 0; kb < 16; ++kb) {
    __syncthreads();
#pragma unroll
    for (int i = 0; i < 4; ++i) {
      __builtin_amdgcn_global_load_lds(
          (const __attribute__((address_space(1))) void*)aps[i],
          (__attribute__((address_space(3))) void*)adst[i], 16, 0, 0);
      __builtin_amdgcn_global_load_lds(
          (const __attribute__((address_space(1))) void*)bps[i],
          (__attribute__((address_space(3))) void*)bdst[i], 16, 0, 0);
      aps[i] += 64; bps[i] += 64;
    }
    asm volatile("s_waitcnt vmcnt(0)" ::: "memory");
    __syncthreads();
    const char* Ac = (const char*)As;
    const char* Bc = (const char*)Bs;
#pragma unroll
    for (int kf = 0; kf < 2; ++kf) {
      short8 af[4], bf_[4];
#pragma unroll
      for (int mt = 0; mt < 4; ++mt) {
        int ra = wm * 64 + mt * 16 + l15;
        af[mt] = *(const short8*)(Ac + ra * 128 + (((grp << 4) + (kf << 6)) ^ ((ra & 7) << 4)));
      }
#pragma unroll
      for (int nt = 0; nt < 4; ++nt) {
        int rb = wn * 64 + nt * 16 + l15;
        bf_[nt] = *(const short8*)(Bc + rb * 128 + (((grp << 4) + (kf << 6)) ^ ((rb & 7) << 4)));
      }
      __builtin_amdgcn_s_setprio(1);
#pragma unroll
      for (int mt = 0; mt < 4; ++mt)
#pragma unroll
        for (int nt = 0; nt < 4; ++nt)
          acc[mt][nt] = __builtin_amdgcn_mfma_f32_16x16x32_bf16(af[mt], bf_[nt], acc[mt][nt], 0, 0, 0);
      __builtin_amdgcn_s_setprio(0);
    }
  }

  // direct epilogue from C-layout: row=(lane>>4)*4+rr, col=lane&15
#pragma unroll
  for (int mt = 0; mt < 4; ++mt)
#pragma unroll
    for (int nt = 0; nt < 4; ++nt) {
      int n = nbase + wn*64 + nt*16 + l15;
#pragma unroll
      for (int rr = 0; rr < 4; ++rr) {
        int m = mbase + wm*64 + mt*16 + grp*4 + rr;
        float v = acc[mt][nt][rr] * oscale;
        if (MODE == 0) {
          out[((size_t)bg * 1024 + m) * 1024 + n] = f2bf(v);
        } else {
          if (n < 1024) {
            kout[(((size_t)bg * H_ + (n >> 6)) * NSLOT + m) * DH_ + (n & 63)] = f2bf(v);
          } else {
            int e = n - 1024;
            vout[(((size_t)bg * H_ + (e >> 6)) * DH_ + (e & 63)) * NSLOT + m] = f2bf(v);
          }
        }
      }
    }
}

// ---------------- 5) null kv fill (slot 1024) ----------------
__global__ void null_fill(const float* __restrict__ null_kv,
                          short* __restrict__ kb_, short* __restrict__ vb_)
{
  int bgh = blockIdx.x;                 // (b*G+g)*H + h
  int g = (bgh >> 4) & 1, h = bgh & 15;
  int t = threadIdx.x;                  // 0..63
  float kvk = null_kv[((size_t)(0 * G_ + g) * H_ + h) * DH_ + t];
  float kvv = null_kv[((size_t)(1 * G_ + g) * H_ + h) * DH_ + t];
  kb_[((size_t)bgh * NSLOT + 1024) * DH_ + t] = f2bf(kvk);
  vb_[((size_t)bgh * DH_ + t) * NSLOT + 1024] = f2bf(kvv);
}

// ---------------- 6) flash attention: 32q/wave, LDS-staged K/V, double-buffered ----
// grid (bgh=64, qb=8, sp=2): linear%8 = bgh%8 -> all blocks of a head on one XCD.
// K/V tiles staged once per block via global_load_lds (16B), XOR-involution swizzle
// (rule #21); tile t+1 staged while tile t computes; one vmcnt+barrier per tile.
__global__ __launch_bounds__(256, 3) void attn_kernel(
    const short* __restrict__ q, const short* __restrict__ k,
    const short* __restrict__ vT, short* __restrict__ o0,
    short* __restrict__ o1, float* __restrict__ ml)
{
  __shared__ short Ks[2][4096];        // [64 slot][64 dh] bf16, swizzled
  __shared__ short Vs[2][4096];        // [64 dh][64 slot] bf16, swizzled
  __shared__ short Ps[4][32 * 72];     // per-wave P, padded rows
  int bgh = blockIdx.x, qb = blockIdx.y, sp = blockIdx.z;
  int bg = bgh >> 4, h = bgh & 15;
  int wid = threadIdx.x >> 6, lane = threadIdx.x & 63;
  int l15 = lane & 15, grp = lane >> 4;
  int qbase = qb * 128 + wid * 32;
  short* Pw = &Ps[wid][0];

  // Q fragments: 32 q rows per wave
  short8 bq[2][2];
#pragma unroll
  for (int qh = 0; qh < 2; ++qh) {
    const short* qp = q + ((size_t)bg * 1024 + qbase + qh * 16 + l15) * 1024 + h * 64 + (grp << 3);
    bq[qh][0] = *(const short8*)qp;
    bq[qh][1] = *(const short8*)(qp + 32);
  }

  // staging source pointers (inverse-swizzled)
  int u0 = wid * 128 + lane, u1 = u0 + 64;
  int r0 = u0 >> 3, j0 = u0 & 7, r1 = u1 >> 3, j1 = u1 & 7;
  const short* kbase = k + (size_t)bgh * NSLOT * DH_;
  const short* vbase = vT + (size_t)bgh * DH_ * NSLOT;
  const short* kss0 = kbase + r0 * 64 + ((j0 ^ (r0 & 7)) << 3);
  const short* kss1 = kbase + r1 * 64 + ((j1 ^ (r1 & 7)) << 3);
  const short* vss0 = vbase + (size_t)r0 * NSLOT + ((j0 ^ (r0 & 7)) << 3);
  const short* vss1 = vbase + (size_t)r1 * NSLOT + ((j1 ^ (r1 & 7)) << 3);

  f32x4 zero = {0.f, 0.f, 0.f, 0.f};
  f32x4 oacc[2][4];
#pragma unroll
  for (int qh = 0; qh < 2; ++qh)
#pragma unroll
    for (int dt = 0; dt < 4; ++dt) oacc[qh][dt] = zero;
  float m_run[2] = {-INFINITY, -INFINITY}, l_run[2] = {0.f, 0.f};

  auto STAGE = [&](int tile, int p) {
    size_t ko = (size_t)tile * 4096;       // K: +64 rows = 4096 shorts
    size_t vo = (size_t)tile * 64;         // V: +64 cols
    short* kd = &Ks[p][0] + wid * 1024;    // wave-uniform base; HW adds lane*16B
    short* vd = &Vs[p][0] + wid * 1024;
    __builtin_amdgcn_global_load_lds(
        (const __attribute__((address_space(1))) void*)(kss0 + ko),
        (__attribute__((address_space(3))) void*)kd, 16, 0, 0);
    __builtin_amdgcn_global_load_lds(
        (const __attribute__((address_space(1))) void*)(kss1 + ko),
        (__attribute__((address_space(3))) void*)(kd + 512), 16, 0, 0);
    __builtin_amdgcn_global_load_lds(
        (const __attribute__((address_space(1))) void*)(vss0 + vo),
        (__attribute__((address_space(3))) void*)vd, 16, 0, 0);
    __builtin_amdgcn_global_load_lds(
        (const __attribute__((address_space(1))) void*)(vss1 + vo),
        (__attribute__((address_space(3))) void*)(vd + 512), 16, 0, 0);
  };

  auto PROCESS = [&](int tile, int p) {
    const char* Kc = (const char*)&Ks[p][0];
    const char* Vc = (const char*)&Vs[p][0];
    f32x4 sacc[2][4];
#pragma unroll
    for (int qh = 0; qh < 2; ++qh)
#pragma unroll
      for (int kt = 0; kt < 4; ++kt) sacc[qh][kt] = zero;
    // QK^T
#pragma unroll
    for (int kf = 0; kf < 2; ++kf) {
      short8 ka[4];
#pragma unroll
      for (int kt = 0; kt < 4; ++kt) {
        int ra = kt * 16 + l15;
        ka[kt] = *(const short8*)(Kc + ra * 128 + (((grp + 4 * kf) ^ (ra & 7)) << 4));
      }
      __builtin_amdgcn_s_setprio(1);
#pragma unroll
      for (int kt = 0; kt < 4; ++kt)
#pragma unroll
        for (int qh = 0; qh < 2; ++qh)
          sacc[qh][kt] = __builtin_amdgcn_mfma_f32_16x16x32_bf16(ka[kt], bq[qh][kf], sacc[qh][kt], 0, 0, 0);
      __builtin_amdgcn_s_setprio(0);
    }
    if (tile == 16) {
#pragma unroll
      for (int qh = 0; qh < 2; ++qh)
#pragma unroll
        for (int kt = 0; kt < 4; ++kt)
#pragma unroll
          for (int rr = 0; rr < 4; ++rr)
            if ((kt * 16 + (grp << 2) + rr) != 0) sacc[qh][kt][rr] = -INFINITY;
    }
    // softmax (log2 domain), defer-max
    float pm[2], mnew[2];
#pragma unroll
    for (int qh = 0; qh < 2; ++qh) {
      float v = fmaxf(fmaxf(vmax4(sacc[qh][0]), vmax4(sacc[qh][1])),
                      fmaxf(vmax4(sacc[qh][2]), vmax4(sacc[qh][3])));
      v = fmaxf(v, __shfl_xor(v, 16));
      v = fmaxf(v, __shfl_xor(v, 32));
      pm[qh] = v;
    }
    bool defer = (__all((pm[0] <= m_run[0] + 8.f) && (pm[1] <= m_run[1] + 8.f)) != 0);
    mnew[0] = defer ? m_run[0] : fmaxf(m_run[0], pm[0]);
    mnew[1] = defer ? m_run[1] : fmaxf(m_run[1], pm[1]);
#pragma unroll
    for (int qh = 0; qh < 2; ++qh) {
#pragma unroll
      for (int kt = 0; kt < 4; ++kt)
#pragma unroll
        for (int rr = 0; rr < 4; ++rr)
          sacc[qh][kt][rr] = exp2f(sacc[qh][kt][rr] - mnew[qh]);
      float ps = (vsum4(sacc[qh][0]) + vsum4(sacc[qh][1])) + (vsum4(sacc[qh][2]) + vsum4(sacc[qh][3]));
      ps += __shfl_xor(ps, 16);
      ps += __shfl_xor(ps, 32);
      if (defer) {
        l_run[qh] += ps;
      } else {
        float alpha = exp2f(m_run[qh] - mnew[qh]);
        f32x4 avec;
#pragma unroll
        for (int rr = 0; rr < 4; ++rr) avec[rr] = __shfl(alpha, (grp << 2) + rr);
#pragma unroll
        for (int dt = 0; dt < 4; ++dt) oacc[qh][dt] *= avec;
        l_run[qh] = l_run[qh] * alpha + ps;
        m_run[qh] = mnew[qh];
      }
      // P -> LDS (per-wave region, no barrier needed)
#pragma unroll
      for (int kt = 0; kt < 4; ++kt) {
        short4v pk;
#pragma unroll
        for (int rr = 0; rr < 4; ++rr) pk[rr] = f2bf_trunc(sacc[qh][kt][rr]);
        *(short4v*)(Pw + (qh * 16 + l15) * 72 + kt * 16 + (grp << 2)) = pk;
      }
    }
    // PV
#pragma unroll
    for (int ks = 0; ks < 2; ++ks) {
      short8 pa[2];
#pragma unroll
      for (int qh = 0; qh < 2; ++qh)
        pa[qh] = *(const short8*)((const char*)Pw + (qh * 16 + l15) * 144 + grp * 16 + ks * 64);
      __builtin_amdgcn_s_setprio(1);
#pragma unroll
      for (int dt = 0; dt < 4; ++dt) {
        int ra = dt * 16 + l15;
        short8 vbf = *(const short8*)(Vc + ra * 128 + (((grp + 4 * ks) ^ (ra & 7)) << 4));
#pragma unroll
        for (int qh = 0; qh < 2; ++qh)
          oacc[qh][dt] = __builtin_amdgcn_mfma_f32_16x16x32_bf16(pa[qh], vbf, oacc[qh][dt], 0, 0, 0);
      }
      __builtin_amdgcn_s_setprio(0);
    }
  };

  int t0 = sp ? 8 : 0, t1 = sp ? 17 : 8;
  STAGE(t0, 0);
  asm volatile("s_waitcnt vmcnt(0)" ::: "memory");
  __syncthreads();
  int tile = t0, p = 0;
  while (true) {
    if (tile + 1 < t1) STAGE(tile + 1, p ^ 1);
    PROCESS(tile, p);
    if (++tile == t1) break;
    asm volatile("s_waitcnt vmcnt(0)" ::: "memory");
    __syncthreads();
    p ^= 1;
  }

  // per-q-row (m,l): ml[sp][bgh][qrow]
  if (grp == 0) {
#pragma unroll
    for (int qh = 0; qh < 2; ++qh) {
      int idx = (sp * 64 + bgh) * 1024 + qbase + qh * 16 + l15;
      f32x2 v; v[0] = m_run[qh]; v[1] = l_run[qh];
      *(f32x2*)(ml + (size_t)idx * 2) = v;
    }
  }
  // un-normalized partial O: oacc[qh][dt][rr] = O[q=qh*16+(grp<<2)+rr][dh=dt*16+l15]
#pragma unroll
  for (int qh = 0; qh < 2; ++qh)
#pragma unroll
    for (int dt = 0; dt < 4; ++dt)
#pragma unroll
      for (int rr = 0; rr < 4; ++rr) {
        int qq = qh * 16 + (grp << 2) + rr;
        int dh = dt * 16 + l15;
        if (sp == 0)
          o0[((size_t)bg * 1024 + qbase + qq) * 1024 + h * 64 + dh] = f2bf(oacc[qh][dt][rr]);
        else
          o1[((size_t)bgh * 1024 + qbase + qq) * 64 + dh] = f2bf(oacc[qh][dt][rr]);
      }
}

// ---------------- 6b) merge the two KV-splits (log2 domain) ----------------
__global__ __launch_bounds__(256) void attn_merge(
    short* __restrict__ obuf, const short* __restrict__ op1,
    const float* __restrict__ ml)
{
  int id = blockIdx.x;                  // bgh*16 + qc (64-row chunk)
  int bgh = id >> 4, qc = id & 15;
  int bg = bgh >> 4, h = bgh & 15;
  int t = threadIdx.x;
  int qq = t >> 2, c = t & 3;
  int qrow = qc * 64 + qq;
  int base0 = ((0 * 64 + bgh) * 1024 + qrow) * 2;
  int base1 = ((1 * 64 + bgh) * 1024 + qrow) * 2;
  float m0 = ml[base0], l0 = ml[base0 + 1];
  float m1 = ml[base1], l1 = ml[base1 + 1];
  float M = fmaxf(m0, m1);
  float w0 = exp2f(m0 - M), w1 = exp2f(m1 - M);
  float linv = 1.0f / (l0 * w0 + l1 * w1);
  w0 *= linv; w1 *= linv;
  size_t loc0 = ((size_t)bg * 1024 + qrow) * 1024 + h * 64 + c * 16;
  size_t loc1 = ((size_t)bgh * 1024 + qrow) * 64 + c * 16;
  short8 a0 = *(const short8*)(obuf + loc0);
  short8 a1 = *(const short8*)(obuf + loc0 + 8);
  short8 b0 = *(const short8*)(op1 + loc1);
  short8 b1 = *(const short8*)(op1 + loc1 + 8);
  short8 r0, r1;
#pragma unroll
  for (int e = 0; e < 8; ++e) {
    r0[e] = f2bf(bf2f(a0[e]) * w0 + bf2f(b0[e]) * w1);
    r1[e] = f2bf(bf2f(a1[e]) * w0 + bf2f(b1[e]) * w1);
  }
  *(short8*)(obuf + loc0) = r0;
  *(short8*)(obuf + loc0 + 8) = r1;
}

// ---------------- 7) finalize: scatter-average + null_token ----------------
__global__ __launch_bounds__(256) void finalize_kernel(
    const short* __restrict__ wo_out, const int* __restrict__ inv,
    const float* __restrict__ null_token, float* __restrict__ outp)
{
  int id = blockIdx.x;                  // b*N + n
  int b = id >> 12, n = id & (N_ - 1);
  int s0 = inv[((size_t)(b * G_ + 0) << 12) + n];
  int s1 = inv[((size_t)(b * G_ + 1) << 12) + n];
  int t = threadIdx.x;
  float* dst = outp + (size_t)id * D_ + t * 4;
  if (s0 < 0 && s1 < 0) {
    *(f32x4*)dst = *(const f32x4*)(null_token + t * 4);
  } else {
    f32x4 sum = {0.f, 0.f, 0.f, 0.f};
    float cnt = 0.f;
    if (s0 >= 0) {
      short4v v = *(const short4v*)(wo_out + (((size_t)(b * G_ + 0) * 1024 + s0) << 10) + t * 4);
#pragma unroll
      for (int e = 0; e < 4; ++e) sum[e] += bf2f(v[e]);
      cnt += 1.f;
    }
    if (s1 >= 0) {
      short4v v = *(const short4v*)(wo_out + (((size_t)(b * G_ + 1) * 1024 + s1) << 10) + t * 4);
#pragma unroll
      for (int e = 0; e < 4; ++e) sum[e] += bf2f(v[e]);
      cnt += 1.f;
    }
    f32x4 rv;
#pragma unroll
    for (int e = 0; e < 4; ++e) rv[e] = sum[e] / cnt;
    *(f32x4*)dst = rv;
  }
}

// ---------------- launch ----------------
extern "C" void kernel_launch(void* const* d_in, const int* in_sizes, int n_in,
                              void* d_out, int out_size, void* d_ws, size_t ws_size,
                              hipStream_t stream) {
  (void)in_sizes; (void)n_in; (void)out_size; (void)ws_size;
  const float* x        = (const float*)d_in[0];
  const float* rt_q     = (const float*)d_in[1];
  const float* rt_kv    = (const float*)d_in[2];
  const float* gamma_q  = (const float*)d_in[3];
  const float* gamma_c  = (const float*)d_in[4];
  const float* wq       = (const float*)d_in[5];
  const float* wkv      = (const float*)d_in[6];
  const float* wo       = (const float*)d_in[7];
  const float* null_kv  = (const float*)d_in[8];
  const float* null_tok = (const float*)d_in[9];
  float* outp = (float*)d_out;

  char* ws = (char*)d_ws;
  size_t off = 0;
  auto alloc = [&](size_t bytes) { char* p = ws + off; off += (bytes + 255) & ~(size_t)255; return p; };
  float* sim   = (float*)alloc((size_t)2 * B_ * G_ * N_ * 4);
  int*   idx   = (int*)  alloc((size_t)2 * B_ * G_ * 1024 * 4);
  int*   inv   = (int*)  alloc((size_t)B_ * G_ * N_ * 4);
  float* ml    = (float*)alloc((size_t)2 * 64 * 1024 * 2 * 4);   // 1MB (m,l) partials
  short* qn    = (short*)alloc((size_t)B_ * G_ * 1024 * 1024 * 2);
  short* cn    = (short*)alloc((size_t)B_ * G_ * 1024 * 1024 * 2);
  short* qproj = (short*)alloc((size_t)B_ * G_ * 1024 * 1024 * 2);
  size_t kvbytes = (size_t)B_ * G_ * H_ * NSLOT * DH_ * 2;
  short* kbuf  = (short*)alloc(kvbytes);
  short* vbuf  = (short*)alloc(kvbytes);
  short* obuf  = (short*)alloc((size_t)B_ * G_ * 1024 * 1024 * 2);
  short* wobuf = (short*)alloc((size_t)B_ * G_ * 1024 * 1024 * 2);
  // aliases into dead regions (lifetimes verified):
  short* wq_bf  = wobuf;  // dead until final gemm writes wobuf
  short* wkv_bf = obuf;   // consumed by gemm<1> before attn writes obuf
  short* wo_bf  = qn;     // converted after gemm#1 consumed qn
  short* op1    = cn;     // split-1 partial O; cn dead after gemm<1>

  hipMemsetAsync(kbuf, 0, kvbytes, stream);
  hipMemsetAsync(vbuf, 0, kvbytes, stream);
  hipMemsetAsync(inv, 0xFF, (size_t)B_ * G_ * N_ * 4, stream);

  wconv<<<2048, 256, 0, stream>>>(wq, wq_bf, 524288);
  wconv<<<4096, 256, 0, stream>>>(wkv, wkv_bf, 1048576);
  sim_kernel<<<B_ * N_ / 4, 256, 0, stream>>>(x, rt_q, rt_kv, sim);
  coor_topk<<<8, 1024, 0, stream>>>(sim, idx, inv);
  gather_rms<<<2 * B_ * G_ * 1024, 256, 0, stream>>>(x, idx, gamma_q, gamma_c, qn, cn);
  gemm_nt<0><<<dim3(8, 8, B_ * G_), 256, 0, stream>>>(qn, wq_bf, qproj, nullptr, nullptr, 1024, ATTN_SCALE);
  wconv<<<2048, 256, 0, stream>>>(wo, wo_bf, 524288);   // into qn (now dead)
  gemm_nt<1><<<dim3(8, 16, B_ * G_), 256, 0, stream>>>(cn, wkv_bf, nullptr, kbuf, vbuf, 2048, 1.0f);
  null_fill<<<B_ * G_ * H_, 64, 0, stream>>>(null_kv, kbuf, vbuf);
  attn_kernel<<<dim3(64, 8, 2), 256, 0, stream>>>(qproj, kbuf, vbuf, obuf, op1, ml);
  attn_merge<<<1024, 256, 0, stream>>>(obuf, op1, ml);
  gemm_nt<0><<<dim3(8, 8, B_ * G_), 256, 0, stream>>>(obuf, wo_bf, wobuf, nullptr, nullptr, 1024, 1.0f);
  finalize_kernel<<<B_ * N_, 256, 0, stream>>>(wobuf, inv, null_tok, outp);
}

// Round 7
// 203.565 us; speedup vs baseline: 1.7651x; 1.0677x over previous
//
#include <hip/hip_runtime.h>

// ---------------- types / helpers ----------------
typedef __attribute__((ext_vector_type(8))) short short8;   // 8 x bf16 (16B)
typedef __attribute__((ext_vector_type(4))) short short4v;  // 4 x bf16 (8B)
typedef __attribute__((ext_vector_type(4))) float f32x4;
typedef __attribute__((ext_vector_type(2))) float f32x2;

#define B_ 2
#define N_ 4096
#define D_ 1024
#define G_ 2
#define H_ 16
#define DH_ 64
#define NSLOT 1088              // 1024 tokens + 1 null + pad to 17*64
#define LOGK 7.0492548412558374f  // log(1152)
#define ATTN_SCALE 0.18033688011112043f  // dh^-0.5 * log2(e): S in log2 domain

__device__ __forceinline__ float bf2f(short s) {
  return __uint_as_float(((unsigned)(unsigned short)s) << 16);
}
__device__ __forceinline__ short f2bf(float f) {   // RNE
  unsigned u = __float_as_uint(f);
  u = (u + 0x7FFFu + ((u >> 16) & 1u)) >> 16;
  return (short)u;
}
__device__ __forceinline__ short f2bf_trunc(float f) {   // truncation (hot path)
  return (short)(__float_as_uint(f) >> 16);
}
__device__ __forceinline__ float vmax4(f32x4 v) {
  return fmaxf(fmaxf(v[0], v[1]), fmaxf(v[2], v[3]));
}
__device__ __forceinline__ float vsum4(f32x4 v) {
  return (v[0] + v[1]) + (v[2] + v[3]);
}

// ---------------- 0) all W f32 -> bf16 in one launch ----------------
__global__ __launch_bounds__(256) void wconv3(
    const float* __restrict__ wq, const float* __restrict__ wkv,
    const float* __restrict__ wo, short* __restrict__ dq,
    short* __restrict__ dkv, short* __restrict__ dwo)
{
  int i = blockIdx.x * 256 + threadIdx.x;   // f32x4 unit; total 2M units
  const float* src; short* dst;
  if (i < 524288) { src = wq; dst = dq; }
  else if (i < 1572864) { src = wkv; dst = dkv; i -= 524288; }
  else { src = wo; dst = dwo; i -= 1572864; }
  f32x4 v = ((const f32x4*)src)[i];
  short4v o;
#pragma unroll
  for (int e = 0; e < 4; ++e) o[e] = f2bf(v[e]);
  ((short4v*)dst)[i] = o;
}

// ---------------- 1) sim = einsum('bnd,gd->bgn') for both routings ----------------
__global__ __launch_bounds__(256) void sim_kernel(
    const float* __restrict__ x, const float* __restrict__ rtq,
    const float* __restrict__ rtkv, float* __restrict__ sim)
{
  int wid = threadIdx.x >> 6, lane = threadIdx.x & 63;
  int row = blockIdx.x * 4 + wid;              // b*N + n
  int b = row >> 12, n = row & (N_ - 1);
  const float* xr = x + (size_t)row * D_;
  float a0 = 0.f, a1 = 0.f, a2 = 0.f, a3 = 0.f;
#pragma unroll
  for (int c = 0; c < 4; ++c) {
    int d = c * 256 + lane * 4;
    f32x4 xv = *(const f32x4*)(xr + d);
    f32x4 r0 = *(const f32x4*)(rtq + d);
    f32x4 r1 = *(const f32x4*)(rtq + D_ + d);
    f32x4 r2 = *(const f32x4*)(rtkv + d);
    f32x4 r3 = *(const f32x4*)(rtkv + D_ + d);
#pragma unroll
    for (int e = 0; e < 4; ++e) {
      a0 += xv[e] * r0[e];
      a1 += xv[e] * r1[e];
      a2 += xv[e] * r2[e];
      a3 += xv[e] * r3[e];
    }
  }
#pragma unroll
  for (int o = 32; o; o >>= 1) {
    a0 += __shfl_xor(a0, o); a1 += __shfl_xor(a1, o);
    a2 += __shfl_xor(a2, o); a3 += __shfl_xor(a3, o);
  }
  if (lane == 0) {
    sim[((size_t)(b)*G_ + 0) * N_ + n] = a0;
    sim[((size_t)(b)*G_ + 1) * N_ + n] = a1;
    sim[((size_t)(B_ + b)*G_ + 0) * N_ + n] = a2;
    sim[((size_t)(B_ + b)*G_ + 1) * N_ + n] = a3;
  }
}

// ---------------- 2) coor_descent + top-k (exact tie semantics) ----------------
// wave-parallel block reductions (16-lane shfl) instead of serial tid==0 loops.
__global__ __launch_bounds__(1024) void coor_topk(
    const float* __restrict__ sim, int* __restrict__ idxout, int* __restrict__ inv)
{
  __shared__ float rbuf[16];
  __shared__ float res;
  __shared__ unsigned keys[N_];
  __shared__ int scanbuf[16];

  int r = blockIdx.x >> 2, b = (blockIdx.x >> 1) & 1, g = blockIdx.x & 1;
  const float* srow = sim + ((size_t)blockIdx.x << 12);
  int tid = threadIdx.x, lane = tid & 63, wid = tid >> 6;

  float sv[4];
#pragma unroll
  for (int j = 0; j < 4; ++j) sv[j] = srow[tid * 4 + j];

  float a = 0.f;
  double epsd = 4.0;
  for (int it = 0; it < 20; ++it) {
    float eps = (float)fmax(epsd, 0.03);
    epsd *= 0.7;
    float sb[4]; float lmax = -INFINITY;
#pragma unroll
    for (int j = 0; j < 4; ++j) {
      float bb = (it == 0) ? (-sv[j]) : (-fmaxf(sv[j] + a, 0.f));
      sb[j] = (sv[j] + bb) / eps;
      lmax = fmaxf(lmax, sb[j]);
    }
#pragma unroll
    for (int o = 32; o; o >>= 1) lmax = fmaxf(lmax, __shfl_xor(lmax, o));
    if (lane == 0) rbuf[wid] = lmax;
    __syncthreads();
    if (tid < 64) {
      float m = (tid < 16) ? rbuf[tid] : -INFINITY;
#pragma unroll
      for (int o = 8; o; o >>= 1) m = fmaxf(m, __shfl_xor(m, o));
      if (tid == 0) res = m;
    }
    __syncthreads();
    float mx = res;
    float lsum = 0.f;
#pragma unroll
    for (int j = 0; j < 4; ++j) lsum += expf(sb[j] - mx);
#pragma unroll
    for (int o = 32; o; o >>= 1) lsum += __shfl_xor(lsum, o);
    if (lane == 0) rbuf[wid] = lsum;
    __syncthreads();
    if (tid < 64) {
      float s = (tid < 16) ? rbuf[tid] : 0.f;
#pragma unroll
      for (int o = 8; o; o >>= 1) s += __shfl_xor(s, o);
      if (tid == 0) res = logf(s) + mx;
    }
    __syncthreads();
    float lse = res;
    a = eps * (LOGK - lse);
  }
  __syncthreads();

  // final scores: exp(min(s+a,0)/0.03); saturated entries are EXACTLY 1.0f
  unsigned kb[4]; int c1 = 0;
#pragma unroll
  for (int j = 0; j < 4; ++j) {
    float sc = expf(fminf(sv[j] + a, 0.f) / 0.03f);
    kb[j] = __float_as_uint(sc);
    keys[tid * 4 + j] = kb[j];
    c1 += (kb[j] == 0x3F800000u);
  }
#pragma unroll
  for (int o = 32; o; o >>= 1) c1 += __shfl_xor(c1, o);
  if (lane == 0) scanbuf[wid] = c1;
  __syncthreads();
  int c1tot = 0;
  for (int i = 0; i < 16; ++i) c1tot += scanbuf[i];
  __syncthreads();

  int flag[4];
  if (c1tot >= 1024) {
#pragma unroll
    for (int j = 0; j < 4; ++j) flag[j] = (kb[j] == 0x3F800000u);
  } else {
#pragma unroll
    for (int j = 0; j < 4; ++j) {
      unsigned kn = kb[j]; int n = tid * 4 + j; int rank = 0;
      for (int m = 0; m < N_; ++m) {
        unsigned km = keys[m];
        rank += (km > kn) || (km == kn && m < n);
      }
      flag[j] = (rank < 1024);
    }
  }

  int cnt = flag[0] + flag[1] + flag[2] + flag[3];
  int inc = cnt;
#pragma unroll
  for (int o = 1; o < 64; o <<= 1) {
    int tt = __shfl_up(inc, o);
    if (lane >= o) inc += tt;
  }
  if (lane == 63) scanbuf[wid] = inc;
  __syncthreads();
  int off = 0;
  for (int w = 0; w < wid; ++w) off += scanbuf[w];
  int pos = off + inc - cnt;
  int* op = idxout + ((size_t)blockIdx.x << 10);
  int* ip = inv + ((size_t)(b * G_ + g) << 12);
#pragma unroll
  for (int j = 0; j < 4; ++j) {
    if (flag[j]) {
      if (pos < 1024) {
        int n = tid * 4 + j;
        op[pos] = n;
        if (r == 0) ip[n] = pos;
      }
      pos++;
    }
  }
}

// ---------------- 3) gather + RMSNorm -> bf16 rows ----------------
__global__ __launch_bounds__(256) void gather_rms(
    const float* __restrict__ x, const int* __restrict__ idx,
    const float* __restrict__ gamma_q, const float* __restrict__ gamma_c,
    short* __restrict__ qn, short* __restrict__ cn)
{
  __shared__ float rb[4];
  __shared__ float tot;
  int id = blockIdx.x;                  // ((r*B+b)*G+g)*1024 + slot
  int r = id >> 12, rem = id & 4095;
  int g = (rem >> 10) & 1;
  int b = rem >> 11;
  int tok = idx[id];
  int t = threadIdx.x;
  const float* xr = x + ((size_t)b * N_ + tok) * D_;
  f32x4 v = *(const f32x4*)(xr + t * 4);
  float ss = v[0]*v[0] + v[1]*v[1] + v[2]*v[2] + v[3]*v[3];
#pragma unroll
  for (int o = 32; o; o >>= 1) ss += __shfl_xor(ss, o);
  if ((t & 63) == 0) rb[t >> 6] = ss;
  __syncthreads();
  if (t == 0) tot = rb[0] + rb[1] + rb[2] + rb[3];
  __syncthreads();
  float scale = 32.0f / fmaxf(sqrtf(tot), 1e-12f);
  const float* gm = (r ? gamma_c : gamma_q) + g * D_;
  f32x4 gv = *(const f32x4*)(gm + t * 4);
  short* dst = (r ? cn : qn) + ((size_t)rem << 10) + t * 4;
  short4v ov;
#pragma unroll
  for (int e = 0; e < 4; ++e) ov[e] = f2bf(v[e] * scale * gv[e]);
  *(short4v*)dst = ov;
}

// ---------------- 4) NT GEMM: C[m,n] = sum_k A[m,k]*W[n,k], both bf16 ----------------
// 512 threads (8 waves, wave = 32x64, acc[2][4]); double-buffered LDS; 2-phase
// pipeline: STAGE(next) -> compute(cur) -> vmcnt(0)+barrier. Involution swizzle
// (rule #21): linear LDS dest + inverse-XOR global source + XOR ds_read.
// MODE 0: C -> bf16 row-major [bg][1024][NB(=1024)], scaled by oscale
// MODE 1: NB=2048; n<1024 -> k[bgh][slot][dh]; n>=1024 -> vT[bgh][dh][slot]
template<int MODE>
__global__ __launch_bounds__(512, 4) void gemm_nt(
    const short* __restrict__ A, const short* __restrict__ Bw,
    short* __restrict__ out, short* __restrict__ kout, short* __restrict__ vout,
    int NB, float oscale)
{
  __shared__ short As[2][8192];   // [buf][128 rows][64 k] bf16, content XOR-swizzled
  __shared__ short Bs[2][8192];
  int t = threadIdx.x, lane = t & 63, wid = t >> 6;
  int grp = lane >> 4, l15 = lane & 15;
  int wm = wid >> 1, wn = wid & 1;               // wave: rows [wm*32,+32), cols [wn*64,+64)
  int mbase = blockIdx.x * 128, nbase = blockIdx.y * 128;
  int bg = blockIdx.z, g = bg & 1;
  const short* Ab = A + ((size_t)bg << 20);
  const short* Bp = Bw + ((size_t)g * NB + nbase) * 1024;

  f32x4 zero = {0.f, 0.f, 0.f, 0.f};
  f32x4 acc[2][4];
#pragma unroll
  for (int i = 0; i < 2; ++i)
#pragma unroll
    for (int j = 0; j < 4; ++j) acc[i][j] = zero;

  // staging: 1024 16B-units per matrix; thread t handles units u1=t, u2=t+512.
  int u1 = t, u2 = t + 512;
  int r1 = u1 >> 3, j1 = u1 & 7, r2 = u2 >> 3, j2 = u2 & 7;
  const short* apA1 = Ab + ((size_t)(mbase + r1) << 10) + ((j1 ^ (r1 & 7)) << 3);
  const short* apA2 = Ab + ((size_t)(mbase + r2) << 10) + ((j2 ^ (r2 & 7)) << 3);
  const short* apB1 = Bp + ((size_t)r1 << 10) + ((j1 ^ (r1 & 7)) << 3);
  const short* apB2 = Bp + ((size_t)r2 << 10) + ((j2 ^ (r2 & 7)) << 3);
  int d1 = wid * 512, d2 = 4096 + wid * 512;   // wave-uniform LDS short-offsets

  auto STAGE = [&](int kb, int p) {
    int ko = kb * 64;
    __builtin_amdgcn_global_load_lds(
        (const __attribute__((address_space(1))) void*)(apA1 + ko),
        (__attribute__((address_space(3))) void*)(&As[p][0] + d1), 16, 0, 0);
    __builtin_amdgcn_global_load_lds(
        (const __attribute__((address_space(1))) void*)(apA2 + ko),
        (__attribute__((address_space(3))) void*)(&As[p][0] + d2), 16, 0, 0);
    __builtin_amdgcn_global_load_lds(
        (const __attribute__((address_space(1))) void*)(apB1 + ko),
        (__attribute__((address_space(3))) void*)(&Bs[p][0] + d1), 16, 0, 0);
    __builtin_amdgcn_global_load_lds(
        (const __attribute__((address_space(1))) void*)(apB2 + ko),
        (__attribute__((address_space(3))) void*)(&Bs[p][0] + d2), 16, 0, 0);
  };

  STAGE(0, 0);
  asm volatile("s_waitcnt vmcnt(0)" ::: "memory");
  __syncthreads();

  for (int kb = 0; kb < 16; ++kb) {
    int p = kb & 1;
    if (kb + 1 < 16) STAGE(kb + 1, p ^ 1);
    const char* Ac = (const char*)&As[p][0];
    const char* Bc = (const char*)&Bs[p][0];
#pragma unroll
    for (int kf = 0; kf < 2; ++kf) {
      short8 af[2], bf_[4];
#pragma unroll
      for (int mt = 0; mt < 2; ++mt) {
        int ra = wm * 32 + mt * 16 + l15;
        af[mt] = *(const short8*)(Ac + ra * 128 + (((grp << 4) + (kf << 6)) ^ ((ra & 7) << 4)));
      }
#pragma unroll
      for (int nt = 0; nt < 4; ++nt) {
        int rb = wn * 64 + nt * 16 + l15;
        bf_[nt] = *(const short8*)(Bc + rb * 128 + (((grp << 4) + (kf << 6)) ^ ((rb & 7) << 4)));
      }
      __builtin_amdgcn_s_setprio(1);
#pragma unroll
      for (int mt = 0; mt < 2; ++mt)
#pragma unroll
        for (int nt = 0; nt < 4; ++nt)
          acc[mt][nt] = __builtin_amdgcn_mfma_f32_16x16x32_bf16(af[mt], bf_[nt], acc[mt][nt], 0, 0, 0);
      __builtin_amdgcn_s_setprio(0);
    }
    if (kb + 1 < 16) {
      asm volatile("s_waitcnt vmcnt(0)" ::: "memory");
      __syncthreads();
    }
  }

  // direct epilogue from C-layout: row=(lane>>4)*4+rr, col=lane&15
#pragma unroll
  for (int mt = 0; mt < 2; ++mt)
#pragma unroll
    for (int nt = 0; nt < 4; ++nt) {
      int n = nbase + wn*64 + nt*16 + l15;
#pragma unroll
      for (int rr = 0; rr < 4; ++rr) {
        int m = mbase + wm*32 + mt*16 + grp*4 + rr;
        float v = acc[mt][nt][rr] * oscale;
        if (MODE == 0) {
          out[((size_t)bg * 1024 + m) * 1024 + n] = f2bf(v);
        } else {
          if (n < 1024) {
            kout[(((size_t)bg * H_ + (n >> 6)) * NSLOT + m) * DH_ + (n & 63)] = f2bf(v);
          } else {
            int e = n - 1024;
            vout[(((size_t)bg * H_ + (e >> 6)) * DH_ + (e & 63)) * NSLOT + m] = f2bf(v);
          }
        }
      }
    }
}

// ---------------- 5) null kv fill (slot 1024) ----------------
__global__ void null_fill(const float* __restrict__ null_kv,
                          short* __restrict__ kb_, short* __restrict__ vb_)
{
  int bgh = blockIdx.x;                 // (b*G+g)*H + h
  int g = (bgh >> 4) & 1, h = bgh & 15;
  int t = threadIdx.x;                  // 0..63
  float kvk = null_kv[((size_t)(0 * G_ + g) * H_ + h) * DH_ + t];
  float kvv = null_kv[((size_t)(1 * G_ + g) * H_ + h) * DH_ + t];
  kb_[((size_t)bgh * NSLOT + 1024) * DH_ + t] = f2bf(kvk);
  vb_[((size_t)bgh * DH_ + t) * NSLOT + 1024] = f2bf(kvv);
}

// ---------------- 6) flash attention: 32q/wave, LDS-staged K/V, double-buffered ----
// grid (bgh=64, qb=8, sp=2): linear%8 = bgh%8 -> all blocks of a head on one XCD.
__global__ __launch_bounds__(256, 3) void attn_kernel(
    const short* __restrict__ q, const short* __restrict__ k,
    const short* __restrict__ vT, short* __restrict__ o0,
    short* __restrict__ o1, float* __restrict__ ml)
{
  __shared__ short Ks[2][4096];        // [64 slot][64 dh] bf16, swizzled
  __shared__ short Vs[2][4096];        // [64 dh][64 slot] bf16, swizzled
  __shared__ short Ps[4][32 * 72];     // per-wave P, padded rows
  int bgh = blockIdx.x, qb = blockIdx.y, sp = blockIdx.z;
  int bg = bgh >> 4, h = bgh & 15;
  int wid = threadIdx.x >> 6, lane = threadIdx.x & 63;
  int l15 = lane & 15, grp = lane >> 4;
  int qbase = qb * 128 + wid * 32;
  short* Pw = &Ps[wid][0];

  // Q fragments: 32 q rows per wave
  short8 bq[2][2];
#pragma unroll
  for (int qh = 0; qh < 2; ++qh) {
    const short* qp = q + ((size_t)bg * 1024 + qbase + qh * 16 + l15) * 1024 + h * 64 + (grp << 3);
    bq[qh][0] = *(const short8*)qp;
    bq[qh][1] = *(const short8*)(qp + 32);
  }

  // staging source pointers (inverse-swizzled)
  int u0 = wid * 128 + lane, u1 = u0 + 64;
  int r0 = u0 >> 3, j0 = u0 & 7, r1 = u1 >> 3, j1 = u1 & 7;
  const short* kbase = k + (size_t)bgh * NSLOT * DH_;
  const short* vbase = vT + (size_t)bgh * DH_ * NSLOT;
  const short* kss0 = kbase + r0 * 64 + ((j0 ^ (r0 & 7)) << 3);
  const short* kss1 = kbase + r1 * 64 + ((j1 ^ (r1 & 7)) << 3);
  const short* vss0 = vbase + (size_t)r0 * NSLOT + ((j0 ^ (r0 & 7)) << 3);
  const short* vss1 = vbase + (size_t)r1 * NSLOT + ((j1 ^ (r1 & 7)) << 3);

  f32x4 zero = {0.f, 0.f, 0.f, 0.f};
  f32x4 oacc[2][4];
#pragma unroll
  for (int qh = 0; qh < 2; ++qh)
#pragma unroll
    for (int dt = 0; dt < 4; ++dt) oacc[qh][dt] = zero;
  float m_run[2] = {-INFINITY, -INFINITY}, l_run[2] = {0.f, 0.f};

  auto STAGE = [&](int tile, int p) {
    size_t ko = (size_t)tile * 4096;       // K: +64 rows = 4096 shorts
    size_t vo = (size_t)tile * 64;         // V: +64 cols
    short* kd = &Ks[p][0] + wid * 1024;    // wave-uniform base; HW adds lane*16B
    short* vd = &Vs[p][0] + wid * 1024;
    __builtin_amdgcn_global_load_lds(
        (const __attribute__((address_space(1))) void*)(kss0 + ko),
        (__attribute__((address_space(3))) void*)kd, 16, 0, 0);
    __builtin_amdgcn_global_load_lds(
        (const __attribute__((address_space(1))) void*)(kss1 + ko),
        (__attribute__((address_space(3))) void*)(kd + 512), 16, 0, 0);
    __builtin_amdgcn_global_load_lds(
        (const __attribute__((address_space(1))) void*)(vss0 + vo),
        (__attribute__((address_space(3))) void*)vd, 16, 0, 0);
    __builtin_amdgcn_global_load_lds(
        (const __attribute__((address_space(1))) void*)(vss1 + vo),
        (__attribute__((address_space(3))) void*)(vd + 512), 16, 0, 0);
  };

  auto PROCESS = [&](int tile, int p) {
    const char* Kc = (const char*)&Ks[p][0];
    const char* Vc = (const char*)&Vs[p][0];
    f32x4 sacc[2][4];
#pragma unroll
    for (int qh = 0; qh < 2; ++qh)
#pragma unroll
      for (int kt = 0; kt < 4; ++kt) sacc[qh][kt] = zero;
    // QK^T
#pragma unroll
    for (int kf = 0; kf < 2; ++kf) {
      short8 ka[4];
#pragma unroll
      for (int kt = 0; kt < 4; ++kt) {
        int ra = kt * 16 + l15;
        ka[kt] = *(const short8*)(Kc + ra * 128 + (((grp + 4 * kf) ^ (ra & 7)) << 4));
      }
      __builtin_amdgcn_s_setprio(1);
#pragma unroll
      for (int kt = 0; kt < 4; ++kt)
#pragma unroll
        for (int qh = 0; qh < 2; ++qh)
          sacc[qh][kt] = __builtin_amdgcn_mfma_f32_16x16x32_bf16(ka[kt], bq[qh][kf], sacc[qh][kt], 0, 0, 0);
      __builtin_amdgcn_s_setprio(0);
    }
    if (tile == 16) {
#pragma unroll
      for (int qh = 0; qh < 2; ++qh)
#pragma unroll
        for (int kt = 0; kt < 4; ++kt)
#pragma unroll
          for (int rr = 0; rr < 4; ++rr)
            if ((kt * 16 + (grp << 2) + rr) != 0) sacc[qh][kt][rr] = -INFINITY;
    }
    // softmax (log2 domain), defer-max
    float pm[2], mnew[2];
#pragma unroll
    for (int qh = 0; qh < 2; ++qh) {
      float v = fmaxf(fmaxf(vmax4(sacc[qh][0]), vmax4(sacc[qh][1])),
                      fmaxf(vmax4(sacc[qh][2]), vmax4(sacc[qh][3])));
      v = fmaxf(v, __shfl_xor(v, 16));
      v = fmaxf(v, __shfl_xor(v, 32));
      pm[qh] = v;
    }
    bool defer = (__all((pm[0] <= m_run[0] + 8.f) && (pm[1] <= m_run[1] + 8.f)) != 0);
    mnew[0] = defer ? m_run[0] : fmaxf(m_run[0], pm[0]);
    mnew[1] = defer ? m_run[1] : fmaxf(m_run[1], pm[1]);
#pragma unroll
    for (int qh = 0; qh < 2; ++qh) {
#pragma unroll
      for (int kt = 0; kt < 4; ++kt)
#pragma unroll
        for (int rr = 0; rr < 4; ++rr)
          sacc[qh][kt][rr] = exp2f(sacc[qh][kt][rr] - mnew[qh]);
      float ps = (vsum4(sacc[qh][0]) + vsum4(sacc[qh][1])) + (vsum4(sacc[qh][2]) + vsum4(sacc[qh][3]));
      ps += __shfl_xor(ps, 16);
      ps += __shfl_xor(ps, 32);
      if (defer) {
        l_run[qh] += ps;
      } else {
        float alpha = exp2f(m_run[qh] - mnew[qh]);
        f32x4 avec;
#pragma unroll
        for (int rr = 0; rr < 4; ++rr) avec[rr] = __shfl(alpha, (grp << 2) + rr);
#pragma unroll
        for (int dt = 0; dt < 4; ++dt) oacc[qh][dt] *= avec;
        l_run[qh] = l_run[qh] * alpha + ps;
        m_run[qh] = mnew[qh];
      }
      // P -> LDS (per-wave region, no barrier needed)
#pragma unroll
      for (int kt = 0; kt < 4; ++kt) {
        short4v pk;
#pragma unroll
        for (int rr = 0; rr < 4; ++rr) pk[rr] = f2bf_trunc(sacc[qh][kt][rr]);
        *(short4v*)(Pw + (qh * 16 + l15) * 72 + kt * 16 + (grp << 2)) = pk;
      }
    }
    // PV
#pragma unroll
    for (int ks = 0; ks < 2; ++ks) {
      short8 pa[2];
#pragma unroll
      for (int qh = 0; qh < 2; ++qh)
        pa[qh] = *(const short8*)((const char*)Pw + (qh * 16 + l15) * 144 + grp * 16 + ks * 64);
      __builtin_amdgcn_s_setprio(1);
#pragma unroll
      for (int dt = 0; dt < 4; ++dt) {
        int ra = dt * 16 + l15;
        short8 vbf = *(const short8*)(Vc + ra * 128 + (((grp + 4 * ks) ^ (ra & 7)) << 4));
#pragma unroll
        for (int qh = 0; qh < 2; ++qh)
          oacc[qh][dt] = __builtin_amdgcn_mfma_f32_16x16x32_bf16(pa[qh], vbf, oacc[qh][dt], 0, 0, 0);
      }
      __builtin_amdgcn_s_setprio(0);
    }
  };

  int t0 = sp ? 8 : 0, t1 = sp ? 17 : 8;
  STAGE(t0, 0);
  asm volatile("s_waitcnt vmcnt(0)" ::: "memory");
  __syncthreads();
  int tile = t0, p = 0;
  while (true) {
    if (tile + 1 < t1) STAGE(tile + 1, p ^ 1);
    PROCESS(tile, p);
    if (++tile == t1) break;
    asm volatile("s_waitcnt vmcnt(0)" ::: "memory");
    __syncthreads();
    p ^= 1;
  }

  // per-q-row (m,l): ml[sp][bgh][qrow]
  if (grp == 0) {
#pragma unroll
    for (int qh = 0; qh < 2; ++qh) {
      int idx = (sp * 64 + bgh) * 1024 + qbase + qh * 16 + l15;
      f32x2 v; v[0] = m_run[qh]; v[1] = l_run[qh];
      *(f32x2*)(ml + (size_t)idx * 2) = v;
    }
  }
  // un-normalized partial O: oacc[qh][dt][rr] = O[q=qh*16+(grp<<2)+rr][dh=dt*16+l15]
#pragma unroll
  for (int qh = 0; qh < 2; ++qh)
#pragma unroll
    for (int dt = 0; dt < 4; ++dt)
#pragma unroll
      for (int rr = 0; rr < 4; ++rr) {
        int qq = qh * 16 + (grp << 2) + rr;
        int dh = dt * 16 + l15;
        if (sp == 0)
          o0[((size_t)bg * 1024 + qbase + qq) * 1024 + h * 64 + dh] = f2bf(oacc[qh][dt][rr]);
        else
          o1[((size_t)bgh * 1024 + qbase + qq) * 64 + dh] = f2bf(oacc[qh][dt][rr]);
      }
}

// ---------------- 6b) merge the two KV-splits (log2 domain) ----------------
__global__ __launch_bounds__(256) void attn_merge(
    short* __restrict__ obuf, const short* __restrict__ op1,
    const float* __restrict__ ml)
{
  int id = blockIdx.x;                  // bgh*16 + qc (64-row chunk)
  int bgh = id >> 4, qc = id & 15;
  int bg = bgh >> 4, h = bgh & 15;
  int t = threadIdx.x;
  int qq = t >> 2, c = t & 3;
  int qrow = qc * 64 + qq;
  int base0 = ((0 * 64 + bgh) * 1024 + qrow) * 2;
  int base1 = ((1 * 64 + bgh) * 1024 + qrow) * 2;
  float m0 = ml[base0], l0 = ml[base0 + 1];
  float m1 = ml[base1], l1 = ml[base1 + 1];
  float M = fmaxf(m0, m1);
  float w0 = exp2f(m0 - M), w1 = exp2f(m1 - M);
  float linv = 1.0f / (l0 * w0 + l1 * w1);
  w0 *= linv; w1 *= linv;
  size_t loc0 = ((size_t)bg * 1024 + qrow) * 1024 + h * 64 + c * 16;
  size_t loc1 = ((size_t)bgh * 1024 + qrow) * 64 + c * 16;
  short8 a0 = *(const short8*)(obuf + loc0);
  short8 a1 = *(const short8*)(obuf + loc0 + 8);
  short8 b0 = *(const short8*)(op1 + loc1);
  short8 b1 = *(const short8*)(op1 + loc1 + 8);
  short8 r0, r1;
#pragma unroll
  for (int e = 0; e < 8; ++e) {
    r0[e] = f2bf(bf2f(a0[e]) * w0 + bf2f(b0[e]) * w1);
    r1[e] = f2bf(bf2f(a1[e]) * w0 + bf2f(b1[e]) * w1);
  }
  *(short8*)(obuf + loc0) = r0;
  *(short8*)(obuf + loc0 + 8) = r1;
}

// ---------------- 7) finalize: scatter-average + null_token ----------------
__global__ __launch_bounds__(256) void finalize_kernel(
    const short* __restrict__ wo_out, const int* __restrict__ inv,
    const float* __restrict__ null_token, float* __restrict__ outp)
{
  int id = blockIdx.x;                  // b*N + n
  int b = id >> 12, n = id & (N_ - 1);
  int s0 = inv[((size_t)(b * G_ + 0) << 12) + n];
  int s1 = inv[((size_t)(b * G_ + 1) << 12) + n];
  int t = threadIdx.x;
  float* dst = outp + (size_t)id * D_ + t * 4;
  if (s0 < 0 && s1 < 0) {
    *(f32x4*)dst = *(const f32x4*)(null_token + t * 4);
  } else {
    f32x4 sum = {0.f, 0.f, 0.f, 0.f};
    float cnt = 0.f;
    if (s0 >= 0) {
      short4v v = *(const short4v*)(wo_out + (((size_t)(b * G_ + 0) * 1024 + s0) << 10) + t * 4);
#pragma unroll
      for (int e = 0; e < 4; ++e) sum[e] += bf2f(v[e]);
      cnt += 1.f;
    }
    if (s1 >= 0) {
      short4v v = *(const short4v*)(wo_out + (((size_t)(b * G_ + 1) * 1024 + s1) << 10) + t * 4);
#pragma unroll
      for (int e = 0; e < 4; ++e) sum[e] += bf2f(v[e]);
      cnt += 1.f;
    }
    f32x4 rv;
#pragma unroll
    for (int e = 0; e < 4; ++e) rv[e] = sum[e] / cnt;
    *(f32x4*)dst = rv;
  }
}

// ---------------- launch ----------------
extern "C" void kernel_launch(void* const* d_in, const int* in_sizes, int n_in,
                              void* d_out, int out_size, void* d_ws, size_t ws_size,
                              hipStream_t stream) {
  (void)in_sizes; (void)n_in; (void)out_size; (void)ws_size;
  const float* x        = (const float*)d_in[0];
  const float* rt_q     = (const float*)d_in[1];
  const float* rt_kv    = (const float*)d_in[2];
  const float* gamma_q  = (const float*)d_in[3];
  const float* gamma_c  = (const float*)d_in[4];
  const float* wq       = (const float*)d_in[5];
  const float* wkv      = (const float*)d_in[6];
  const float* wo       = (const float*)d_in[7];
  const float* null_kv  = (const float*)d_in[8];
  const float* null_tok = (const float*)d_in[9];
  float* outp = (float*)d_out;

  char* ws = (char*)d_ws;
  size_t off = 0;
  auto alloc = [&](size_t bytes) { char* p = ws + off; off += (bytes + 255) & ~(size_t)255; return p; };
  float* sim   = (float*)alloc((size_t)2 * B_ * G_ * N_ * 4);
  int*   idx   = (int*)  alloc((size_t)2 * B_ * G_ * 1024 * 4);
  int*   inv   = (int*)  alloc((size_t)B_ * G_ * N_ * 4);
  float* ml    = (float*)alloc((size_t)2 * 64 * 1024 * 2 * 4);   // 1MB (m,l) partials
  short* qn    = (short*)alloc((size_t)B_ * G_ * 1024 * 1024 * 2);
  short* cn    = (short*)alloc((size_t)B_ * G_ * 1024 * 1024 * 2);
  short* qproj = (short*)alloc((size_t)B_ * G_ * 1024 * 1024 * 2);
  size_t kvbytes = (size_t)B_ * G_ * H_ * NSLOT * DH_ * 2;
  short* kbuf  = (short*)alloc(kvbytes);
  short* vbuf  = (short*)alloc(kvbytes);
  short* obuf  = (short*)alloc((size_t)B_ * G_ * 1024 * 1024 * 2);
  short* wobuf = (short*)alloc((size_t)B_ * G_ * 1024 * 1024 * 2);
  short* wo_bf = (short*)alloc((size_t)G_ * 1024 * 1024 * 2);    // own slot (4.2MB)
  // aliases into dead regions (lifetimes verified):
  short* wq_bf  = wobuf;  // dead until final gemm writes wobuf
  short* wkv_bf = obuf;   // consumed by gemm<1> before attn writes obuf
  short* op1    = cn;     // split-1 partial O; cn dead after gemm<1>

  hipMemsetAsync(kbuf, 0, kvbytes, stream);
  hipMemsetAsync(vbuf, 0, kvbytes, stream);
  hipMemsetAsync(inv, 0xFF, (size_t)B_ * G_ * N_ * 4, stream);

  wconv3<<<8192, 256, 0, stream>>>(wq, wkv, wo, wq_bf, wkv_bf, wo_bf);
  sim_kernel<<<B_ * N_ / 4, 256, 0, stream>>>(x, rt_q, rt_kv, sim);
  coor_topk<<<8, 1024, 0, stream>>>(sim, idx, inv);
  gather_rms<<<2 * B_ * G_ * 1024, 256, 0, stream>>>(x, idx, gamma_q, gamma_c, qn, cn);
  gemm_nt<0><<<dim3(8, 8, B_ * G_), 512, 0, stream>>>(qn, wq_bf, qproj, nullptr, nullptr, 1024, ATTN_SCALE);
  gemm_nt<1><<<dim3(8, 16, B_ * G_), 512, 0, stream>>>(cn, wkv_bf, nullptr, kbuf, vbuf, 2048, 1.0f);
  null_fill<<<B_ * G_ * H_, 64, 0, stream>>>(null_kv, kbuf, vbuf);
  attn_kernel<<<dim3(64, 8, 2), 256, 0, stream>>>(qproj, kbuf, vbuf, obuf, op1, ml);
  attn_merge<<<1024, 256, 0, stream>>>(obuf, op1, ml);
  gemm_nt<0><<<dim3(8, 8, B_ * G_), 512, 0, stream>>>(obuf, wo_bf, wobuf, nullptr, nullptr, 1024, 1.0f);
  finalize_kernel<<<B_ * N_, 256, 0, stream>>>(wobuf, inv, null_tok, outp);
}

// Round 8
// 191.324 us; speedup vs baseline: 1.8780x; 1.0640x over previous
//
#include <hip/hip_runtime.h>

// ---------------- types / helpers ----------------
typedef __attribute__((ext_vector_type(8))) short short8;   // 8 x bf16 (16B)
typedef __attribute__((ext_vector_type(4))) short short4v;  // 4 x bf16 (8B)
typedef __attribute__((ext_vector_type(4))) float f32x4;

#define B_ 2
#define N_ 4096
#define D_ 1024
#define G_ 2
#define H_ 16
#define DH_ 64
#define NSLOT 1088              // 1024 tokens + 1 null + pad to 17*64
#define LOGK 7.0492548412558374f  // log(1152)
#define ATTN_SCALE 0.18033688011112043f  // dh^-0.5 * log2(e): S in log2 domain
#define FIXED_M 32.0f           // fixed softmax max (log2 domain); |S|<~12 << 32

__device__ __forceinline__ float bf2f(short s) {
  return __uint_as_float(((unsigned)(unsigned short)s) << 16);
}
__device__ __forceinline__ short f2bf(float f) {   // RNE
  unsigned u = __float_as_uint(f);
  u = (u + 0x7FFFu + ((u >> 16) & 1u)) >> 16;
  return (short)u;
}
__device__ __forceinline__ short f2bf_trunc(float f) {   // truncation (hot path)
  return (short)(__float_as_uint(f) >> 16);
}

// ---------------- 0) all W f32 -> bf16 in one launch ----------------
__global__ __launch_bounds__(256) void wconv3(
    const float* __restrict__ wq, const float* __restrict__ wkv,
    const float* __restrict__ wo, short* __restrict__ dq,
    short* __restrict__ dkv, short* __restrict__ dwo)
{
  int i = blockIdx.x * 256 + threadIdx.x;   // f32x4 unit; total 2M units
  const float* src; short* dst;
  if (i < 524288) { src = wq; dst = dq; }
  else if (i < 1572864) { src = wkv; dst = dkv; i -= 524288; }
  else { src = wo; dst = dwo; i -= 1572864; }
  f32x4 v = ((const f32x4*)src)[i];
  short4v o;
#pragma unroll
  for (int e = 0; e < 4; ++e) o[e] = f2bf(v[e]);
  ((short4v*)dst)[i] = o;
}

// ---------------- 1) sim = einsum('bnd,gd->bgn') for both routings ----------------
__global__ __launch_bounds__(256) void sim_kernel(
    const float* __restrict__ x, const float* __restrict__ rtq,
    const float* __restrict__ rtkv, float* __restrict__ sim)
{
  int wid = threadIdx.x >> 6, lane = threadIdx.x & 63;
  int row = blockIdx.x * 4 + wid;              // b*N + n
  int b = row >> 12, n = row & (N_ - 1);
  const float* xr = x + (size_t)row * D_;
  float a0 = 0.f, a1 = 0.f, a2 = 0.f, a3 = 0.f;
#pragma unroll
  for (int c = 0; c < 4; ++c) {
    int d = c * 256 + lane * 4;
    f32x4 xv = *(const f32x4*)(xr + d);
    f32x4 r0 = *(const f32x4*)(rtq + d);
    f32x4 r1 = *(const f32x4*)(rtq + D_ + d);
    f32x4 r2 = *(const f32x4*)(rtkv + d);
    f32x4 r3 = *(const f32x4*)(rtkv + D_ + d);
#pragma unroll
    for (int e = 0; e < 4; ++e) {
      a0 += xv[e] * r0[e];
      a1 += xv[e] * r1[e];
      a2 += xv[e] * r2[e];
      a3 += xv[e] * r3[e];
    }
  }
#pragma unroll
  for (int o = 32; o; o >>= 1) {
    a0 += __shfl_xor(a0, o); a1 += __shfl_xor(a1, o);
    a2 += __shfl_xor(a2, o); a3 += __shfl_xor(a3, o);
  }
  if (lane == 0) {
    sim[((size_t)(b)*G_ + 0) * N_ + n] = a0;
    sim[((size_t)(b)*G_ + 1) * N_ + n] = a1;
    sim[((size_t)(B_ + b)*G_ + 0) * N_ + n] = a2;
    sim[((size_t)(B_ + b)*G_ + 1) * N_ + n] = a3;
  }
}

// ---------------- 2) coor_descent + top-k (exact tie semantics) ----------------
__global__ __launch_bounds__(1024) void coor_topk(
    const float* __restrict__ sim, int* __restrict__ idxout, int* __restrict__ inv)
{
  __shared__ float rbuf[16];
  __shared__ float res;
  __shared__ unsigned keys[N_];
  __shared__ int scanbuf[16];

  int r = blockIdx.x >> 2, b = (blockIdx.x >> 1) & 1, g = blockIdx.x & 1;
  const float* srow = sim + ((size_t)blockIdx.x << 12);
  int tid = threadIdx.x, lane = tid & 63, wid = tid >> 6;

  float sv[4];
#pragma unroll
  for (int j = 0; j < 4; ++j) sv[j] = srow[tid * 4 + j];

  float a = 0.f;
  double epsd = 4.0;
  for (int it = 0; it < 20; ++it) {
    float eps = (float)fmax(epsd, 0.03);
    epsd *= 0.7;
    float sb[4]; float lmax = -INFINITY;
#pragma unroll
    for (int j = 0; j < 4; ++j) {
      float bb = (it == 0) ? (-sv[j]) : (-fmaxf(sv[j] + a, 0.f));
      sb[j] = (sv[j] + bb) / eps;
      lmax = fmaxf(lmax, sb[j]);
    }
#pragma unroll
    for (int o = 32; o; o >>= 1) lmax = fmaxf(lmax, __shfl_xor(lmax, o));
    if (lane == 0) rbuf[wid] = lmax;
    __syncthreads();
    if (tid < 64) {
      float m = (tid < 16) ? rbuf[tid] : -INFINITY;
#pragma unroll
      for (int o = 8; o; o >>= 1) m = fmaxf(m, __shfl_xor(m, o));
      if (tid == 0) res = m;
    }
    __syncthreads();
    float mx = res;
    float lsum = 0.f;
#pragma unroll
    for (int j = 0; j < 4; ++j) lsum += expf(sb[j] - mx);
#pragma unroll
    for (int o = 32; o; o >>= 1) lsum += __shfl_xor(lsum, o);
    if (lane == 0) rbuf[wid] = lsum;
    __syncthreads();
    if (tid < 64) {
      float s = (tid < 16) ? rbuf[tid] : 0.f;
#pragma unroll
      for (int o = 8; o; o >>= 1) s += __shfl_xor(s, o);
      if (tid == 0) res = logf(s) + mx;
    }
    __syncthreads();
    float lse = res;
    a = eps * (LOGK - lse);
  }
  __syncthreads();

  // final scores: exp(min(s+a,0)/0.03); saturated entries are EXACTLY 1.0f
  unsigned kb[4]; int c1 = 0;
#pragma unroll
  for (int j = 0; j < 4; ++j) {
    float sc = expf(fminf(sv[j] + a, 0.f) / 0.03f);
    kb[j] = __float_as_uint(sc);
    keys[tid * 4 + j] = kb[j];
    c1 += (kb[j] == 0x3F800000u);
  }
#pragma unroll
  for (int o = 32; o; o >>= 1) c1 += __shfl_xor(c1, o);
  if (lane == 0) scanbuf[wid] = c1;
  __syncthreads();
  int c1tot = 0;
  for (int i = 0; i < 16; ++i) c1tot += scanbuf[i];
  __syncthreads();

  int flag[4];
  if (c1tot >= 1024) {
#pragma unroll
    for (int j = 0; j < 4; ++j) flag[j] = (kb[j] == 0x3F800000u);
  } else {
#pragma unroll
    for (int j = 0; j < 4; ++j) {
      unsigned kn = kb[j]; int n = tid * 4 + j; int rank = 0;
      for (int m = 0; m < N_; ++m) {
        unsigned km = keys[m];
        rank += (km > kn) || (km == kn && m < n);
      }
      flag[j] = (rank < 1024);
    }
  }

  int cnt = flag[0] + flag[1] + flag[2] + flag[3];
  int inc = cnt;
#pragma unroll
  for (int o = 1; o < 64; o <<= 1) {
    int tt = __shfl_up(inc, o);
    if (lane >= o) inc += tt;
  }
  if (lane == 63) scanbuf[wid] = inc;
  __syncthreads();
  int off = 0;
  for (int w = 0; w < wid; ++w) off += scanbuf[w];
  int pos = off + inc - cnt;
  int* op = idxout + ((size_t)blockIdx.x << 10);
  int* ip = inv + ((size_t)(b * G_ + g) << 12);
#pragma unroll
  for (int j = 0; j < 4; ++j) {
    if (flag[j]) {
      if (pos < 1024) {
        int n = tid * 4 + j;
        op[pos] = n;
        if (r == 0) ip[n] = pos;
      }
      pos++;
    }
  }
}

// ---------------- 3) gather + RMSNorm -> bf16 rows ----------------
__global__ __launch_bounds__(256) void gather_rms(
    const float* __restrict__ x, const int* __restrict__ idx,
    const float* __restrict__ gamma_q, const float* __restrict__ gamma_c,
    short* __restrict__ qn, short* __restrict__ cn)
{
  __shared__ float rb[4];
  __shared__ float tot;
  int id = blockIdx.x;                  // ((r*B+b)*G+g)*1024 + slot
  int r = id >> 12, rem = id & 4095;
  int g = (rem >> 10) & 1;
  int b = rem >> 11;
  int tok = idx[id];
  int t = threadIdx.x;
  const float* xr = x + ((size_t)b * N_ + tok) * D_;
  f32x4 v = *(const f32x4*)(xr + t * 4);
  float ss = v[0]*v[0] + v[1]*v[1] + v[2]*v[2] + v[3]*v[3];
#pragma unroll
  for (int o = 32; o; o >>= 1) ss += __shfl_xor(ss, o);
  if ((t & 63) == 0) rb[t >> 6] = ss;
  __syncthreads();
  if (t == 0) tot = rb[0] + rb[1] + rb[2] + rb[3];
  __syncthreads();
  float scale = 32.0f / fmaxf(sqrtf(tot), 1e-12f);
  const float* gm = (r ? gamma_c : gamma_q) + g * D_;
  f32x4 gv = *(const f32x4*)(gm + t * 4);
  short* dst = (r ? cn : qn) + ((size_t)rem << 10) + t * 4;
  short4v ov;
#pragma unroll
  for (int e = 0; e < 4; ++e) ov[e] = f2bf(v[e] * scale * gv[e]);
  *(short4v*)dst = ov;
}

// ---------------- 4) fused NT GEMM (qproj + kv): 512 thr, dbuf LDS, 2-phase ----
// blockIdx.y<8: qproj (NB=1024, out row-major, scale ATTN_SCALE)
// blockIdx.y>=8: kv (NB=2048; n<1024 -> k[bgh][slot][dh]; else vT[bgh][dh][slot])
__global__ __launch_bounds__(512, 4) void gemm_qkv(
    const short* __restrict__ qn, const short* __restrict__ cn,
    const short* __restrict__ wqb, const short* __restrict__ wkvb,
    short* __restrict__ qout, short* __restrict__ kout, short* __restrict__ vout)
{
  __shared__ short As[2][8192];
  __shared__ short Bs[2][8192];
  int t = threadIdx.x, lane = t & 63, wid = t >> 6;
  int grp = lane >> 4, l15 = lane & 15;
  int wm = wid >> 1, wn = wid & 1;
  int ny = blockIdx.y;
  bool isq = ny < 8;
  const short* A  = isq ? qn : cn;
  const short* Bw = isq ? wqb : wkvb;
  int NB = isq ? 1024 : 2048;
  int nbase = (isq ? ny : ny - 8) * 128;
  float oscale = isq ? ATTN_SCALE : 1.0f;
  int mbase = blockIdx.x * 128;
  int bg = blockIdx.z, g = bg & 1;
  const short* Ab = A + ((size_t)bg << 20);
  const short* Bp = Bw + ((size_t)g * NB + nbase) * 1024;

  f32x4 zero = {0.f, 0.f, 0.f, 0.f};
  f32x4 acc[2][4];
#pragma unroll
  for (int i = 0; i < 2; ++i)
#pragma unroll
    for (int j = 0; j < 4; ++j) acc[i][j] = zero;

  int u1 = t, u2 = t + 512;
  int r1 = u1 >> 3, j1 = u1 & 7, r2 = u2 >> 3, j2 = u2 & 7;
  const short* apA1 = Ab + ((size_t)(mbase + r1) << 10) + ((j1 ^ (r1 & 7)) << 3);
  const short* apA2 = Ab + ((size_t)(mbase + r2) << 10) + ((j2 ^ (r2 & 7)) << 3);
  const short* apB1 = Bp + ((size_t)r1 << 10) + ((j1 ^ (r1 & 7)) << 3);
  const short* apB2 = Bp + ((size_t)r2 << 10) + ((j2 ^ (r2 & 7)) << 3);
  int d1 = wid * 512, d2 = 4096 + wid * 512;

  auto STAGE = [&](int kb, int p) {
    int ko = kb * 64;
    __builtin_amdgcn_global_load_lds(
        (const __attribute__((address_space(1))) void*)(apA1 + ko),
        (__attribute__((address_space(3))) void*)(&As[p][0] + d1), 16, 0, 0);
    __builtin_amdgcn_global_load_lds(
        (const __attribute__((address_space(1))) void*)(apA2 + ko),
        (__attribute__((address_space(3))) void*)(&As[p][0] + d2), 16, 0, 0);
    __builtin_amdgcn_global_load_lds(
        (const __attribute__((address_space(1))) void*)(apB1 + ko),
        (__attribute__((address_space(3))) void*)(&Bs[p][0] + d1), 16, 0, 0);
    __builtin_amdgcn_global_load_lds(
        (const __attribute__((address_space(1))) void*)(apB2 + ko),
        (__attribute__((address_space(3))) void*)(&Bs[p][0] + d2), 16, 0, 0);
  };

  STAGE(0, 0);
  asm volatile("s_waitcnt vmcnt(0)" ::: "memory");
  __syncthreads();

  for (int kb = 0; kb < 16; ++kb) {
    int p = kb & 1;
    if (kb + 1 < 16) STAGE(kb + 1, p ^ 1);
    const char* Ac = (const char*)&As[p][0];
    const char* Bc = (const char*)&Bs[p][0];
#pragma unroll
    for (int kf = 0; kf < 2; ++kf) {
      short8 af[2], bf_[4];
#pragma unroll
      for (int mt = 0; mt < 2; ++mt) {
        int ra = wm * 32 + mt * 16 + l15;
        af[mt] = *(const short8*)(Ac + ra * 128 + (((grp << 4) + (kf << 6)) ^ ((ra & 7) << 4)));
      }
#pragma unroll
      for (int nt = 0; nt < 4; ++nt) {
        int rb = wn * 64 + nt * 16 + l15;
        bf_[nt] = *(const short8*)(Bc + rb * 128 + (((grp << 4) + (kf << 6)) ^ ((rb & 7) << 4)));
      }
      __builtin_amdgcn_s_setprio(1);
#pragma unroll
      for (int mt = 0; mt < 2; ++mt)
#pragma unroll
        for (int nt = 0; nt < 4; ++nt)
          acc[mt][nt] = __builtin_amdgcn_mfma_f32_16x16x32_bf16(af[mt], bf_[nt], acc[mt][nt], 0, 0, 0);
      __builtin_amdgcn_s_setprio(0);
    }
    if (kb + 1 < 16) {
      asm volatile("s_waitcnt vmcnt(0)" ::: "memory");
      __syncthreads();
    }
  }

#pragma unroll
  for (int mt = 0; mt < 2; ++mt)
#pragma unroll
    for (int nt = 0; nt < 4; ++nt) {
      int n = nbase + wn*64 + nt*16 + l15;
#pragma unroll
      for (int rr = 0; rr < 4; ++rr) {
        int m = mbase + wm*32 + mt*16 + grp*4 + rr;
        float v = acc[mt][nt][rr] * oscale;
        if (isq) {
          qout[((size_t)bg * 1024 + m) * 1024 + n] = f2bf(v);
        } else {
          if (n < 1024) {
            kout[(((size_t)bg * H_ + (n >> 6)) * NSLOT + m) * DH_ + (n & 63)] = f2bf(v);
          } else {
            int e = n - 1024;
            vout[(((size_t)bg * H_ + (e >> 6)) * DH_ + (e & 63)) * NSLOT + m] = f2bf(v);
          }
        }
      }
    }
}

// ---------------- 4b) wo GEMM, K-split 2: partials to out0/out1 ----------------
__global__ __launch_bounds__(512, 4) void gemm_wo(
    const short* __restrict__ A, const short* __restrict__ Bw,
    short* __restrict__ out0, short* __restrict__ out1)
{
  __shared__ short As[2][8192];
  __shared__ short Bs[2][8192];
  int t = threadIdx.x, lane = t & 63, wid = t >> 6;
  int grp = lane >> 4, l15 = lane & 15;
  int wm = wid >> 1, wn = wid & 1;
  int mbase = blockIdx.x * 128, nbase = blockIdx.y * 128;
  int z = blockIdx.z, bg = z >> 1, sp = z & 1, g = bg & 1;
  short* out = sp ? out1 : out0;
  const short* Ab = A + ((size_t)bg << 20);
  const short* Bp = Bw + ((size_t)g * 1024 + nbase) * 1024;

  f32x4 zero = {0.f, 0.f, 0.f, 0.f};
  f32x4 acc[2][4];
#pragma unroll
  for (int i = 0; i < 2; ++i)
#pragma unroll
    for (int j = 0; j < 4; ++j) acc[i][j] = zero;

  int u1 = t, u2 = t + 512;
  int r1 = u1 >> 3, j1 = u1 & 7, r2 = u2 >> 3, j2 = u2 & 7;
  const short* apA1 = Ab + ((size_t)(mbase + r1) << 10) + ((j1 ^ (r1 & 7)) << 3);
  const short* apA2 = Ab + ((size_t)(mbase + r2) << 10) + ((j2 ^ (r2 & 7)) << 3);
  const short* apB1 = Bp + ((size_t)r1 << 10) + ((j1 ^ (r1 & 7)) << 3);
  const short* apB2 = Bp + ((size_t)r2 << 10) + ((j2 ^ (r2 & 7)) << 3);
  int d1 = wid * 512, d2 = 4096 + wid * 512;

  auto STAGE = [&](int kb, int p) {
    int ko = kb * 64;
    __builtin_amdgcn_global_load_lds(
        (const __attribute__((address_space(1))) void*)(apA1 + ko),
        (__attribute__((address_space(3))) void*)(&As[p][0] + d1), 16, 0, 0);
    __builtin_amdgcn_global_load_lds(
        (const __attribute__((address_space(1))) void*)(apA2 + ko),
        (__attribute__((address_space(3))) void*)(&As[p][0] + d2), 16, 0, 0);
    __builtin_amdgcn_global_load_lds(
        (const __attribute__((address_space(1))) void*)(apB1 + ko),
        (__attribute__((address_space(3))) void*)(&Bs[p][0] + d1), 16, 0, 0);
    __builtin_amdgcn_global_load_lds(
        (const __attribute__((address_space(1))) void*)(apB2 + ko),
        (__attribute__((address_space(3))) void*)(&Bs[p][0] + d2), 16, 0, 0);
  };

  int kb0 = sp * 8;
  STAGE(kb0, 0);
  asm volatile("s_waitcnt vmcnt(0)" ::: "memory");
  __syncthreads();

  for (int kk = 0; kk < 8; ++kk) {
    int p = kk & 1;
    if (kk + 1 < 8) STAGE(kb0 + kk + 1, p ^ 1);
    const char* Ac = (const char*)&As[p][0];
    const char* Bc = (const char*)&Bs[p][0];
#pragma unroll
    for (int kf = 0; kf < 2; ++kf) {
      short8 af[2], bf_[4];
#pragma unroll
      for (int mt = 0; mt < 2; ++mt) {
        int ra = wm * 32 + mt * 16 + l15;
        af[mt] = *(const short8*)(Ac + ra * 128 + (((grp << 4) + (kf << 6)) ^ ((ra & 7) << 4)));
      }
#pragma unroll
      for (int nt = 0; nt < 4; ++nt) {
        int rb = wn * 64 + nt * 16 + l15;
        bf_[nt] = *(const short8*)(Bc + rb * 128 + (((grp << 4) + (kf << 6)) ^ ((rb & 7) << 4)));
      }
      __builtin_amdgcn_s_setprio(1);
#pragma unroll
      for (int mt = 0; mt < 2; ++mt)
#pragma unroll
        for (int nt = 0; nt < 4; ++nt)
          acc[mt][nt] = __builtin_amdgcn_mfma_f32_16x16x32_bf16(af[mt], bf_[nt], acc[mt][nt], 0, 0, 0);
      __builtin_amdgcn_s_setprio(0);
    }
    if (kk + 1 < 8) {
      asm volatile("s_waitcnt vmcnt(0)" ::: "memory");
      __syncthreads();
    }
  }

#pragma unroll
  for (int mt = 0; mt < 2; ++mt)
#pragma unroll
    for (int nt = 0; nt < 4; ++nt) {
      int n = nbase + wn*64 + nt*16 + l15;
#pragma unroll
      for (int rr = 0; rr < 4; ++rr) {
        int m = mbase + wm*32 + mt*16 + grp*4 + rr;
        out[((size_t)bg * 1024 + m) * 1024 + n] = f2bf(acc[mt][nt][rr]);
      }
    }
}

// ---------------- 5) null kv fill (slot 1024) ----------------
__global__ void null_fill(const float* __restrict__ null_kv,
                          short* __restrict__ kb_, short* __restrict__ vb_)
{
  int bgh = blockIdx.x;                 // (b*G+g)*H + h
  int g = (bgh >> 4) & 1, h = bgh & 15;
  int t = threadIdx.x;                  // 0..63
  float kvk = null_kv[((size_t)(0 * G_ + g) * H_ + h) * DH_ + t];
  float kvv = null_kv[((size_t)(1 * G_ + g) * H_ + h) * DH_ + t];
  kb_[((size_t)bgh * NSLOT + 1024) * DH_ + t] = f2bf(kvk);
  vb_[((size_t)bgh * DH_ + t) * NSLOT + 1024] = f2bf(kvv);
}

// ---------------- 6) flash attention: fixed-M softmax, l via ones-MFMA ----------
// grid (bgh=64, qb=8, sp=2). K/V LDS-staged double-buffered (rule-#21 involution).
// P = exp2(S - 32) with -32 folded into the MFMA C-init; l = P x ones via MFMA.
__global__ __launch_bounds__(256, 3) void attn_kernel(
    const short* __restrict__ q, const short* __restrict__ k,
    const short* __restrict__ vT, short* __restrict__ o0,
    short* __restrict__ o1, float* __restrict__ ml)
{
  __shared__ short Ks[2][4096];        // [64 slot][64 dh] bf16, swizzled
  __shared__ short Vs[2][4096];        // [64 dh][64 slot] bf16, swizzled
  __shared__ short Ps[4][32 * 72];     // per-wave P, padded rows
  int bgh = blockIdx.x, qb = blockIdx.y, sp = blockIdx.z;
  int bg = bgh >> 4, h = bgh & 15;
  int wid = threadIdx.x >> 6, lane = threadIdx.x & 63;
  int l15 = lane & 15, grp = lane >> 4;
  int qbase = qb * 128 + wid * 32;
  short* Pw = &Ps[wid][0];

  short8 bq[2][2];
#pragma unroll
  for (int qh = 0; qh < 2; ++qh) {
    const short* qp = q + ((size_t)bg * 1024 + qbase + qh * 16 + l15) * 1024 + h * 64 + (grp << 3);
    bq[qh][0] = *(const short8*)qp;
    bq[qh][1] = *(const short8*)(qp + 32);
  }
  // constant ones B-fragment: column n=0 all ones -> D col 0 = row-sum(P)
  short8 ones8;
  short ov = (l15 == 0) ? (short)0x3F80 : (short)0;
#pragma unroll
  for (int e = 0; e < 8; ++e) ones8[e] = ov;

  int u0 = wid * 128 + lane, u1 = u0 + 64;
  int r0 = u0 >> 3, j0 = u0 & 7, r1 = u1 >> 3, j1 = u1 & 7;
  const short* kbase = k + (size_t)bgh * NSLOT * DH_;
  const short* vbase = vT + (size_t)bgh * DH_ * NSLOT;
  const short* kss0 = kbase + r0 * 64 + ((j0 ^ (r0 & 7)) << 3);
  const short* kss1 = kbase + r1 * 64 + ((j1 ^ (r1 & 7)) << 3);
  const short* vss0 = vbase + (size_t)r0 * NSLOT + ((j0 ^ (r0 & 7)) << 3);
  const short* vss1 = vbase + (size_t)r1 * NSLOT + ((j1 ^ (r1 & 7)) << 3);

  f32x4 zero = {0.f, 0.f, 0.f, 0.f};
  f32x4 minit = {-FIXED_M, -FIXED_M, -FIXED_M, -FIXED_M};
  f32x4 oacc[2][4], lacc[2];
#pragma unroll
  for (int qh = 0; qh < 2; ++qh) {
    lacc[qh] = zero;
#pragma unroll
    for (int dt = 0; dt < 4; ++dt) oacc[qh][dt] = zero;
  }

  auto STAGE = [&](int tile, int p) {
    size_t ko = (size_t)tile * 4096;
    size_t vo = (size_t)tile * 64;
    short* kd = &Ks[p][0] + wid * 1024;
    short* vd = &Vs[p][0] + wid * 1024;
    __builtin_amdgcn_global_load_lds(
        (const __attribute__((address_space(1))) void*)(kss0 + ko),
        (__attribute__((address_space(3))) void*)kd, 16, 0, 0);
    __builtin_amdgcn_global_load_lds(
        (const __attribute__((address_space(1))) void*)(kss1 + ko),
        (__attribute__((address_space(3))) void*)(kd + 512), 16, 0, 0);
    __builtin_amdgcn_global_load_lds(
        (const __attribute__((address_space(1))) void*)(vss0 + vo),
        (__attribute__((address_space(3))) void*)vd, 16, 0, 0);
    __builtin_amdgcn_global_load_lds(
        (const __attribute__((address_space(1))) void*)(vss1 + vo),
        (__attribute__((address_space(3))) void*)(vd + 512), 16, 0, 0);
  };

  auto PROCESS = [&](int tile, int p) {
    const char* Kc = (const char*)&Ks[p][0];
    const char* Vc = (const char*)&Vs[p][0];
    f32x4 sacc[2][4];
#pragma unroll
    for (int qh = 0; qh < 2; ++qh)
#pragma unroll
      for (int kt = 0; kt < 4; ++kt) sacc[qh][kt] = minit;   // C-init = -M
    // QK^T (S - M accumulates)
#pragma unroll
    for (int kf = 0; kf < 2; ++kf) {
      short8 ka[4];
#pragma unroll
      for (int kt = 0; kt < 4; ++kt) {
        int ra = kt * 16 + l15;
        ka[kt] = *(const short8*)(Kc + ra * 128 + (((grp + 4 * kf) ^ (ra & 7)) << 4));
      }
      __builtin_amdgcn_s_setprio(1);
#pragma unroll
      for (int kt = 0; kt < 4; ++kt)
#pragma unroll
        for (int qh = 0; qh < 2; ++qh)
          sacc[qh][kt] = __builtin_amdgcn_mfma_f32_16x16x32_bf16(ka[kt], bq[qh][kf], sacc[qh][kt], 0, 0, 0);
      __builtin_amdgcn_s_setprio(0);
    }
    if (tile == 16) {
#pragma unroll
      for (int qh = 0; qh < 2; ++qh)
#pragma unroll
        for (int kt = 0; kt < 4; ++kt)
#pragma unroll
          for (int rr = 0; rr < 4; ++rr)
            if ((kt * 16 + (grp << 2) + rr) != 0) sacc[qh][kt][rr] = -INFINITY;
    }
    // P = exp2(S - M); pack to LDS
#pragma unroll
    for (int qh = 0; qh < 2; ++qh)
#pragma unroll
      for (int kt = 0; kt < 4; ++kt) {
        short4v pk;
#pragma unroll
        for (int rr = 0; rr < 4; ++rr) pk[rr] = f2bf_trunc(exp2f(sacc[qh][kt][rr]));
        *(short4v*)(Pw + (qh * 16 + l15) * 72 + kt * 16 + (grp << 2)) = pk;
      }
    // PV + l
#pragma unroll
    for (int ks = 0; ks < 2; ++ks) {
      short8 pa[2];
#pragma unroll
      for (int qh = 0; qh < 2; ++qh)
        pa[qh] = *(const short8*)((const char*)Pw + (qh * 16 + l15) * 144 + grp * 16 + ks * 64);
      __builtin_amdgcn_s_setprio(1);
#pragma unroll
      for (int dt = 0; dt < 4; ++dt) {
        int ra = dt * 16 + l15;
        short8 vbf = *(const short8*)(Vc + ra * 128 + (((grp + 4 * ks) ^ (ra & 7)) << 4));
#pragma unroll
        for (int qh = 0; qh < 2; ++qh)
          oacc[qh][dt] = __builtin_amdgcn_mfma_f32_16x16x32_bf16(pa[qh], vbf, oacc[qh][dt], 0, 0, 0);
      }
#pragma unroll
      for (int qh = 0; qh < 2; ++qh)
        lacc[qh] = __builtin_amdgcn_mfma_f32_16x16x32_bf16(pa[qh], ones8, lacc[qh], 0, 0, 0);
      __builtin_amdgcn_s_setprio(0);
    }
  };

  int t0 = sp ? 8 : 0, t1 = sp ? 17 : 8;
  STAGE(t0, 0);
  asm volatile("s_waitcnt vmcnt(0)" ::: "memory");
  __syncthreads();
  int tile = t0, p = 0;
  while (true) {
    if (tile + 1 < t1) STAGE(tile + 1, p ^ 1);
    PROCESS(tile, p);
    if (++tile == t1) break;
    asm volatile("s_waitcnt vmcnt(0)" ::: "memory");
    __syncthreads();
    p ^= 1;
  }

  // l: lanes l15==0 hold l[q=(grp<<2)+rr] in lacc[qh][rr]
  if (l15 == 0) {
#pragma unroll
    for (int qh = 0; qh < 2; ++qh)
#pragma unroll
      for (int rr = 0; rr < 4; ++rr)
        ml[(size_t)(sp * 64 + bgh) * 1024 + qbase + qh * 16 + (grp << 2) + rr] = lacc[qh][rr];
  }
  // un-normalized partial O
#pragma unroll
  for (int qh = 0; qh < 2; ++qh)
#pragma unroll
    for (int dt = 0; dt < 4; ++dt)
#pragma unroll
      for (int rr = 0; rr < 4; ++rr) {
        int qq = qh * 16 + (grp << 2) + rr;
        int dh = dt * 16 + l15;
        if (sp == 0)
          o0[((size_t)bg * 1024 + qbase + qq) * 1024 + h * 64 + dh] = f2bf(oacc[qh][dt][rr]);
        else
          o1[((size_t)bgh * 1024 + qbase + qq) * 64 + dh] = f2bf(oacc[qh][dt][rr]);
      }
}

// ---------------- 6b) merge: O = (O0 + O1) / (l0 + l1) (same fixed M) ----------
__global__ __launch_bounds__(256) void attn_merge(
    short* __restrict__ obuf, const short* __restrict__ op1,
    const float* __restrict__ ml)
{
  int id = blockIdx.x;                  // bgh*16 + qc (64-row chunk)
  int bgh = id >> 4, qc = id & 15;
  int bg = bgh >> 4, h = bgh & 15;
  int t = threadIdx.x;
  int qq = t >> 2, c = t & 3;
  int qrow = qc * 64 + qq;
  float l0 = ml[(size_t)bgh * 1024 + qrow];
  float l1 = ml[(size_t)(64 + bgh) * 1024 + qrow];
  float w = 1.0f / (l0 + l1);
  size_t loc0 = ((size_t)bg * 1024 + qrow) * 1024 + h * 64 + c * 16;
  size_t loc1 = ((size_t)bgh * 1024 + qrow) * 64 + c * 16;
  short8 a0 = *(const short8*)(obuf + loc0);
  short8 a1 = *(const short8*)(obuf + loc0 + 8);
  short8 b0 = *(const short8*)(op1 + loc1);
  short8 b1 = *(const short8*)(op1 + loc1 + 8);
  short8 r0, r1;
#pragma unroll
  for (int e = 0; e < 8; ++e) {
    r0[e] = f2bf((bf2f(a0[e]) + bf2f(b0[e])) * w);
    r1[e] = f2bf((bf2f(a1[e]) + bf2f(b1[e])) * w);
  }
  *(short8*)(obuf + loc0) = r0;
  *(short8*)(obuf + loc0 + 8) = r1;
}

// ---------------- 7) finalize: sum K-split wo partials, scatter-average ---------
__global__ __launch_bounds__(256) void finalize_kernel(
    const short* __restrict__ wo0, const short* __restrict__ wo1,
    const int* __restrict__ inv, const float* __restrict__ null_token,
    float* __restrict__ outp)
{
  int id = blockIdx.x;                  // b*N + n
  int b = id >> 12, n = id & (N_ - 1);
  int s0 = inv[((size_t)(b * G_ + 0) << 12) + n];
  int s1 = inv[((size_t)(b * G_ + 1) << 12) + n];
  int t = threadIdx.x;
  float* dst = outp + (size_t)id * D_ + t * 4;
  if (s0 < 0 && s1 < 0) {
    *(f32x4*)dst = *(const f32x4*)(null_token + t * 4);
  } else {
    f32x4 sum = {0.f, 0.f, 0.f, 0.f};
    float cnt = 0.f;
    if (s0 >= 0) {
      size_t loc = (((size_t)(b * G_ + 0) * 1024 + s0) << 10) + t * 4;
      short4v v = *(const short4v*)(wo0 + loc);
      short4v v2 = *(const short4v*)(wo1 + loc);
#pragma unroll
      for (int e = 0; e < 4; ++e) sum[e] += bf2f(v[e]) + bf2f(v2[e]);
      cnt += 1.f;
    }
    if (s1 >= 0) {
      size_t loc = (((size_t)(b * G_ + 1) * 1024 + s1) << 10) + t * 4;
      short4v v = *(const short4v*)(wo0 + loc);
      short4v v2 = *(const short4v*)(wo1 + loc);
#pragma unroll
      for (int e = 0; e < 4; ++e) sum[e] += bf2f(v[e]) + bf2f(v2[e]);
      cnt += 1.f;
    }
    f32x4 rv;
#pragma unroll
    for (int e = 0; e < 4; ++e) rv[e] = sum[e] / cnt;
    *(f32x4*)dst = rv;
  }
}

// ---------------- launch ----------------
extern "C" void kernel_launch(void* const* d_in, const int* in_sizes, int n_in,
                              void* d_out, int out_size, void* d_ws, size_t ws_size,
                              hipStream_t stream) {
  (void)in_sizes; (void)n_in; (void)out_size; (void)ws_size;
  const float* x        = (const float*)d_in[0];
  const float* rt_q     = (const float*)d_in[1];
  const float* rt_kv    = (const float*)d_in[2];
  const float* gamma_q  = (const float*)d_in[3];
  const float* gamma_c  = (const float*)d_in[4];
  const float* wq       = (const float*)d_in[5];
  const float* wkv      = (const float*)d_in[6];
  const float* wo       = (const float*)d_in[7];
  const float* null_kv  = (const float*)d_in[8];
  const float* null_tok = (const float*)d_in[9];
  float* outp = (float*)d_out;

  char* ws = (char*)d_ws;
  size_t off = 0;
  auto alloc = [&](size_t bytes) { char* p = ws + off; off += (bytes + 255) & ~(size_t)255; return p; };
  float* sim   = (float*)alloc((size_t)2 * B_ * G_ * N_ * 4);
  int*   idx   = (int*)  alloc((size_t)2 * B_ * G_ * 1024 * 4);
  int*   inv   = (int*)  alloc((size_t)B_ * G_ * N_ * 4);
  float* ml    = (float*)alloc((size_t)2 * 64 * 1024 * 4);       // 512KB l partials
  short* qn    = (short*)alloc((size_t)B_ * G_ * 1024 * 1024 * 2);
  short* cn    = (short*)alloc((size_t)B_ * G_ * 1024 * 1024 * 2);
  short* qproj = (short*)alloc((size_t)B_ * G_ * 1024 * 1024 * 2);
  size_t kvbytes = (size_t)B_ * G_ * H_ * NSLOT * DH_ * 2;       // 256-aligned
  short* kbuf  = (short*)alloc(kvbytes);
  short* vbuf  = (short*)alloc(kvbytes);
  short* obuf  = (short*)alloc((size_t)B_ * G_ * 1024 * 1024 * 2);
  short* wobuf = (short*)alloc((size_t)B_ * G_ * 1024 * 1024 * 2);
  short* wo_bf = (short*)alloc((size_t)G_ * 1024 * 1024 * 2);
  // aliases into dead regions (lifetimes verified):
  short* wq_bf  = wobuf;  // dead until gemm_wo writes wobuf (after gemm_qkv)
  short* wkv_bf = obuf;   // consumed by gemm_qkv before attn writes obuf
  short* op1    = cn;     // split-1 partial O; cn dead after gemm_qkv
  short* wobuf2 = qproj;  // wo K-split half 1; qproj dead after attn

  hipMemsetAsync(kbuf, 0, kvbytes * 2, stream);   // kbuf+vbuf contiguous
  hipMemsetAsync(inv, 0xFF, (size_t)B_ * G_ * N_ * 4, stream);

  wconv3<<<8192, 256, 0, stream>>>(wq, wkv, wo, wq_bf, wkv_bf, wo_bf);
  sim_kernel<<<B_ * N_ / 4, 256, 0, stream>>>(x, rt_q, rt_kv, sim);
  coor_topk<<<8, 1024, 0, stream>>>(sim, idx, inv);
  gather_rms<<<2 * B_ * G_ * 1024, 256, 0, stream>>>(x, idx, gamma_q, gamma_c, qn, cn);
  gemm_qkv<<<dim3(8, 24, B_ * G_), 512, 0, stream>>>(qn, cn, wq_bf, wkv_bf, qproj, kbuf, vbuf);
  null_fill<<<B_ * G_ * H_, 64, 0, stream>>>(null_kv, kbuf, vbuf);
  attn_kernel<<<dim3(64, 8, 2), 256, 0, stream>>>(qproj, kbuf, vbuf, obuf, op1, ml);
  attn_merge<<<1024, 256, 0, stream>>>(obuf, op1, ml);
  gemm_wo<<<dim3(8, 8, 2 * B_ * G_), 512, 0, stream>>>(obuf, wo_bf, wobuf, wobuf2);
  finalize_kernel<<<B_ * N_, 256, 0, stream>>>(wobuf, wobuf2, inv, null_tok, outp);
}

// Round 9
// 183.245 us; speedup vs baseline: 1.9608x; 1.0441x over previous
//
#include <hip/hip_runtime.h>

// ---------------- types / helpers ----------------
typedef __attribute__((ext_vector_type(8))) short short8;   // 8 x bf16 (16B)
typedef __attribute__((ext_vector_type(4))) short short4v;  // 4 x bf16 (8B)
typedef __attribute__((ext_vector_type(4))) float f32x4;

#define B_ 2
#define N_ 4096
#define D_ 1024
#define G_ 2
#define H_ 16
#define DH_ 64
#define NSLOT 1088              // 1024 tokens + 1 null + pad to 17*64
#define LOGK 7.0492548412558374f  // log(1152)
#define ATTN_SCALE 0.18033688011112043f  // dh^-0.5 * log2(e): S in log2 domain
#define FIXED_M 32.0f           // fixed softmax max (log2 domain); |S|<~12 << 32

#define BAR() __builtin_amdgcn_s_barrier()
#define WAITV4 asm volatile("s_waitcnt vmcnt(4)" ::: "memory")
#define WAITV0 asm volatile("s_waitcnt vmcnt(0)" ::: "memory")

__device__ __forceinline__ float bf2f(short s) {
  return __uint_as_float(((unsigned)(unsigned short)s) << 16);
}
__device__ __forceinline__ short f2bf(float f) {   // RNE
  unsigned u = __float_as_uint(f);
  u = (u + 0x7FFFu + ((u >> 16) & 1u)) >> 16;
  return (short)u;
}
__device__ __forceinline__ short f2bf_trunc(float f) {   // truncation (hot path)
  return (short)(__float_as_uint(f) >> 16);
}

// ---------------- 0) all W f32 -> bf16 in one launch ----------------
__global__ __launch_bounds__(256) void wconv3(
    const float* __restrict__ wq, const float* __restrict__ wkv,
    const float* __restrict__ wo, short* __restrict__ dq,
    short* __restrict__ dkv, short* __restrict__ dwo)
{
  int i = blockIdx.x * 256 + threadIdx.x;   // f32x4 unit; total 2M units
  const float* src; short* dst;
  if (i < 524288) { src = wq; dst = dq; }
  else if (i < 1572864) { src = wkv; dst = dkv; i -= 524288; }
  else { src = wo; dst = dwo; i -= 1572864; }
  f32x4 v = ((const f32x4*)src)[i];
  short4v o;
#pragma unroll
  for (int e = 0; e < 4; ++e) o[e] = f2bf(v[e]);
  ((short4v*)dst)[i] = o;
}

// ---------------- 1) sim = einsum('bnd,gd->bgn') for both routings ----------------
__global__ __launch_bounds__(256) void sim_kernel(
    const float* __restrict__ x, const float* __restrict__ rtq,
    const float* __restrict__ rtkv, float* __restrict__ sim)
{
  int wid = threadIdx.x >> 6, lane = threadIdx.x & 63;
  int row = blockIdx.x * 4 + wid;              // b*N + n
  int b = row >> 12, n = row & (N_ - 1);
  const float* xr = x + (size_t)row * D_;
  float a0 = 0.f, a1 = 0.f, a2 = 0.f, a3 = 0.f;
#pragma unroll
  for (int c = 0; c < 4; ++c) {
    int d = c * 256 + lane * 4;
    f32x4 xv = *(const f32x4*)(xr + d);
    f32x4 r0 = *(const f32x4*)(rtq + d);
    f32x4 r1 = *(const f32x4*)(rtq + D_ + d);
    f32x4 r2 = *(const f32x4*)(rtkv + d);
    f32x4 r3 = *(const f32x4*)(rtkv + D_ + d);
#pragma unroll
    for (int e = 0; e < 4; ++e) {
      a0 += xv[e] * r0[e];
      a1 += xv[e] * r1[e];
      a2 += xv[e] * r2[e];
      a3 += xv[e] * r3[e];
    }
  }
#pragma unroll
  for (int o = 32; o; o >>= 1) {
    a0 += __shfl_xor(a0, o); a1 += __shfl_xor(a1, o);
    a2 += __shfl_xor(a2, o); a3 += __shfl_xor(a3, o);
  }
  if (lane == 0) {
    sim[((size_t)(b)*G_ + 0) * N_ + n] = a0;
    sim[((size_t)(b)*G_ + 1) * N_ + n] = a1;
    sim[((size_t)(B_ + b)*G_ + 0) * N_ + n] = a2;
    sim[((size_t)(B_ + b)*G_ + 1) * N_ + n] = a3;
  }
}

// ---------------- 2) coor_descent + top-k (exact tie semantics) ----------------
__global__ __launch_bounds__(1024) void coor_topk(
    const float* __restrict__ sim, int* __restrict__ idxout, int* __restrict__ inv)
{
  __shared__ float rbuf[16];
  __shared__ float res;
  __shared__ unsigned keys[N_];
  __shared__ int scanbuf[16];

  int r = blockIdx.x >> 2, b = (blockIdx.x >> 1) & 1, g = blockIdx.x & 1;
  const float* srow = sim + ((size_t)blockIdx.x << 12);
  int tid = threadIdx.x, lane = tid & 63, wid = tid >> 6;

  float sv[4];
#pragma unroll
  for (int j = 0; j < 4; ++j) sv[j] = srow[tid * 4 + j];

  float a = 0.f;
  double epsd = 4.0;
  for (int it = 0; it < 20; ++it) {
    float eps = (float)fmax(epsd, 0.03);
    epsd *= 0.7;
    float sb[4]; float lmax = -INFINITY;
#pragma unroll
    for (int j = 0; j < 4; ++j) {
      float bb = (it == 0) ? (-sv[j]) : (-fmaxf(sv[j] + a, 0.f));
      sb[j] = (sv[j] + bb) / eps;
      lmax = fmaxf(lmax, sb[j]);
    }
#pragma unroll
    for (int o = 32; o; o >>= 1) lmax = fmaxf(lmax, __shfl_xor(lmax, o));
    if (lane == 0) rbuf[wid] = lmax;
    __syncthreads();
    if (tid < 64) {
      float m = (tid < 16) ? rbuf[tid] : -INFINITY;
#pragma unroll
      for (int o = 8; o; o >>= 1) m = fmaxf(m, __shfl_xor(m, o));
      if (tid == 0) res = m;
    }
    __syncthreads();
    float mx = res;
    float lsum = 0.f;
#pragma unroll
    for (int j = 0; j < 4; ++j) lsum += expf(sb[j] - mx);
#pragma unroll
    for (int o = 32; o; o >>= 1) lsum += __shfl_xor(lsum, o);
    if (lane == 0) rbuf[wid] = lsum;
    __syncthreads();
    if (tid < 64) {
      float s = (tid < 16) ? rbuf[tid] : 0.f;
#pragma unroll
      for (int o = 8; o; o >>= 1) s += __shfl_xor(s, o);
      if (tid == 0) res = logf(s) + mx;
    }
    __syncthreads();
    float lse = res;
    a = eps * (LOGK - lse);
  }
  __syncthreads();

  // final scores: exp(min(s+a,0)/0.03); saturated entries are EXACTLY 1.0f
  unsigned kb[4]; int c1 = 0;
#pragma unroll
  for (int j = 0; j < 4; ++j) {
    float sc = expf(fminf(sv[j] + a, 0.f) / 0.03f);
    kb[j] = __float_as_uint(sc);
    keys[tid * 4 + j] = kb[j];
    c1 += (kb[j] == 0x3F800000u);
  }
#pragma unroll
  for (int o = 32; o; o >>= 1) c1 += __shfl_xor(c1, o);
  if (lane == 0) scanbuf[wid] = c1;
  __syncthreads();
  int c1tot = 0;
  for (int i = 0; i < 16; ++i) c1tot += scanbuf[i];
  __syncthreads();

  int flag[4];
  if (c1tot >= 1024) {
#pragma unroll
    for (int j = 0; j < 4; ++j) flag[j] = (kb[j] == 0x3F800000u);
  } else {
#pragma unroll
    for (int j = 0; j < 4; ++j) {
      unsigned kn = kb[j]; int n = tid * 4 + j; int rank = 0;
      for (int m = 0; m < N_; ++m) {
        unsigned km = keys[m];
        rank += (km > kn) || (km == kn && m < n);
      }
      flag[j] = (rank < 1024);
    }
  }

  int cnt = flag[0] + flag[1] + flag[2] + flag[3];
  int inc = cnt;
#pragma unroll
  for (int o = 1; o < 64; o <<= 1) {
    int tt = __shfl_up(inc, o);
    if (lane >= o) inc += tt;
  }
  if (lane == 63) scanbuf[wid] = inc;
  __syncthreads();
  int off = 0;
  for (int w = 0; w < wid; ++w) off += scanbuf[w];
  int pos = off + inc - cnt;
  int* op = idxout + ((size_t)blockIdx.x << 10);
  int* ip = inv + ((size_t)(b * G_ + g) << 12);
#pragma unroll
  for (int j = 0; j < 4; ++j) {
    if (flag[j]) {
      if (pos < 1024) {
        int n = tid * 4 + j;
        op[pos] = n;
        if (r == 0) ip[n] = pos;
      }
      pos++;
    }
  }
}

// ---------------- 3) gather + RMSNorm -> bf16 rows ----------------
__global__ __launch_bounds__(256) void gather_rms(
    const float* __restrict__ x, const int* __restrict__ idx,
    const float* __restrict__ gamma_q, const float* __restrict__ gamma_c,
    short* __restrict__ qn, short* __restrict__ cn)
{
  __shared__ float rb[4];
  __shared__ float tot;
  int id = blockIdx.x;                  // ((r*B+b)*G+g)*1024 + slot
  int r = id >> 12, rem = id & 4095;
  int g = (rem >> 10) & 1;
  int b = rem >> 11;
  int tok = idx[id];
  int t = threadIdx.x;
  const float* xr = x + ((size_t)b * N_ + tok) * D_;
  f32x4 v = *(const f32x4*)(xr + t * 4);
  float ss = v[0]*v[0] + v[1]*v[1] + v[2]*v[2] + v[3]*v[3];
#pragma unroll
  for (int o = 32; o; o >>= 1) ss += __shfl_xor(ss, o);
  if ((t & 63) == 0) rb[t >> 6] = ss;
  __syncthreads();
  if (t == 0) tot = rb[0] + rb[1] + rb[2] + rb[3];
  __syncthreads();
  float scale = 32.0f / fmaxf(sqrtf(tot), 1e-12f);
  const float* gm = (r ? gamma_c : gamma_q) + g * D_;
  f32x4 gv = *(const f32x4*)(gm + t * 4);
  short* dst = (r ? cn : qn) + ((size_t)rem << 10) + t * 4;
  short4v ov;
#pragma unroll
  for (int e = 0; e < 4; ++e) ov[e] = f2bf(v[e] * scale * gv[e]);
  *(short4v*)dst = ov;
}

// ---------------- 4) fused NT GEMM (qproj + kv): XCD-swizzled, 3-deep pipeline ----
// blockIdx (8,24,4) remapped: s=(lin%8)*96+lin/8 -> each XCD owns 96 contiguous
// work items (one bg's A panel + 12 B-tiles, ~L2-resident).
// Pipeline: counted vmcnt(4), raw s_barrier (no implicit drain), 2-buffer 3-deep.
__global__ __launch_bounds__(512, 4) void gemm_qkv(
    const short* __restrict__ qn, const short* __restrict__ cn,
    const short* __restrict__ wqb, const short* __restrict__ wkvb,
    short* __restrict__ qout, short* __restrict__ kout, short* __restrict__ vout)
{
  __shared__ short As[2][8192];
  __shared__ short Bs[2][8192];
  int t = threadIdx.x, lane = t & 63, wid = t >> 6;
  int grp = lane >> 4, l15 = lane & 15;
  int wm = wid >> 1, wn = wid & 1;
  // XCD-aware bijective swizzle (nwg=768, cpx=96)
  int lin = blockIdx.x + 8 * (blockIdx.y + 24 * blockIdx.z);
  int s = (lin & 7) * 96 + (lin >> 3);
  int bx = s & 7, ny = (s >> 3) % 24, bg = s / 192;
  bool isq = ny < 8;
  const short* A  = isq ? qn : cn;
  const short* Bw = isq ? wqb : wkvb;
  int NB = isq ? 1024 : 2048;
  int nbase = (isq ? ny : ny - 8) * 128;
  float oscale = isq ? ATTN_SCALE : 1.0f;
  int mbase = bx * 128;
  int g = bg & 1;
  const short* Ab = A + ((size_t)bg << 20);
  const short* Bp = Bw + ((size_t)g * NB + nbase) * 1024;

  f32x4 zero = {0.f, 0.f, 0.f, 0.f};
  f32x4 acc[2][4];
#pragma unroll
  for (int i = 0; i < 2; ++i)
#pragma unroll
    for (int j = 0; j < 4; ++j) acc[i][j] = zero;

  int u1 = t, u2 = t + 512;
  int r1 = u1 >> 3, j1 = u1 & 7, r2 = u2 >> 3, j2 = u2 & 7;
  const short* apA1 = Ab + ((size_t)(mbase + r1) << 10) + ((j1 ^ (r1 & 7)) << 3);
  const short* apA2 = Ab + ((size_t)(mbase + r2) << 10) + ((j2 ^ (r2 & 7)) << 3);
  const short* apB1 = Bp + ((size_t)r1 << 10) + ((j1 ^ (r1 & 7)) << 3);
  const short* apB2 = Bp + ((size_t)r2 << 10) + ((j2 ^ (r2 & 7)) << 3);
  int d1 = wid * 512, d2 = 4096 + wid * 512;

  auto STAGE = [&](int kb, int p) {
    int ko = kb * 64;
    __builtin_amdgcn_global_load_lds(
        (const __attribute__((address_space(1))) void*)(apA1 + ko),
        (__attribute__((address_space(3))) void*)(&As[p][0] + d1), 16, 0, 0);
    __builtin_amdgcn_global_load_lds(
        (const __attribute__((address_space(1))) void*)(apA2 + ko),
        (__attribute__((address_space(3))) void*)(&As[p][0] + d2), 16, 0, 0);
    __builtin_amdgcn_global_load_lds(
        (const __attribute__((address_space(1))) void*)(apB1 + ko),
        (__attribute__((address_space(3))) void*)(&Bs[p][0] + d1), 16, 0, 0);
    __builtin_amdgcn_global_load_lds(
        (const __attribute__((address_space(1))) void*)(apB2 + ko),
        (__attribute__((address_space(3))) void*)(&Bs[p][0] + d2), 16, 0, 0);
  };

  STAGE(0, 0);
  STAGE(1, 1);
  WAITV4;            // tile 0 landed; tile 1 in flight
  BAR();

  for (int kb = 0; kb < 16; ++kb) {
    int p = kb & 1;
    const char* Ac = (const char*)&As[p][0];
    const char* Bc = (const char*)&Bs[p][0];
#pragma unroll
    for (int kf = 0; kf < 2; ++kf) {
      short8 af[2], bf_[4];
#pragma unroll
      for (int mt = 0; mt < 2; ++mt) {
        int ra = wm * 32 + mt * 16 + l15;
        af[mt] = *(const short8*)(Ac + ra * 128 + (((grp << 4) + (kf << 6)) ^ ((ra & 7) << 4)));
      }
#pragma unroll
      for (int nt = 0; nt < 4; ++nt) {
        int rb = wn * 64 + nt * 16 + l15;
        bf_[nt] = *(const short8*)(Bc + rb * 128 + (((grp << 4) + (kf << 6)) ^ ((rb & 7) << 4)));
      }
      __builtin_amdgcn_s_setprio(1);
#pragma unroll
      for (int mt = 0; mt < 2; ++mt)
#pragma unroll
        for (int nt = 0; nt < 4; ++nt)
          acc[mt][nt] = __builtin_amdgcn_mfma_f32_16x16x32_bf16(af[mt], bf_[nt], acc[mt][nt], 0, 0, 0);
      __builtin_amdgcn_s_setprio(0);
    }
    if (kb + 1 < 16) {
      BAR();                               // all waves done reading buf[p]
      if (kb + 2 < 16) { STAGE(kb + 2, p); WAITV4; }
      else             { WAITV0; }
      BAR();                               // tile kb+1 visible to all
    }
  }

#pragma unroll
  for (int mt = 0; mt < 2; ++mt)
#pragma unroll
    for (int nt = 0; nt < 4; ++nt) {
      int n = nbase + wn*64 + nt*16 + l15;
#pragma unroll
      for (int rr = 0; rr < 4; ++rr) {
        int m = mbase + wm*32 + mt*16 + grp*4 + rr;
        float v = acc[mt][nt][rr] * oscale;
        if (isq) {
          qout[((size_t)bg * 1024 + m) * 1024 + n] = f2bf(v);
        } else {
          if (n < 1024) {
            kout[(((size_t)bg * H_ + (n >> 6)) * NSLOT + m) * DH_ + (n & 63)] = f2bf(v);
          } else {
            int e = n - 1024;
            vout[(((size_t)bg * H_ + (e >> 6)) * DH_ + (e & 63)) * NSLOT + m] = f2bf(v);
          }
        }
      }
    }
}

// ---------------- 4b) wo GEMM, K-split 2, XCD-swizzled (each XCD = one (bg,sp)) --
__global__ __launch_bounds__(512, 4) void gemm_wo(
    const short* __restrict__ A, const short* __restrict__ Bw,
    short* __restrict__ out0, short* __restrict__ out1)
{
  __shared__ short As[2][8192];
  __shared__ short Bs[2][8192];
  int t = threadIdx.x, lane = t & 63, wid = t >> 6;
  int grp = lane >> 4, l15 = lane & 15;
  int wm = wid >> 1, wn = wid & 1;
  // swizzle (nwg=512, cpx=64): each XCD gets one full (bg,sp) -> 2MB L2 set
  int lin = blockIdx.x + 8 * (blockIdx.y + 8 * blockIdx.z);
  int s = (lin & 7) * 64 + (lin >> 3);
  int mbase = (s & 7) * 128, nbase = ((s >> 3) & 7) * 128;
  int z = s >> 6, bg = z >> 1, sp = z & 1, g = bg & 1;
  short* out = sp ? out1 : out0;
  const short* Ab = A + ((size_t)bg << 20);
  const short* Bp = Bw + ((size_t)g * 1024 + nbase) * 1024;

  f32x4 zero = {0.f, 0.f, 0.f, 0.f};
  f32x4 acc[2][4];
#pragma unroll
  for (int i = 0; i < 2; ++i)
#pragma unroll
    for (int j = 0; j < 4; ++j) acc[i][j] = zero;

  int u1 = t, u2 = t + 512;
  int r1 = u1 >> 3, j1 = u1 & 7, r2 = u2 >> 3, j2 = u2 & 7;
  const short* apA1 = Ab + ((size_t)(mbase + r1) << 10) + ((j1 ^ (r1 & 7)) << 3);
  const short* apA2 = Ab + ((size_t)(mbase + r2) << 10) + ((j2 ^ (r2 & 7)) << 3);
  const short* apB1 = Bp + ((size_t)r1 << 10) + ((j1 ^ (r1 & 7)) << 3);
  const short* apB2 = Bp + ((size_t)r2 << 10) + ((j2 ^ (r2 & 7)) << 3);
  int d1 = wid * 512, d2 = 4096 + wid * 512;

  auto STAGE = [&](int kb, int p) {
    int ko = kb * 64;
    __builtin_amdgcn_global_load_lds(
        (const __attribute__((address_space(1))) void*)(apA1 + ko),
        (__attribute__((address_space(3))) void*)(&As[p][0] + d1), 16, 0, 0);
    __builtin_amdgcn_global_load_lds(
        (const __attribute__((address_space(1))) void*)(apA2 + ko),
        (__attribute__((address_space(3))) void*)(&As[p][0] + d2), 16, 0, 0);
    __builtin_amdgcn_global_load_lds(
        (const __attribute__((address_space(1))) void*)(apB1 + ko),
        (__attribute__((address_space(3))) void*)(&Bs[p][0] + d1), 16, 0, 0);
    __builtin_amdgcn_global_load_lds(
        (const __attribute__((address_space(1))) void*)(apB2 + ko),
        (__attribute__((address_space(3))) void*)(&Bs[p][0] + d2), 16, 0, 0);
  };

  int kb0 = sp * 8;
  STAGE(kb0, 0);
  STAGE(kb0 + 1, 1);
  WAITV4;
  BAR();

  for (int kk = 0; kk < 8; ++kk) {
    int p = kk & 1;
    const char* Ac = (const char*)&As[p][0];
    const char* Bc = (const char*)&Bs[p][0];
#pragma unroll
    for (int kf = 0; kf < 2; ++kf) {
      short8 af[2], bf_[4];
#pragma unroll
      for (int mt = 0; mt < 2; ++mt) {
        int ra = wm * 32 + mt * 16 + l15;
        af[mt] = *(const short8*)(Ac + ra * 128 + (((grp << 4) + (kf << 6)) ^ ((ra & 7) << 4)));
      }
#pragma unroll
      for (int nt = 0; nt < 4; ++nt) {
        int rb = wn * 64 + nt * 16 + l15;
        bf_[nt] = *(const short8*)(Bc + rb * 128 + (((grp << 4) + (kf << 6)) ^ ((rb & 7) << 4)));
      }
      __builtin_amdgcn_s_setprio(1);
#pragma unroll
      for (int mt = 0; mt < 2; ++mt)
#pragma unroll
        for (int nt = 0; nt < 4; ++nt)
          acc[mt][nt] = __builtin_amdgcn_mfma_f32_16x16x32_bf16(af[mt], bf_[nt], acc[mt][nt], 0, 0, 0);
      __builtin_amdgcn_s_setprio(0);
    }
    if (kk + 1 < 8) {
      BAR();
      if (kk + 2 < 8) { STAGE(kb0 + kk + 2, p); WAITV4; }
      else            { WAITV0; }
      BAR();
    }
  }

#pragma unroll
  for (int mt = 0; mt < 2; ++mt)
#pragma unroll
    for (int nt = 0; nt < 4; ++nt) {
      int n = nbase + wn*64 + nt*16 + l15;
#pragma unroll
      for (int rr = 0; rr < 4; ++rr) {
        int m = mbase + wm*32 + mt*16 + grp*4 + rr;
        out[((size_t)bg * 1024 + m) * 1024 + n] = f2bf(acc[mt][nt][rr]);
      }
    }
}

// ---------------- 5) null kv fill (slot 1024) ----------------
__global__ void null_fill(const float* __restrict__ null_kv,
                          short* __restrict__ kb_, short* __restrict__ vb_)
{
  int bgh = blockIdx.x;                 // (b*G+g)*H + h
  int g = (bgh >> 4) & 1, h = bgh & 15;
  int t = threadIdx.x;                  // 0..63
  float kvk = null_kv[((size_t)(0 * G_ + g) * H_ + h) * DH_ + t];
  float kvv = null_kv[((size_t)(1 * G_ + g) * H_ + h) * DH_ + t];
  kb_[((size_t)bgh * NSLOT + 1024) * DH_ + t] = f2bf(kvk);
  vb_[((size_t)bgh * DH_ + t) * NSLOT + 1024] = f2bf(kvv);
}

// ---------------- 6) flash attention: fixed-M, 3-deep counted-vmcnt pipeline ----
// grid (bgh=64, qb=8, sp=2): bgh%8 -> all blocks of a head on one XCD.
__global__ __launch_bounds__(256, 3) void attn_kernel(
    const short* __restrict__ q, const short* __restrict__ k,
    const short* __restrict__ vT, short* __restrict__ o0,
    short* __restrict__ o1, float* __restrict__ ml)
{
  __shared__ short Ks[2][4096];        // [64 slot][64 dh] bf16, swizzled
  __shared__ short Vs[2][4096];        // [64 dh][64 slot] bf16, swizzled
  __shared__ short Ps[4][32 * 72];     // per-wave P, padded rows
  int bgh = blockIdx.x, qb = blockIdx.y, sp = blockIdx.z;
  int bg = bgh >> 4, h = bgh & 15;
  int wid = threadIdx.x >> 6, lane = threadIdx.x & 63;
  int l15 = lane & 15, grp = lane >> 4;
  int qbase = qb * 128 + wid * 32;
  short* Pw = &Ps[wid][0];

  short8 bq[2][2];
#pragma unroll
  for (int qh = 0; qh < 2; ++qh) {
    const short* qp = q + ((size_t)bg * 1024 + qbase + qh * 16 + l15) * 1024 + h * 64 + (grp << 3);
    bq[qh][0] = *(const short8*)qp;
    bq[qh][1] = *(const short8*)(qp + 32);
  }
  // constant ones B-fragment: column n=0 all ones -> D col 0 = row-sum(P)
  short8 ones8;
  short ov = (l15 == 0) ? (short)0x3F80 : (short)0;
#pragma unroll
  for (int e = 0; e < 8; ++e) ones8[e] = ov;

  int u0 = wid * 128 + lane, u1 = u0 + 64;
  int r0 = u0 >> 3, j0 = u0 & 7, r1 = u1 >> 3, j1 = u1 & 7;
  const short* kbase = k + (size_t)bgh * NSLOT * DH_;
  const short* vbase = vT + (size_t)bgh * DH_ * NSLOT;
  const short* kss0 = kbase + r0 * 64 + ((j0 ^ (r0 & 7)) << 3);
  const short* kss1 = kbase + r1 * 64 + ((j1 ^ (r1 & 7)) << 3);
  const short* vss0 = vbase + (size_t)r0 * NSLOT + ((j0 ^ (r0 & 7)) << 3);
  const short* vss1 = vbase + (size_t)r1 * NSLOT + ((j1 ^ (r1 & 7)) << 3);

  f32x4 zero = {0.f, 0.f, 0.f, 0.f};
  f32x4 minit = {-FIXED_M, -FIXED_M, -FIXED_M, -FIXED_M};
  f32x4 oacc[2][4], lacc[2];
#pragma unroll
  for (int qh = 0; qh < 2; ++qh) {
    lacc[qh] = zero;
#pragma unroll
    for (int dt = 0; dt < 4; ++dt) oacc[qh][dt] = zero;
  }

  auto STAGE = [&](int tile, int p) {
    size_t ko = (size_t)tile * 4096;
    size_t vo = (size_t)tile * 64;
    short* kd = &Ks[p][0] + wid * 1024;
    short* vd = &Vs[p][0] + wid * 1024;
    __builtin_amdgcn_global_load_lds(
        (const __attribute__((address_space(1))) void*)(kss0 + ko),
        (__attribute__((address_space(3))) void*)kd, 16, 0, 0);
    __builtin_amdgcn_global_load_lds(
        (const __attribute__((address_space(1))) void*)(kss1 + ko),
        (__attribute__((address_space(3))) void*)(kd + 512), 16, 0, 0);
    __builtin_amdgcn_global_load_lds(
        (const __attribute__((address_space(1))) void*)(vss0 + vo),
        (__attribute__((address_space(3))) void*)vd, 16, 0, 0);
    __builtin_amdgcn_global_load_lds(
        (const __attribute__((address_space(1))) void*)(vss1 + vo),
        (__attribute__((address_space(3))) void*)(vd + 512), 16, 0, 0);
  };

  auto PROCESS = [&](int tile, int p) {
    const char* Kc = (const char*)&Ks[p][0];
    const char* Vc = (const char*)&Vs[p][0];
    f32x4 sacc[2][4];
#pragma unroll
    for (int qh = 0; qh < 2; ++qh)
#pragma unroll
      for (int kt = 0; kt < 4; ++kt) sacc[qh][kt] = minit;   // C-init = -M
#pragma unroll
    for (int kf = 0; kf < 2; ++kf) {
      short8 ka[4];
#pragma unroll
      for (int kt = 0; kt < 4; ++kt) {
        int ra = kt * 16 + l15;
        ka[kt] = *(const short8*)(Kc + ra * 128 + (((grp + 4 * kf) ^ (ra & 7)) << 4));
      }
      __builtin_amdgcn_s_setprio(1);
#pragma unroll
      for (int kt = 0; kt < 4; ++kt)
#pragma unroll
        for (int qh = 0; qh < 2; ++qh)
          sacc[qh][kt] = __builtin_amdgcn_mfma_f32_16x16x32_bf16(ka[kt], bq[qh][kf], sacc[qh][kt], 0, 0, 0);
      __builtin_amdgcn_s_setprio(0);
    }
    if (tile == 16) {
#pragma unroll
      for (int qh = 0; qh < 2; ++qh)
#pragma unroll
        for (int kt = 0; kt < 4; ++kt)
#pragma unroll
          for (int rr = 0; rr < 4; ++rr)
            if ((kt * 16 + (grp << 2) + rr) != 0) sacc[qh][kt][rr] = -INFINITY;
    }
    // P = exp2(S - M); pack to LDS
#pragma unroll
    for (int qh = 0; qh < 2; ++qh)
#pragma unroll
      for (int kt = 0; kt < 4; ++kt) {
        short4v pk;
#pragma unroll
        for (int rr = 0; rr < 4; ++rr) pk[rr] = f2bf_trunc(exp2f(sacc[qh][kt][rr]));
        *(short4v*)(Pw + (qh * 16 + l15) * 72 + kt * 16 + (grp << 2)) = pk;
      }
    // PV + l
#pragma unroll
    for (int ks = 0; ks < 2; ++ks) {
      short8 pa[2];
#pragma unroll
      for (int qh = 0; qh < 2; ++qh)
        pa[qh] = *(const short8*)((const char*)Pw + (qh * 16 + l15) * 144 + grp * 16 + ks * 64);
      __builtin_amdgcn_s_setprio(1);
#pragma unroll
      for (int dt = 0; dt < 4; ++dt) {
        int ra = dt * 16 + l15;
        short8 vbf = *(const short8*)(Vc + ra * 128 + (((grp + 4 * ks) ^ (ra & 7)) << 4));
#pragma unroll
        for (int qh = 0; qh < 2; ++qh)
          oacc[qh][dt] = __builtin_amdgcn_mfma_f32_16x16x32_bf16(pa[qh], vbf, oacc[qh][dt], 0, 0, 0);
      }
#pragma unroll
      for (int qh = 0; qh < 2; ++qh)
        lacc[qh] = __builtin_amdgcn_mfma_f32_16x16x32_bf16(pa[qh], ones8, lacc[qh], 0, 0, 0);
      __builtin_amdgcn_s_setprio(0);
    }
  };

  int t0 = sp ? 8 : 0, t1 = sp ? 17 : 8;
  STAGE(t0, 0);
  STAGE(t0 + 1, 1);          // both splits have >=8 tiles
  WAITV4;
  BAR();
  for (int tile = t0; tile < t1; ++tile) {
    int p = (tile - t0) & 1;
    PROCESS(tile, p);
    if (tile + 1 < t1) {
      BAR();
      if (tile + 2 < t1) { STAGE(tile + 2, p); WAITV4; }
      else               { WAITV0; }
      BAR();
    }
  }

  // l: lanes l15==0 hold l[q=(grp<<2)+rr] in lacc[qh][rr]
  if (l15 == 0) {
#pragma unroll
    for (int qh = 0; qh < 2; ++qh)
#pragma unroll
      for (int rr = 0; rr < 4; ++rr)
        ml[(size_t)(sp * 64 + bgh) * 1024 + qbase + qh * 16 + (grp << 2) + rr] = lacc[qh][rr];
  }
  // un-normalized partial O
#pragma unroll
  for (int qh = 0; qh < 2; ++qh)
#pragma unroll
    for (int dt = 0; dt < 4; ++dt)
#pragma unroll
      for (int rr = 0; rr < 4; ++rr) {
        int qq = qh * 16 + (grp << 2) + rr;
        int dh = dt * 16 + l15;
        if (sp == 0)
          o0[((size_t)bg * 1024 + qbase + qq) * 1024 + h * 64 + dh] = f2bf(oacc[qh][dt][rr]);
        else
          o1[((size_t)bgh * 1024 + qbase + qq) * 64 + dh] = f2bf(oacc[qh][dt][rr]);
      }
}

// ---------------- 6b) merge: O = (O0 + O1) / (l0 + l1) (same fixed M) ----------
__global__ __launch_bounds__(256) void attn_merge(
    short* __restrict__ obuf, const short* __restrict__ op1,
    const float* __restrict__ ml)
{
  int id = blockIdx.x;                  // bgh*16 + qc (64-row chunk)
  int bgh = id >> 4, qc = id & 15;
  int bg = bgh >> 4, h = bgh & 15;
  int t = threadIdx.x;
  int qq = t >> 2, c = t & 3;
  int qrow = qc * 64 + qq;
  float l0 = ml[(size_t)bgh * 1024 + qrow];
  float l1 = ml[(size_t)(64 + bgh) * 1024 + qrow];
  float w = 1.0f / (l0 + l1);
  size_t loc0 = ((size_t)bg * 1024 + qrow) * 1024 + h * 64 + c * 16;
  size_t loc1 = ((size_t)bgh * 1024 + qrow) * 64 + c * 16;
  short8 a0 = *(const short8*)(obuf + loc0);
  short8 a1 = *(const short8*)(obuf + loc0 + 8);
  short8 b0 = *(const short8*)(op1 + loc1);
  short8 b1 = *(const short8*)(op1 + loc1 + 8);
  short8 r0, r1;
#pragma unroll
  for (int e = 0; e < 8; ++e) {
    r0[e] = f2bf((bf2f(a0[e]) + bf2f(b0[e])) * w);
    r1[e] = f2bf((bf2f(a1[e]) + bf2f(b1[e])) * w);
  }
  *(short8*)(obuf + loc0) = r0;
  *(short8*)(obuf + loc0 + 8) = r1;
}

// ---------------- 7) finalize: sum K-split wo partials, scatter-average ---------
__global__ __launch_bounds__(256) void finalize_kernel(
    const short* __restrict__ wo0, const short* __restrict__ wo1,
    const int* __restrict__ inv, const float* __restrict__ null_token,
    float* __restrict__ outp)
{
  int id = blockIdx.x;                  // b*N + n
  int b = id >> 12, n = id & (N_ - 1);
  int s0 = inv[((size_t)(b * G_ + 0) << 12) + n];
  int s1 = inv[((size_t)(b * G_ + 1) << 12) + n];
  int t = threadIdx.x;
  float* dst = outp + (size_t)id * D_ + t * 4;
  if (s0 < 0 && s1 < 0) {
    *(f32x4*)dst = *(const f32x4*)(null_token + t * 4);
  } else {
    f32x4 sum = {0.f, 0.f, 0.f, 0.f};
    float cnt = 0.f;
    if (s0 >= 0) {
      size_t loc = (((size_t)(b * G_ + 0) * 1024 + s0) << 10) + t * 4;
      short4v v = *(const short4v*)(wo0 + loc);
      short4v v2 = *(const short4v*)(wo1 + loc);
#pragma unroll
      for (int e = 0; e < 4; ++e) sum[e] += bf2f(v[e]) + bf2f(v2[e]);
      cnt += 1.f;
    }
    if (s1 >= 0) {
      size_t loc = (((size_t)(b * G_ + 1) * 1024 + s1) << 10) + t * 4;
      short4v v = *(const short4v*)(wo0 + loc);
      short4v v2 = *(const short4v*)(wo1 + loc);
#pragma unroll
      for (int e = 0; e < 4; ++e) sum[e] += bf2f(v[e]) + bf2f(v2[e]);
      cnt += 1.f;
    }
    f32x4 rv;
#pragma unroll
    for (int e = 0; e < 4; ++e) rv[e] = sum[e] / cnt;
    *(f32x4*)dst = rv;
  }
}

// ---------------- launch ----------------
extern "C" void kernel_launch(void* const* d_in, const int* in_sizes, int n_in,
                              void* d_out, int out_size, void* d_ws, size_t ws_size,
                              hipStream_t stream) {
  (void)in_sizes; (void)n_in; (void)out_size; (void)ws_size;
  const float* x        = (const float*)d_in[0];
  const float* rt_q     = (const float*)d_in[1];
  const float* rt_kv    = (const float*)d_in[2];
  const float* gamma_q  = (const float*)d_in[3];
  const float* gamma_c  = (const float*)d_in[4];
  const float* wq       = (const float*)d_in[5];
  const float* wkv      = (const float*)d_in[6];
  const float* wo       = (const float*)d_in[7];
  const float* null_kv  = (const float*)d_in[8];
  const float* null_tok = (const float*)d_in[9];
  float* outp = (float*)d_out;

  char* ws = (char*)d_ws;
  size_t off = 0;
  auto alloc = [&](size_t bytes) { char* p = ws + off; off += (bytes + 255) & ~(size_t)255; return p; };
  float* sim   = (float*)alloc((size_t)2 * B_ * G_ * N_ * 4);
  int*   idx   = (int*)  alloc((size_t)2 * B_ * G_ * 1024 * 4);
  int*   inv   = (int*)  alloc((size_t)B_ * G_ * N_ * 4);
  float* ml    = (float*)alloc((size_t)2 * 64 * 1024 * 4);       // 512KB l partials
  short* qn    = (short*)alloc((size_t)B_ * G_ * 1024 * 1024 * 2);
  short* cn    = (short*)alloc((size_t)B_ * G_ * 1024 * 1024 * 2);
  short* qproj = (short*)alloc((size_t)B_ * G_ * 1024 * 1024 * 2);
  size_t kvbytes = (size_t)B_ * G_ * H_ * NSLOT * DH_ * 2;       // 256-aligned
  short* kbuf  = (short*)alloc(kvbytes);
  short* vbuf  = (short*)alloc(kvbytes);
  short* obuf  = (short*)alloc((size_t)B_ * G_ * 1024 * 1024 * 2);
  short* wobuf = (short*)alloc((size_t)B_ * G_ * 1024 * 1024 * 2);
  short* wo_bf = (short*)alloc((size_t)G_ * 1024 * 1024 * 2);
  // aliases into dead regions (lifetimes verified):
  short* wq_bf  = wobuf;  // dead until gemm_wo writes wobuf (after gemm_qkv)
  short* wkv_bf = obuf;   // consumed by gemm_qkv before attn writes obuf
  short* op1    = cn;     // split-1 partial O; cn dead after gemm_qkv
  short* wobuf2 = qproj;  // wo K-split half 1; qproj dead after attn

  hipMemsetAsync(kbuf, 0, kvbytes * 2, stream);   // kbuf+vbuf contiguous
  hipMemsetAsync(inv, 0xFF, (size_t)B_ * G_ * N_ * 4, stream);

  wconv3<<<8192, 256, 0, stream>>>(wq, wkv, wo, wq_bf, wkv_bf, wo_bf);
  sim_kernel<<<B_ * N_ / 4, 256, 0, stream>>>(x, rt_q, rt_kv, sim);
  coor_topk<<<8, 1024, 0, stream>>>(sim, idx, inv);
  gather_rms<<<2 * B_ * G_ * 1024, 256, 0, stream>>>(x, idx, gamma_q, gamma_c, qn, cn);
  gemm_qkv<<<dim3(8, 24, B_ * G_), 512, 0, stream>>>(qn, cn, wq_bf, wkv_bf, qproj, kbuf, vbuf);
  null_fill<<<B_ * G_ * H_, 64, 0, stream>>>(null_kv, kbuf, vbuf);
  attn_kernel<<<dim3(64, 8, 2), 256, 0, stream>>>(qproj, kbuf, vbuf, obuf, op1, ml);
  attn_merge<<<1024, 256, 0, stream>>>(obuf, op1, ml);
  gemm_wo<<<dim3(8, 8, 2 * B_ * G_), 512, 0, stream>>>(obuf, wo_bf, wobuf, wobuf2);
  finalize_kernel<<<B_ * N_, 256, 0, stream>>>(wobuf, wobuf2, inv, null_tok, outp);
}

// Round 10
// 179.914 us; speedup vs baseline: 1.9971x; 1.0185x over previous
//
#include <hip/hip_runtime.h>

// ---------------- types / helpers ----------------
typedef __attribute__((ext_vector_type(8))) short short8;   // 8 x bf16 (16B)
typedef __attribute__((ext_vector_type(4))) short short4v;  // 4 x bf16 (8B)
typedef __attribute__((ext_vector_type(4))) float f32x4;

#define B_ 2
#define N_ 4096
#define D_ 1024
#define G_ 2
#define H_ 16
#define DH_ 64
#define NSLOT 1088              // 1024 tokens + 1 null + pad to 17*64
#define LOGK 7.0492548412558374f  // log(1152)
#define ATTN_SCALE 0.18033688011112043f  // dh^-0.5 * log2(e): S in log2 domain
#define FIXED_M 32.0f           // fixed softmax max (log2 domain); |S|<~12 << 32

#define BAR() __builtin_amdgcn_s_barrier()
#define WAITV8 asm volatile("s_waitcnt vmcnt(8)" ::: "memory")
#define WAITV4 asm volatile("s_waitcnt vmcnt(4)" ::: "memory")
#define WAITV0 asm volatile("s_waitcnt vmcnt(0)" ::: "memory")
#define GLDS(src, dst) __builtin_amdgcn_global_load_lds( \
    (const __attribute__((address_space(1))) void*)(src), \
    (__attribute__((address_space(3))) void*)(dst), 16, 0, 0)

__device__ __forceinline__ float bf2f(short s) {
  return __uint_as_float(((unsigned)(unsigned short)s) << 16);
}
__device__ __forceinline__ short f2bf(float f) {   // RNE
  unsigned u = __float_as_uint(f);
  u = (u + 0x7FFFu + ((u >> 16) & 1u)) >> 16;
  return (short)u;
}
__device__ __forceinline__ short f2bf_trunc(float f) {   // truncation (hot path)
  return (short)(__float_as_uint(f) >> 16);
}

// ---------------- 1) prep: wconv3 + sim + null_fill fused (all independent) ----
__global__ __launch_bounds__(256) void prep_kernel(
    const float* __restrict__ wq, const float* __restrict__ wkv,
    const float* __restrict__ wo, short* __restrict__ dq,
    short* __restrict__ dkv, short* __restrict__ dwo,
    const float* __restrict__ x, const float* __restrict__ rtq,
    const float* __restrict__ rtkv, float* __restrict__ sim,
    const float* __restrict__ null_kv, short* __restrict__ kb_,
    short* __restrict__ vb_)
{
  int bid = blockIdx.x;
  if (bid < 8192) {
    // ---- weight f32 -> bf16 ----
    int i = bid * 256 + threadIdx.x;   // f32x4 unit
    const float* src; short* dst;
    if (i < 524288) { src = wq; dst = dq; }
    else if (i < 1572864) { src = wkv; dst = dkv; i -= 524288; }
    else { src = wo; dst = dwo; i -= 1572864; }
    f32x4 v = ((const f32x4*)src)[i];
    short4v o;
#pragma unroll
    for (int e = 0; e < 4; ++e) o[e] = f2bf(v[e]);
    ((short4v*)dst)[i] = o;
  } else if (bid < 10240) {
    // ---- sim = einsum('bnd,gd->bgn') ----
    int wid = threadIdx.x >> 6, lane = threadIdx.x & 63;
    int row = (bid - 8192) * 4 + wid;            // b*N + n
    int b = row >> 12, n = row & (N_ - 1);
    const float* xr = x + (size_t)row * D_;
    float a0 = 0.f, a1 = 0.f, a2 = 0.f, a3 = 0.f;
#pragma unroll
    for (int c = 0; c < 4; ++c) {
      int d = c * 256 + lane * 4;
      f32x4 xv = *(const f32x4*)(xr + d);
      f32x4 r0 = *(const f32x4*)(rtq + d);
      f32x4 r1 = *(const f32x4*)(rtq + D_ + d);
      f32x4 r2 = *(const f32x4*)(rtkv + d);
      f32x4 r3 = *(const f32x4*)(rtkv + D_ + d);
#pragma unroll
      for (int e = 0; e < 4; ++e) {
        a0 += xv[e] * r0[e];
        a1 += xv[e] * r1[e];
        a2 += xv[e] * r2[e];
        a3 += xv[e] * r3[e];
      }
    }
#pragma unroll
    for (int o = 32; o; o >>= 1) {
      a0 += __shfl_xor(a0, o); a1 += __shfl_xor(a1, o);
      a2 += __shfl_xor(a2, o); a3 += __shfl_xor(a3, o);
    }
    if (lane == 0) {
      sim[((size_t)(b)*G_ + 0) * N_ + n] = a0;
      sim[((size_t)(b)*G_ + 1) * N_ + n] = a1;
      sim[((size_t)(B_ + b)*G_ + 0) * N_ + n] = a2;
      sim[((size_t)(B_ + b)*G_ + 1) * N_ + n] = a3;
    }
  } else {
    // ---- null kv fill (slot 1024) ----
    int bgh = (bid - 10240) * 4 + (threadIdx.x >> 6);
    int g = (bgh >> 4) & 1, h = bgh & 15;
    int t = threadIdx.x & 63;
    float kvk = null_kv[((size_t)(0 * G_ + g) * H_ + h) * DH_ + t];
    float kvv = null_kv[((size_t)(1 * G_ + g) * H_ + h) * DH_ + t];
    kb_[((size_t)bgh * NSLOT + 1024) * DH_ + t] = f2bf(kvk);
    vb_[((size_t)bgh * DH_ + t) * NSLOT + 1024] = f2bf(kvv);
  }
}

// ---------------- 2) coor_descent + top-k (exact tie semantics) ----------------
__global__ __launch_bounds__(1024) void coor_topk(
    const float* __restrict__ sim, int* __restrict__ idxout, int* __restrict__ inv)
{
  __shared__ float rbuf[16];
  __shared__ float res;
  __shared__ unsigned keys[N_];
  __shared__ int scanbuf[16];

  int r = blockIdx.x >> 2, b = (blockIdx.x >> 1) & 1, g = blockIdx.x & 1;
  const float* srow = sim + ((size_t)blockIdx.x << 12);
  int tid = threadIdx.x, lane = tid & 63, wid = tid >> 6;

  float sv[4];
#pragma unroll
  for (int j = 0; j < 4; ++j) sv[j] = srow[tid * 4 + j];

  float a = 0.f;
  double epsd = 4.0;
  for (int it = 0; it < 20; ++it) {
    float eps = (float)fmax(epsd, 0.03);
    epsd *= 0.7;
    float sb[4]; float lmax = -INFINITY;
#pragma unroll
    for (int j = 0; j < 4; ++j) {
      float bb = (it == 0) ? (-sv[j]) : (-fmaxf(sv[j] + a, 0.f));
      sb[j] = (sv[j] + bb) / eps;
      lmax = fmaxf(lmax, sb[j]);
    }
#pragma unroll
    for (int o = 32; o; o >>= 1) lmax = fmaxf(lmax, __shfl_xor(lmax, o));
    if (lane == 0) rbuf[wid] = lmax;
    __syncthreads();
    if (tid < 64) {
      float m = (tid < 16) ? rbuf[tid] : -INFINITY;
#pragma unroll
      for (int o = 8; o; o >>= 1) m = fmaxf(m, __shfl_xor(m, o));
      if (tid == 0) res = m;
    }
    __syncthreads();
    float mx = res;
    float lsum = 0.f;
#pragma unroll
    for (int j = 0; j < 4; ++j) lsum += expf(sb[j] - mx);
#pragma unroll
    for (int o = 32; o; o >>= 1) lsum += __shfl_xor(lsum, o);
    if (lane == 0) rbuf[wid] = lsum;
    __syncthreads();
    if (tid < 64) {
      float s = (tid < 16) ? rbuf[tid] : 0.f;
#pragma unroll
      for (int o = 8; o; o >>= 1) s += __shfl_xor(s, o);
      if (tid == 0) res = logf(s) + mx;
    }
    __syncthreads();
    float lse = res;
    a = eps * (LOGK - lse);
  }
  __syncthreads();

  // final scores: exp(min(s+a,0)/0.03); saturated entries are EXACTLY 1.0f
  unsigned kb[4]; int c1 = 0;
#pragma unroll
  for (int j = 0; j < 4; ++j) {
    float sc = expf(fminf(sv[j] + a, 0.f) / 0.03f);
    kb[j] = __float_as_uint(sc);
    keys[tid * 4 + j] = kb[j];
    c1 += (kb[j] == 0x3F800000u);
  }
#pragma unroll
  for (int o = 32; o; o >>= 1) c1 += __shfl_xor(c1, o);
  if (lane == 0) scanbuf[wid] = c1;
  __syncthreads();
  int c1tot = 0;
  for (int i = 0; i < 16; ++i) c1tot += scanbuf[i];
  __syncthreads();

  int flag[4];
  if (c1tot >= 1024) {
#pragma unroll
    for (int j = 0; j < 4; ++j) flag[j] = (kb[j] == 0x3F800000u);
  } else {
#pragma unroll
    for (int j = 0; j < 4; ++j) {
      unsigned kn = kb[j]; int n = tid * 4 + j; int rank = 0;
      for (int m = 0; m < N_; ++m) {
        unsigned km = keys[m];
        rank += (km > kn) || (km == kn && m < n);
      }
      flag[j] = (rank < 1024);
    }
  }

  int cnt = flag[0] + flag[1] + flag[2] + flag[3];
  int inc = cnt;
#pragma unroll
  for (int o = 1; o < 64; o <<= 1) {
    int tt = __shfl_up(inc, o);
    if (lane >= o) inc += tt;
  }
  if (lane == 63) scanbuf[wid] = inc;
  __syncthreads();
  int off = 0;
  for (int w = 0; w < wid; ++w) off += scanbuf[w];
  int pos = off + inc - cnt;
  int* op = idxout + ((size_t)blockIdx.x << 10);
  int* ip = inv + ((size_t)(b * G_ + g) << 12);
#pragma unroll
  for (int j = 0; j < 4; ++j) {
    if (flag[j]) {
      if (pos < 1024) {
        int n = tid * 4 + j;
        op[pos] = n;
        if (r == 0) ip[n] = pos;
      }
      pos++;
    }
  }
}

// ---------------- 3) gather + RMSNorm -> bf16 rows ----------------
__global__ __launch_bounds__(256) void gather_rms(
    const float* __restrict__ x, const int* __restrict__ idx,
    const float* __restrict__ gamma_q, const float* __restrict__ gamma_c,
    short* __restrict__ qn, short* __restrict__ cn)
{
  __shared__ float rb[4];
  __shared__ float tot;
  int id = blockIdx.x;                  // ((r*B+b)*G+g)*1024 + slot
  int r = id >> 12, rem = id & 4095;
  int g = (rem >> 10) & 1;
  int b = rem >> 11;
  int tok = idx[id];
  int t = threadIdx.x;
  const float* xr = x + ((size_t)b * N_ + tok) * D_;
  f32x4 v = *(const f32x4*)(xr + t * 4);
  float ss = v[0]*v[0] + v[1]*v[1] + v[2]*v[2] + v[3]*v[3];
#pragma unroll
  for (int o = 32; o; o >>= 1) ss += __shfl_xor(ss, o);
  if ((t & 63) == 0) rb[t >> 6] = ss;
  __syncthreads();
  if (t == 0) tot = rb[0] + rb[1] + rb[2] + rb[3];
  __syncthreads();
  float scale = 32.0f / fmaxf(sqrtf(tot), 1e-12f);
  const float* gm = (r ? gamma_c : gamma_q) + g * D_;
  f32x4 gv = *(const f32x4*)(gm + t * 4);
  short* dst = (r ? cn : qn) + ((size_t)rem << 10) + t * 4;
  short4v ov;
#pragma unroll
  for (int e = 0; e < 4; ++e) ov[e] = f2bf(v[e] * scale * gv[e]);
  *(short4v*)dst = ov;
}

// ---------------- 4) fused NT GEMM (qproj + kv): acc[4][4], 4 waves, 128^2 ----
// XCD swizzle (nwg=768, cpx=96). 2 blocks/CU (64KB LDS). Counted vmcnt(8),
// raw s_barrier, 3-deep pipeline. Involution swizzle (rule #21).
__global__ __launch_bounds__(256, 2) void gemm_qkv(
    const short* __restrict__ qn, const short* __restrict__ cn,
    const short* __restrict__ wqb, const short* __restrict__ wkvb,
    short* __restrict__ qout, short* __restrict__ kout, short* __restrict__ vout)
{
  __shared__ short As[2][8192];
  __shared__ short Bs[2][8192];
  int t = threadIdx.x, lane = t & 63, wid = t >> 6;
  int grp = lane >> 4, l15 = lane & 15;
  int wm = wid >> 1, wn = wid & 1;
  int lin = blockIdx.x + 8 * (blockIdx.y + 24 * blockIdx.z);
  int s = (lin & 7) * 96 + (lin >> 3);
  int bx = s & 7, ny = (s >> 3) % 24, bg = s / 192;
  bool isq = ny < 8;
  const short* A  = isq ? qn : cn;
  const short* Bw = isq ? wqb : wkvb;
  int NB = isq ? 1024 : 2048;
  int nbase = (isq ? ny : ny - 8) * 128;
  float oscale = isq ? ATTN_SCALE : 1.0f;
  int mbase = bx * 128;
  int g = bg & 1;
  const short* Ab = A + ((size_t)bg << 20);
  const short* Bp = Bw + ((size_t)g * NB + nbase) * 1024;

  f32x4 zero = {0.f, 0.f, 0.f, 0.f};
  f32x4 acc[4][4];
#pragma unroll
  for (int i = 0; i < 4; ++i)
#pragma unroll
    for (int j = 0; j < 4; ++j) acc[i][j] = zero;

  // staging: 1024 16B-units per matrix; thread t covers units c*256+t, c=0..3
  const short* apA[4]; const short* apB[4]; int dstoff[4];
#pragma unroll
  for (int c = 0; c < 4; ++c) {
    int u = c * 256 + t;
    int row = u >> 3, j = u & 7;
    int cu = (j ^ (row & 7)) << 3;
    apA[c] = Ab + ((size_t)(mbase + row) << 10) + cu;
    apB[c] = Bp + ((size_t)row << 10) + cu;
    dstoff[c] = c * 2048 + wid * 512;   // wave-uniform; HW adds lane*16B
  }

  auto STAGE = [&](int kb, int p) {
    int ko = kb * 64;
#pragma unroll
    for (int c = 0; c < 4; ++c) {
      GLDS(apA[c] + ko, &As[p][0] + dstoff[c]);
      GLDS(apB[c] + ko, &Bs[p][0] + dstoff[c]);
    }
  };

  STAGE(0, 0);
  STAGE(1, 1);
  WAITV8;
  BAR();

  for (int kb = 0; kb < 16; ++kb) {
    int p = kb & 1;
    const char* Ac = (const char*)&As[p][0];
    const char* Bc = (const char*)&Bs[p][0];
#pragma unroll
    for (int kf = 0; kf < 2; ++kf) {
      short8 af[4], bf_[4];
#pragma unroll
      for (int mt = 0; mt < 4; ++mt) {
        int ra = wm * 64 + mt * 16 + l15;
        af[mt] = *(const short8*)(Ac + ra * 128 + (((grp << 4) + (kf << 6)) ^ ((ra & 7) << 4)));
      }
#pragma unroll
      for (int nt = 0; nt < 4; ++nt) {
        int rb = wn * 64 + nt * 16 + l15;
        bf_[nt] = *(const short8*)(Bc + rb * 128 + (((grp << 4) + (kf << 6)) ^ ((rb & 7) << 4)));
      }
      __builtin_amdgcn_s_setprio(1);
#pragma unroll
      for (int mt = 0; mt < 4; ++mt)
#pragma unroll
        for (int nt = 0; nt < 4; ++nt)
          acc[mt][nt] = __builtin_amdgcn_mfma_f32_16x16x32_bf16(af[mt], bf_[nt], acc[mt][nt], 0, 0, 0);
      __builtin_amdgcn_s_setprio(0);
    }
    if (kb + 1 < 16) {
      BAR();
      if (kb + 2 < 16) { STAGE(kb + 2, p); WAITV8; }
      else             { WAITV0; }
      BAR();
    }
  }

#pragma unroll
  for (int mt = 0; mt < 4; ++mt)
#pragma unroll
    for (int nt = 0; nt < 4; ++nt) {
      int n = nbase + wn*64 + nt*16 + l15;
#pragma unroll
      for (int rr = 0; rr < 4; ++rr) {
        int m = mbase + wm*64 + mt*16 + grp*4 + rr;
        float v = acc[mt][nt][rr] * oscale;
        if (isq) {
          qout[((size_t)bg * 1024 + m) * 1024 + n] = f2bf(v);
        } else {
          if (n < 1024) {
            kout[(((size_t)bg * H_ + (n >> 6)) * NSLOT + m) * DH_ + (n & 63)] = f2bf(v);
          } else {
            int e = n - 1024;
            vout[(((size_t)bg * H_ + (e >> 6)) * DH_ + (e & 63)) * NSLOT + m] = f2bf(v);
          }
        }
      }
    }
}

// ---------------- 4b) wo GEMM, K-split 2, acc[4][4], XCD-swizzled ----------------
__global__ __launch_bounds__(256, 2) void gemm_wo(
    const short* __restrict__ A, const short* __restrict__ Bw,
    short* __restrict__ out0, short* __restrict__ out1)
{
  __shared__ short As[2][8192];
  __shared__ short Bs[2][8192];
  int t = threadIdx.x, lane = t & 63, wid = t >> 6;
  int grp = lane >> 4, l15 = lane & 15;
  int wm = wid >> 1, wn = wid & 1;
  int lin = blockIdx.x + 8 * (blockIdx.y + 8 * blockIdx.z);
  int s = (lin & 7) * 64 + (lin >> 3);
  int mbase = (s & 7) * 128, nbase = ((s >> 3) & 7) * 128;
  int z = s >> 6, bg = z >> 1, sp = z & 1, g = bg & 1;
  short* out = sp ? out1 : out0;
  const short* Ab = A + ((size_t)bg << 20);
  const short* Bp = Bw + ((size_t)g * 1024 + nbase) * 1024;

  f32x4 zero = {0.f, 0.f, 0.f, 0.f};
  f32x4 acc[4][4];
#pragma unroll
  for (int i = 0; i < 4; ++i)
#pragma unroll
    for (int j = 0; j < 4; ++j) acc[i][j] = zero;

  const short* apA[4]; const short* apB[4]; int dstoff[4];
#pragma unroll
  for (int c = 0; c < 4; ++c) {
    int u = c * 256 + t;
    int row = u >> 3, j = u & 7;
    int cu = (j ^ (row & 7)) << 3;
    apA[c] = Ab + ((size_t)(mbase + row) << 10) + cu;
    apB[c] = Bp + ((size_t)row << 10) + cu;
    dstoff[c] = c * 2048 + wid * 512;
  }

  auto STAGE = [&](int kb, int p) {
    int ko = kb * 64;
#pragma unroll
    for (int c = 0; c < 4; ++c) {
      GLDS(apA[c] + ko, &As[p][0] + dstoff[c]);
      GLDS(apB[c] + ko, &Bs[p][0] + dstoff[c]);
    }
  };

  int kb0 = sp * 8;
  STAGE(kb0, 0);
  STAGE(kb0 + 1, 1);
  WAITV8;
  BAR();

  for (int kk = 0; kk < 8; ++kk) {
    int p = kk & 1;
    const char* Ac = (const char*)&As[p][0];
    const char* Bc = (const char*)&Bs[p][0];
#pragma unroll
    for (int kf = 0; kf < 2; ++kf) {
      short8 af[4], bf_[4];
#pragma unroll
      for (int mt = 0; mt < 4; ++mt) {
        int ra = wm * 64 + mt * 16 + l15;
        af[mt] = *(const short8*)(Ac + ra * 128 + (((grp << 4) + (kf << 6)) ^ ((ra & 7) << 4)));
      }
#pragma unroll
      for (int nt = 0; nt < 4; ++nt) {
        int rb = wn * 64 + nt * 16 + l15;
        bf_[nt] = *(const short8*)(Bc + rb * 128 + (((grp << 4) + (kf << 6)) ^ ((rb & 7) << 4)));
      }
      __builtin_amdgcn_s_setprio(1);
#pragma unroll
      for (int mt = 0; mt < 4; ++mt)
#pragma unroll
        for (int nt = 0; nt < 4; ++nt)
          acc[mt][nt] = __builtin_amdgcn_mfma_f32_16x16x32_bf16(af[mt], bf_[nt], acc[mt][nt], 0, 0, 0);
      __builtin_amdgcn_s_setprio(0);
    }
    if (kk + 1 < 8) {
      BAR();
      if (kk + 2 < 8) { STAGE(kb0 + kk + 2, p); WAITV8; }
      else            { WAITV0; }
      BAR();
    }
  }

#pragma unroll
  for (int mt = 0; mt < 4; ++mt)
#pragma unroll
    for (int nt = 0; nt < 4; ++nt) {
      int n = nbase + wn*64 + nt*16 + l15;
#pragma unroll
      for (int rr = 0; rr < 4; ++rr) {
        int m = mbase + wm*64 + mt*16 + grp*4 + rr;
        out[((size_t)bg * 1024 + m) * 1024 + n] = f2bf(acc[mt][nt][rr]);
      }
    }
}

// ---------------- 6) flash attention: fixed-M, 3-deep counted-vmcnt pipeline ----
// grid (bgh=64, qb=8, sp=2): bgh%8 -> all blocks of a head on one XCD.
__global__ __launch_bounds__(256, 3) void attn_kernel(
    const short* __restrict__ q, const short* __restrict__ k,
    const short* __restrict__ vT, short* __restrict__ o0,
    short* __restrict__ o1, float* __restrict__ ml)
{
  __shared__ short Ks[2][4096];        // [64 slot][64 dh] bf16, swizzled
  __shared__ short Vs[2][4096];        // [64 dh][64 slot] bf16, swizzled
  __shared__ short Ps[4][32 * 72];     // per-wave P, padded rows
  int bgh = blockIdx.x, qb = blockIdx.y, sp = blockIdx.z;
  int bg = bgh >> 4, h = bgh & 15;
  int wid = threadIdx.x >> 6, lane = threadIdx.x & 63;
  int l15 = lane & 15, grp = lane >> 4;
  int qbase = qb * 128 + wid * 32;
  short* Pw = &Ps[wid][0];

  short8 bq[2][2];
#pragma unroll
  for (int qh = 0; qh < 2; ++qh) {
    const short* qp = q + ((size_t)bg * 1024 + qbase + qh * 16 + l15) * 1024 + h * 64 + (grp << 3);
    bq[qh][0] = *(const short8*)qp;
    bq[qh][1] = *(const short8*)(qp + 32);
  }
  // constant ones B-fragment: column n=0 all ones -> D col 0 = row-sum(P)
  short8 ones8;
  short ov = (l15 == 0) ? (short)0x3F80 : (short)0;
#pragma unroll
  for (int e = 0; e < 8; ++e) ones8[e] = ov;

  int u0 = wid * 128 + lane, u1 = u0 + 64;
  int r0 = u0 >> 3, j0 = u0 & 7, r1 = u1 >> 3, j1 = u1 & 7;
  const short* kbase = k + (size_t)bgh * NSLOT * DH_;
  const short* vbase = vT + (size_t)bgh * DH_ * NSLOT;
  const short* kss0 = kbase + r0 * 64 + ((j0 ^ (r0 & 7)) << 3);
  const short* kss1 = kbase + r1 * 64 + ((j1 ^ (r1 & 7)) << 3);
  const short* vss0 = vbase + (size_t)r0 * NSLOT + ((j0 ^ (r0 & 7)) << 3);
  const short* vss1 = vbase + (size_t)r1 * NSLOT + ((j1 ^ (r1 & 7)) << 3);

  f32x4 zero = {0.f, 0.f, 0.f, 0.f};
  f32x4 minit = {-FIXED_M, -FIXED_M, -FIXED_M, -FIXED_M};
  f32x4 oacc[2][4], lacc[2];
#pragma unroll
  for (int qh = 0; qh < 2; ++qh) {
    lacc[qh] = zero;
#pragma unroll
    for (int dt = 0; dt < 4; ++dt) oacc[qh][dt] = zero;
  }

  auto STAGE = [&](int tile, int p) {
    size_t ko = (size_t)tile * 4096;
    size_t vo = (size_t)tile * 64;
    short* kd = &Ks[p][0] + wid * 1024;
    short* vd = &Vs[p][0] + wid * 1024;
    GLDS(kss0 + ko, kd);
    GLDS(kss1 + ko, kd + 512);
    GLDS(vss0 + vo, vd);
    GLDS(vss1 + vo, vd + 512);
  };

  auto PROCESS = [&](int tile, int p) {
    const char* Kc = (const char*)&Ks[p][0];
    const char* Vc = (const char*)&Vs[p][0];
    f32x4 sacc[2][4];
#pragma unroll
    for (int qh = 0; qh < 2; ++qh)
#pragma unroll
      for (int kt = 0; kt < 4; ++kt) sacc[qh][kt] = minit;   // C-init = -M
#pragma unroll
    for (int kf = 0; kf < 2; ++kf) {
      short8 ka[4];
#pragma unroll
      for (int kt = 0; kt < 4; ++kt) {
        int ra = kt * 16 + l15;
        ka[kt] = *(const short8*)(Kc + ra * 128 + (((grp + 4 * kf) ^ (ra & 7)) << 4));
      }
      __builtin_amdgcn_s_setprio(1);
#pragma unroll
      for (int kt = 0; kt < 4; ++kt)
#pragma unroll
        for (int qh = 0; qh < 2; ++qh)
          sacc[qh][kt] = __builtin_amdgcn_mfma_f32_16x16x32_bf16(ka[kt], bq[qh][kf], sacc[qh][kt], 0, 0, 0);
      __builtin_amdgcn_s_setprio(0);
    }
    if (tile == 16) {
#pragma unroll
      for (int qh = 0; qh < 2; ++qh)
#pragma unroll
        for (int kt = 0; kt < 4; ++kt)
#pragma unroll
          for (int rr = 0; rr < 4; ++rr)
            if ((kt * 16 + (grp << 2) + rr) != 0) sacc[qh][kt][rr] = -INFINITY;
    }
    // P = exp2(S - M); pack to LDS
#pragma unroll
    for (int qh = 0; qh < 2; ++qh)
#pragma unroll
      for (int kt = 0; kt < 4; ++kt) {
        short4v pk;
#pragma unroll
        for (int rr = 0; rr < 4; ++rr) pk[rr] = f2bf_trunc(exp2f(sacc[qh][kt][rr]));
        *(short4v*)(Pw + (qh * 16 + l15) * 72 + kt * 16 + (grp << 2)) = pk;
      }
    // PV + l
#pragma unroll
    for (int ks = 0; ks < 2; ++ks) {
      short8 pa[2];
#pragma unroll
      for (int qh = 0; qh < 2; ++qh)
        pa[qh] = *(const short8*)((const char*)Pw + (qh * 16 + l15) * 144 + grp * 16 + ks * 64);
      __builtin_amdgcn_s_setprio(1);
#pragma unroll
      for (int dt = 0; dt < 4; ++dt) {
        int ra = dt * 16 + l15;
        short8 vbf = *(const short8*)(Vc + ra * 128 + (((grp + 4 * ks) ^ (ra & 7)) << 4));
#pragma unroll
        for (int qh = 0; qh < 2; ++qh)
          oacc[qh][dt] = __builtin_amdgcn_mfma_f32_16x16x32_bf16(pa[qh], vbf, oacc[qh][dt], 0, 0, 0);
      }
#pragma unroll
      for (int qh = 0; qh < 2; ++qh)
        lacc[qh] = __builtin_amdgcn_mfma_f32_16x16x32_bf16(pa[qh], ones8, lacc[qh], 0, 0, 0);
      __builtin_amdgcn_s_setprio(0);
    }
  };

  int t0 = sp ? 8 : 0, t1 = sp ? 17 : 8;
  STAGE(t0, 0);
  STAGE(t0 + 1, 1);
  WAITV4;
  BAR();
  for (int tile = t0; tile < t1; ++tile) {
    int p = (tile - t0) & 1;
    PROCESS(tile, p);
    if (tile + 1 < t1) {
      BAR();
      if (tile + 2 < t1) { STAGE(tile + 2, p); WAITV4; }
      else               { WAITV0; }
      BAR();
    }
  }

  // l: lanes l15==0 hold l[q=(grp<<2)+rr] in lacc[qh][rr]
  if (l15 == 0) {
#pragma unroll
    for (int qh = 0; qh < 2; ++qh)
#pragma unroll
      for (int rr = 0; rr < 4; ++rr)
        ml[(size_t)(sp * 64 + bgh) * 1024 + qbase + qh * 16 + (grp << 2) + rr] = lacc[qh][rr];
  }
  // un-normalized partial O
#pragma unroll
  for (int qh = 0; qh < 2; ++qh)
#pragma unroll
    for (int dt = 0; dt < 4; ++dt)
#pragma unroll
      for (int rr = 0; rr < 4; ++rr) {
        int qq = qh * 16 + (grp << 2) + rr;
        int dh = dt * 16 + l15;
        if (sp == 0)
          o0[((size_t)bg * 1024 + qbase + qq) * 1024 + h * 64 + dh] = f2bf(oacc[qh][dt][rr]);
        else
          o1[((size_t)bgh * 1024 + qbase + qq) * 64 + dh] = f2bf(oacc[qh][dt][rr]);
      }
}

// ---------------- 6b) merge: O = (O0 + O1) / (l0 + l1) (same fixed M) ----------
__global__ __launch_bounds__(256) void attn_merge(
    short* __restrict__ obuf, const short* __restrict__ op1,
    const float* __restrict__ ml)
{
  int id = blockIdx.x;                  // bgh*16 + qc (64-row chunk)
  int bgh = id >> 4, qc = id & 15;
  int bg = bgh >> 4, h = bgh & 15;
  int t = threadIdx.x;
  int qq = t >> 2, c = t & 3;
  int qrow = qc * 64 + qq;
  float l0 = ml[(size_t)bgh * 1024 + qrow];
  float l1 = ml[(size_t)(64 + bgh) * 1024 + qrow];
  float w = 1.0f / (l0 + l1);
  size_t loc0 = ((size_t)bg * 1024 + qrow) * 1024 + h * 64 + c * 16;
  size_t loc1 = ((size_t)bgh * 1024 + qrow) * 64 + c * 16;
  short8 a0 = *(const short8*)(obuf + loc0);
  short8 a1 = *(const short8*)(obuf + loc0 + 8);
  short8 b0 = *(const short8*)(op1 + loc1);
  short8 b1 = *(const short8*)(op1 + loc1 + 8);
  short8 r0, r1;
#pragma unroll
  for (int e = 0; e < 8; ++e) {
    r0[e] = f2bf((bf2f(a0[e]) + bf2f(b0[e])) * w);
    r1[e] = f2bf((bf2f(a1[e]) + bf2f(b1[e])) * w);
  }
  *(short8*)(obuf + loc0) = r0;
  *(short8*)(obuf + loc0 + 8) = r1;
}

// ---------------- 7) finalize: sum K-split wo partials, scatter-average ---------
__global__ __launch_bounds__(256) void finalize_kernel(
    const short* __restrict__ wo0, const short* __restrict__ wo1,
    const int* __restrict__ inv, const float* __restrict__ null_token,
    float* __restrict__ outp)
{
  int id = blockIdx.x;                  // b*N + n
  int b = id >> 12, n = id & (N_ - 1);
  int s0 = inv[((size_t)(b * G_ + 0) << 12) + n];
  int s1 = inv[((size_t)(b * G_ + 1) << 12) + n];
  int t = threadIdx.x;
  float* dst = outp + (size_t)id * D_ + t * 4;
  if (s0 < 0 && s1 < 0) {
    *(f32x4*)dst = *(const f32x4*)(null_token + t * 4);
  } else {
    f32x4 sum = {0.f, 0.f, 0.f, 0.f};
    float cnt = 0.f;
    if (s0 >= 0) {
      size_t loc = (((size_t)(b * G_ + 0) * 1024 + s0) << 10) + t * 4;
      short4v v = *(const short4v*)(wo0 + loc);
      short4v v2 = *(const short4v*)(wo1 + loc);
#pragma unroll
      for (int e = 0; e < 4; ++e) sum[e] += bf2f(v[e]) + bf2f(v2[e]);
      cnt += 1.f;
    }
    if (s1 >= 0) {
      size_t loc = (((size_t)(b * G_ + 1) * 1024 + s1) << 10) + t * 4;
      short4v v = *(const short4v*)(wo0 + loc);
      short4v v2 = *(const short4v*)(wo1 + loc);
#pragma unroll
      for (int e = 0; e < 4; ++e) sum[e] += bf2f(v[e]) + bf2f(v2[e]);
      cnt += 1.f;
    }
    f32x4 rv;
#pragma unroll
    for (int e = 0; e < 4; ++e) rv[e] = sum[e] / cnt;
    *(f32x4*)dst = rv;
  }
}

// ---------------- launch ----------------
extern "C" void kernel_launch(void* const* d_in, const int* in_sizes, int n_in,
                              void* d_out, int out_size, void* d_ws, size_t ws_size,
                              hipStream_t stream) {
  (void)in_sizes; (void)n_in; (void)out_size; (void)ws_size;
  const float* x        = (const float*)d_in[0];
  const float* rt_q     = (const float*)d_in[1];
  const float* rt_kv    = (const float*)d_in[2];
  const float* gamma_q  = (const float*)d_in[3];
  const float* gamma_c  = (const float*)d_in[4];
  const float* wq       = (const float*)d_in[5];
  const float* wkv      = (const float*)d_in[6];
  const float* wo       = (const float*)d_in[7];
  const float* null_kv  = (const float*)d_in[8];
  const float* null_tok = (const float*)d_in[9];
  float* outp = (float*)d_out;

  char* ws = (char*)d_ws;
  size_t off = 0;
  auto alloc = [&](size_t bytes) { char* p = ws + off; off += (bytes + 255) & ~(size_t)255; return p; };
  float* sim   = (float*)alloc((size_t)2 * B_ * G_ * N_ * 4);
  int*   idx   = (int*)  alloc((size_t)2 * B_ * G_ * 1024 * 4);
  int*   inv   = (int*)  alloc((size_t)B_ * G_ * N_ * 4);
  float* ml    = (float*)alloc((size_t)2 * 64 * 1024 * 4);       // 512KB l partials
  short* qn    = (short*)alloc((size_t)B_ * G_ * 1024 * 1024 * 2);
  short* cn    = (short*)alloc((size_t)B_ * G_ * 1024 * 1024 * 2);
  short* qproj = (short*)alloc((size_t)B_ * G_ * 1024 * 1024 * 2);
  size_t kvbytes = (size_t)B_ * G_ * H_ * NSLOT * DH_ * 2;       // 256-aligned
  short* kbuf  = (short*)alloc(kvbytes);
  short* vbuf  = (short*)alloc(kvbytes);
  short* obuf  = (short*)alloc((size_t)B_ * G_ * 1024 * 1024 * 2);
  short* wobuf = (short*)alloc((size_t)B_ * G_ * 1024 * 1024 * 2);
  short* wo_bf = (short*)alloc((size_t)G_ * 1024 * 1024 * 2);
  // aliases into dead regions (lifetimes verified):
  short* wq_bf  = wobuf;  // dead until gemm_wo writes wobuf (after gemm_qkv)
  short* wkv_bf = obuf;   // consumed by gemm_qkv before attn writes obuf
  short* op1    = cn;     // split-1 partial O; cn dead after gemm_qkv
  short* wobuf2 = qproj;  // wo K-split half 1; qproj dead after attn

  // NOTE: no kbuf/vbuf memset needed — pad K rows (slots 1025..1087) only enter
  // tile 16 where S is masked to -inf before exp2; pad V columns multiply P=0;
  // all residual bit patterns are finite bf16.
  hipMemsetAsync(inv, 0xFF, (size_t)B_ * G_ * N_ * 4, stream);

  prep_kernel<<<10256, 256, 0, stream>>>(wq, wkv, wo, wq_bf, wkv_bf, wo_bf,
                                         x, rt_q, rt_kv, sim, null_kv, kbuf, vbuf);
  coor_topk<<<8, 1024, 0, stream>>>(sim, idx, inv);
  gather_rms<<<2 * B_ * G_ * 1024, 256, 0, stream>>>(x, idx, gamma_q, gamma_c, qn, cn);
  gemm_qkv<<<dim3(8, 24, B_ * G_), 256, 0, stream>>>(qn, cn, wq_bf, wkv_bf, qproj, kbuf, vbuf);
  attn_kernel<<<dim3(64, 8, 2), 256, 0, stream>>>(qproj, kbuf, vbuf, obuf, op1, ml);
  attn_merge<<<1024, 256, 0, stream>>>(obuf, op1, ml);
  gemm_wo<<<dim3(8, 8, 2 * B_ * G_), 256, 0, stream>>>(obuf, wo_bf, wobuf, wobuf2);
  finalize_kernel<<<B_ * N_, 256, 0, stream>>>(wobuf, wobuf2, inv, null_tok, outp);
}

// Round 11
// 169.685 us; speedup vs baseline: 2.1175x; 1.0603x over previous
//
#include <hip/hip_runtime.h>

// ---------------- types / helpers ----------------
typedef __attribute__((ext_vector_type(8))) short short8;   // 8 x bf16 (16B)
typedef __attribute__((ext_vector_type(4))) short short4v;  // 4 x bf16 (8B)
typedef __attribute__((ext_vector_type(4))) float f32x4;

#define B_ 2
#define N_ 4096
#define D_ 1024
#define G_ 2
#define H_ 16
#define DH_ 64
#define NSLOT 1088              // 1024 tokens + 1 null + pad to 17*64
#define LOGK 7.0492548412558374f  // log(1152)
#define ATTN_SCALE 0.18033688011112043f  // dh^-0.5 * log2(e): S in log2 domain
#define FIXED_M 32.0f           // fixed softmax max (log2 domain); |S|<~12 << 32

#define BAR() __builtin_amdgcn_s_barrier()
#define WAITV4 asm volatile("s_waitcnt vmcnt(4)" ::: "memory")
#define WAITV0 asm volatile("s_waitcnt vmcnt(0)" ::: "memory")
#define GLDS(src, dst) __builtin_amdgcn_global_load_lds( \
    (const __attribute__((address_space(1))) void*)(src), \
    (__attribute__((address_space(3))) void*)(dst), 16, 0, 0)

__device__ __forceinline__ float bf2f(short s) {
  return __uint_as_float(((unsigned)(unsigned short)s) << 16);
}
__device__ __forceinline__ short f2bf(float f) {   // RNE
  unsigned u = __float_as_uint(f);
  u = (u + 0x7FFFu + ((u >> 16) & 1u)) >> 16;
  return (short)u;
}
__device__ __forceinline__ short f2bf_trunc(float f) {   // truncation (hot path)
  return (short)(__float_as_uint(f) >> 16);
}

// ---------------- 1) prep: wconv3 + sim + null_fill fused (all independent) ----
__global__ __launch_bounds__(256) void prep_kernel(
    const float* __restrict__ wq, const float* __restrict__ wkv,
    const float* __restrict__ wo, short* __restrict__ dq,
    short* __restrict__ dkv, short* __restrict__ dwo,
    const float* __restrict__ x, const float* __restrict__ rtq,
    const float* __restrict__ rtkv, float* __restrict__ sim,
    const float* __restrict__ null_kv, short* __restrict__ kb_,
    short* __restrict__ vb_)
{
  int bid = blockIdx.x;
  if (bid < 8192) {
    // ---- weight f32 -> bf16 ----
    int i = bid * 256 + threadIdx.x;   // f32x4 unit
    const float* src; short* dst;
    if (i < 524288) { src = wq; dst = dq; }
    else if (i < 1572864) { src = wkv; dst = dkv; i -= 524288; }
    else { src = wo; dst = dwo; i -= 1572864; }
    f32x4 v = ((const f32x4*)src)[i];
    short4v o;
#pragma unroll
    for (int e = 0; e < 4; ++e) o[e] = f2bf(v[e]);
    ((short4v*)dst)[i] = o;
  } else if (bid < 10240) {
    // ---- sim = einsum('bnd,gd->bgn') ----
    int wid = threadIdx.x >> 6, lane = threadIdx.x & 63;
    int row = (bid - 8192) * 4 + wid;            // b*N + n
    int b = row >> 12, n = row & (N_ - 1);
    const float* xr = x + (size_t)row * D_;
    float a0 = 0.f, a1 = 0.f, a2 = 0.f, a3 = 0.f;
#pragma unroll
    for (int c = 0; c < 4; ++c) {
      int d = c * 256 + lane * 4;
      f32x4 xv = *(const f32x4*)(xr + d);
      f32x4 r0 = *(const f32x4*)(rtq + d);
      f32x4 r1 = *(const f32x4*)(rtq + D_ + d);
      f32x4 r2 = *(const f32x4*)(rtkv + d);
      f32x4 r3 = *(const f32x4*)(rtkv + D_ + d);
#pragma unroll
      for (int e = 0; e < 4; ++e) {
        a0 += xv[e] * r0[e];
        a1 += xv[e] * r1[e];
        a2 += xv[e] * r2[e];
        a3 += xv[e] * r3[e];
      }
    }
#pragma unroll
    for (int o = 32; o; o >>= 1) {
      a0 += __shfl_xor(a0, o); a1 += __shfl_xor(a1, o);
      a2 += __shfl_xor(a2, o); a3 += __shfl_xor(a3, o);
    }
    if (lane == 0) {
      sim[((size_t)(b)*G_ + 0) * N_ + n] = a0;
      sim[((size_t)(b)*G_ + 1) * N_ + n] = a1;
      sim[((size_t)(B_ + b)*G_ + 0) * N_ + n] = a2;
      sim[((size_t)(B_ + b)*G_ + 1) * N_ + n] = a3;
    }
  } else {
    // ---- null kv fill (slot 1024) ----
    int bgh = (bid - 10240) * 4 + (threadIdx.x >> 6);
    int g = (bgh >> 4) & 1, h = bgh & 15;
    int t = threadIdx.x & 63;
    float kvk = null_kv[((size_t)(0 * G_ + g) * H_ + h) * DH_ + t];
    float kvv = null_kv[((size_t)(1 * G_ + g) * H_ + h) * DH_ + t];
    kb_[((size_t)bgh * NSLOT + 1024) * DH_ + t] = f2bf(kvk);
    vb_[((size_t)bgh * DH_ + t) * NSLOT + 1024] = f2bf(kvv);
  }
}

// ---------------- 2) coor_descent + top-k (exact tie semantics) ----------------
__global__ __launch_bounds__(1024) void coor_topk(
    const float* __restrict__ sim, int* __restrict__ idxout, int* __restrict__ inv)
{
  __shared__ float rbuf[16];
  __shared__ float res;
  __shared__ unsigned keys[N_];
  __shared__ int scanbuf[16];

  int r = blockIdx.x >> 2, b = (blockIdx.x >> 1) & 1, g = blockIdx.x & 1;
  const float* srow = sim + ((size_t)blockIdx.x << 12);
  int tid = threadIdx.x, lane = tid & 63, wid = tid >> 6;

  float sv[4];
#pragma unroll
  for (int j = 0; j < 4; ++j) sv[j] = srow[tid * 4 + j];

  float a = 0.f;
  double epsd = 4.0;
  for (int it = 0; it < 20; ++it) {
    float eps = (float)fmax(epsd, 0.03);
    epsd *= 0.7;
    float sb[4]; float lmax = -INFINITY;
#pragma unroll
    for (int j = 0; j < 4; ++j) {
      float bb = (it == 0) ? (-sv[j]) : (-fmaxf(sv[j] + a, 0.f));
      sb[j] = (sv[j] + bb) / eps;
      lmax = fmaxf(lmax, sb[j]);
    }
#pragma unroll
    for (int o = 32; o; o >>= 1) lmax = fmaxf(lmax, __shfl_xor(lmax, o));
    if (lane == 0) rbuf[wid] = lmax;
    __syncthreads();
    if (tid < 64) {
      float m = (tid < 16) ? rbuf[tid] : -INFINITY;
#pragma unroll
      for (int o = 8; o; o >>= 1) m = fmaxf(m, __shfl_xor(m, o));
      if (tid == 0) res = m;
    }
    __syncthreads();
    float mx = res;
    float lsum = 0.f;
#pragma unroll
    for (int j = 0; j < 4; ++j) lsum += expf(sb[j] - mx);
#pragma unroll
    for (int o = 32; o; o >>= 1) lsum += __shfl_xor(lsum, o);
    if (lane == 0) rbuf[wid] = lsum;
    __syncthreads();
    if (tid < 64) {
      float s = (tid < 16) ? rbuf[tid] : 0.f;
#pragma unroll
      for (int o = 8; o; o >>= 1) s += __shfl_xor(s, o);
      if (tid == 0) res = logf(s) + mx;
    }
    __syncthreads();
    float lse = res;
    a = eps * (LOGK - lse);
  }
  __syncthreads();

  // final scores: exp(min(s+a,0)/0.03); saturated entries are EXACTLY 1.0f
  unsigned kb[4]; int c1 = 0;
#pragma unroll
  for (int j = 0; j < 4; ++j) {
    float sc = expf(fminf(sv[j] + a, 0.f) / 0.03f);
    kb[j] = __float_as_uint(sc);
    keys[tid * 4 + j] = kb[j];
    c1 += (kb[j] == 0x3F800000u);
  }
#pragma unroll
  for (int o = 32; o; o >>= 1) c1 += __shfl_xor(c1, o);
  if (lane == 0) scanbuf[wid] = c1;
  __syncthreads();
  int c1tot = 0;
  for (int i = 0; i < 16; ++i) c1tot += scanbuf[i];
  __syncthreads();

  int flag[4];
  if (c1tot >= 1024) {
#pragma unroll
    for (int j = 0; j < 4; ++j) flag[j] = (kb[j] == 0x3F800000u);
  } else {
#pragma unroll
    for (int j = 0; j < 4; ++j) {
      unsigned kn = kb[j]; int n = tid * 4 + j; int rank = 0;
      for (int m = 0; m < N_; ++m) {
        unsigned km = keys[m];
        rank += (km > kn) || (km == kn && m < n);
      }
      flag[j] = (rank < 1024);
    }
  }

  int cnt = flag[0] + flag[1] + flag[2] + flag[3];
  int inc = cnt;
#pragma unroll
  for (int o = 1; o < 64; o <<= 1) {
    int tt = __shfl_up(inc, o);
    if (lane >= o) inc += tt;
  }
  if (lane == 63) scanbuf[wid] = inc;
  __syncthreads();
  int off = 0;
  for (int w = 0; w < wid; ++w) off += scanbuf[w];
  int pos = off + inc - cnt;
  int* op = idxout + ((size_t)blockIdx.x << 10);
  int* ip = inv + ((size_t)(b * G_ + g) << 12);
#pragma unroll
  for (int j = 0; j < 4; ++j) {
    if (flag[j]) {
      if (pos < 1024) {
        int n = tid * 4 + j;
        op[pos] = n;
        if (r == 0) ip[n] = pos;
      }
      pos++;
    }
  }
}

// ---------------- 3) gather + RMSNorm -> bf16 rows ----------------
__global__ __launch_bounds__(256) void gather_rms(
    const float* __restrict__ x, const int* __restrict__ idx,
    const float* __restrict__ gamma_q, const float* __restrict__ gamma_c,
    short* __restrict__ qn, short* __restrict__ cn)
{
  __shared__ float rb[4];
  __shared__ float tot;
  int id = blockIdx.x;                  // ((r*B+b)*G+g)*1024 + slot
  int r = id >> 12, rem = id & 4095;
  int g = (rem >> 10) & 1;
  int b = rem >> 11;
  int tok = idx[id];
  int t = threadIdx.x;
  const float* xr = x + ((size_t)b * N_ + tok) * D_;
  f32x4 v = *(const f32x4*)(xr + t * 4);
  float ss = v[0]*v[0] + v[1]*v[1] + v[2]*v[2] + v[3]*v[3];
#pragma unroll
  for (int o = 32; o; o >>= 1) ss += __shfl_xor(ss, o);
  if ((t & 63) == 0) rb[t >> 6] = ss;
  __syncthreads();
  if (t == 0) tot = rb[0] + rb[1] + rb[2] + rb[3];
  __syncthreads();
  float scale = 32.0f / fmaxf(sqrtf(tot), 1e-12f);
  const float* gm = (r ? gamma_c : gamma_q) + g * D_;
  f32x4 gv = *(const f32x4*)(gm + t * 4);
  short* dst = (r ? cn : qn) + ((size_t)rem << 10) + t * 4;
  short4v ov;
#pragma unroll
  for (int e = 0; e < 4; ++e) ov[e] = f2bf(v[e] * scale * gv[e]);
  *(short4v*)dst = ov;
}

// ---------------- 4) fused NT GEMM (qproj + kv): m97 structure ----------------
// 128^2 tile, 4 waves, acc[4][4], BK=64, SINGLE-buffer 32KB LDS (3 blocks/CU ->
// cross-block overlap covers the per-step drain). XCD swizzle (nwg=768, cpx=96).
// Involution LDS swizzle (rule #21).
__global__ __launch_bounds__(256, 3) void gemm_qkv(
    const short* __restrict__ qn, const short* __restrict__ cn,
    const short* __restrict__ wqb, const short* __restrict__ wkvb,
    short* __restrict__ qout, short* __restrict__ kout, short* __restrict__ vout)
{
  __shared__ short As[8192];
  __shared__ short Bs[8192];
  int t = threadIdx.x, lane = t & 63, wid = t >> 6;
  int grp = lane >> 4, l15 = lane & 15;
  int wm = wid >> 1, wn = wid & 1;
  int lin = blockIdx.x + 8 * (blockIdx.y + 24 * blockIdx.z);
  int s = (lin & 7) * 96 + (lin >> 3);
  int bx = s & 7, ny = (s >> 3) % 24, bg = s / 192;
  bool isq = ny < 8;
  const short* A  = isq ? qn : cn;
  const short* Bw = isq ? wqb : wkvb;
  int NB = isq ? 1024 : 2048;
  int nbase = (isq ? ny : ny - 8) * 128;
  float oscale = isq ? ATTN_SCALE : 1.0f;
  int mbase = bx * 128;
  int g = bg & 1;
  const short* Ab = A + ((size_t)bg << 20);
  const short* Bp = Bw + ((size_t)g * NB + nbase) * 1024;

  f32x4 zero = {0.f, 0.f, 0.f, 0.f};
  f32x4 acc[4][4];
#pragma unroll
  for (int i = 0; i < 4; ++i)
#pragma unroll
    for (int j = 0; j < 4; ++j) acc[i][j] = zero;

  // staging: 1024 16B-units per matrix; thread t covers units c*256+t, c=0..3
  const short* apA[4]; const short* apB[4]; int dstoff[4];
#pragma unroll
  for (int c = 0; c < 4; ++c) {
    int u = c * 256 + t;
    int row = u >> 3, j = u & 7;
    int cu = (j ^ (row & 7)) << 3;
    apA[c] = Ab + ((size_t)(mbase + row) << 10) + cu;
    apB[c] = Bp + ((size_t)row << 10) + cu;
    dstoff[c] = c * 2048 + wid * 512;   // wave-uniform; HW adds lane*16B
  }

  for (int kb = 0; kb < 16; ++kb) {
    int ko = kb * 64;
    if (kb) __syncthreads();            // all waves done reading LDS
#pragma unroll
    for (int c = 0; c < 4; ++c) {
      GLDS(apA[c] + ko, As + dstoff[c]);
      GLDS(apB[c] + ko, Bs + dstoff[c]);
    }
    WAITV0;
    __syncthreads();                    // tile visible to all waves
    const char* Ac = (const char*)As;
    const char* Bc = (const char*)Bs;
#pragma unroll
    for (int kf = 0; kf < 2; ++kf) {
      short8 af[4], bf_[4];
#pragma unroll
      for (int mt = 0; mt < 4; ++mt) {
        int ra = wm * 64 + mt * 16 + l15;
        af[mt] = *(const short8*)(Ac + ra * 128 + (((grp << 4) + (kf << 6)) ^ ((ra & 7) << 4)));
      }
#pragma unroll
      for (int nt = 0; nt < 4; ++nt) {
        int rb = wn * 64 + nt * 16 + l15;
        bf_[nt] = *(const short8*)(Bc + rb * 128 + (((grp << 4) + (kf << 6)) ^ ((rb & 7) << 4)));
      }
      __builtin_amdgcn_s_setprio(1);
#pragma unroll
      for (int mt = 0; mt < 4; ++mt)
#pragma unroll
        for (int nt = 0; nt < 4; ++nt)
          acc[mt][nt] = __builtin_amdgcn_mfma_f32_16x16x32_bf16(af[mt], bf_[nt], acc[mt][nt], 0, 0, 0);
      __builtin_amdgcn_s_setprio(0);
    }
  }

#pragma unroll
  for (int mt = 0; mt < 4; ++mt)
#pragma unroll
    for (int nt = 0; nt < 4; ++nt) {
      int n = nbase + wn*64 + nt*16 + l15;
#pragma unroll
      for (int rr = 0; rr < 4; ++rr) {
        int m = mbase + wm*64 + mt*16 + grp*4 + rr;
        float v = acc[mt][nt][rr] * oscale;
        if (isq) {
          qout[((size_t)bg * 1024 + m) * 1024 + n] = f2bf(v);
        } else {
          if (n < 1024) {
            kout[(((size_t)bg * H_ + (n >> 6)) * NSLOT + m) * DH_ + (n & 63)] = f2bf(v);
          } else {
            int e = n - 1024;
            vout[(((size_t)bg * H_ + (e >> 6)) * DH_ + (e & 63)) * NSLOT + m] = f2bf(v);
          }
        }
      }
    }
}

// ---------------- 4b) wo GEMM, K-split 2, m97 structure, XCD-swizzled ----------
__global__ __launch_bounds__(256, 3) void gemm_wo(
    const short* __restrict__ A, const short* __restrict__ Bw,
    short* __restrict__ out0, short* __restrict__ out1)
{
  __shared__ short As[8192];
  __shared__ short Bs[8192];
  int t = threadIdx.x, lane = t & 63, wid = t >> 6;
  int grp = lane >> 4, l15 = lane & 15;
  int wm = wid >> 1, wn = wid & 1;
  int lin = blockIdx.x + 8 * (blockIdx.y + 8 * blockIdx.z);
  int s = (lin & 7) * 64 + (lin >> 3);
  int mbase = (s & 7) * 128, nbase = ((s >> 3) & 7) * 128;
  int z = s >> 6, bg = z >> 1, sp = z & 1, g = bg & 1;
  short* out = sp ? out1 : out0;
  const short* Ab = A + ((size_t)bg << 20);
  const short* Bp = Bw + ((size_t)g * 1024 + nbase) * 1024;

  f32x4 zero = {0.f, 0.f, 0.f, 0.f};
  f32x4 acc[4][4];
#pragma unroll
  for (int i = 0; i < 4; ++i)
#pragma unroll
    for (int j = 0; j < 4; ++j) acc[i][j] = zero;

  const short* apA[4]; const short* apB[4]; int dstoff[4];
#pragma unroll
  for (int c = 0; c < 4; ++c) {
    int u = c * 256 + t;
    int row = u >> 3, j = u & 7;
    int cu = (j ^ (row & 7)) << 3;
    apA[c] = Ab + ((size_t)(mbase + row) << 10) + cu;
    apB[c] = Bp + ((size_t)row << 10) + cu;
    dstoff[c] = c * 2048 + wid * 512;
  }

  int kb0 = sp * 8;
  for (int kk = 0; kk < 8; ++kk) {
    int ko = (kb0 + kk) * 64;
    if (kk) __syncthreads();
#pragma unroll
    for (int c = 0; c < 4; ++c) {
      GLDS(apA[c] + ko, As + dstoff[c]);
      GLDS(apB[c] + ko, Bs + dstoff[c]);
    }
    WAITV0;
    __syncthreads();
    const char* Ac = (const char*)As;
    const char* Bc = (const char*)Bs;
#pragma unroll
    for (int kf = 0; kf < 2; ++kf) {
      short8 af[4], bf_[4];
#pragma unroll
      for (int mt = 0; mt < 4; ++mt) {
        int ra = wm * 64 + mt * 16 + l15;
        af[mt] = *(const short8*)(Ac + ra * 128 + (((grp << 4) + (kf << 6)) ^ ((ra & 7) << 4)));
      }
#pragma unroll
      for (int nt = 0; nt < 4; ++nt) {
        int rb = wn * 64 + nt * 16 + l15;
        bf_[nt] = *(const short8*)(Bc + rb * 128 + (((grp << 4) + (kf << 6)) ^ ((rb & 7) << 4)));
      }
      __builtin_amdgcn_s_setprio(1);
#pragma unroll
      for (int mt = 0; mt < 4; ++mt)
#pragma unroll
        for (int nt = 0; nt < 4; ++nt)
          acc[mt][nt] = __builtin_amdgcn_mfma_f32_16x16x32_bf16(af[mt], bf_[nt], acc[mt][nt], 0, 0, 0);
      __builtin_amdgcn_s_setprio(0);
    }
  }

#pragma unroll
  for (int mt = 0; mt < 4; ++mt)
#pragma unroll
    for (int nt = 0; nt < 4; ++nt) {
      int n = nbase + wn*64 + nt*16 + l15;
#pragma unroll
      for (int rr = 0; rr < 4; ++rr) {
        int m = mbase + wm*64 + mt*16 + grp*4 + rr;
        out[((size_t)bg * 1024 + m) * 1024 + n] = f2bf(acc[mt][nt][rr]);
      }
    }
}

// ---------------- 6) flash attention: fixed-M, 3-deep counted-vmcnt pipeline ----
// grid (bgh=64, qb=8, sp=2): bgh%8 -> all blocks of a head on one XCD.
__global__ __launch_bounds__(256, 3) void attn_kernel(
    const short* __restrict__ q, const short* __restrict__ k,
    const short* __restrict__ vT, short* __restrict__ o0,
    short* __restrict__ o1, float* __restrict__ ml)
{
  __shared__ short Ks[2][4096];        // [64 slot][64 dh] bf16, swizzled
  __shared__ short Vs[2][4096];        // [64 dh][64 slot] bf16, swizzled
  __shared__ short Ps[4][32 * 72];     // per-wave P, padded rows
  int bgh = blockIdx.x, qb = blockIdx.y, sp = blockIdx.z;
  int bg = bgh >> 4, h = bgh & 15;
  int wid = threadIdx.x >> 6, lane = threadIdx.x & 63;
  int l15 = lane & 15, grp = lane >> 4;
  int qbase = qb * 128 + wid * 32;
  short* Pw = &Ps[wid][0];

  short8 bq[2][2];
#pragma unroll
  for (int qh = 0; qh < 2; ++qh) {
    const short* qp = q + ((size_t)bg * 1024 + qbase + qh * 16 + l15) * 1024 + h * 64 + (grp << 3);
    bq[qh][0] = *(const short8*)qp;
    bq[qh][1] = *(const short8*)(qp + 32);
  }
  // constant ones B-fragment: column n=0 all ones -> D col 0 = row-sum(P)
  short8 ones8;
  short ov = (l15 == 0) ? (short)0x3F80 : (short)0;
#pragma unroll
  for (int e = 0; e < 8; ++e) ones8[e] = ov;

  int u0 = wid * 128 + lane, u1 = u0 + 64;
  int r0 = u0 >> 3, j0 = u0 & 7, r1 = u1 >> 3, j1 = u1 & 7;
  const short* kbase = k + (size_t)bgh * NSLOT * DH_;
  const short* vbase = vT + (size_t)bgh * DH_ * NSLOT;
  const short* kss0 = kbase + r0 * 64 + ((j0 ^ (r0 & 7)) << 3);
  const short* kss1 = kbase + r1 * 64 + ((j1 ^ (r1 & 7)) << 3);
  const short* vss0 = vbase + (size_t)r0 * NSLOT + ((j0 ^ (r0 & 7)) << 3);
  const short* vss1 = vbase + (size_t)r1 * NSLOT + ((j1 ^ (r1 & 7)) << 3);

  f32x4 zero = {0.f, 0.f, 0.f, 0.f};
  f32x4 minit = {-FIXED_M, -FIXED_M, -FIXED_M, -FIXED_M};
  f32x4 oacc[2][4], lacc[2];
#pragma unroll
  for (int qh = 0; qh < 2; ++qh) {
    lacc[qh] = zero;
#pragma unroll
    for (int dt = 0; dt < 4; ++dt) oacc[qh][dt] = zero;
  }

  auto STAGE = [&](int tile, int p) {
    size_t ko = (size_t)tile * 4096;
    size_t vo = (size_t)tile * 64;
    short* kd = &Ks[p][0] + wid * 1024;
    short* vd = &Vs[p][0] + wid * 1024;
    GLDS(kss0 + ko, kd);
    GLDS(kss1 + ko, kd + 512);
    GLDS(vss0 + vo, vd);
    GLDS(vss1 + vo, vd + 512);
  };

  auto PROCESS = [&](int tile, int p) {
    const char* Kc = (const char*)&Ks[p][0];
    const char* Vc = (const char*)&Vs[p][0];
    f32x4 sacc[2][4];
#pragma unroll
    for (int qh = 0; qh < 2; ++qh)
#pragma unroll
      for (int kt = 0; kt < 4; ++kt) sacc[qh][kt] = minit;   // C-init = -M
#pragma unroll
    for (int kf = 0; kf < 2; ++kf) {
      short8 ka[4];
#pragma unroll
      for (int kt = 0; kt < 4; ++kt) {
        int ra = kt * 16 + l15;
        ka[kt] = *(const short8*)(Kc + ra * 128 + (((grp + 4 * kf) ^ (ra & 7)) << 4));
      }
      __builtin_amdgcn_s_setprio(1);
#pragma unroll
      for (int kt = 0; kt < 4; ++kt)
#pragma unroll
        for (int qh = 0; qh < 2; ++qh)
          sacc[qh][kt] = __builtin_amdgcn_mfma_f32_16x16x32_bf16(ka[kt], bq[qh][kf], sacc[qh][kt], 0, 0, 0);
      __builtin_amdgcn_s_setprio(0);
    }
    if (tile == 16) {
#pragma unroll
      for (int qh = 0; qh < 2; ++qh)
#pragma unroll
        for (int kt = 0; kt < 4; ++kt)
#pragma unroll
          for (int rr = 0; rr < 4; ++rr)
            if ((kt * 16 + (grp << 2) + rr) != 0) sacc[qh][kt][rr] = -INFINITY;
    }
    // P = exp2(S - M); pack to LDS
#pragma unroll
    for (int qh = 0; qh < 2; ++qh)
#pragma unroll
      for (int kt = 0; kt < 4; ++kt) {
        short4v pk;
#pragma unroll
        for (int rr = 0; rr < 4; ++rr) pk[rr] = f2bf_trunc(exp2f(sacc[qh][kt][rr]));
        *(short4v*)(Pw + (qh * 16 + l15) * 72 + kt * 16 + (grp << 2)) = pk;
      }
    // PV + l
#pragma unroll
    for (int ks = 0; ks < 2; ++ks) {
      short8 pa[2];
#pragma unroll
      for (int qh = 0; qh < 2; ++qh)
        pa[qh] = *(const short8*)((const char*)Pw + (qh * 16 + l15) * 144 + grp * 16 + ks * 64);
      __builtin_amdgcn_s_setprio(1);
#pragma unroll
      for (int dt = 0; dt < 4; ++dt) {
        int ra = dt * 16 + l15;
        short8 vbf = *(const short8*)(Vc + ra * 128 + (((grp + 4 * ks) ^ (ra & 7)) << 4));
#pragma unroll
        for (int qh = 0; qh < 2; ++qh)
          oacc[qh][dt] = __builtin_amdgcn_mfma_f32_16x16x32_bf16(pa[qh], vbf, oacc[qh][dt], 0, 0, 0);
      }
#pragma unroll
      for (int qh = 0; qh < 2; ++qh)
        lacc[qh] = __builtin_amdgcn_mfma_f32_16x16x32_bf16(pa[qh], ones8, lacc[qh], 0, 0, 0);
      __builtin_amdgcn_s_setprio(0);
    }
  };

  int t0 = sp ? 8 : 0, t1 = sp ? 17 : 8;
  STAGE(t0, 0);
  STAGE(t0 + 1, 1);
  WAITV4;
  BAR();
  for (int tile = t0; tile < t1; ++tile) {
    int p = (tile - t0) & 1;
    PROCESS(tile, p);
    if (tile + 1 < t1) {
      BAR();
      if (tile + 2 < t1) { STAGE(tile + 2, p); WAITV4; }
      else               { WAITV0; }
      BAR();
    }
  }

  // l: lanes l15==0 hold l[q=(grp<<2)+rr] in lacc[qh][rr]
  if (l15 == 0) {
#pragma unroll
    for (int qh = 0; qh < 2; ++qh)
#pragma unroll
      for (int rr = 0; rr < 4; ++rr)
        ml[(size_t)(sp * 64 + bgh) * 1024 + qbase + qh * 16 + (grp << 2) + rr] = lacc[qh][rr];
  }
  // un-normalized partial O
#pragma unroll
  for (int qh = 0; qh < 2; ++qh)
#pragma unroll
    for (int dt = 0; dt < 4; ++dt)
#pragma unroll
      for (int rr = 0; rr < 4; ++rr) {
        int qq = qh * 16 + (grp << 2) + rr;
        int dh = dt * 16 + l15;
        if (sp == 0)
          o0[((size_t)bg * 1024 + qbase + qq) * 1024 + h * 64 + dh] = f2bf(oacc[qh][dt][rr]);
        else
          o1[((size_t)bgh * 1024 + qbase + qq) * 64 + dh] = f2bf(oacc[qh][dt][rr]);
      }
}

// ---------------- 6b) merge: O = (O0 + O1) / (l0 + l1) (same fixed M) ----------
__global__ __launch_bounds__(256) void attn_merge(
    short* __restrict__ obuf, const short* __restrict__ op1,
    const float* __restrict__ ml)
{
  int id = blockIdx.x;                  // bgh*16 + qc (64-row chunk)
  int bgh = id >> 4, qc = id & 15;
  int bg = bgh >> 4, h = bgh & 15;
  int t = threadIdx.x;
  int qq = t >> 2, c = t & 3;
  int qrow = qc * 64 + qq;
  float l0 = ml[(size_t)bgh * 1024 + qrow];
  float l1 = ml[(size_t)(64 + bgh) * 1024 + qrow];
  float w = 1.0f / (l0 + l1);
  size_t loc0 = ((size_t)bg * 1024 + qrow) * 1024 + h * 64 + c * 16;
  size_t loc1 = ((size_t)bgh * 1024 + qrow) * 64 + c * 16;
  short8 a0 = *(const short8*)(obuf + loc0);
  short8 a1 = *(const short8*)(obuf + loc0 + 8);
  short8 b0 = *(const short8*)(op1 + loc1);
  short8 b1 = *(const short8*)(op1 + loc1 + 8);
  short8 r0, r1;
#pragma unroll
  for (int e = 0; e < 8; ++e) {
    r0[e] = f2bf((bf2f(a0[e]) + bf2f(b0[e])) * w);
    r1[e] = f2bf((bf2f(a1[e]) + bf2f(b1[e])) * w);
  }
  *(short8*)(obuf + loc0) = r0;
  *(short8*)(obuf + loc0 + 8) = r1;
}

// ---------------- 7) finalize: sum K-split wo partials, scatter-average ---------
__global__ __launch_bounds__(256) void finalize_kernel(
    const short* __restrict__ wo0, const short* __restrict__ wo1,
    const int* __restrict__ inv, const float* __restrict__ null_token,
    float* __restrict__ outp)
{
  int id = blockIdx.x;                  // b*N + n
  int b = id >> 12, n = id & (N_ - 1);
  int s0 = inv[((size_t)(b * G_ + 0) << 12) + n];
  int s1 = inv[((size_t)(b * G_ + 1) << 12) + n];
  int t = threadIdx.x;
  float* dst = outp + (size_t)id * D_ + t * 4;
  if (s0 < 0 && s1 < 0) {
    *(f32x4*)dst = *(const f32x4*)(null_token + t * 4);
  } else {
    f32x4 sum = {0.f, 0.f, 0.f, 0.f};
    float cnt = 0.f;
    if (s0 >= 0) {
      size_t loc = (((size_t)(b * G_ + 0) * 1024 + s0) << 10) + t * 4;
      short4v v = *(const short4v*)(wo0 + loc);
      short4v v2 = *(const short4v*)(wo1 + loc);
#pragma unroll
      for (int e = 0; e < 4; ++e) sum[e] += bf2f(v[e]) + bf2f(v2[e]);
      cnt += 1.f;
    }
    if (s1 >= 0) {
      size_t loc = (((size_t)(b * G_ + 1) * 1024 + s1) << 10) + t * 4;
      short4v v = *(const short4v*)(wo0 + loc);
      short4v v2 = *(const short4v*)(wo1 + loc);
#pragma unroll
      for (int e = 0; e < 4; ++e) sum[e] += bf2f(v[e]) + bf2f(v2[e]);
      cnt += 1.f;
    }
    f32x4 rv;
#pragma unroll
    for (int e = 0; e < 4; ++e) rv[e] = sum[e] / cnt;
    *(f32x4*)dst = rv;
  }
}

// ---------------- launch ----------------
extern "C" void kernel_launch(void* const* d_in, const int* in_sizes, int n_in,
                              void* d_out, int out_size, void* d_ws, size_t ws_size,
                              hipStream_t stream) {
  (void)in_sizes; (void)n_in; (void)out_size; (void)ws_size;
  const float* x        = (const float*)d_in[0];
  const float* rt_q     = (const float*)d_in[1];
  const float* rt_kv    = (const float*)d_in[2];
  const float* gamma_q  = (const float*)d_in[3];
  const float* gamma_c  = (const float*)d_in[4];
  const float* wq       = (const float*)d_in[5];
  const float* wkv      = (const float*)d_in[6];
  const float* wo       = (const float*)d_in[7];
  const float* null_kv  = (const float*)d_in[8];
  const float* null_tok = (const float*)d_in[9];
  float* outp = (float*)d_out;

  char* ws = (char*)d_ws;
  size_t off = 0;
  auto alloc = [&](size_t bytes) { char* p = ws + off; off += (bytes + 255) & ~(size_t)255; return p; };
  float* sim   = (float*)alloc((size_t)2 * B_ * G_ * N_ * 4);
  int*   idx   = (int*)  alloc((size_t)2 * B_ * G_ * 1024 * 4);
  int*   inv   = (int*)  alloc((size_t)B_ * G_ * N_ * 4);
  float* ml    = (float*)alloc((size_t)2 * 64 * 1024 * 4);       // 512KB l partials
  short* qn    = (short*)alloc((size_t)B_ * G_ * 1024 * 1024 * 2);
  short* cn    = (short*)alloc((size_t)B_ * G_ * 1024 * 1024 * 2);
  short* qproj = (short*)alloc((size_t)B_ * G_ * 1024 * 1024 * 2);
  size_t kvbytes = (size_t)B_ * G_ * H_ * NSLOT * DH_ * 2;       // 256-aligned
  short* kbuf  = (short*)alloc(kvbytes);
  short* vbuf  = (short*)alloc(kvbytes);
  short* obuf  = (short*)alloc((size_t)B_ * G_ * 1024 * 1024 * 2);
  short* wobuf = (short*)alloc((size_t)B_ * G_ * 1024 * 1024 * 2);
  short* wo_bf = (short*)alloc((size_t)G_ * 1024 * 1024 * 2);
  // aliases into dead regions (lifetimes verified):
  short* wq_bf  = wobuf;  // dead until gemm_wo writes wobuf (after gemm_qkv)
  short* wkv_bf = obuf;   // consumed by gemm_qkv before attn writes obuf
  short* op1    = cn;     // split-1 partial O; cn dead after gemm_qkv
  short* wobuf2 = qproj;  // wo K-split half 1; qproj dead after attn

  // NOTE: no kbuf/vbuf memset needed — pad K rows (slots 1025..1087) only enter
  // tile 16 where S is masked to -inf before exp2; pad V columns multiply P=0;
  // all residual bit patterns are finite bf16.
  hipMemsetAsync(inv, 0xFF, (size_t)B_ * G_ * N_ * 4, stream);

  prep_kernel<<<10256, 256, 0, stream>>>(wq, wkv, wo, wq_bf, wkv_bf, wo_bf,
                                         x, rt_q, rt_kv, sim, null_kv, kbuf, vbuf);
  coor_topk<<<8, 1024, 0, stream>>>(sim, idx, inv);
  gather_rms<<<2 * B_ * G_ * 1024, 256, 0, stream>>>(x, idx, gamma_q, gamma_c, qn, cn);
  gemm_qkv<<<dim3(8, 24, B_ * G_), 256, 0, stream>>>(qn, cn, wq_bf, wkv_bf, qproj, kbuf, vbuf);
  attn_kernel<<<dim3(64, 8, 2), 256, 0, stream>>>(qproj, kbuf, vbuf, obuf, op1, ml);
  attn_merge<<<1024, 256, 0, stream>>>(obuf, op1, ml);
  gemm_wo<<<dim3(8, 8, 2 * B_ * G_), 256, 0, stream>>>(obuf, wo_bf, wobuf, wobuf2);
  finalize_kernel<<<B_ * N_, 256, 0, stream>>>(wobuf, wobuf2, inv, null_tok, outp);
}

// Round 12
// 164.927 us; speedup vs baseline: 2.1786x; 1.0288x over previous
//
#include <hip/hip_runtime.h>

// ---------------- types / helpers ----------------
typedef __attribute__((ext_vector_type(8))) short short8;   // 8 x bf16 (16B)
typedef __attribute__((ext_vector_type(4))) short short4v;  // 4 x bf16 (8B)
typedef __attribute__((ext_vector_type(4))) float f32x4;

#define B_ 2
#define N_ 4096
#define D_ 1024
#define G_ 2
#define H_ 16
#define DH_ 64
#define NSLOT 1088              // 1024 tokens + 1 null + pad to 17*64
#define LOGK 7.0492548412558374f  // log(1152)
#define ATTN_SCALE 0.18033688011112043f  // dh^-0.5 * log2(e): S in log2 domain
#define FIXED_M 32.0f           // fixed softmax max (log2 domain); |S|<~12 << 32

#define BAR() __builtin_amdgcn_s_barrier()
#define WAITV4 asm volatile("s_waitcnt vmcnt(4)" ::: "memory")
#define WAITV0 asm volatile("s_waitcnt vmcnt(0)" ::: "memory")
#define GLDS(src, dst) __builtin_amdgcn_global_load_lds( \
    (const __attribute__((address_space(1))) void*)(src), \
    (__attribute__((address_space(3))) void*)(dst), 16, 0, 0)

__device__ __forceinline__ float bf2f(short s) {
  return __uint_as_float(((unsigned)(unsigned short)s) << 16);
}
__device__ __forceinline__ short f2bf(float f) {   // RNE
  unsigned u = __float_as_uint(f);
  u = (u + 0x7FFFu + ((u >> 16) & 1u)) >> 16;
  return (short)u;
}
__device__ __forceinline__ short f2bf_trunc(float f) {   // truncation (hot path)
  return (short)(__float_as_uint(f) >> 16);
}

// ---------------- 1) prep: sim + null_fill (wconv moved into topk dispatch) ----
__global__ __launch_bounds__(256) void prep_kernel(
    const float* __restrict__ x, const float* __restrict__ rtq,
    const float* __restrict__ rtkv, float* __restrict__ sim,
    const float* __restrict__ null_kv, short* __restrict__ kb_,
    short* __restrict__ vb_)
{
  int bid = blockIdx.x;
  if (bid < 2048) {
    // ---- sim = einsum('bnd,gd->bgn') ----
    int wid = threadIdx.x >> 6, lane = threadIdx.x & 63;
    int row = bid * 4 + wid;                     // b*N + n
    int b = row >> 12, n = row & (N_ - 1);
    const float* xr = x + (size_t)row * D_;
    float a0 = 0.f, a1 = 0.f, a2 = 0.f, a3 = 0.f;
#pragma unroll
    for (int c = 0; c < 4; ++c) {
      int d = c * 256 + lane * 4;
      f32x4 xv = *(const f32x4*)(xr + d);
      f32x4 r0 = *(const f32x4*)(rtq + d);
      f32x4 r1 = *(const f32x4*)(rtq + D_ + d);
      f32x4 r2 = *(const f32x4*)(rtkv + d);
      f32x4 r3 = *(const f32x4*)(rtkv + D_ + d);
#pragma unroll
      for (int e = 0; e < 4; ++e) {
        a0 += xv[e] * r0[e];
        a1 += xv[e] * r1[e];
        a2 += xv[e] * r2[e];
        a3 += xv[e] * r3[e];
      }
    }
#pragma unroll
    for (int o = 32; o; o >>= 1) {
      a0 += __shfl_xor(a0, o); a1 += __shfl_xor(a1, o);
      a2 += __shfl_xor(a2, o); a3 += __shfl_xor(a3, o);
    }
    if (lane == 0) {
      sim[((size_t)(b)*G_ + 0) * N_ + n] = a0;
      sim[((size_t)(b)*G_ + 1) * N_ + n] = a1;
      sim[((size_t)(B_ + b)*G_ + 0) * N_ + n] = a2;
      sim[((size_t)(B_ + b)*G_ + 1) * N_ + n] = a3;
    }
  } else {
    // ---- null kv fill (slot 1024) ----
    int bgh = (bid - 2048) * 4 + (threadIdx.x >> 6);
    int g = (bgh >> 4) & 1, h = bgh & 15;
    int t = threadIdx.x & 63;
    float kvk = null_kv[((size_t)(0 * G_ + g) * H_ + h) * DH_ + t];
    float kvv = null_kv[((size_t)(1 * G_ + g) * H_ + h) * DH_ + t];
    kb_[((size_t)bgh * NSLOT + 1024) * DH_ + t] = f2bf(kvk);
    vb_[((size_t)bgh * DH_ + t) * NSLOT + 1024] = f2bf(kvv);
  }
}

// ---------------- 2) coor_descent+topk (blocks 0-7) || wconv (blocks 8-519) ----
// topk uses only 8 CUs; the 17MB weight conversion rides on the idle 248 CUs.
// topk reductions: wave-local max+sum shuffles, ONE (m,s)-pair LDS round/iter.
__global__ __launch_bounds__(1024) void topk_wconv(
    const float* __restrict__ sim, int* __restrict__ idxout, int* __restrict__ inv,
    const float* __restrict__ wq, const float* __restrict__ wkv,
    const float* __restrict__ wo, short* __restrict__ dq,
    short* __restrict__ dkv, short* __restrict__ dwo)
{
  if (blockIdx.x >= 8) {
    // ---- weight f32 -> bf16: 4 f32x4 units per thread ----
    int base = (blockIdx.x - 8) * 4096 + threadIdx.x;
#pragma unroll
    for (int c = 0; c < 4; ++c) {
      int i = base + c * 1024;
      const float* src; short* dst;
      if (i < 524288) { src = wq; dst = dq; }
      else if (i < 1572864) { src = wkv; dst = dkv; i -= 524288; }
      else { src = wo; dst = dwo; i -= 1572864; }
      f32x4 v = ((const f32x4*)src)[i];
      short4v o;
#pragma unroll
      for (int e = 0; e < 4; ++e) o[e] = f2bf(v[e]);
      ((short4v*)dst)[i] = o;
    }
    return;
  }

  __shared__ float rbm[16];
  __shared__ float rbs[16];
  __shared__ float res;
  __shared__ unsigned keys[N_];
  __shared__ int scanbuf[16];

  int r = blockIdx.x >> 2, b = (blockIdx.x >> 1) & 1, g = blockIdx.x & 1;
  const float* srow = sim + ((size_t)blockIdx.x << 12);
  int tid = threadIdx.x, lane = tid & 63, wid = tid >> 6;

  float sv[4];
#pragma unroll
  for (int j = 0; j < 4; ++j) sv[j] = srow[tid * 4 + j];

  float a = 0.f;
  double epsd = 4.0;
  for (int it = 0; it < 20; ++it) {
    float eps = (float)fmax(epsd, 0.03);
    epsd *= 0.7;
    float sb[4]; float mt = -INFINITY;
#pragma unroll
    for (int j = 0; j < 4; ++j) {
      float bb = (it == 0) ? (-sv[j]) : (-fmaxf(sv[j] + a, 0.f));
      sb[j] = (sv[j] + bb) / eps;
      mt = fmaxf(mt, sb[j]);
    }
#pragma unroll
    for (int o = 32; o; o >>= 1) mt = fmaxf(mt, __shfl_xor(mt, o));
    float st = 0.f;
#pragma unroll
    for (int j = 0; j < 4; ++j) st += expf(sb[j] - mt);
#pragma unroll
    for (int o = 32; o; o >>= 1) st += __shfl_xor(st, o);
    if (lane == 0) { rbm[wid] = mt; rbs[wid] = st; }
    __syncthreads();
    if (tid < 64) {
      float m2 = (tid < 16) ? rbm[tid] : -INFINITY;
      float s2 = (tid < 16) ? rbs[tid] : 0.f;
#pragma unroll
      for (int o = 8; o; o >>= 1) {
        float mo = __shfl_xor(m2, o), so = __shfl_xor(s2, o);
        float mn = fmaxf(m2, mo);
        s2 = s2 * expf(m2 - mn) + so * expf(mo - mn);
        m2 = mn;
      }
      if (tid == 0) res = logf(s2) + m2;
    }
    __syncthreads();
    float lse = res;
    a = eps * (LOGK - lse);
  }
  __syncthreads();

  // final scores: exp(min(s+a,0)/0.03); saturated entries are EXACTLY 1.0f
  unsigned kb[4]; int c1 = 0;
#pragma unroll
  for (int j = 0; j < 4; ++j) {
    float sc = expf(fminf(sv[j] + a, 0.f) / 0.03f);
    kb[j] = __float_as_uint(sc);
    keys[tid * 4 + j] = kb[j];
    c1 += (kb[j] == 0x3F800000u);
  }
#pragma unroll
  for (int o = 32; o; o >>= 1) c1 += __shfl_xor(c1, o);
  if (lane == 0) scanbuf[wid] = c1;
  __syncthreads();
  int c1tot = 0;
  for (int i = 0; i < 16; ++i) c1tot += scanbuf[i];
  __syncthreads();

  int flag[4];
  if (c1tot >= 1024) {
#pragma unroll
    for (int j = 0; j < 4; ++j) flag[j] = (kb[j] == 0x3F800000u);
  } else {
#pragma unroll
    for (int j = 0; j < 4; ++j) {
      unsigned kn = kb[j]; int n = tid * 4 + j; int rank = 0;
      for (int m = 0; m < N_; ++m) {
        unsigned km = keys[m];
        rank += (km > kn) || (km == kn && m < n);
      }
      flag[j] = (rank < 1024);
    }
  }

  int cnt = flag[0] + flag[1] + flag[2] + flag[3];
  int inc = cnt;
#pragma unroll
  for (int o = 1; o < 64; o <<= 1) {
    int tt = __shfl_up(inc, o);
    if (lane >= o) inc += tt;
  }
  if (lane == 63) scanbuf[wid] = inc;
  __syncthreads();
  int off = 0;
  for (int w = 0; w < wid; ++w) off += scanbuf[w];
  int pos = off + inc - cnt;
  int* op = idxout + ((size_t)blockIdx.x << 10);
  int* ip = inv + ((size_t)(b * G_ + g) << 12);
#pragma unroll
  for (int j = 0; j < 4; ++j) {
    if (flag[j]) {
      if (pos < 1024) {
        int n = tid * 4 + j;
        op[pos] = n;
        if (r == 0) ip[n] = pos;
      }
      pos++;
    }
  }
}

// ---------------- 3) gather + RMSNorm -> bf16 rows ----------------
__global__ __launch_bounds__(256) void gather_rms(
    const float* __restrict__ x, const int* __restrict__ idx,
    const float* __restrict__ gamma_q, const float* __restrict__ gamma_c,
    short* __restrict__ qn, short* __restrict__ cn)
{
  __shared__ float rb[4];
  __shared__ float tot;
  int id = blockIdx.x;                  // ((r*B+b)*G+g)*1024 + slot
  int r = id >> 12, rem = id & 4095;
  int g = (rem >> 10) & 1;
  int b = rem >> 11;
  int tok = idx[id];
  int t = threadIdx.x;
  const float* xr = x + ((size_t)b * N_ + tok) * D_;
  f32x4 v = *(const f32x4*)(xr + t * 4);
  float ss = v[0]*v[0] + v[1]*v[1] + v[2]*v[2] + v[3]*v[3];
#pragma unroll
  for (int o = 32; o; o >>= 1) ss += __shfl_xor(ss, o);
  if ((t & 63) == 0) rb[t >> 6] = ss;
  __syncthreads();
  if (t == 0) tot = rb[0] + rb[1] + rb[2] + rb[3];
  __syncthreads();
  float scale = 32.0f / fmaxf(sqrtf(tot), 1e-12f);
  const float* gm = (r ? gamma_c : gamma_q) + g * D_;
  f32x4 gv = *(const f32x4*)(gm + t * 4);
  short* dst = (r ? cn : qn) + ((size_t)rem << 10) + t * 4;
  short4v ov;
#pragma unroll
  for (int e = 0; e < 4; ++e) ov[e] = f2bf(v[e] * scale * gv[e]);
  *(short4v*)dst = ov;
}

// ---------------- 4) fused NT GEMM (qproj + kv): m97 structure ----------------
// 128^2 tile, 4 waves, acc[4][4], BK=64, SINGLE-buffer 32KB LDS (3 blocks/CU ->
// cross-block overlap covers the per-step drain). XCD swizzle (nwg=768, cpx=96).
// Involution LDS swizzle (rule #21).
__global__ __launch_bounds__(256, 3) void gemm_qkv(
    const short* __restrict__ qn, const short* __restrict__ cn,
    const short* __restrict__ wqb, const short* __restrict__ wkvb,
    short* __restrict__ qout, short* __restrict__ kout, short* __restrict__ vout)
{
  __shared__ short As[8192];
  __shared__ short Bs[8192];
  int t = threadIdx.x, lane = t & 63, wid = t >> 6;
  int grp = lane >> 4, l15 = lane & 15;
  int wm = wid >> 1, wn = wid & 1;
  int lin = blockIdx.x + 8 * (blockIdx.y + 24 * blockIdx.z);
  int s = (lin & 7) * 96 + (lin >> 3);
  int bx = s & 7, ny = (s >> 3) % 24, bg = s / 192;
  bool isq = ny < 8;
  const short* A  = isq ? qn : cn;
  const short* Bw = isq ? wqb : wkvb;
  int NB = isq ? 1024 : 2048;
  int nbase = (isq ? ny : ny - 8) * 128;
  float oscale = isq ? ATTN_SCALE : 1.0f;
  int mbase = bx * 128;
  int g = bg & 1;
  const short* Ab = A + ((size_t)bg << 20);
  const short* Bp = Bw + ((size_t)g * NB + nbase) * 1024;

  f32x4 zero = {0.f, 0.f, 0.f, 0.f};
  f32x4 acc[4][4];
#pragma unroll
  for (int i = 0; i < 4; ++i)
#pragma unroll
    for (int j = 0; j < 4; ++j) acc[i][j] = zero;

  // staging: 1024 16B-units per matrix; thread t covers units c*256+t, c=0..3
  const short* apA[4]; const short* apB[4]; int dstoff[4];
#pragma unroll
  for (int c = 0; c < 4; ++c) {
    int u = c * 256 + t;
    int row = u >> 3, j = u & 7;
    int cu = (j ^ (row & 7)) << 3;
    apA[c] = Ab + ((size_t)(mbase + row) << 10) + cu;
    apB[c] = Bp + ((size_t)row << 10) + cu;
    dstoff[c] = c * 2048 + wid * 512;   // wave-uniform; HW adds lane*16B
  }

  for (int kb = 0; kb < 16; ++kb) {
    int ko = kb * 64;
    if (kb) __syncthreads();            // all waves done reading LDS
#pragma unroll
    for (int c = 0; c < 4; ++c) {
      GLDS(apA[c] + ko, As + dstoff[c]);
      GLDS(apB[c] + ko, Bs + dstoff[c]);
    }
    WAITV0;
    __syncthreads();                    // tile visible to all waves
    const char* Ac = (const char*)As;
    const char* Bc = (const char*)Bs;
#pragma unroll
    for (int kf = 0; kf < 2; ++kf) {
      short8 af[4], bf_[4];
#pragma unroll
      for (int mt = 0; mt < 4; ++mt) {
        int ra = wm * 64 + mt * 16 + l15;
        af[mt] = *(const short8*)(Ac + ra * 128 + (((grp << 4) + (kf << 6)) ^ ((ra & 7) << 4)));
      }
#pragma unroll
      for (int nt = 0; nt < 4; ++nt) {
        int rb = wn * 64 + nt * 16 + l15;
        bf_[nt] = *(const short8*)(Bc + rb * 128 + (((grp << 4) + (kf << 6)) ^ ((rb & 7) << 4)));
      }
      __builtin_amdgcn_s_setprio(1);
#pragma unroll
      for (int mt = 0; mt < 4; ++mt)
#pragma unroll
        for (int nt = 0; nt < 4; ++nt)
          acc[mt][nt] = __builtin_amdgcn_mfma_f32_16x16x32_bf16(af[mt], bf_[nt], acc[mt][nt], 0, 0, 0);
      __builtin_amdgcn_s_setprio(0);
    }
  }

#pragma unroll
  for (int mt = 0; mt < 4; ++mt)
#pragma unroll
    for (int nt = 0; nt < 4; ++nt) {
      int n = nbase + wn*64 + nt*16 + l15;
#pragma unroll
      for (int rr = 0; rr < 4; ++rr) {
        int m = mbase + wm*64 + mt*16 + grp*4 + rr;
        float v = acc[mt][nt][rr] * oscale;
        if (isq) {
          qout[((size_t)bg * 1024 + m) * 1024 + n] = f2bf(v);
        } else {
          if (n < 1024) {
            kout[(((size_t)bg * H_ + (n >> 6)) * NSLOT + m) * DH_ + (n & 63)] = f2bf(v);
          } else {
            int e = n - 1024;
            vout[(((size_t)bg * H_ + (e >> 6)) * DH_ + (e & 63)) * NSLOT + m] = f2bf(v);
          }
        }
      }
    }
}

// ---------------- 4b) wo GEMM, K-split 2, m97 structure, XCD-swizzled ----------
__global__ __launch_bounds__(256, 3) void gemm_wo(
    const short* __restrict__ A, const short* __restrict__ Bw,
    short* __restrict__ out0, short* __restrict__ out1)
{
  __shared__ short As[8192];
  __shared__ short Bs[8192];
  int t = threadIdx.x, lane = t & 63, wid = t >> 6;
  int grp = lane >> 4, l15 = lane & 15;
  int wm = wid >> 1, wn = wid & 1;
  int lin = blockIdx.x + 8 * (blockIdx.y + 8 * blockIdx.z);
  int s = (lin & 7) * 64 + (lin >> 3);
  int mbase = (s & 7) * 128, nbase = ((s >> 3) & 7) * 128;
  int z = s >> 6, bg = z >> 1, sp = z & 1, g = bg & 1;
  short* out = sp ? out1 : out0;
  const short* Ab = A + ((size_t)bg << 20);
  const short* Bp = Bw + ((size_t)g * 1024 + nbase) * 1024;

  f32x4 zero = {0.f, 0.f, 0.f, 0.f};
  f32x4 acc[4][4];
#pragma unroll
  for (int i = 0; i < 4; ++i)
#pragma unroll
    for (int j = 0; j < 4; ++j) acc[i][j] = zero;

  const short* apA[4]; const short* apB[4]; int dstoff[4];
#pragma unroll
  for (int c = 0; c < 4; ++c) {
    int u = c * 256 + t;
    int row = u >> 3, j = u & 7;
    int cu = (j ^ (row & 7)) << 3;
    apA[c] = Ab + ((size_t)(mbase + row) << 10) + cu;
    apB[c] = Bp + ((size_t)row << 10) + cu;
    dstoff[c] = c * 2048 + wid * 512;
  }

  int kb0 = sp * 8;
  for (int kk = 0; kk < 8; ++kk) {
    int ko = (kb0 + kk) * 64;
    if (kk) __syncthreads();
#pragma unroll
    for (int c = 0; c < 4; ++c) {
      GLDS(apA[c] + ko, As + dstoff[c]);
      GLDS(apB[c] + ko, Bs + dstoff[c]);
    }
    WAITV0;
    __syncthreads();
    const char* Ac = (const char*)As;
    const char* Bc = (const char*)Bs;
#pragma unroll
    for (int kf = 0; kf < 2; ++kf) {
      short8 af[4], bf_[4];
#pragma unroll
      for (int mt = 0; mt < 4; ++mt) {
        int ra = wm * 64 + mt * 16 + l15;
        af[mt] = *(const short8*)(Ac + ra * 128 + (((grp << 4) + (kf << 6)) ^ ((ra & 7) << 4)));
      }
#pragma unroll
      for (int nt = 0; nt < 4; ++nt) {
        int rb = wn * 64 + nt * 16 + l15;
        bf_[nt] = *(const short8*)(Bc + rb * 128 + (((grp << 4) + (kf << 6)) ^ ((rb & 7) << 4)));
      }
      __builtin_amdgcn_s_setprio(1);
#pragma unroll
      for (int mt = 0; mt < 4; ++mt)
#pragma unroll
        for (int nt = 0; nt < 4; ++nt)
          acc[mt][nt] = __builtin_amdgcn_mfma_f32_16x16x32_bf16(af[mt], bf_[nt], acc[mt][nt], 0, 0, 0);
      __builtin_amdgcn_s_setprio(0);
    }
  }

#pragma unroll
  for (int mt = 0; mt < 4; ++mt)
#pragma unroll
    for (int nt = 0; nt < 4; ++nt) {
      int n = nbase + wn*64 + nt*16 + l15;
#pragma unroll
      for (int rr = 0; rr < 4; ++rr) {
        int m = mbase + wm*64 + mt*16 + grp*4 + rr;
        out[((size_t)bg * 1024 + m) * 1024 + n] = f2bf(acc[mt][nt][rr]);
      }
    }
}

// ---------------- 6) flash attention: fixed-M, 3-deep counted-vmcnt pipeline ----
// grid (bgh=64, qb=8, sp=2): bgh%8 -> all blocks of a head on one XCD.
__global__ __launch_bounds__(256, 3) void attn_kernel(
    const short* __restrict__ q, const short* __restrict__ k,
    const short* __restrict__ vT, short* __restrict__ o0,
    short* __restrict__ o1, float* __restrict__ ml)
{
  __shared__ short Ks[2][4096];        // [64 slot][64 dh] bf16, swizzled
  __shared__ short Vs[2][4096];        // [64 dh][64 slot] bf16, swizzled
  __shared__ short Ps[4][32 * 72];     // per-wave P, padded rows
  int bgh = blockIdx.x, qb = blockIdx.y, sp = blockIdx.z;
  int bg = bgh >> 4, h = bgh & 15;
  int wid = threadIdx.x >> 6, lane = threadIdx.x & 63;
  int l15 = lane & 15, grp = lane >> 4;
  int qbase = qb * 128 + wid * 32;
  short* Pw = &Ps[wid][0];

  short8 bq[2][2];
#pragma unroll
  for (int qh = 0; qh < 2; ++qh) {
    const short* qp = q + ((size_t)bg * 1024 + qbase + qh * 16 + l15) * 1024 + h * 64 + (grp << 3);
    bq[qh][0] = *(const short8*)qp;
    bq[qh][1] = *(const short8*)(qp + 32);
  }
  // constant ones B-fragment: column n=0 all ones -> D col 0 = row-sum(P)
  short8 ones8;
  short ov = (l15 == 0) ? (short)0x3F80 : (short)0;
#pragma unroll
  for (int e = 0; e < 8; ++e) ones8[e] = ov;

  int u0 = wid * 128 + lane, u1 = u0 + 64;
  int r0 = u0 >> 3, j0 = u0 & 7, r1 = u1 >> 3, j1 = u1 & 7;
  const short* kbase = k + (size_t)bgh * NSLOT * DH_;
  const short* vbase = vT + (size_t)bgh * DH_ * NSLOT;
  const short* kss0 = kbase + r0 * 64 + ((j0 ^ (r0 & 7)) << 3);
  const short* kss1 = kbase + r1 * 64 + ((j1 ^ (r1 & 7)) << 3);
  const short* vss0 = vbase + (size_t)r0 * NSLOT + ((j0 ^ (r0 & 7)) << 3);
  const short* vss1 = vbase + (size_t)r1 * NSLOT + ((j1 ^ (r1 & 7)) << 3);

  f32x4 zero = {0.f, 0.f, 0.f, 0.f};
  f32x4 minit = {-FIXED_M, -FIXED_M, -FIXED_M, -FIXED_M};
  f32x4 oacc[2][4], lacc[2];
#pragma unroll
  for (int qh = 0; qh < 2; ++qh) {
    lacc[qh] = zero;
#pragma unroll
    for (int dt = 0; dt < 4; ++dt) oacc[qh][dt] = zero;
  }

  auto STAGE = [&](int tile, int p) {
    size_t ko = (size_t)tile * 4096;
    size_t vo = (size_t)tile * 64;
    short* kd = &Ks[p][0] + wid * 1024;
    short* vd = &Vs[p][0] + wid * 1024;
    GLDS(kss0 + ko, kd);
    GLDS(kss1 + ko, kd + 512);
    GLDS(vss0 + vo, vd);
    GLDS(vss1 + vo, vd + 512);
  };

  auto PROCESS = [&](int tile, int p) {
    const char* Kc = (const char*)&Ks[p][0];
    const char* Vc = (const char*)&Vs[p][0];
    f32x4 sacc[2][4];
#pragma unroll
    for (int qh = 0; qh < 2; ++qh)
#pragma unroll
      for (int kt = 0; kt < 4; ++kt) sacc[qh][kt] = minit;   // C-init = -M
#pragma unroll
    for (int kf = 0; kf < 2; ++kf) {
      short8 ka[4];
#pragma unroll
      for (int kt = 0; kt < 4; ++kt) {
        int ra = kt * 16 + l15;
        ka[kt] = *(const short8*)(Kc + ra * 128 + (((grp + 4 * kf) ^ (ra & 7)) << 4));
      }
      __builtin_amdgcn_s_setprio(1);
#pragma unroll
      for (int kt = 0; kt < 4; ++kt)
#pragma unroll
        for (int qh = 0; qh < 2; ++qh)
          sacc[qh][kt] = __builtin_amdgcn_mfma_f32_16x16x32_bf16(ka[kt], bq[qh][kf], sacc[qh][kt], 0, 0, 0);
      __builtin_amdgcn_s_setprio(0);
    }
    if (tile == 16) {
#pragma unroll
      for (int qh = 0; qh < 2; ++qh)
#pragma unroll
        for (int kt = 0; kt < 4; ++kt)
#pragma unroll
          for (int rr = 0; rr < 4; ++rr)
            if ((kt * 16 + (grp << 2) + rr) != 0) sacc[qh][kt][rr] = -INFINITY;
    }
    // P = exp2(S - M); pack to LDS
#pragma unroll
    for (int qh = 0; qh < 2; ++qh)
#pragma unroll
      for (int kt = 0; kt < 4; ++kt) {
        short4v pk;
#pragma unroll
        for (int rr = 0; rr < 4; ++rr) pk[rr] = f2bf_trunc(exp2f(sacc[qh][kt][rr]));
        *(short4v*)(Pw + (qh * 16 + l15) * 72 + kt * 16 + (grp << 2)) = pk;
      }
    // PV + l
#pragma unroll
    for (int ks = 0; ks < 2; ++ks) {
      short8 pa[2];
#pragma unroll
      for (int qh = 0; qh < 2; ++qh)
        pa[qh] = *(const short8*)((const char*)Pw + (qh * 16 + l15) * 144 + grp * 16 + ks * 64);
      __builtin_amdgcn_s_setprio(1);
#pragma unroll
      for (int dt = 0; dt < 4; ++dt) {
        int ra = dt * 16 + l15;
        short8 vbf = *(const short8*)(Vc + ra * 128 + (((grp + 4 * ks) ^ (ra & 7)) << 4));
#pragma unroll
        for (int qh = 0; qh < 2; ++qh)
          oacc[qh][dt] = __builtin_amdgcn_mfma_f32_16x16x32_bf16(pa[qh], vbf, oacc[qh][dt], 0, 0, 0);
      }
#pragma unroll
      for (int qh = 0; qh < 2; ++qh)
        lacc[qh] = __builtin_amdgcn_mfma_f32_16x16x32_bf16(pa[qh], ones8, lacc[qh], 0, 0, 0);
      __builtin_amdgcn_s_setprio(0);
    }
  };

  int t0 = sp ? 8 : 0, t1 = sp ? 17 : 8;
  STAGE(t0, 0);
  STAGE(t0 + 1, 1);
  WAITV4;
  BAR();
  for (int tile = t0; tile < t1; ++tile) {
    int p = (tile - t0) & 1;
    PROCESS(tile, p);
    if (tile + 1 < t1) {
      BAR();
      if (tile + 2 < t1) { STAGE(tile + 2, p); WAITV4; }
      else               { WAITV0; }
      BAR();
    }
  }

  // l: lanes l15==0 hold l[q=(grp<<2)+rr] in lacc[qh][rr]
  if (l15 == 0) {
#pragma unroll
    for (int qh = 0; qh < 2; ++qh)
#pragma unroll
      for (int rr = 0; rr < 4; ++rr)
        ml[(size_t)(sp * 64 + bgh) * 1024 + qbase + qh * 16 + (grp << 2) + rr] = lacc[qh][rr];
  }
  // un-normalized partial O
#pragma unroll
  for (int qh = 0; qh < 2; ++qh)
#pragma unroll
    for (int dt = 0; dt < 4; ++dt)
#pragma unroll
      for (int rr = 0; rr < 4; ++rr) {
        int qq = qh * 16 + (grp << 2) + rr;
        int dh = dt * 16 + l15;
        if (sp == 0)
          o0[((size_t)bg * 1024 + qbase + qq) * 1024 + h * 64 + dh] = f2bf(oacc[qh][dt][rr]);
        else
          o1[((size_t)bgh * 1024 + qbase + qq) * 64 + dh] = f2bf(oacc[qh][dt][rr]);
      }
}

// ---------------- 6b) merge: O = (O0 + O1) / (l0 + l1) (same fixed M) ----------
__global__ __launch_bounds__(256) void attn_merge(
    short* __restrict__ obuf, const short* __restrict__ op1,
    const float* __restrict__ ml)
{
  int id = blockIdx.x;                  // bgh*16 + qc (64-row chunk)
  int bgh = id >> 4, qc = id & 15;
  int bg = bgh >> 4, h = bgh & 15;
  int t = threadIdx.x;
  int qq = t >> 2, c = t & 3;
  int qrow = qc * 64 + qq;
  float l0 = ml[(size_t)bgh * 1024 + qrow];
  float l1 = ml[(size_t)(64 + bgh) * 1024 + qrow];
  float w = 1.0f / (l0 + l1);
  size_t loc0 = ((size_t)bg * 1024 + qrow) * 1024 + h * 64 + c * 16;
  size_t loc1 = ((size_t)bgh * 1024 + qrow) * 64 + c * 16;
  short8 a0 = *(const short8*)(obuf + loc0);
  short8 a1 = *(const short8*)(obuf + loc0 + 8);
  short8 b0 = *(const short8*)(op1 + loc1);
  short8 b1 = *(const short8*)(op1 + loc1 + 8);
  short8 r0, r1;
#pragma unroll
  for (int e = 0; e < 8; ++e) {
    r0[e] = f2bf((bf2f(a0[e]) + bf2f(b0[e])) * w);
    r1[e] = f2bf((bf2f(a1[e]) + bf2f(b1[e])) * w);
  }
  *(short8*)(obuf + loc0) = r0;
  *(short8*)(obuf + loc0 + 8) = r1;
}

// ---------------- 7) finalize: sum K-split wo partials, scatter-average ---------
__global__ __launch_bounds__(256) void finalize_kernel(
    const short* __restrict__ wo0, const short* __restrict__ wo1,
    const int* __restrict__ inv, const float* __restrict__ null_token,
    float* __restrict__ outp)
{
  int id = blockIdx.x;                  // b*N + n
  int b = id >> 12, n = id & (N_ - 1);
  int s0 = inv[((size_t)(b * G_ + 0) << 12) + n];
  int s1 = inv[((size_t)(b * G_ + 1) << 12) + n];
  int t = threadIdx.x;
  float* dst = outp + (size_t)id * D_ + t * 4;
  if (s0 < 0 && s1 < 0) {
    *(f32x4*)dst = *(const f32x4*)(null_token + t * 4);
  } else {
    f32x4 sum = {0.f, 0.f, 0.f, 0.f};
    float cnt = 0.f;
    if (s0 >= 0) {
      size_t loc = (((size_t)(b * G_ + 0) * 1024 + s0) << 10) + t * 4;
      short4v v = *(const short4v*)(wo0 + loc);
      short4v v2 = *(const short4v*)(wo1 + loc);
#pragma unroll
      for (int e = 0; e < 4; ++e) sum[e] += bf2f(v[e]) + bf2f(v2[e]);
      cnt += 1.f;
    }
    if (s1 >= 0) {
      size_t loc = (((size_t)(b * G_ + 1) * 1024 + s1) << 10) + t * 4;
      short4v v = *(const short4v*)(wo0 + loc);
      short4v v2 = *(const short4v*)(wo1 + loc);
#pragma unroll
      for (int e = 0; e < 4; ++e) sum[e] += bf2f(v[e]) + bf2f(v2[e]);
      cnt += 1.f;
    }
    f32x4 rv;
#pragma unroll
    for (int e = 0; e < 4; ++e) rv[e] = sum[e] / cnt;
    *(f32x4*)dst = rv;
  }
}

// ---------------- launch ----------------
extern "C" void kernel_launch(void* const* d_in, const int* in_sizes, int n_in,
                              void* d_out, int out_size, void* d_ws, size_t ws_size,
                              hipStream_t stream) {
  (void)in_sizes; (void)n_in; (void)out_size; (void)ws_size;
  const float* x        = (const float*)d_in[0];
  const float* rt_q     = (const float*)d_in[1];
  const float* rt_kv    = (const float*)d_in[2];
  const float* gamma_q  = (const float*)d_in[3];
  const float* gamma_c  = (const float*)d_in[4];
  const float* wq       = (const float*)d_in[5];
  const float* wkv      = (const float*)d_in[6];
  const float* wo       = (const float*)d_in[7];
  const float* null_kv  = (const float*)d_in[8];
  const float* null_tok = (const float*)d_in[9];
  float* outp = (float*)d_out;

  char* ws = (char*)d_ws;
  size_t off = 0;
  auto alloc = [&](size_t bytes) { char* p = ws + off; off += (bytes + 255) & ~(size_t)255; return p; };
  float* sim   = (float*)alloc((size_t)2 * B_ * G_ * N_ * 4);
  int*   idx   = (int*)  alloc((size_t)2 * B_ * G_ * 1024 * 4);
  int*   inv   = (int*)  alloc((size_t)B_ * G_ * N_ * 4);
  float* ml    = (float*)alloc((size_t)2 * 64 * 1024 * 4);       // 512KB l partials
  short* qn    = (short*)alloc((size_t)B_ * G_ * 1024 * 1024 * 2);
  short* cn    = (short*)alloc((size_t)B_ * G_ * 1024 * 1024 * 2);
  short* qproj = (short*)alloc((size_t)B_ * G_ * 1024 * 1024 * 2);
  size_t kvbytes = (size_t)B_ * G_ * H_ * NSLOT * DH_ * 2;       // 256-aligned
  short* kbuf  = (short*)alloc(kvbytes);
  short* vbuf  = (short*)alloc(kvbytes);
  short* obuf  = (short*)alloc((size_t)B_ * G_ * 1024 * 1024 * 2);
  short* wobuf = (short*)alloc((size_t)B_ * G_ * 1024 * 1024 * 2);
  short* wo_bf = (short*)alloc((size_t)G_ * 1024 * 1024 * 2);
  // aliases into dead regions (lifetimes verified):
  short* wq_bf  = wobuf;  // dead until gemm_wo writes wobuf (after gemm_qkv)
  short* wkv_bf = obuf;   // consumed by gemm_qkv before attn writes obuf
  short* op1    = cn;     // split-1 partial O; cn dead after gemm_qkv
  short* wobuf2 = qproj;  // wo K-split half 1; qproj dead after attn

  // NOTE: no kbuf/vbuf memset needed — pad K rows (slots 1025..1087) only enter
  // tile 16 where S is masked to -inf before exp2; pad V columns multiply P=0;
  // all residual bit patterns are finite bf16.
  hipMemsetAsync(inv, 0xFF, (size_t)B_ * G_ * N_ * 4, stream);

  prep_kernel<<<2064, 256, 0, stream>>>(x, rt_q, rt_kv, sim, null_kv, kbuf, vbuf);
  topk_wconv<<<520, 1024, 0, stream>>>(sim, idx, inv, wq, wkv, wo,
                                       wq_bf, wkv_bf, wo_bf);
  gather_rms<<<2 * B_ * G_ * 1024, 256, 0, stream>>>(x, idx, gamma_q, gamma_c, qn, cn);
  gemm_qkv<<<dim3(8, 24, B_ * G_), 256, 0, stream>>>(qn, cn, wq_bf, wkv_bf, qproj, kbuf, vbuf);
  attn_kernel<<<dim3(64, 8, 2), 256, 0, stream>>>(qproj, kbuf, vbuf, obuf, op1, ml);
  attn_merge<<<1024, 256, 0, stream>>>(obuf, op1, ml);
  gemm_wo<<<dim3(8, 8, 2 * B_ * G_), 256, 0, stream>>>(obuf, wo_bf, wobuf, wobuf2);
  finalize_kernel<<<B_ * N_, 256, 0, stream>>>(wobuf, wobuf2, inv, null_tok, outp);
}

// Round 13
// 158.206 us; speedup vs baseline: 2.2712x; 1.0425x over previous
//
#include <hip/hip_runtime.h>

// ---------------- types / helpers ----------------
typedef __attribute__((ext_vector_type(8))) short short8;   // 8 x bf16 (16B)
typedef __attribute__((ext_vector_type(4))) short short4v;  // 4 x bf16 (8B)
typedef __attribute__((ext_vector_type(4))) float f32x4;

#define B_ 2
#define N_ 4096
#define D_ 1024
#define G_ 2
#define H_ 16
#define DH_ 64
#define NSLOT 1088              // 1024 tokens + 1 null + pad to 17*64
#define LOGK 7.0492548412558374f  // log(1152)
#define ATTN_SCALE 0.18033688011112043f  // dh^-0.5 * log2(e): S in log2 domain
#define FIXED_M 32.0f           // fixed softmax max (log2 domain); |S|<~12 << 32

#define BAR() __builtin_amdgcn_s_barrier()
#define WAITV4 asm volatile("s_waitcnt vmcnt(4)" ::: "memory")
#define WAITV0 asm volatile("s_waitcnt vmcnt(0)" ::: "memory")
#define GLDS(src, dst) __builtin_amdgcn_global_load_lds( \
    (const __attribute__((address_space(1))) void*)(src), \
    (__attribute__((address_space(3))) void*)(dst), 16, 0, 0)

__device__ __forceinline__ float bf2f(short s) {
  return __uint_as_float(((unsigned)(unsigned short)s) << 16);
}
__device__ __forceinline__ short f2bf(float f) {   // RNE
  unsigned u = __float_as_uint(f);
  u = (u + 0x7FFFu + ((u >> 16) & 1u)) >> 16;
  return (short)u;
}
__device__ __forceinline__ short f2bf_trunc(float f) {   // truncation (hot path)
  return (short)(__float_as_uint(f) >> 16);
}

// ---------------- 1) prep: sim + null_fill ----------------
__global__ __launch_bounds__(256) void prep_kernel(
    const float* __restrict__ x, const float* __restrict__ rtq,
    const float* __restrict__ rtkv, float* __restrict__ sim,
    const float* __restrict__ null_kv, short* __restrict__ kb_,
    short* __restrict__ vb_)
{
  int bid = blockIdx.x;
  if (bid < 2048) {
    // ---- sim = einsum('bnd,gd->bgn') ----
    int wid = threadIdx.x >> 6, lane = threadIdx.x & 63;
    int row = bid * 4 + wid;                     // b*N + n
    int b = row >> 12, n = row & (N_ - 1);
    const float* xr = x + (size_t)row * D_;
    float a0 = 0.f, a1 = 0.f, a2 = 0.f, a3 = 0.f;
#pragma unroll
    for (int c = 0; c < 4; ++c) {
      int d = c * 256 + lane * 4;
      f32x4 xv = *(const f32x4*)(xr + d);
      f32x4 r0 = *(const f32x4*)(rtq + d);
      f32x4 r1 = *(const f32x4*)(rtq + D_ + d);
      f32x4 r2 = *(const f32x4*)(rtkv + d);
      f32x4 r3 = *(const f32x4*)(rtkv + D_ + d);
#pragma unroll
      for (int e = 0; e < 4; ++e) {
        a0 += xv[e] * r0[e];
        a1 += xv[e] * r1[e];
        a2 += xv[e] * r2[e];
        a3 += xv[e] * r3[e];
      }
    }
#pragma unroll
    for (int o = 32; o; o >>= 1) {
      a0 += __shfl_xor(a0, o); a1 += __shfl_xor(a1, o);
      a2 += __shfl_xor(a2, o); a3 += __shfl_xor(a3, o);
    }
    if (lane == 0) {
      sim[((size_t)(b)*G_ + 0) * N_ + n] = a0;
      sim[((size_t)(b)*G_ + 1) * N_ + n] = a1;
      sim[((size_t)(B_ + b)*G_ + 0) * N_ + n] = a2;
      sim[((size_t)(B_ + b)*G_ + 1) * N_ + n] = a3;
    }
  } else {
    // ---- null kv fill (slot 1024) ----
    int bgh = (bid - 2048) * 4 + (threadIdx.x >> 6);
    int g = (bgh >> 4) & 1, h = bgh & 15;
    int t = threadIdx.x & 63;
    float kvk = null_kv[((size_t)(0 * G_ + g) * H_ + h) * DH_ + t];
    float kvv = null_kv[((size_t)(1 * G_ + g) * H_ + h) * DH_ + t];
    kb_[((size_t)bgh * NSLOT + 1024) * DH_ + t] = f2bf(kvk);
    vb_[((size_t)bgh * DH_ + t) * NSLOT + 1024] = f2bf(kvv);
  }
}

// ---------------- 2) coor_descent+topk (blocks 0-7) || wconv (blocks 8-519) ----
__global__ __launch_bounds__(1024) void topk_wconv(
    const float* __restrict__ sim, int* __restrict__ idxout, int* __restrict__ inv,
    const float* __restrict__ wq, const float* __restrict__ wkv,
    const float* __restrict__ wo, short* __restrict__ dq,
    short* __restrict__ dkv, short* __restrict__ dwo)
{
  if (blockIdx.x >= 8) {
    // ---- weight f32 -> bf16: 4 f32x4 units per thread ----
    int base = (blockIdx.x - 8) * 4096 + threadIdx.x;
#pragma unroll
    for (int c = 0; c < 4; ++c) {
      int i = base + c * 1024;
      const float* src; short* dst;
      if (i < 524288) { src = wq; dst = dq; }
      else if (i < 1572864) { src = wkv; dst = dkv; i -= 524288; }
      else { src = wo; dst = dwo; i -= 1572864; }
      f32x4 v = ((const f32x4*)src)[i];
      short4v o;
#pragma unroll
      for (int e = 0; e < 4; ++e) o[e] = f2bf(v[e]);
      ((short4v*)dst)[i] = o;
    }
    return;
  }

  __shared__ float rbm[16];
  __shared__ float rbs[16];
  __shared__ float res;
  __shared__ unsigned keys[N_];
  __shared__ int scanbuf[16];

  int r = blockIdx.x >> 2, b = (blockIdx.x >> 1) & 1, g = blockIdx.x & 1;
  const float* srow = sim + ((size_t)blockIdx.x << 12);
  int tid = threadIdx.x, lane = tid & 63, wid = tid >> 6;

  float sv[4];
#pragma unroll
  for (int j = 0; j < 4; ++j) sv[j] = srow[tid * 4 + j];

  float a = 0.f;
  double epsd = 4.0;
  for (int it = 0; it < 20; ++it) {
    float eps = (float)fmax(epsd, 0.03);
    epsd *= 0.7;
    float sb[4]; float mt = -INFINITY;
#pragma unroll
    for (int j = 0; j < 4; ++j) {
      float bb = (it == 0) ? (-sv[j]) : (-fmaxf(sv[j] + a, 0.f));
      sb[j] = (sv[j] + bb) / eps;
      mt = fmaxf(mt, sb[j]);
    }
#pragma unroll
    for (int o = 32; o; o >>= 1) mt = fmaxf(mt, __shfl_xor(mt, o));
    float st = 0.f;
#pragma unroll
    for (int j = 0; j < 4; ++j) st += expf(sb[j] - mt);
#pragma unroll
    for (int o = 32; o; o >>= 1) st += __shfl_xor(st, o);
    if (lane == 0) { rbm[wid] = mt; rbs[wid] = st; }
    __syncthreads();
    if (tid < 64) {
      float m2 = (tid < 16) ? rbm[tid] : -INFINITY;
      float s2 = (tid < 16) ? rbs[tid] : 0.f;
#pragma unroll
      for (int o = 8; o; o >>= 1) {
        float mo = __shfl_xor(m2, o), so = __shfl_xor(s2, o);
        float mn = fmaxf(m2, mo);
        s2 = s2 * expf(m2 - mn) + so * expf(mo - mn);
        m2 = mn;
      }
      if (tid == 0) res = logf(s2) + m2;
    }
    __syncthreads();
    float lse = res;
    a = eps * (LOGK - lse);
  }
  __syncthreads();

  // final scores: exp(min(s+a,0)/0.03); saturated entries are EXACTLY 1.0f
  unsigned kb[4]; int c1 = 0;
#pragma unroll
  for (int j = 0; j < 4; ++j) {
    float sc = expf(fminf(sv[j] + a, 0.f) / 0.03f);
    kb[j] = __float_as_uint(sc);
    keys[tid * 4 + j] = kb[j];
    c1 += (kb[j] == 0x3F800000u);
  }
#pragma unroll
  for (int o = 32; o; o >>= 1) c1 += __shfl_xor(c1, o);
  if (lane == 0) scanbuf[wid] = c1;
  __syncthreads();
  int c1tot = 0;
  for (int i = 0; i < 16; ++i) c1tot += scanbuf[i];
  __syncthreads();

  int flag[4];
  if (c1tot >= 1024) {
#pragma unroll
    for (int j = 0; j < 4; ++j) flag[j] = (kb[j] == 0x3F800000u);
  } else {
#pragma unroll
    for (int j = 0; j < 4; ++j) {
      unsigned kn = kb[j]; int n = tid * 4 + j; int rank = 0;
      for (int m = 0; m < N_; ++m) {
        unsigned km = keys[m];
        rank += (km > kn) || (km == kn && m < n);
      }
      flag[j] = (rank < 1024);
    }
  }

  int cnt = flag[0] + flag[1] + flag[2] + flag[3];
  int inc = cnt;
#pragma unroll
  for (int o = 1; o < 64; o <<= 1) {
    int tt = __shfl_up(inc, o);
    if (lane >= o) inc += tt;
  }
  if (lane == 63) scanbuf[wid] = inc;
  __syncthreads();
  int off = 0;
  for (int w = 0; w < wid; ++w) off += scanbuf[w];
  int pos = off + inc - cnt;
  int* op = idxout + ((size_t)blockIdx.x << 10);
  int* ip = inv + ((size_t)(b * G_ + g) << 12);
#pragma unroll
  for (int j = 0; j < 4; ++j) {
    if (flag[j]) {
      if (pos < 1024) {
        int n = tid * 4 + j;
        op[pos] = n;
        if (r == 0) ip[n] = pos;
      }
      pos++;
    }
  }
}

// ---------------- 3) gather + RMSNorm -> bf16 rows ----------------
__global__ __launch_bounds__(256) void gather_rms(
    const float* __restrict__ x, const int* __restrict__ idx,
    const float* __restrict__ gamma_q, const float* __restrict__ gamma_c,
    short* __restrict__ qn, short* __restrict__ cn)
{
  __shared__ float rb[4];
  __shared__ float tot;
  int id = blockIdx.x;                  // ((r*B+b)*G+g)*1024 + slot
  int r = id >> 12, rem = id & 4095;
  int g = (rem >> 10) & 1;
  int b = rem >> 11;
  int tok = idx[id];
  int t = threadIdx.x;
  const float* xr = x + ((size_t)b * N_ + tok) * D_;
  f32x4 v = *(const f32x4*)(xr + t * 4);
  float ss = v[0]*v[0] + v[1]*v[1] + v[2]*v[2] + v[3]*v[3];
#pragma unroll
  for (int o = 32; o; o >>= 1) ss += __shfl_xor(ss, o);
  if ((t & 63) == 0) rb[t >> 6] = ss;
  __syncthreads();
  if (t == 0) tot = rb[0] + rb[1] + rb[2] + rb[3];
  __syncthreads();
  float scale = 32.0f / fmaxf(sqrtf(tot), 1e-12f);
  const float* gm = (r ? gamma_c : gamma_q) + g * D_;
  f32x4 gv = *(const f32x4*)(gm + t * 4);
  short* dst = (r ? cn : qn) + ((size_t)rem << 10) + t * 4;
  short4v ov;
#pragma unroll
  for (int e = 0; e < 4; ++e) ov[e] = f2bf(v[e] * scale * gv[e]);
  *(short4v*)dst = ov;
}

// ---------------- 4) fused NT GEMM (qproj + kv): m97 structure ----------------
__global__ __launch_bounds__(256, 3) void gemm_qkv(
    const short* __restrict__ qn, const short* __restrict__ cn,
    const short* __restrict__ wqb, const short* __restrict__ wkvb,
    short* __restrict__ qout, short* __restrict__ kout, short* __restrict__ vout)
{
  __shared__ short As[8192];
  __shared__ short Bs[8192];
  int t = threadIdx.x, lane = t & 63, wid = t >> 6;
  int grp = lane >> 4, l15 = lane & 15;
  int wm = wid >> 1, wn = wid & 1;
  int lin = blockIdx.x + 8 * (blockIdx.y + 24 * blockIdx.z);
  int s = (lin & 7) * 96 + (lin >> 3);
  int bx = s & 7, ny = (s >> 3) % 24, bg = s / 192;
  bool isq = ny < 8;
  const short* A  = isq ? qn : cn;
  const short* Bw = isq ? wqb : wkvb;
  int NB = isq ? 1024 : 2048;
  int nbase = (isq ? ny : ny - 8) * 128;
  float oscale = isq ? ATTN_SCALE : 1.0f;
  int mbase = bx * 128;
  int g = bg & 1;
  const short* Ab = A + ((size_t)bg << 20);
  const short* Bp = Bw + ((size_t)g * NB + nbase) * 1024;

  f32x4 zero = {0.f, 0.f, 0.f, 0.f};
  f32x4 acc[4][4];
#pragma unroll
  for (int i = 0; i < 4; ++i)
#pragma unroll
    for (int j = 0; j < 4; ++j) acc[i][j] = zero;

  const short* apA[4]; const short* apB[4]; int dstoff[4];
#pragma unroll
  for (int c = 0; c < 4; ++c) {
    int u = c * 256 + t;
    int row = u >> 3, j = u & 7;
    int cu = (j ^ (row & 7)) << 3;
    apA[c] = Ab + ((size_t)(mbase + row) << 10) + cu;
    apB[c] = Bp + ((size_t)row << 10) + cu;
    dstoff[c] = c * 2048 + wid * 512;   // wave-uniform; HW adds lane*16B
  }

  for (int kb = 0; kb < 16; ++kb) {
    int ko = kb * 64;
    if (kb) __syncthreads();            // all waves done reading LDS
#pragma unroll
    for (int c = 0; c < 4; ++c) {
      GLDS(apA[c] + ko, As + dstoff[c]);
      GLDS(apB[c] + ko, Bs + dstoff[c]);
    }
    WAITV0;
    __syncthreads();                    // tile visible to all waves
    const char* Ac = (const char*)As;
    const char* Bc = (const char*)Bs;
#pragma unroll
    for (int kf = 0; kf < 2; ++kf) {
      short8 af[4], bf_[4];
#pragma unroll
      for (int mt = 0; mt < 4; ++mt) {
        int ra = wm * 64 + mt * 16 + l15;
        af[mt] = *(const short8*)(Ac + ra * 128 + (((grp << 4) + (kf << 6)) ^ ((ra & 7) << 4)));
      }
#pragma unroll
      for (int nt = 0; nt < 4; ++nt) {
        int rb = wn * 64 + nt * 16 + l15;
        bf_[nt] = *(const short8*)(Bc + rb * 128 + (((grp << 4) + (kf << 6)) ^ ((rb & 7) << 4)));
      }
      __builtin_amdgcn_s_setprio(1);
#pragma unroll
      for (int mt = 0; mt < 4; ++mt)
#pragma unroll
        for (int nt = 0; nt < 4; ++nt)
          acc[mt][nt] = __builtin_amdgcn_mfma_f32_16x16x32_bf16(af[mt], bf_[nt], acc[mt][nt], 0, 0, 0);
      __builtin_amdgcn_s_setprio(0);
    }
  }

#pragma unroll
  for (int mt = 0; mt < 4; ++mt)
#pragma unroll
    for (int nt = 0; nt < 4; ++nt) {
      int n = nbase + wn*64 + nt*16 + l15;
#pragma unroll
      for (int rr = 0; rr < 4; ++rr) {
        int m = mbase + wm*64 + mt*16 + grp*4 + rr;
        float v = acc[mt][nt][rr] * oscale;
        if (isq) {
          qout[((size_t)bg * 1024 + m) * 1024 + n] = f2bf(v);
        } else {
          if (n < 1024) {
            kout[(((size_t)bg * H_ + (n >> 6)) * NSLOT + m) * DH_ + (n & 63)] = f2bf(v);
          } else {
            int e = n - 1024;
            vout[(((size_t)bg * H_ + (e >> 6)) * DH_ + (e & 63)) * NSLOT + m] = f2bf(v);
          }
        }
      }
    }
}

// ---------------- 4b) wo GEMM, K-split 2, m97 structure, XCD-swizzled ----------
__global__ __launch_bounds__(256, 3) void gemm_wo(
    const short* __restrict__ A, const short* __restrict__ Bw,
    short* __restrict__ out0, short* __restrict__ out1)
{
  __shared__ short As[8192];
  __shared__ short Bs[8192];
  int t = threadIdx.x, lane = t & 63, wid = t >> 6;
  int grp = lane >> 4, l15 = lane & 15;
  int wm = wid >> 1, wn = wid & 1;
  int lin = blockIdx.x + 8 * (blockIdx.y + 8 * blockIdx.z);
  int s = (lin & 7) * 64 + (lin >> 3);
  int mbase = (s & 7) * 128, nbase = ((s >> 3) & 7) * 128;
  int z = s >> 6, bg = z >> 1, sp = z & 1, g = bg & 1;
  short* out = sp ? out1 : out0;
  const short* Ab = A + ((size_t)bg << 20);
  const short* Bp = Bw + ((size_t)g * 1024 + nbase) * 1024;

  f32x4 zero = {0.f, 0.f, 0.f, 0.f};
  f32x4 acc[4][4];
#pragma unroll
  for (int i = 0; i < 4; ++i)
#pragma unroll
    for (int j = 0; j < 4; ++j) acc[i][j] = zero;

  const short* apA[4]; const short* apB[4]; int dstoff[4];
#pragma unroll
  for (int c = 0; c < 4; ++c) {
    int u = c * 256 + t;
    int row = u >> 3, j = u & 7;
    int cu = (j ^ (row & 7)) << 3;
    apA[c] = Ab + ((size_t)(mbase + row) << 10) + cu;
    apB[c] = Bp + ((size_t)row << 10) + cu;
    dstoff[c] = c * 2048 + wid * 512;
  }

  int kb0 = sp * 8;
  for (int kk = 0; kk < 8; ++kk) {
    int ko = (kb0 + kk) * 64;
    if (kk) __syncthreads();
#pragma unroll
    for (int c = 0; c < 4; ++c) {
      GLDS(apA[c] + ko, As + dstoff[c]);
      GLDS(apB[c] + ko, Bs + dstoff[c]);
    }
    WAITV0;
    __syncthreads();
    const char* Ac = (const char*)As;
    const char* Bc = (const char*)Bs;
#pragma unroll
    for (int kf = 0; kf < 2; ++kf) {
      short8 af[4], bf_[4];
#pragma unroll
      for (int mt = 0; mt < 4; ++mt) {
        int ra = wm * 64 + mt * 16 + l15;
        af[mt] = *(const short8*)(Ac + ra * 128 + (((grp << 4) + (kf << 6)) ^ ((ra & 7) << 4)));
      }
#pragma unroll
      for (int nt = 0; nt < 4; ++nt) {
        int rb = wn * 64 + nt * 16 + l15;
        bf_[nt] = *(const short8*)(Bc + rb * 128 + (((grp << 4) + (kf << 6)) ^ ((rb & 7) << 4)));
      }
      __builtin_amdgcn_s_setprio(1);
#pragma unroll
      for (int mt = 0; mt < 4; ++mt)
#pragma unroll
        for (int nt = 0; nt < 4; ++nt)
          acc[mt][nt] = __builtin_amdgcn_mfma_f32_16x16x32_bf16(af[mt], bf_[nt], acc[mt][nt], 0, 0, 0);
      __builtin_amdgcn_s_setprio(0);
    }
  }

#pragma unroll
  for (int mt = 0; mt < 4; ++mt)
#pragma unroll
    for (int nt = 0; nt < 4; ++nt) {
      int n = nbase + wn*64 + nt*16 + l15;
#pragma unroll
      for (int rr = 0; rr < 4; ++rr) {
        int m = mbase + wm*64 + mt*16 + grp*4 + rr;
        out[((size_t)bg * 1024 + m) * 1024 + n] = f2bf(acc[mt][nt][rr]);
      }
    }
}

// ---------------- 6) flash attention: fixed-M, no KV-split, normalize in epilogue
// grid (bgh=64, qb=8): bgh%8 -> all blocks of a head on one XCD. 17 tiles/block;
// l[q] accumulated via ones-MFMA; O/l applied in-register before the store.
__global__ __launch_bounds__(256, 3) void attn_kernel(
    const short* __restrict__ q, const short* __restrict__ k,
    const short* __restrict__ vT, short* __restrict__ o0)
{
  __shared__ short Ks[2][4096];        // [64 slot][64 dh] bf16, swizzled
  __shared__ short Vs[2][4096];        // [64 dh][64 slot] bf16, swizzled
  __shared__ short Ps[4][32 * 72];     // per-wave P, padded rows
  int bgh = blockIdx.x, qb = blockIdx.y;
  int bg = bgh >> 4, h = bgh & 15;
  int wid = threadIdx.x >> 6, lane = threadIdx.x & 63;
  int l15 = lane & 15, grp = lane >> 4;
  int qbase = qb * 128 + wid * 32;
  short* Pw = &Ps[wid][0];

  short8 bq[2][2];
#pragma unroll
  for (int qh = 0; qh < 2; ++qh) {
    const short* qp = q + ((size_t)bg * 1024 + qbase + qh * 16 + l15) * 1024 + h * 64 + (grp << 3);
    bq[qh][0] = *(const short8*)qp;
    bq[qh][1] = *(const short8*)(qp + 32);
  }
  // constant ones B-fragment: column n=0 all ones -> D col 0 = row-sum(P)
  short8 ones8;
  short ov = (l15 == 0) ? (short)0x3F80 : (short)0;
#pragma unroll
  for (int e = 0; e < 8; ++e) ones8[e] = ov;

  int u0 = wid * 128 + lane, u1 = u0 + 64;
  int r0 = u0 >> 3, j0 = u0 & 7, r1 = u1 >> 3, j1 = u1 & 7;
  const short* kbase = k + (size_t)bgh * NSLOT * DH_;
  const short* vbase = vT + (size_t)bgh * DH_ * NSLOT;
  const short* kss0 = kbase + r0 * 64 + ((j0 ^ (r0 & 7)) << 3);
  const short* kss1 = kbase + r1 * 64 + ((j1 ^ (r1 & 7)) << 3);
  const short* vss0 = vbase + (size_t)r0 * NSLOT + ((j0 ^ (r0 & 7)) << 3);
  const short* vss1 = vbase + (size_t)r1 * NSLOT + ((j1 ^ (r1 & 7)) << 3);

  f32x4 zero = {0.f, 0.f, 0.f, 0.f};
  f32x4 minit = {-FIXED_M, -FIXED_M, -FIXED_M, -FIXED_M};
  f32x4 oacc[2][4], lacc[2];
#pragma unroll
  for (int qh = 0; qh < 2; ++qh) {
    lacc[qh] = zero;
#pragma unroll
    for (int dt = 0; dt < 4; ++dt) oacc[qh][dt] = zero;
  }

  auto STAGE = [&](int tile, int p) {
    size_t ko = (size_t)tile * 4096;
    size_t vo = (size_t)tile * 64;
    short* kd = &Ks[p][0] + wid * 1024;
    short* vd = &Vs[p][0] + wid * 1024;
    GLDS(kss0 + ko, kd);
    GLDS(kss1 + ko, kd + 512);
    GLDS(vss0 + vo, vd);
    GLDS(vss1 + vo, vd + 512);
  };

  auto PROCESS = [&](int tile, int p) {
    const char* Kc = (const char*)&Ks[p][0];
    const char* Vc = (const char*)&Vs[p][0];
    f32x4 sacc[2][4];
#pragma unroll
    for (int qh = 0; qh < 2; ++qh)
#pragma unroll
      for (int kt = 0; kt < 4; ++kt) sacc[qh][kt] = minit;   // C-init = -M
#pragma unroll
    for (int kf = 0; kf < 2; ++kf) {
      short8 ka[4];
#pragma unroll
      for (int kt = 0; kt < 4; ++kt) {
        int ra = kt * 16 + l15;
        ka[kt] = *(const short8*)(Kc + ra * 128 + (((grp + 4 * kf) ^ (ra & 7)) << 4));
      }
      __builtin_amdgcn_s_setprio(1);
#pragma unroll
      for (int kt = 0; kt < 4; ++kt)
#pragma unroll
        for (int qh = 0; qh < 2; ++qh)
          sacc[qh][kt] = __builtin_amdgcn_mfma_f32_16x16x32_bf16(ka[kt], bq[qh][kf], sacc[qh][kt], 0, 0, 0);
      __builtin_amdgcn_s_setprio(0);
    }
    if (tile == 16) {
#pragma unroll
      for (int qh = 0; qh < 2; ++qh)
#pragma unroll
        for (int kt = 0; kt < 4; ++kt)
#pragma unroll
          for (int rr = 0; rr < 4; ++rr)
            if ((kt * 16 + (grp << 2) + rr) != 0) sacc[qh][kt][rr] = -INFINITY;
    }
    // P = exp2(S - M); pack to LDS
#pragma unroll
    for (int qh = 0; qh < 2; ++qh)
#pragma unroll
      for (int kt = 0; kt < 4; ++kt) {
        short4v pk;
#pragma unroll
        for (int rr = 0; rr < 4; ++rr) pk[rr] = f2bf_trunc(exp2f(sacc[qh][kt][rr]));
        *(short4v*)(Pw + (qh * 16 + l15) * 72 + kt * 16 + (grp << 2)) = pk;
      }
    // PV + l
#pragma unroll
    for (int ks = 0; ks < 2; ++ks) {
      short8 pa[2];
#pragma unroll
      for (int qh = 0; qh < 2; ++qh)
        pa[qh] = *(const short8*)((const char*)Pw + (qh * 16 + l15) * 144 + grp * 16 + ks * 64);
      __builtin_amdgcn_s_setprio(1);
#pragma unroll
      for (int dt = 0; dt < 4; ++dt) {
        int ra = dt * 16 + l15;
        short8 vbf = *(const short8*)(Vc + ra * 128 + (((grp + 4 * ks) ^ (ra & 7)) << 4));
#pragma unroll
        for (int qh = 0; qh < 2; ++qh)
          oacc[qh][dt] = __builtin_amdgcn_mfma_f32_16x16x32_bf16(pa[qh], vbf, oacc[qh][dt], 0, 0, 0);
      }
#pragma unroll
      for (int qh = 0; qh < 2; ++qh)
        lacc[qh] = __builtin_amdgcn_mfma_f32_16x16x32_bf16(pa[qh], ones8, lacc[qh], 0, 0, 0);
      __builtin_amdgcn_s_setprio(0);
    }
  };

  STAGE(0, 0);
  STAGE(1, 1);
  WAITV4;
  BAR();
  for (int tile = 0; tile < 17; ++tile) {
    int p = tile & 1;
    PROCESS(tile, p);
    if (tile + 1 < 17) {
      BAR();
      if (tile + 2 < 17) { STAGE(tile + 2, p); WAITV4; }
      else               { WAITV0; }
      BAR();
    }
  }

  // normalize in-register: l[q=grp*4+rr] lives in lacc[qh][rr] at lane grp*16
#pragma unroll
  for (int qh = 0; qh < 2; ++qh)
#pragma unroll
    for (int rr = 0; rr < 4; ++rr) {
      float lv = __shfl(lacc[qh][rr], grp << 4);
      float inv_l = 1.0f / lv;
      int qq = qh * 16 + (grp << 2) + rr;
#pragma unroll
      for (int dt = 0; dt < 4; ++dt) {
        int dh = dt * 16 + l15;
        o0[((size_t)bg * 1024 + qbase + qq) * 1024 + h * 64 + dh] =
            f2bf(oacc[qh][dt][rr] * inv_l);
      }
    }
}

// ---------------- 7) finalize: sum K-split wo partials, scatter-average ---------
__global__ __launch_bounds__(256) void finalize_kernel(
    const short* __restrict__ wo0, const short* __restrict__ wo1,
    const int* __restrict__ inv, const float* __restrict__ null_token,
    float* __restrict__ outp)
{
  int id = blockIdx.x;                  // b*N + n
  int b = id >> 12, n = id & (N_ - 1);
  int s0 = inv[((size_t)(b * G_ + 0) << 12) + n];
  int s1 = inv[((size_t)(b * G_ + 1) << 12) + n];
  int t = threadIdx.x;
  float* dst = outp + (size_t)id * D_ + t * 4;
  if (s0 < 0 && s1 < 0) {
    *(f32x4*)dst = *(const f32x4*)(null_token + t * 4);
  } else {
    f32x4 sum = {0.f, 0.f, 0.f, 0.f};
    float cnt = 0.f;
    if (s0 >= 0) {
      size_t loc = (((size_t)(b * G_ + 0) * 1024 + s0) << 10) + t * 4;
      short4v v = *(const short4v*)(wo0 + loc);
      short4v v2 = *(const short4v*)(wo1 + loc);
#pragma unroll
      for (int e = 0; e < 4; ++e) sum[e] += bf2f(v[e]) + bf2f(v2[e]);
      cnt += 1.f;
    }
    if (s1 >= 0) {
      size_t loc = (((size_t)(b * G_ + 1) * 1024 + s1) << 10) + t * 4;
      short4v v = *(const short4v*)(wo0 + loc);
      short4v v2 = *(const short4v*)(wo1 + loc);
#pragma unroll
      for (int e = 0; e < 4; ++e) sum[e] += bf2f(v[e]) + bf2f(v2[e]);
      cnt += 1.f;
    }
    f32x4 rv;
#pragma unroll
    for (int e = 0; e < 4; ++e) rv[e] = sum[e] / cnt;
    *(f32x4*)dst = rv;
  }
}

// ---------------- launch ----------------
extern "C" void kernel_launch(void* const* d_in, const int* in_sizes, int n_in,
                              void* d_out, int out_size, void* d_ws, size_t ws_size,
                              hipStream_t stream) {
  (void)in_sizes; (void)n_in; (void)out_size; (void)ws_size;
  const float* x        = (const float*)d_in[0];
  const float* rt_q     = (const float*)d_in[1];
  const float* rt_kv    = (const float*)d_in[2];
  const float* gamma_q  = (const float*)d_in[3];
  const float* gamma_c  = (const float*)d_in[4];
  const float* wq       = (const float*)d_in[5];
  const float* wkv      = (const float*)d_in[6];
  const float* wo       = (const float*)d_in[7];
  const float* null_kv  = (const float*)d_in[8];
  const float* null_tok = (const float*)d_in[9];
  float* outp = (float*)d_out;

  char* ws = (char*)d_ws;
  size_t off = 0;
  auto alloc = [&](size_t bytes) { char* p = ws + off; off += (bytes + 255) & ~(size_t)255; return p; };
  float* sim   = (float*)alloc((size_t)2 * B_ * G_ * N_ * 4);
  int*   idx   = (int*)  alloc((size_t)2 * B_ * G_ * 1024 * 4);
  int*   inv   = (int*)  alloc((size_t)B_ * G_ * N_ * 4);
  short* qn    = (short*)alloc((size_t)B_ * G_ * 1024 * 1024 * 2);
  short* cn    = (short*)alloc((size_t)B_ * G_ * 1024 * 1024 * 2);
  short* qproj = (short*)alloc((size_t)B_ * G_ * 1024 * 1024 * 2);
  size_t kvbytes = (size_t)B_ * G_ * H_ * NSLOT * DH_ * 2;       // 256-aligned
  short* kbuf  = (short*)alloc(kvbytes);
  short* vbuf  = (short*)alloc(kvbytes);
  short* obuf  = (short*)alloc((size_t)B_ * G_ * 1024 * 1024 * 2);
  short* wobuf = (short*)alloc((size_t)B_ * G_ * 1024 * 1024 * 2);
  short* wo_bf = (short*)alloc((size_t)G_ * 1024 * 1024 * 2);
  // aliases into dead regions (lifetimes verified):
  short* wq_bf  = wobuf;  // dead until gemm_wo writes wobuf (after gemm_qkv)
  short* wkv_bf = obuf;   // consumed by gemm_qkv before attn writes obuf
  short* wobuf2 = qproj;  // wo K-split half 1; qproj dead after attn

  // NOTE: no kbuf/vbuf memset needed — pad K rows (slots 1025..1087) only enter
  // tile 16 where S is masked to -inf before exp2; pad V columns multiply P=0;
  // all residual bit patterns are finite bf16.
  hipMemsetAsync(inv, 0xFF, (size_t)B_ * G_ * N_ * 4, stream);

  prep_kernel<<<2064, 256, 0, stream>>>(x, rt_q, rt_kv, sim, null_kv, kbuf, vbuf);
  topk_wconv<<<520, 1024, 0, stream>>>(sim, idx, inv, wq, wkv, wo,
                                       wq_bf, wkv_bf, wo_bf);
  gather_rms<<<2 * B_ * G_ * 1024, 256, 0, stream>>>(x, idx, gamma_q, gamma_c, qn, cn);
  gemm_qkv<<<dim3(8, 24, B_ * G_), 256, 0, stream>>>(qn, cn, wq_bf, wkv_bf, qproj, kbuf, vbuf);
  attn_kernel<<<dim3(64, 8), 256, 0, stream>>>(qproj, kbuf, vbuf, obuf);
  gemm_wo<<<dim3(8, 8, 2 * B_ * G_), 256, 0, stream>>>(obuf, wo_bf, wobuf, wobuf2);
  finalize_kernel<<<B_ * N_, 256, 0, stream>>>(wobuf, wobuf2, inv, null_tok, outp);
}

// Round 14
// 157.014 us; speedup vs baseline: 2.2884x; 1.0076x over previous
//
#include <hip/hip_runtime.h>

// ---------------- types / helpers ----------------
typedef __attribute__((ext_vector_type(8))) short short8;   // 8 x bf16 (16B)
typedef __attribute__((ext_vector_type(4))) short short4v;  // 4 x bf16 (8B)
typedef __attribute__((ext_vector_type(4))) float f32x4;

#define B_ 2
#define N_ 4096
#define D_ 1024
#define G_ 2
#define H_ 16
#define DH_ 64
#define NSLOT 1088              // 1024 tokens + 1 null + pad to 17*64
#define LOGK 7.0492548412558374f  // log(1152)
#define ATTN_SCALE 0.18033688011112043f  // dh^-0.5 * log2(e): S in log2 domain
#define FIXED_M 32.0f           // fixed softmax max (log2 domain); |S|<~12 << 32

#define BAR() __builtin_amdgcn_s_barrier()
#define WAITV4 asm volatile("s_waitcnt vmcnt(4)" ::: "memory")
#define WAITV0 asm volatile("s_waitcnt vmcnt(0)" ::: "memory")
#define LGKM0() do { asm volatile("s_waitcnt lgkmcnt(0)" ::: "memory"); \
                     __builtin_amdgcn_sched_barrier(0); } while (0)
#define GLDS(src, dst) __builtin_amdgcn_global_load_lds( \
    (const __attribute__((address_space(1))) void*)(src), \
    (__attribute__((address_space(3))) void*)(dst), 16, 0, 0)

__device__ __forceinline__ float bf2f(short s) {
  return __uint_as_float(((unsigned)(unsigned short)s) << 16);
}
__device__ __forceinline__ short f2bf(float f) {   // RNE
  unsigned u = __float_as_uint(f);
  u = (u + 0x7FFFu + ((u >> 16) & 1u)) >> 16;
  return (short)u;
}
__device__ __forceinline__ short f2bf_trunc(float f) {   // truncation (hot path)
  return (short)(__float_as_uint(f) >> 16);
}

// ---------------- 1) prep: sim only ----------------
__global__ __launch_bounds__(256) void prep_kernel(
    const float* __restrict__ x, const float* __restrict__ rtq,
    const float* __restrict__ rtkv, float* __restrict__ sim)
{
  int wid = threadIdx.x >> 6, lane = threadIdx.x & 63;
  int row = blockIdx.x * 4 + wid;                // b*N + n
  int b = row >> 12, n = row & (N_ - 1);
  const float* xr = x + (size_t)row * D_;
  float a0 = 0.f, a1 = 0.f, a2 = 0.f, a3 = 0.f;
#pragma unroll
  for (int c = 0; c < 4; ++c) {
    int d = c * 256 + lane * 4;
    f32x4 xv = *(const f32x4*)(xr + d);
    f32x4 r0 = *(const f32x4*)(rtq + d);
    f32x4 r1 = *(const f32x4*)(rtq + D_ + d);
    f32x4 r2 = *(const f32x4*)(rtkv + d);
    f32x4 r3 = *(const f32x4*)(rtkv + D_ + d);
#pragma unroll
    for (int e = 0; e < 4; ++e) {
      a0 += xv[e] * r0[e];
      a1 += xv[e] * r1[e];
      a2 += xv[e] * r2[e];
      a3 += xv[e] * r3[e];
    }
  }
#pragma unroll
  for (int o = 32; o; o >>= 1) {
    a0 += __shfl_xor(a0, o); a1 += __shfl_xor(a1, o);
    a2 += __shfl_xor(a2, o); a3 += __shfl_xor(a3, o);
  }
  if (lane == 0) {
    sim[((size_t)(b)*G_ + 0) * N_ + n] = a0;
    sim[((size_t)(b)*G_ + 1) * N_ + n] = a1;
    sim[((size_t)(B_ + b)*G_ + 0) * N_ + n] = a2;
    sim[((size_t)(B_ + b)*G_ + 1) * N_ + n] = a3;
  }
}

// ---- 2) topk (blocks 0-7) || wconv (blocks 8-519) || null_fill (520-523) ----
__global__ __launch_bounds__(1024) void topk_wconv(
    const float* __restrict__ sim, int* __restrict__ idxout, int* __restrict__ inv,
    const float* __restrict__ wq, const float* __restrict__ wkv,
    const float* __restrict__ wo, short* __restrict__ dq,
    short* __restrict__ dkv, short* __restrict__ dwo,
    const float* __restrict__ null_kv, short* __restrict__ kb_,
    short* __restrict__ vb_)
{
  if (blockIdx.x >= 520) {
    // ---- null kv fill (slot 1024): 16 bgh per block ----
    int bgh = (blockIdx.x - 520) * 16 + (threadIdx.x >> 6);
    int g = (bgh >> 4) & 1, h = bgh & 15;
    int t = threadIdx.x & 63;
    float kvk = null_kv[((size_t)(0 * G_ + g) * H_ + h) * DH_ + t];
    float kvv = null_kv[((size_t)(1 * G_ + g) * H_ + h) * DH_ + t];
    kb_[((size_t)bgh * NSLOT + 1024) * DH_ + t] = f2bf(kvk);
    vb_[((size_t)bgh * DH_ + t) * NSLOT + 1024] = f2bf(kvv);
    return;
  }
  if (blockIdx.x >= 8) {
    // ---- weight f32 -> bf16: 4 f32x4 units per thread ----
    int base = (blockIdx.x - 8) * 4096 + threadIdx.x;
#pragma unroll
    for (int c = 0; c < 4; ++c) {
      int i = base + c * 1024;
      const float* src; short* dst;
      if (i < 524288) { src = wq; dst = dq; }
      else if (i < 1572864) { src = wkv; dst = dkv; i -= 524288; }
      else { src = wo; dst = dwo; i -= 1572864; }
      f32x4 v = ((const f32x4*)src)[i];
      short4v o;
#pragma unroll
      for (int e = 0; e < 4; ++e) o[e] = f2bf(v[e]);
      ((short4v*)dst)[i] = o;
    }
    return;
  }

  __shared__ float rbm[16];
  __shared__ float rbs[16];
  __shared__ float res;
  __shared__ unsigned keys[N_];
  __shared__ int scanbuf[16];

  int r = blockIdx.x >> 2, b = (blockIdx.x >> 1) & 1, g = blockIdx.x & 1;
  const float* srow = sim + ((size_t)blockIdx.x << 12);
  int tid = threadIdx.x, lane = tid & 63, wid = tid >> 6;

  float sv[4];
#pragma unroll
  for (int j = 0; j < 4; ++j) sv[j] = srow[tid * 4 + j];

  float a = 0.f;
  double epsd = 4.0;
  for (int it = 0; it < 20; ++it) {
    float eps = (float)fmax(epsd, 0.03);
    epsd *= 0.7;
    float sb[4]; float mt = -INFINITY;
#pragma unroll
    for (int j = 0; j < 4; ++j) {
      float bb = (it == 0) ? (-sv[j]) : (-fmaxf(sv[j] + a, 0.f));
      sb[j] = (sv[j] + bb) / eps;
      mt = fmaxf(mt, sb[j]);
    }
#pragma unroll
    for (int o = 32; o; o >>= 1) mt = fmaxf(mt, __shfl_xor(mt, o));
    float st = 0.f;
#pragma unroll
    for (int j = 0; j < 4; ++j) st += expf(sb[j] - mt);
#pragma unroll
    for (int o = 32; o; o >>= 1) st += __shfl_xor(st, o);
    if (lane == 0) { rbm[wid] = mt; rbs[wid] = st; }
    __syncthreads();
    if (tid < 64) {
      float m2 = (tid < 16) ? rbm[tid] : -INFINITY;
      float s2 = (tid < 16) ? rbs[tid] : 0.f;
#pragma unroll
      for (int o = 8; o; o >>= 1) {
        float mo = __shfl_xor(m2, o), so = __shfl_xor(s2, o);
        float mn = fmaxf(m2, mo);
        s2 = s2 * expf(m2 - mn) + so * expf(mo - mn);
        m2 = mn;
      }
      if (tid == 0) res = logf(s2) + m2;
    }
    __syncthreads();
    float lse = res;
    a = eps * (LOGK - lse);
  }
  __syncthreads();

  // final scores: exp(min(s+a,0)/0.03); saturated entries are EXACTLY 1.0f
  unsigned kb[4]; int c1 = 0;
#pragma unroll
  for (int j = 0; j < 4; ++j) {
    float sc = expf(fminf(sv[j] + a, 0.f) / 0.03f);
    kb[j] = __float_as_uint(sc);
    keys[tid * 4 + j] = kb[j];
    c1 += (kb[j] == 0x3F800000u);
  }
#pragma unroll
  for (int o = 32; o; o >>= 1) c1 += __shfl_xor(c1, o);
  if (lane == 0) scanbuf[wid] = c1;
  __syncthreads();
  int c1tot = 0;
  for (int i = 0; i < 16; ++i) c1tot += scanbuf[i];
  __syncthreads();

  int flag[4];
  if (c1tot >= 1024) {
#pragma unroll
    for (int j = 0; j < 4; ++j) flag[j] = (kb[j] == 0x3F800000u);
  } else {
#pragma unroll
    for (int j = 0; j < 4; ++j) {
      unsigned kn = kb[j]; int n = tid * 4 + j; int rank = 0;
      for (int m = 0; m < N_; ++m) {
        unsigned km = keys[m];
        rank += (km > kn) || (km == kn && m < n);
      }
      flag[j] = (rank < 1024);
    }
  }

  int cnt = flag[0] + flag[1] + flag[2] + flag[3];
  int inc = cnt;
#pragma unroll
  for (int o = 1; o < 64; o <<= 1) {
    int tt = __shfl_up(inc, o);
    if (lane >= o) inc += tt;
  }
  if (lane == 63) scanbuf[wid] = inc;
  __syncthreads();
  int off = 0;
  for (int w = 0; w < wid; ++w) off += scanbuf[w];
  int pos = off + inc - cnt;
  int* op = idxout + ((size_t)blockIdx.x << 10);
  int* ip = inv + ((size_t)(b * G_ + g) << 12);
#pragma unroll
  for (int j = 0; j < 4; ++j) {
    if (flag[j]) {
      if (pos < 1024) {
        int n = tid * 4 + j;
        op[pos] = n;
        if (r == 0) ip[n] = pos;
      }
      pos++;
    }
  }
}

// ---------------- 3) gather + RMSNorm -> bf16 rows ----------------
__global__ __launch_bounds__(256) void gather_rms(
    const float* __restrict__ x, const int* __restrict__ idx,
    const float* __restrict__ gamma_q, const float* __restrict__ gamma_c,
    short* __restrict__ qn, short* __restrict__ cn)
{
  __shared__ float rb[4];
  __shared__ float tot;
  int id = blockIdx.x;                  // ((r*B+b)*G+g)*1024 + slot
  int r = id >> 12, rem = id & 4095;
  int g = (rem >> 10) & 1;
  int b = rem >> 11;
  int tok = idx[id];
  int t = threadIdx.x;
  const float* xr = x + ((size_t)b * N_ + tok) * D_;
  f32x4 v = *(const f32x4*)(xr + t * 4);
  float ss = v[0]*v[0] + v[1]*v[1] + v[2]*v[2] + v[3]*v[3];
#pragma unroll
  for (int o = 32; o; o >>= 1) ss += __shfl_xor(ss, o);
  if ((t & 63) == 0) rb[t >> 6] = ss;
  __syncthreads();
  if (t == 0) tot = rb[0] + rb[1] + rb[2] + rb[3];
  __syncthreads();
  float scale = 32.0f / fmaxf(sqrtf(tot), 1e-12f);
  const float* gm = (r ? gamma_c : gamma_q) + g * D_;
  f32x4 gv = *(const f32x4*)(gm + t * 4);
  short* dst = (r ? cn : qn) + ((size_t)rem << 10) + t * 4;
  short4v ov;
#pragma unroll
  for (int e = 0; e < 4; ++e) ov[e] = f2bf(v[e] * scale * gv[e]);
  *(short4v*)dst = ov;
}

// ---------------- 4) fused NT GEMM (qproj + kv): m97 + overlapped stage -------
// Single 32KB buffer, 3 blocks/CU. Per step: read kf1 frags -> MFMA kf1 ->
// read kf0 frags -> lgkm fence -> barrier -> STAGE(t+1) overlapped with MFMA
// kf0 (register-fed) -> vmcnt(0) (mostly satisfied) -> barrier.
__global__ __launch_bounds__(256, 3) void gemm_qkv(
    const short* __restrict__ qn, const short* __restrict__ cn,
    const short* __restrict__ wqb, const short* __restrict__ wkvb,
    short* __restrict__ qout, short* __restrict__ kout, short* __restrict__ vout)
{
  __shared__ short As[8192];
  __shared__ short Bs[8192];
  int t = threadIdx.x, lane = t & 63, wid = t >> 6;
  int grp = lane >> 4, l15 = lane & 15;
  int wm = wid >> 1, wn = wid & 1;
  int lin = blockIdx.x + 8 * (blockIdx.y + 24 * blockIdx.z);
  int s = (lin & 7) * 96 + (lin >> 3);
  int bx = s & 7, ny = (s >> 3) % 24, bg = s / 192;
  bool isq = ny < 8;
  const short* A  = isq ? qn : cn;
  const short* Bw = isq ? wqb : wkvb;
  int NB = isq ? 1024 : 2048;
  int nbase = (isq ? ny : ny - 8) * 128;
  float oscale = isq ? ATTN_SCALE : 1.0f;
  int mbase = bx * 128;
  int g = bg & 1;
  const short* Ab = A + ((size_t)bg << 20);
  const short* Bp = Bw + ((size_t)g * NB + nbase) * 1024;

  f32x4 zero = {0.f, 0.f, 0.f, 0.f};
  f32x4 acc[4][4];
#pragma unroll
  for (int i = 0; i < 4; ++i)
#pragma unroll
    for (int j = 0; j < 4; ++j) acc[i][j] = zero;

  const short* apA[4]; const short* apB[4]; int dstoff[4];
#pragma unroll
  for (int c = 0; c < 4; ++c) {
    int u = c * 256 + t;
    int row = u >> 3, j = u & 7;
    int cu = (j ^ (row & 7)) << 3;
    apA[c] = Ab + ((size_t)(mbase + row) << 10) + cu;
    apB[c] = Bp + ((size_t)row << 10) + cu;
    dstoff[c] = c * 2048 + wid * 512;   // wave-uniform; HW adds lane*16B
  }

  auto STAGE = [&](int kb) {
    int ko = kb * 64;
#pragma unroll
    for (int c = 0; c < 4; ++c) {
      GLDS(apA[c] + ko, As + dstoff[c]);
      GLDS(apB[c] + ko, Bs + dstoff[c]);
    }
  };

  STAGE(0);
  WAITV0;
  BAR();

  const char* Ac = (const char*)As;
  const char* Bc = (const char*)Bs;
  for (int kb = 0; kb < 16; ++kb) {
    short8 af1[4], bf1[4], af0[4], bf0[4];
    // kf=1 fragments, compute immediately
#pragma unroll
    for (int mt = 0; mt < 4; ++mt) {
      int ra = wm * 64 + mt * 16 + l15;
      af1[mt] = *(const short8*)(Ac + ra * 128 + ((16 + 64) << 0 ? (((grp << 4) + 64) ^ ((ra & 7) << 4)) : 0));
    }
#pragma unroll
    for (int nt = 0; nt < 4; ++nt) {
      int rb = wn * 64 + nt * 16 + l15;
      bf1[nt] = *(const short8*)(Bc + rb * 128 + (((grp << 4) + 64) ^ ((rb & 7) << 4)));
    }
    __builtin_amdgcn_s_setprio(1);
#pragma unroll
    for (int mt = 0; mt < 4; ++mt)
#pragma unroll
      for (int nt = 0; nt < 4; ++nt)
        acc[mt][nt] = __builtin_amdgcn_mfma_f32_16x16x32_bf16(af1[mt], bf1[nt], acc[mt][nt], 0, 0, 0);
    __builtin_amdgcn_s_setprio(0);
    // kf=0 fragments into registers
#pragma unroll
    for (int mt = 0; mt < 4; ++mt) {
      int ra = wm * 64 + mt * 16 + l15;
      af0[mt] = *(const short8*)(Ac + ra * 128 + (((grp << 4)) ^ ((ra & 7) << 4)));
    }
#pragma unroll
    for (int nt = 0; nt < 4; ++nt) {
      int rb = wn * 64 + nt * 16 + l15;
      bf0[nt] = *(const short8*)(Bc + rb * 128 + (((grp << 4)) ^ ((rb & 7) << 4)));
    }
    LGKM0();                       // all LDS reads done (rule #18 fence)
    BAR();                         // every wave finished reading the buffer
    if (kb + 1 < 16) STAGE(kb + 1);   // overwrite overlapped with reg-fed MFMA
    __builtin_amdgcn_s_setprio(1);
#pragma unroll
    for (int mt = 0; mt < 4; ++mt)
#pragma unroll
      for (int nt = 0; nt < 4; ++nt)
        acc[mt][nt] = __builtin_amdgcn_mfma_f32_16x16x32_bf16(af0[mt], bf0[nt], acc[mt][nt], 0, 0, 0);
    __builtin_amdgcn_s_setprio(0);
    if (kb + 1 < 16) {
      WAITV0;                      // next tile landed (mostly covered by MFMA)
      BAR();
    }
  }

#pragma unroll
  for (int mt = 0; mt < 4; ++mt)
#pragma unroll
    for (int nt = 0; nt < 4; ++nt) {
      int n = nbase + wn*64 + nt*16 + l15;
#pragma unroll
      for (int rr = 0; rr < 4; ++rr) {
        int m = mbase + wm*64 + mt*16 + grp*4 + rr;
        float v = acc[mt][nt][rr] * oscale;
        if (isq) {
          qout[((size_t)bg * 1024 + m) * 1024 + n] = f2bf(v);
        } else {
          if (n < 1024) {
            kout[(((size_t)bg * H_ + (n >> 6)) * NSLOT + m) * DH_ + (n & 63)] = f2bf(v);
          } else {
            int e = n - 1024;
            vout[(((size_t)bg * H_ + (e >> 6)) * DH_ + (e & 63)) * NSLOT + m] = f2bf(v);
          }
        }
      }
    }
}

// ---------------- 4b) wo GEMM, K-split 2, same overlapped-stage structure -----
__global__ __launch_bounds__(256, 3) void gemm_wo(
    const short* __restrict__ A, const short* __restrict__ Bw,
    short* __restrict__ out0, short* __restrict__ out1)
{
  __shared__ short As[8192];
  __shared__ short Bs[8192];
  int t = threadIdx.x, lane = t & 63, wid = t >> 6;
  int grp = lane >> 4, l15 = lane & 15;
  int wm = wid >> 1, wn = wid & 1;
  int lin = blockIdx.x + 8 * (blockIdx.y + 8 * blockIdx.z);
  int s = (lin & 7) * 64 + (lin >> 3);
  int mbase = (s & 7) * 128, nbase = ((s >> 3) & 7) * 128;
  int z = s >> 6, bg = z >> 1, sp = z & 1, g = bg & 1;
  short* out = sp ? out1 : out0;
  const short* Ab = A + ((size_t)bg << 20);
  const short* Bp = Bw + ((size_t)g * 1024 + nbase) * 1024;

  f32x4 zero = {0.f, 0.f, 0.f, 0.f};
  f32x4 acc[4][4];
#pragma unroll
  for (int i = 0; i < 4; ++i)
#pragma unroll
    for (int j = 0; j < 4; ++j) acc[i][j] = zero;

  const short* apA[4]; const short* apB[4]; int dstoff[4];
#pragma unroll
  for (int c = 0; c < 4; ++c) {
    int u = c * 256 + t;
    int row = u >> 3, j = u & 7;
    int cu = (j ^ (row & 7)) << 3;
    apA[c] = Ab + ((size_t)(mbase + row) << 10) + cu;
    apB[c] = Bp + ((size_t)row << 10) + cu;
    dstoff[c] = c * 2048 + wid * 512;
  }

  auto STAGE = [&](int kb) {
    int ko = kb * 64;
#pragma unroll
    for (int c = 0; c < 4; ++c) {
      GLDS(apA[c] + ko, As + dstoff[c]);
      GLDS(apB[c] + ko, Bs + dstoff[c]);
    }
  };

  int kb0 = sp * 8;
  STAGE(kb0);
  WAITV0;
  BAR();

  const char* Ac = (const char*)As;
  const char* Bc = (const char*)Bs;
  for (int kk = 0; kk < 8; ++kk) {
    short8 af1[4], bf1[4], af0[4], bf0[4];
#pragma unroll
    for (int mt = 0; mt < 4; ++mt) {
      int ra = wm * 64 + mt * 16 + l15;
      af1[mt] = *(const short8*)(Ac + ra * 128 + (((grp << 4) + 64) ^ ((ra & 7) << 4)));
    }
#pragma unroll
    for (int nt = 0; nt < 4; ++nt) {
      int rb = wn * 64 + nt * 16 + l15;
      bf1[nt] = *(const short8*)(Bc + rb * 128 + (((grp << 4) + 64) ^ ((rb & 7) << 4)));
    }
    __builtin_amdgcn_s_setprio(1);
#pragma unroll
    for (int mt = 0; mt < 4; ++mt)
#pragma unroll
      for (int nt = 0; nt < 4; ++nt)
        acc[mt][nt] = __builtin_amdgcn_mfma_f32_16x16x32_bf16(af1[mt], bf1[nt], acc[mt][nt], 0, 0, 0);
    __builtin_amdgcn_s_setprio(0);
#pragma unroll
    for (int mt = 0; mt < 4; ++mt) {
      int ra = wm * 64 + mt * 16 + l15;
      af0[mt] = *(const short8*)(Ac + ra * 128 + (((grp << 4)) ^ ((ra & 7) << 4)));
    }
#pragma unroll
    for (int nt = 0; nt < 4; ++nt) {
      int rb = wn * 64 + nt * 16 + l15;
      bf0[nt] = *(const short8*)(Bc + rb * 128 + (((grp << 4)) ^ ((rb & 7) << 4)));
    }
    LGKM0();
    BAR();
    if (kk + 1 < 8) STAGE(kb0 + kk + 1);
    __builtin_amdgcn_s_setprio(1);
#pragma unroll
    for (int mt = 0; mt < 4; ++mt)
#pragma unroll
      for (int nt = 0; nt < 4; ++nt)
        acc[mt][nt] = __builtin_amdgcn_mfma_f32_16x16x32_bf16(af0[mt], bf0[nt], acc[mt][nt], 0, 0, 0);
    __builtin_amdgcn_s_setprio(0);
    if (kk + 1 < 8) {
      WAITV0;
      BAR();
    }
  }

#pragma unroll
  for (int mt = 0; mt < 4; ++mt)
#pragma unroll
    for (int nt = 0; nt < 4; ++nt) {
      int n = nbase + wn*64 + nt*16 + l15;
#pragma unroll
      for (int rr = 0; rr < 4; ++rr) {
        int m = mbase + wm*64 + mt*16 + grp*4 + rr;
        out[((size_t)bg * 1024 + m) * 1024 + n] = f2bf(acc[mt][nt][rr]);
      }
    }
}

// ---------------- 6) flash attention: fixed-M, no KV-split, normalize in epilogue
__global__ __launch_bounds__(256, 3) void attn_kernel(
    const short* __restrict__ q, const short* __restrict__ k,
    const short* __restrict__ vT, short* __restrict__ o0)
{
  __shared__ short Ks[2][4096];        // [64 slot][64 dh] bf16, swizzled
  __shared__ short Vs[2][4096];        // [64 dh][64 slot] bf16, swizzled
  __shared__ short Ps[4][32 * 72];     // per-wave P, padded rows
  int bgh = blockIdx.x, qb = blockIdx.y;
  int bg = bgh >> 4, h = bgh & 15;
  int wid = threadIdx.x >> 6, lane = threadIdx.x & 63;
  int l15 = lane & 15, grp = lane >> 4;
  int qbase = qb * 128 + wid * 32;
  short* Pw = &Ps[wid][0];

  short8 bq[2][2];
#pragma unroll
  for (int qh = 0; qh < 2; ++qh) {
    const short* qp = q + ((size_t)bg * 1024 + qbase + qh * 16 + l15) * 1024 + h * 64 + (grp << 3);
    bq[qh][0] = *(const short8*)qp;
    bq[qh][1] = *(const short8*)(qp + 32);
  }
  // constant ones B-fragment: column n=0 all ones -> D col 0 = row-sum(P)
  short8 ones8;
  short ov = (l15 == 0) ? (short)0x3F80 : (short)0;
#pragma unroll
  for (int e = 0; e < 8; ++e) ones8[e] = ov;

  int u0 = wid * 128 + lane, u1 = u0 + 64;
  int r0 = u0 >> 3, j0 = u0 & 7, r1 = u1 >> 3, j1 = u1 & 7;
  const short* kbase = k + (size_t)bgh * NSLOT * DH_;
  const short* vbase = vT + (size_t)bgh * DH_ * NSLOT;
  const short* kss0 = kbase + r0 * 64 + ((j0 ^ (r0 & 7)) << 3);
  const short* kss1 = kbase + r1 * 64 + ((j1 ^ (r1 & 7)) << 3);
  const short* vss0 = vbase + (size_t)r0 * NSLOT + ((j0 ^ (r0 & 7)) << 3);
  const short* vss1 = vbase + (size_t)r1 * NSLOT + ((j1 ^ (r1 & 7)) << 3);

  f32x4 zero = {0.f, 0.f, 0.f, 0.f};
  f32x4 minit = {-FIXED_M, -FIXED_M, -FIXED_M, -FIXED_M};
  f32x4 oacc[2][4], lacc[2];
#pragma unroll
  for (int qh = 0; qh < 2; ++qh) {
    lacc[qh] = zero;
#pragma unroll
    for (int dt = 0; dt < 4; ++dt) oacc[qh][dt] = zero;
  }

  auto STAGE = [&](int tile, int p) {
    size_t ko = (size_t)tile * 4096;
    size_t vo = (size_t)tile * 64;
    short* kd = &Ks[p][0] + wid * 1024;
    short* vd = &Vs[p][0] + wid * 1024;
    GLDS(kss0 + ko, kd);
    GLDS(kss1 + ko, kd + 512);
    GLDS(vss0 + vo, vd);
    GLDS(vss1 + vo, vd + 512);
  };

  auto PROCESS = [&](int tile, int p) {
    const char* Kc = (const char*)&Ks[p][0];
    const char* Vc = (const char*)&Vs[p][0];
    f32x4 sacc[2][4];
#pragma unroll
    for (int qh = 0; qh < 2; ++qh)
#pragma unroll
      for (int kt = 0; kt < 4; ++kt) sacc[qh][kt] = minit;   // C-init = -M
#pragma unroll
    for (int kf = 0; kf < 2; ++kf) {
      short8 ka[4];
#pragma unroll
      for (int kt = 0; kt < 4; ++kt) {
        int ra = kt * 16 + l15;
        ka[kt] = *(const short8*)(Kc + ra * 128 + (((grp + 4 * kf) ^ (ra & 7)) << 4));
      }
      __builtin_amdgcn_s_setprio(1);
#pragma unroll
      for (int kt = 0; kt < 4; ++kt)
#pragma unroll
        for (int qh = 0; qh < 2; ++qh)
          sacc[qh][kt] = __builtin_amdgcn_mfma_f32_16x16x32_bf16(ka[kt], bq[qh][kf], sacc[qh][kt], 0, 0, 0);
      __builtin_amdgcn_s_setprio(0);
    }
    if (tile == 16) {
#pragma unroll
      for (int qh = 0; qh < 2; ++qh)
#pragma unroll
        for (int kt = 0; kt < 4; ++kt)
#pragma unroll
          for (int rr = 0; rr < 4; ++rr)
            if ((kt * 16 + (grp << 2) + rr) != 0) sacc[qh][kt][rr] = -INFINITY;
    }
    // P = exp2(S - M); pack to LDS
#pragma unroll
    for (int qh = 0; qh < 2; ++qh)
#pragma unroll
      for (int kt = 0; kt < 4; ++kt) {
        short4v pk;
#pragma unroll
        for (int rr = 0; rr < 4; ++rr) pk[rr] = f2bf_trunc(exp2f(sacc[qh][kt][rr]));
        *(short4v*)(Pw + (qh * 16 + l15) * 72 + kt * 16 + (grp << 2)) = pk;
      }
    // PV + l
#pragma unroll
    for (int ks = 0; ks < 2; ++ks) {
      short8 pa[2];
#pragma unroll
      for (int qh = 0; qh < 2; ++qh)
        pa[qh] = *(const short8*)((const char*)Pw + (qh * 16 + l15) * 144 + grp * 16 + ks * 64);
      __builtin_amdgcn_s_setprio(1);
#pragma unroll
      for (int dt = 0; dt < 4; ++dt) {
        int ra = dt * 16 + l15;
        short8 vbf = *(const short8*)(Vc + ra * 128 + (((grp + 4 * ks) ^ (ra & 7)) << 4));
#pragma unroll
        for (int qh = 0; qh < 2; ++qh)
          oacc[qh][dt] = __builtin_amdgcn_mfma_f32_16x16x32_bf16(pa[qh], vbf, oacc[qh][dt], 0, 0, 0);
      }
#pragma unroll
      for (int qh = 0; qh < 2; ++qh)
        lacc[qh] = __builtin_amdgcn_mfma_f32_16x16x32_bf16(pa[qh], ones8, lacc[qh], 0, 0, 0);
      __builtin_amdgcn_s_setprio(0);
    }
  };

  STAGE(0, 0);
  STAGE(1, 1);
  WAITV4;
  BAR();
  for (int tile = 0; tile < 17; ++tile) {
    int p = tile & 1;
    PROCESS(tile, p);
    if (tile + 1 < 17) {
      BAR();
      if (tile + 2 < 17) { STAGE(tile + 2, p); WAITV4; }
      else               { WAITV0; }
      BAR();
    }
  }

  // normalize in-register: l[q=grp*4+rr] lives in lacc[qh][rr] at lane grp*16
#pragma unroll
  for (int qh = 0; qh < 2; ++qh)
#pragma unroll
    for (int rr = 0; rr < 4; ++rr) {
      float lv = __shfl(lacc[qh][rr], grp << 4);
      float inv_l = 1.0f / lv;
      int qq = qh * 16 + (grp << 2) + rr;
#pragma unroll
      for (int dt = 0; dt < 4; ++dt) {
        int dh = dt * 16 + l15;
        o0[((size_t)bg * 1024 + qbase + qq) * 1024 + h * 64 + dh] =
            f2bf(oacc[qh][dt][rr] * inv_l);
      }
    }
}

// ---------------- 7) finalize: sum K-split wo partials, scatter-average ---------
__global__ __launch_bounds__(256) void finalize_kernel(
    const short* __restrict__ wo0, const short* __restrict__ wo1,
    const int* __restrict__ inv, const float* __restrict__ null_token,
    float* __restrict__ outp)
{
  int id = blockIdx.x;                  // b*N + n
  int b = id >> 12, n = id & (N_ - 1);
  int s0 = inv[((size_t)(b * G_ + 0) << 12) + n];
  int s1 = inv[((size_t)(b * G_ + 1) << 12) + n];
  int t = threadIdx.x;
  float* dst = outp + (size_t)id * D_ + t * 4;
  if (s0 < 0 && s1 < 0) {
    *(f32x4*)dst = *(const f32x4*)(null_token + t * 4);
  } else {
    f32x4 sum = {0.f, 0.f, 0.f, 0.f};
    float cnt = 0.f;
    if (s0 >= 0) {
      size_t loc = (((size_t)(b * G_ + 0) * 1024 + s0) << 10) + t * 4;
      short4v v = *(const short4v*)(wo0 + loc);
      short4v v2 = *(const short4v*)(wo1 + loc);
#pragma unroll
      for (int e = 0; e < 4; ++e) sum[e] += bf2f(v[e]) + bf2f(v2[e]);
      cnt += 1.f;
    }
    if (s1 >= 0) {
      size_t loc = (((size_t)(b * G_ + 1) * 1024 + s1) << 10) + t * 4;
      short4v v = *(const short4v*)(wo0 + loc);
      short4v v2 = *(const short4v*)(wo1 + loc);
#pragma unroll
      for (int e = 0; e < 4; ++e) sum[e] += bf2f(v[e]) + bf2f(v2[e]);
      cnt += 1.f;
    }
    f32x4 rv;
#pragma unroll
    for (int e = 0; e < 4; ++e) rv[e] = sum[e] / cnt;
    *(f32x4*)dst = rv;
  }
}

// ---------------- launch ----------------
extern "C" void kernel_launch(void* const* d_in, const int* in_sizes, int n_in,
                              void* d_out, int out_size, void* d_ws, size_t ws_size,
                              hipStream_t stream) {
  (void)in_sizes; (void)n_in; (void)out_size; (void)ws_size;
  const float* x        = (const float*)d_in[0];
  const float* rt_q     = (const float*)d_in[1];
  const float* rt_kv    = (const float*)d_in[2];
  const float* gamma_q  = (const float*)d_in[3];
  const float* gamma_c  = (const float*)d_in[4];
  const float* wq       = (const float*)d_in[5];
  const float* wkv      = (const float*)d_in[6];
  const float* wo       = (const float*)d_in[7];
  const float* null_kv  = (const float*)d_in[8];
  const float* null_tok = (const float*)d_in[9];
  float* outp = (float*)d_out;

  char* ws = (char*)d_ws;
  size_t off = 0;
  auto alloc = [&](size_t bytes) { char* p = ws + off; off += (bytes + 255) & ~(size_t)255; return p; };
  float* sim   = (float*)alloc((size_t)2 * B_ * G_ * N_ * 4);
  int*   idx   = (int*)  alloc((size_t)2 * B_ * G_ * 1024 * 4);
  int*   inv   = (int*)  alloc((size_t)B_ * G_ * N_ * 4);
  short* qn    = (short*)alloc((size_t)B_ * G_ * 1024 * 1024 * 2);
  short* cn    = (short*)alloc((size_t)B_ * G_ * 1024 * 1024 * 2);
  short* qproj = (short*)alloc((size_t)B_ * G_ * 1024 * 1024 * 2);
  size_t kvbytes = (size_t)B_ * G_ * H_ * NSLOT * DH_ * 2;       // 256-aligned
  short* kbuf  = (short*)alloc(kvbytes);
  short* vbuf  = (short*)alloc(kvbytes);
  short* obuf  = (short*)alloc((size_t)B_ * G_ * 1024 * 1024 * 2);
  short* wobuf = (short*)alloc((size_t)B_ * G_ * 1024 * 1024 * 2);
  short* wo_bf = (short*)alloc((size_t)G_ * 1024 * 1024 * 2);
  // aliases into dead regions (lifetimes verified):
  short* wq_bf  = wobuf;  // dead until gemm_wo writes wobuf (after gemm_qkv)
  short* wkv_bf = obuf;   // consumed by gemm_qkv before attn writes obuf
  short* wobuf2 = qproj;  // wo K-split half 1; qproj dead after attn

  // NOTE: no kbuf/vbuf memset needed — pad K rows (slots 1025..1087) only enter
  // tile 16 where S is masked to -inf before exp2; pad V columns multiply P=0;
  // all residual bit patterns are finite bf16.
  hipMemsetAsync(inv, 0xFF, (size_t)B_ * G_ * N_ * 4, stream);

  prep_kernel<<<2048, 256, 0, stream>>>(x, rt_q, rt_kv, sim);
  topk_wconv<<<524, 1024, 0, stream>>>(sim, idx, inv, wq, wkv, wo,
                                       wq_bf, wkv_bf, wo_bf,
                                       null_kv, kbuf, vbuf);
  gather_rms<<<2 * B_ * G_ * 1024, 256, 0, stream>>>(x, idx, gamma_q, gamma_c, qn, cn);
  gemm_qkv<<<dim3(8, 24, B_ * G_), 256, 0, stream>>>(qn, cn, wq_bf, wkv_bf, qproj, kbuf, vbuf);
  attn_kernel<<<dim3(64, 8), 256, 0, stream>>>(qproj, kbuf, vbuf, obuf);
  gemm_wo<<<dim3(8, 8, 2 * B_ * G_), 256, 0, stream>>>(obuf, wo_bf, wobuf, wobuf2);
  finalize_kernel<<<B_ * N_, 256, 0, stream>>>(wobuf, wobuf2, inv, null_tok, outp);
}